// Round 1
// baseline (12535.661 us; speedup 1.0000x reference)
//
#include <hip/hip_runtime.h>
#include <math.h>

#define S_LEN 1024
#define NB 8
#define CDIM 512
#define KCB 4096
#define DH 64
#define NLAYER 6
#define NTOK (S_LEN*NB)
#define TOKC ((long)NTOK*CDIM)

// ---------------------------------------------------------------------------
// Generic fp32 SGEMM: C[M,N] = A[M,K] @ op(B) (+bias) (+residual) (relu)
// BL=0: B is W[N,K] row-major (C = A @ W^T)   BL=1: B is [K,N] row-major
// OREMAP: output row r=(s*NB+b) written to row (b*S_LEN+s)   (sim -> logits)
// AREMAP: A row for token r read from physical row (b*S_LEN+s) (logits as A)
// SOFTA : A elements transformed expf(a - m_row) * inv_l_row  (softmax(sim))
// Tile 128x128x8, 256 threads, 8x8 micro-tile.
// ---------------------------------------------------------------------------
template<int BL, bool BIAS, bool RES, bool RELU, bool OREMAP, bool AREMAP, bool SOFTA>
__global__ __launch_bounds__(256)
void sgemm_k(const float* __restrict__ A, const float* __restrict__ B,
             const float* __restrict__ bias, const float* __restrict__ Rsrc, int ldr,
             float* __restrict__ C, int ldc, int M, int N, int K,
             const float* __restrict__ stats)
{
  __shared__ float As[8][128];
  __shared__ float Bs[8][132];
  const int t  = threadIdx.x;
  const int m0 = blockIdx.y * 128;
  const int n0 = blockIdx.x * 128;
  const int tx = t & 15, ty = t >> 4;

  float acc[8][8];
#pragma unroll
  for (int i = 0; i < 8; ++i)
#pragma unroll
    for (int j = 0; j < 8; ++j) acc[i][j] = 0.f;

  const int arow = t >> 1, acol = (t & 1) * 4;
  const int atok = m0 + arow;
  long aphys = atok;
  if (AREMAP) aphys = (long)(atok & (NB-1)) * S_LEN + (atok >> 3);
  const float* aptr = A + aphys * (long)K + acol;
  float sm_m = 0.f, sm_inv = 0.f;
  if (SOFTA) { sm_m = stats[2*aphys]; sm_inv = stats[2*aphys+1]; }

  const float* bptr;
  int brow_s, bcol_s;
  if (BL == 0) { brow_s = t >> 1; bcol_s = (t & 1) * 4; bptr = B + (long)(n0 + brow_s) * K + bcol_s; }
  else         { brow_s = t >> 5; bcol_s = (t & 31) * 4; bptr = B + (long)brow_s * N + n0 + bcol_s; }

  for (int k0 = 0; k0 < K; k0 += 8) {
    float4 av = *(const float4*)(aptr + k0);
    float4 bv;
    if (BL == 0) bv = *(const float4*)(bptr + k0);
    else         bv = *(const float4*)(bptr + (long)k0 * N);
    if (SOFTA) {
      av.x = expf(av.x - sm_m) * sm_inv;
      av.y = expf(av.y - sm_m) * sm_inv;
      av.z = expf(av.z - sm_m) * sm_inv;
      av.w = expf(av.w - sm_m) * sm_inv;
    }
    __syncthreads();
    As[acol+0][arow] = av.x; As[acol+1][arow] = av.y;
    As[acol+2][arow] = av.z; As[acol+3][arow] = av.w;
    if (BL == 0) {
      Bs[bcol_s+0][brow_s] = bv.x; Bs[bcol_s+1][brow_s] = bv.y;
      Bs[bcol_s+2][brow_s] = bv.z; Bs[bcol_s+3][brow_s] = bv.w;
    } else {
      *(float4*)&Bs[brow_s][bcol_s] = bv;
    }
    __syncthreads();
#pragma unroll
    for (int kk = 0; kk < 8; ++kk) {
      float4 a0 = *(const float4*)&As[kk][ty*4];
      float4 a1 = *(const float4*)&As[kk][64 + ty*4];
      float4 b0 = *(const float4*)&Bs[kk][tx*4];
      float4 b1 = *(const float4*)&Bs[kk][64 + tx*4];
      float ar[8] = {a0.x,a0.y,a0.z,a0.w, a1.x,a1.y,a1.z,a1.w};
      float br[8] = {b0.x,b0.y,b0.z,b0.w, b1.x,b1.y,b1.z,b1.w};
#pragma unroll
      for (int i = 0; i < 8; ++i)
#pragma unroll
        for (int j = 0; j < 8; ++j) acc[i][j] = fmaf(ar[i], br[j], acc[i][j]);
    }
  }

#pragma unroll
  for (int ih = 0; ih < 2; ++ih)
#pragma unroll
  for (int i = 0; i < 4; ++i) {
    const int row = ih*64 + ty*4 + i;
    const int rm = m0 + row;
    long orow = rm;
    if (OREMAP) orow = (long)(rm & (NB-1)) * S_LEN + (rm >> 3);
#pragma unroll
    for (int jh = 0; jh < 2; ++jh) {
      const int cn = n0 + jh*64 + tx*4;
      float4 v;
      v.x = acc[ih*4+i][jh*4+0];
      v.y = acc[ih*4+i][jh*4+1];
      v.z = acc[ih*4+i][jh*4+2];
      v.w = acc[ih*4+i][jh*4+3];
      if (BIAS) {
        float4 bb = *(const float4*)(bias + cn);
        v.x += bb.x; v.y += bb.y; v.z += bb.z; v.w += bb.w;
      }
      if (RES) {
        float4 rr = *(const float4*)(Rsrc + (long)rm*ldr + cn);
        v.x += rr.x; v.y += rr.y; v.z += rr.z; v.w += rr.w;
      }
      if (RELU) {
        v.x = fmaxf(v.x, 0.f); v.y = fmaxf(v.y, 0.f);
        v.z = fmaxf(v.z, 0.f); v.w = fmaxf(v.w, 0.f);
      }
      *(float4*)(C + orow*(long)ldc + cn) = v;
    }
  }
}

// ---------------------------------------------------------------------------
// Fused flash-style fp32 attention. One block: 64 query rows for one (b,head).
// Q/K staged transposed ([d][row]) for float4 dot products; V staged [t][d];
// P staged transposed ([key][row]) so PV reads are float4. Online softmax with
// 16-lane shuffle reductions (rows are owned by 16-thread groups).
// ---------------------------------------------------------------------------
__global__ __launch_bounds__(256)
void attn_k(const float* __restrict__ Qp, int ldq,
            const float* __restrict__ Kp, int ldk,
            const float* __restrict__ Vp, int ldv,
            float* __restrict__ Op, int ldo)
{
  __shared__ float qsT[64][68];
  __shared__ float kps[64][68];
  __shared__ float vs [64][68];
  const int t  = threadIdx.x;
  const int b  = blockIdx.y >> 3, hd = blockIdx.y & 7;
  const int s0 = blockIdx.x * 64;
  const int qoff = hd * DH;
  const int tx = t & 15, ty = t >> 4;
  const int lr = t >> 2;
  const int ld0 = (t & 3) * 4;

  {
    const float* qrow = Qp + ((long)(s0 + lr) * NB + b) * ldq + qoff;
#pragma unroll
    for (int rep = 0; rep < 4; ++rep) {
      const int d = ld0 + rep*16;
      float4 v = *(const float4*)(qrow + d);
      qsT[d+0][lr]=v.x; qsT[d+1][lr]=v.y; qsT[d+2][lr]=v.z; qsT[d+3][lr]=v.w;
    }
  }
  float m_run[4], l_run[4], accv[4][4];
#pragma unroll
  for (int i = 0; i < 4; ++i) {
    m_run[i] = -INFINITY; l_run[i] = 0.f;
#pragma unroll
    for (int j = 0; j < 4; ++j) accv[i][j] = 0.f;
  }
  __syncthreads();

  for (int t0 = 0; t0 < S_LEN; t0 += 64) {
    {
      const float* krow = Kp + ((long)(t0 + lr) * NB + b) * ldk + qoff;
      const float* vrow = Vp + ((long)(t0 + lr) * NB + b) * ldv + qoff;
#pragma unroll
      for (int rep = 0; rep < 4; ++rep) {
        const int d = ld0 + rep*16;
        float4 kv4 = *(const float4*)(krow + d);
        kps[d+0][lr]=kv4.x; kps[d+1][lr]=kv4.y; kps[d+2][lr]=kv4.z; kps[d+3][lr]=kv4.w;
        float4 vv4 = *(const float4*)(vrow + d);
        *(float4*)&vs[lr][d] = vv4;
      }
    }
    __syncthreads();
    float sc[4][4];
#pragma unroll
    for (int i = 0; i < 4; ++i)
#pragma unroll
      for (int j = 0; j < 4; ++j) sc[i][j] = 0.f;
#pragma unroll 8
    for (int d = 0; d < 64; ++d) {
      float4 qa = *(const float4*)&qsT[d][ty*4];
      float4 kb = *(const float4*)&kps[d][tx*4];
      float aa[4] = {qa.x,qa.y,qa.z,qa.w};
      float bb[4] = {kb.x,kb.y,kb.z,kb.w};
#pragma unroll
      for (int i = 0; i < 4; ++i)
#pragma unroll
        for (int j = 0; j < 4; ++j) sc[i][j] = fmaf(aa[i], bb[j], sc[i][j]);
    }
    float pm[4];
#pragma unroll
    for (int i = 0; i < 4; ++i) {
#pragma unroll
      for (int j = 0; j < 4; ++j) sc[i][j] *= 0.125f;
      pm[i] = fmaxf(fmaxf(sc[i][0], sc[i][1]), fmaxf(sc[i][2], sc[i][3]));
    }
#pragma unroll
    for (int off = 1; off < 16; off <<= 1)
#pragma unroll
      for (int i = 0; i < 4; ++i) pm[i] = fmaxf(pm[i], __shfl_xor(pm[i], off));
    float rs[4];
#pragma unroll
    for (int i = 0; i < 4; ++i) {
      const float mnew = fmaxf(m_run[i], pm[i]);
      const float corr = expf(m_run[i] - mnew);
      m_run[i] = mnew;
      l_run[i] *= corr;
      float lsum = 0.f;
#pragma unroll
      for (int j = 0; j < 4; ++j) { sc[i][j] = expf(sc[i][j] - mnew); lsum += sc[i][j]; }
      rs[i] = lsum;
#pragma unroll
      for (int j = 0; j < 4; ++j) accv[i][j] *= corr;
    }
#pragma unroll
    for (int off = 1; off < 16; off <<= 1)
#pragma unroll
      for (int i = 0; i < 4; ++i) rs[i] += __shfl_xor(rs[i], off);
#pragma unroll
    for (int i = 0; i < 4; ++i) l_run[i] += rs[i];
    __syncthreads();                     // everyone done reading kps as K^T
#pragma unroll
    for (int i = 0; i < 4; ++i)
#pragma unroll
      for (int j = 0; j < 4; ++j) kps[tx*4+j][ty*4+i] = sc[i][j];
    __syncthreads();                     // P visible
#pragma unroll 8
    for (int tt = 0; tt < 64; ++tt) {
      float4 pr = *(const float4*)&kps[tt][ty*4];
      float4 vv = *(const float4*)&vs[tt][tx*4];
      float pa[4] = {pr.x,pr.y,pr.z,pr.w};
      float vb[4] = {vv.x,vv.y,vv.z,vv.w};
#pragma unroll
      for (int i = 0; i < 4; ++i)
#pragma unroll
        for (int j = 0; j < 4; ++j) accv[i][j] = fmaf(pa[i], vb[j], accv[i][j]);
    }
    __syncthreads();                     // done with kps/vs before next tile
  }
#pragma unroll
  for (int i = 0; i < 4; ++i) {
    const float inv = 1.0f / l_run[i];
    float* op = Op + ((long)(s0 + ty*4 + i) * NB + b) * ldo + qoff + tx*4;
    float4 v;
    v.x = accv[i][0]*inv; v.y = accv[i][1]*inv; v.z = accv[i][2]*inv; v.w = accv[i][3]*inv;
    *(float4*)op = v;
  }
}

// ---------------------------------------------------------------------------
// LayerNorm over c=512, one wave per row (4 rows per 256-thread block).
// Two-pass (mean then centered var) to match mean((x-m)^2) numerics.
// ---------------------------------------------------------------------------
__global__ __launch_bounds__(256)
void ln_k(const float* __restrict__ X, const float* __restrict__ g,
          const float* __restrict__ bb, float* __restrict__ Y)
{
  const int t = threadIdx.x;
  const int lane = t & 63;
  const long row = (long)blockIdx.x * 4 + (t >> 6);
  const float* xr = X + row * CDIM;
  float4 v0 = *(const float4*)(xr + lane*4);
  float4 v1 = *(const float4*)(xr + 256 + lane*4);
  float s = v0.x+v0.y+v0.z+v0.w + v1.x+v1.y+v1.z+v1.w;
#pragma unroll
  for (int off = 1; off < 64; off <<= 1) s += __shfl_xor(s, off);
  const float mean = s * (1.0f/512.0f);
  float d[8] = {v0.x-mean, v0.y-mean, v0.z-mean, v0.w-mean,
                v1.x-mean, v1.y-mean, v1.z-mean, v1.w-mean};
  float sq = d[0]*d[0]+d[1]*d[1]+d[2]*d[2]+d[3]*d[3]
           + d[4]*d[4]+d[5]*d[5]+d[6]*d[6]+d[7]*d[7];
#pragma unroll
  for (int off = 1; off < 64; off <<= 1) sq += __shfl_xor(sq, off);
  const float inv = 1.0f / sqrtf(sq * (1.0f/512.0f) + 1e-5f);
  float4 g0 = *(const float4*)(g + lane*4);
  float4 g1 = *(const float4*)(g + 256 + lane*4);
  float4 b0 = *(const float4*)(bb + lane*4);
  float4 b1 = *(const float4*)(bb + 256 + lane*4);
  float4 o0, o1;
  o0.x = d[0]*inv*g0.x + b0.x; o0.y = d[1]*inv*g0.y + b0.y;
  o0.z = d[2]*inv*g0.z + b0.z; o0.w = d[3]*inv*g0.w + b0.w;
  o1.x = d[4]*inv*g1.x + b1.x; o1.y = d[5]*inv*g1.y + b1.y;
  o1.z = d[6]*inv*g1.z + b1.z; o1.w = d[7]*inv*g1.w + b1.w;
  *(float4*)(Y + row*CDIM + lane*4) = o0;
  *(float4*)(Y + row*CDIM + 256 + lane*4) = o1;
}

// ---------------------------------------------------------------------------
// Pack x (N,C,H,W) -> enc_flat (S,n,c) and posisted = enc_flat + PE2D.
// ---------------------------------------------------------------------------
__global__ void pack_pe_k(const float* __restrict__ x, float* __restrict__ encf,
                          float* __restrict__ posd)
{
  __shared__ float tl[32][33];
  const int b = blockIdx.z;
  const int s0 = blockIdx.x*32, c0 = blockIdx.y*32;
#pragma unroll
  for (int i = 0; i < 4; ++i) {
    int ci = threadIdx.y + i*8;
    tl[ci][threadIdx.x] = x[((long)b*CDIM + c0+ci)*S_LEN + s0 + threadIdx.x];
  }
  __syncthreads();
#pragma unroll
  for (int i = 0; i < 4; ++i) {
    int si = threadIdx.y + i*8;
    int s = s0 + si;
    int ch = c0 + threadIdx.x;
    float val = tl[threadIdx.x][si];
    long o = ((long)s*NB + b)*CDIM + ch;
    encf[o] = val;
    int pos = (ch < 256) ? (s & 31) : (s >> 5);   // w for first half, h for second
    int j = (ch & 255) >> 1;
    float dv = expf((float)(2*j) * (-9.210340371976184f / 256.0f));
    float ang = (float)pos * dv;
    float pe = (ch & 1) ? cosf(ang) : sinf(ang);
    posd[o] = val + pe;
  }
}

// (S,n,c) token-major -> (n,c,S) output layout
__global__ void tpose_k(const float* __restrict__ in, float* __restrict__ out)
{
  __shared__ float tl[32][33];
  const int b = blockIdx.z;
  const int s0 = blockIdx.x*32, c0 = blockIdx.y*32;
#pragma unroll
  for (int i = 0; i < 4; ++i) {
    int si = threadIdx.y + i*8;
    tl[si][threadIdx.x] = in[((long)(s0+si)*NB + b)*CDIM + c0 + threadIdx.x];
  }
  __syncthreads();
#pragma unroll
  for (int i = 0; i < 4; ++i) {
    int ci = threadIdx.y + i*8;
    out[((long)b*CDIM + c0+ci)*S_LEN + s0 + threadIdx.x] = tl[threadIdx.x][ci];
  }
}

// cb_w (c,K) -> cbT (K,c) for contiguous "hard" gathers
__global__ void cbt_k(const float* __restrict__ cb, float* __restrict__ cbT)
{
  __shared__ float tl[32][33];
  const int k0 = blockIdx.x*32, c0 = blockIdx.y*32;
#pragma unroll
  for (int i = 0; i < 4; ++i) {
    int ci = threadIdx.y + i*8;
    tl[ci][threadIdx.x] = cb[(long)(c0+ci)*KCB + k0 + threadIdx.x];
  }
  __syncthreads();
#pragma unroll
  for (int i = 0; i < 4; ++i) {
    int ki = threadIdx.y + i*8;
    cbT[(long)(k0+ki)*CDIM + c0 + threadIdx.x] = tl[threadIdx.x][ki];
  }
}

// Per-token row of logits (already in (b,s,k) layout): max, argmax (np
// first-occurrence tie rule), 1/sum(exp). Writes codes to d_out as float.
__global__ __launch_bounds__(256)
void simstats_k(const float* __restrict__ logits, float* __restrict__ stats,
                int* __restrict__ codes_tok, float* __restrict__ codes_out)
{
  const long phys = blockIdx.x;
  const float* rowp = logits + phys * KCB;
  const int t = threadIdx.x;
  float vals[16];
#pragma unroll
  for (int rep = 0; rep < 4; ++rep) {
    float4 v = *(const float4*)(rowp + rep*1024 + t*4);
    vals[rep*4+0]=v.x; vals[rep*4+1]=v.y; vals[rep*4+2]=v.z; vals[rep*4+3]=v.w;
  }
  float mv = -INFINITY; int mi = 0;
#pragma unroll
  for (int rep = 0; rep < 4; ++rep)
#pragma unroll
    for (int j = 0; j < 4; ++j) {
      float xv = vals[rep*4+j];
      int ix = rep*1024 + t*4 + j;
      if (xv > mv) { mv = xv; mi = ix; }
    }
  const int lane = t & 63, wid = t >> 6;
#pragma unroll
  for (int off = 1; off < 64; off <<= 1) {
    float ov = __shfl_xor(mv, off);
    int   oi = __shfl_xor(mi, off);
    if (ov > mv || (ov == mv && oi < mi)) { mv = ov; mi = oi; }
  }
  __shared__ float smax[4]; __shared__ int sidx[4]; __shared__ float ssum[4];
  __shared__ float fm; __shared__ int fi;
  if (lane == 0) { smax[wid] = mv; sidx[wid] = mi; }
  __syncthreads();
  if (t == 0) {
    float bm = smax[0]; int bi = sidx[0];
    for (int wq = 1; wq < 4; ++wq)
      if (smax[wq] > bm || (smax[wq] == bm && sidx[wq] < bi)) { bm = smax[wq]; bi = sidx[wq]; }
    fm = bm; fi = bi;
  }
  __syncthreads();
  const float Mx = fm;
  float se = 0.f;
#pragma unroll
  for (int q = 0; q < 16; ++q) se += expf(vals[q] - Mx);
#pragma unroll
  for (int off = 1; off < 64; off <<= 1) se += __shfl_xor(se, off);
  if (lane == 0) ssum[wid] = se;
  __syncthreads();
  if (t == 0) {
    float tot = ssum[0]+ssum[1]+ssum[2]+ssum[3];
    stats[2*phys]   = Mx;
    stats[2*phys+1] = 1.0f / tot;
    int b = (int)(phys >> 10), s = (int)(phys & 1023);
    codes_tok[s*NB + b] = fi;
    codes_out[phys] = (float)fi;
  }
}

// quant = (hard - soft) + soft  (straight-through forward), also emit hard
__global__ __launch_bounds__(128)
void quant_k(const float* __restrict__ soft, const int* __restrict__ codes_tok,
             const float* __restrict__ cbT, float* __restrict__ quant,
             float* __restrict__ hardb)
{
  const int r = blockIdx.x;
  const int code = codes_tok[r];
  const int c = threadIdx.x * 4;
  float4 h  = *(const float4*)(cbT + (long)code*CDIM + c);
  float4 sf = *(const float4*)(soft + (long)r*CDIM + c);
  float4 q;
  q.x = (h.x - sf.x) + sf.x; q.y = (h.y - sf.y) + sf.y;
  q.z = (h.z - sf.z) + sf.z; q.w = (h.w - sf.w) + sf.w;
  *(float4*)(quant + (long)r*CDIM + c) = q;
  *(float4*)(hardb + (long)r*CDIM + c) = h;
}

// Detect the storage format of the bool mask buffer (uint8/int32/int64/fp32).
__global__ void maskdetect_k(const void* __restrict__ mask, int* __restrict__ flag)
{
  const unsigned int* wds = (const unsigned int*)mask;
  int t = threadIdx.x;
  int okI = 1, okF = 1, okL = 1;
  for (int i = t; i < 2048; i += 256) {
    unsigned int u = wds[i];
    if (u > 1u) okI = 0;
    if (u != 0u && u != 0x3F800000u) okF = 0;
    if ((i & 1) ? (u != 0u) : (u > 1u)) okL = 0;
  }
  __shared__ int sI, sF, sL;
  if (t == 0) { sI = 1; sF = 1; sL = 1; }
  __syncthreads();
  if (!okI) atomicAnd(&sI, 0);
  if (!okF) atomicAnd(&sF, 0);
  if (!okL) atomicAnd(&sL, 0);
  __syncthreads();
  if (t == 0) {
    int f;
    if (sI && sL) f = 3;       // int64 0/1
    else if (sI)  f = 1;       // int32 0/1
    else if (sF)  f = 2;       // float 0/1
    else          f = 0;       // packed uint8 bools
    *flag = f;
  }
}

// mixed = mask ? enc_flat : post
__global__ __launch_bounds__(256)
void mixed_k(const float* __restrict__ encf, const float* __restrict__ post,
             const void* __restrict__ mask, const int* __restrict__ flag,
             float* __restrict__ outx)
{
  long gid = (long)blockIdx.x * blockDim.x + threadIdx.x;
  int r = (int)(gid >> 7);
  int c = (int)(gid & 127) * 4;
  int f = *flag;
  bool mv;
  if (f == 0)      mv = ((const unsigned char*)mask)[r] != 0;
  else if (f == 1) mv = ((const int*)mask)[r] != 0;
  else if (f == 3) mv = ((const long long*)mask)[r] != 0;
  else             mv = ((const float*)mask)[r] != 0.0f;
  const float* src = mv ? encf : post;
  *(float4*)(outx + (long)r*CDIM + c) = *(const float4*)(src + (long)r*CDIM + c);
}

// ---------------------------------------------------------------------------
// Host-side wrappers and orchestration
// ---------------------------------------------------------------------------
static void gemm_b(hipStream_t st, const float* A, const float* W, const float* bias,
                   float* C, int M, int N, int K, int ldc) {
  sgemm_k<0,true,false,false,false,false,false><<<dim3(N/128, M/128), 256, 0, st>>>(
      A, W, bias, nullptr, 0, C, ldc, M, N, K, nullptr);
}
static void gemm_br(hipStream_t st, const float* A, const float* W, const float* bias,
                    const float* R, int ldr, float* C, int M, int N, int K, int ldc) {
  sgemm_k<0,true,true,false,false,false,false><<<dim3(N/128, M/128), 256, 0, st>>>(
      A, W, bias, R, ldr, C, ldc, M, N, K, nullptr);
}
static void gemm_brelu(hipStream_t st, const float* A, const float* W, const float* bias,
                       float* C, int M, int N, int K, int ldc) {
  sgemm_k<0,true,false,true,false,false,false><<<dim3(N/128, M/128), 256, 0, st>>>(
      A, W, bias, nullptr, 0, C, ldc, M, N, K, nullptr);
}

extern "C" void kernel_launch(void* const* d_in, const int* in_sizes, int n_in,
                              void* d_out, int out_size, void* d_ws, size_t ws_size,
                              hipStream_t stream)
{
  const float* x       = (const float*)d_in[0];
  const float* pre_w   = (const float*)d_in[1];
  const float* pre_b   = (const float*)d_in[2];
  const float* post_w  = (const float*)d_in[3];
  const float* post_b  = (const float*)d_in[4];
  const float* cb_w    = (const float*)d_in[5];
  const float* e_qkv_w = (const float*)d_in[6];
  const float* e_qkv_b = (const float*)d_in[7];
  const float* e_o_w   = (const float*)d_in[8];
  const float* e_o_b   = (const float*)d_in[9];
  const float* e_ln1_w = (const float*)d_in[10];
  const float* e_ln1_b = (const float*)d_in[11];
  const float* e_ln2_w = (const float*)d_in[12];
  const float* e_ln2_b = (const float*)d_in[13];
  const float* e_f1_w  = (const float*)d_in[14];
  const float* e_f1_b  = (const float*)d_in[15];
  const float* e_f2_w  = (const float*)d_in[16];
  const float* e_f2_b  = (const float*)d_in[17];
  const float* d_sqkv_w= (const float*)d_in[18];
  const float* d_sqkv_b= (const float*)d_in[19];
  const float* d_so_w  = (const float*)d_in[20];
  const float* d_so_b  = (const float*)d_in[21];
  const float* d_cqkv_w= (const float*)d_in[22];
  const float* d_cqkv_b= (const float*)d_in[23];
  const float* d_co_w  = (const float*)d_in[24];
  const float* d_co_b  = (const float*)d_in[25];
  const float* d_ln1w  = (const float*)d_in[26];
  const float* d_ln1b  = (const float*)d_in[27];
  const float* d_ln2w  = (const float*)d_in[28];
  const float* d_ln2b  = (const float*)d_in[29];
  const float* d_ln3w  = (const float*)d_in[30];
  const float* d_ln3b  = (const float*)d_in[31];
  const float* d_f1w   = (const float*)d_in[32];
  const float* d_f1b   = (const float*)d_in[33];
  const float* d_f2w   = (const float*)d_in[34];
  const float* d_f2b   = (const float*)d_in[35];
  const void*  mask    = d_in[36];

  float* out = (float*)d_out;
  float* o_quant  = out;
  float* o_high   = out + 4194304;
  float* o_softs  = out + 8388608;
  float* o_hards  = out + 12582912;
  float* o_codes  = out + 16777216;
  float* o_logits = out + 16785408;

  float* ws    = (float*)d_ws;
  float* ENC   = ws;                 // enc_flat (no PE), needed for mask mixin
  float* Xb    = ws + TOKC;          // running activation
  float* T1    = ws + 2*TOKC;
  float* T2    = ws + 3*TOKC;
  float* QKV   = ws + 4*TOKC;        // 3*TOKC (also FFN hidden / hard+quant)
  float* MEMB  = ws + 7*TOKC;        // post (decoder memory)
  float* CBT   = ws + 8*TOKC;        // KCB*CDIM
  float* STATS = CBT + (long)KCB*CDIM;         // 2*NTOK floats (max, 1/sum)
  int*   CODES = (int*)(STATS + 2*NTOK);       // NTOK ints (token order)
  int*   FLAG  = CODES + NTOK;
  float* HARDB = QKV;
  float* QUANT = QKV + TOKC;

  const size_t NEED = (size_t)(8*TOKC + (long)KCB*CDIM + 2*NTOK + NTOK + 16) * 4;
  if (ws_size < NEED) return;        // workspace too small: bail (output stays poison)

  const int M = NTOK;
  dim3 tgrid(S_LEN/32, CDIM/32, NB), tblk(32, 8);

  pack_pe_k<<<tgrid, tblk, 0, stream>>>(x, ENC, Xb);
  cbt_k<<<dim3(KCB/32, CDIM/32), tblk, 0, stream>>>(cb_w, CBT);
  maskdetect_k<<<1, 256, 0, stream>>>(mask, FLAG);

  // -------- encoder --------
  for (int i = 0; i < NLAYER; ++i) {
    gemm_b(stream, Xb, e_qkv_w + (long)i*3*CDIM*CDIM, e_qkv_b + i*3*CDIM, QKV, M, 3*CDIM, CDIM, 3*CDIM);
    attn_k<<<dim3(S_LEN/64, NB*8), 256, 0, stream>>>(QKV, 3*CDIM, QKV+CDIM, 3*CDIM, QKV+2*CDIM, 3*CDIM, T1, CDIM);
    gemm_br(stream, T1, e_o_w + (long)i*CDIM*CDIM, e_o_b + i*CDIM, Xb, CDIM, T2, M, CDIM, CDIM, CDIM);
    ln_k<<<M/4, 256, 0, stream>>>(T2, e_ln1_w + i*CDIM, e_ln1_b + i*CDIM, T1);
    gemm_brelu(stream, T1, e_f1_w + (long)i*CDIM*CDIM, e_f1_b + i*CDIM, QKV, M, CDIM, CDIM, CDIM);
    gemm_br(stream, QKV, e_f2_w + (long)i*CDIM*CDIM, e_f2_b + i*CDIM, T1, CDIM, T2, M, CDIM, CDIM, CDIM);
    ln_k<<<M/4, 256, 0, stream>>>(T2, e_ln2_w + i*CDIM, e_ln2_b + i*CDIM, Xb);
  }

  // -------- codebook / quantizer --------
  gemm_b(stream, Xb, pre_w, pre_b, T1, M, CDIM, CDIM, CDIM);                 // pre
  tpose_k<<<tgrid, tblk, 0, stream>>>(T1, o_high);
  sgemm_k<1,false,false,false,true,false,false><<<dim3(KCB/128, M/128), 256, 0, stream>>>(
      T1, cb_w, nullptr, nullptr, 0, o_logits, KCB, M, KCB, CDIM, nullptr);  // sim -> logits
  simstats_k<<<NTOK, 256, 0, stream>>>(o_logits, STATS, CODES, o_codes);
  sgemm_k<0,false,false,false,false,true,true><<<dim3(CDIM/128, M/128), 256, 0, stream>>>(
      o_logits, cb_w, nullptr, nullptr, 0, T2, CDIM, M, CDIM, KCB, STATS);   // soft
  tpose_k<<<tgrid, tblk, 0, stream>>>(T2, o_softs);
  quant_k<<<NTOK, 128, 0, stream>>>(T2, CODES, CBT, QUANT, HARDB);
  tpose_k<<<tgrid, tblk, 0, stream>>>(HARDB, o_hards);
  gemm_b(stream, QUANT, post_w, post_b, MEMB, M, CDIM, CDIM, CDIM);          // post
  mixed_k<<<4096, 256, 0, stream>>>(ENC, MEMB, mask, FLAG, Xb);

  // -------- decoder --------
  for (int i = 0; i < NLAYER; ++i) {
    gemm_b(stream, Xb, d_sqkv_w + (long)i*3*CDIM*CDIM, d_sqkv_b + i*3*CDIM, QKV, M, 3*CDIM, CDIM, 3*CDIM);
    attn_k<<<dim3(S_LEN/64, NB*8), 256, 0, stream>>>(QKV, 3*CDIM, QKV+CDIM, 3*CDIM, QKV+2*CDIM, 3*CDIM, T1, CDIM);
    gemm_br(stream, T1, d_so_w + (long)i*CDIM*CDIM, d_so_b + i*CDIM, Xb, CDIM, T2, M, CDIM, CDIM, CDIM);
    ln_k<<<M/4, 256, 0, stream>>>(T2, d_ln1w + i*CDIM, d_ln1b + i*CDIM, Xb);
    // cross-attention: q from x, k/v from memory (post)
    gemm_b(stream, Xb, d_cqkv_w + (long)i*3*CDIM*CDIM, d_cqkv_b + i*3*CDIM, QKV, M, CDIM, CDIM, CDIM);
    gemm_b(stream, MEMB, d_cqkv_w + (long)i*3*CDIM*CDIM + (long)CDIM*CDIM,
           d_cqkv_b + i*3*CDIM + CDIM, QKV + TOKC, M, 2*CDIM, CDIM, 2*CDIM);
    attn_k<<<dim3(S_LEN/64, NB*8), 256, 0, stream>>>(QKV, CDIM, QKV+TOKC, 2*CDIM, QKV+TOKC+CDIM, 2*CDIM, T1, CDIM);
    gemm_br(stream, T1, d_co_w + (long)i*CDIM*CDIM, d_co_b + i*CDIM, Xb, CDIM, T2, M, CDIM, CDIM, CDIM);
    ln_k<<<M/4, 256, 0, stream>>>(T2, d_ln2w + i*CDIM, d_ln2b + i*CDIM, Xb);
    gemm_brelu(stream, Xb, d_f1w + (long)i*CDIM*CDIM, d_f1b + i*CDIM, QKV, M, CDIM, CDIM, CDIM);
    gemm_br(stream, QKV, d_f2w + (long)i*CDIM*CDIM, d_f2b + i*CDIM, Xb, CDIM, T2, M, CDIM, CDIM, CDIM);
    ln_k<<<M/4, 256, 0, stream>>>(T2, d_ln3w + i*CDIM, d_ln3b + i*CDIM, Xb);
  }
  tpose_k<<<tgrid, tblk, 0, stream>>>(Xb, o_quant);
}

// Round 2
// 9274.442 us; speedup vs baseline: 1.3516x; 1.3516x over previous
//
#include <hip/hip_runtime.h>
#include <math.h>

#define S_LEN 1024
#define NB 8
#define CDIM 512
#define KCB 4096
#define DH 64
#define NLAYER 6
#define NTOK (S_LEN*NB)
#define TOKC ((long)NTOK*CDIM)

typedef __attribute__((ext_vector_type(8))) _Float16 f16x8;
typedef __attribute__((ext_vector_type(4))) float f32x4;

// ---------------------------------------------------------------------------
// fp32 SGEMM with register prefetch. C[M,N] = A[M,K] @ op(B) (+bias/res/relu)
// BL=0: B = W[N,K] (C = A@W^T). BL=1: B = [K,N]. TN in {64,128} (TN=64 only BL=0).
// OREMAP: output row (s*NB+b) -> (b*S_LEN+s)  (sim -> logits layout)
// ---------------------------------------------------------------------------
template<int TN, int BL, bool BIAS, bool RES, bool RELU, bool OREMAP>
__global__ __launch_bounds__(256)
void sgemm_k(const float* __restrict__ A, const float* __restrict__ B,
             const float* __restrict__ bias, const float* __restrict__ Rsrc, int ldr,
             float* __restrict__ C, int ldc, int M, int N, int K)
{
  constexpr int NJ = TN / 64;
  __shared__ float As[8][128];
  __shared__ float Bs[8][TN + 4];
  const int t  = threadIdx.x;
  const int m0 = blockIdx.y * 128;
  const int n0 = blockIdx.x * TN;
  const int tx = t & 15, ty = t >> 4;

  float acc[8][NJ*4];
#pragma unroll
  for (int i = 0; i < 8; ++i)
#pragma unroll
    for (int j = 0; j < NJ*4; ++j) acc[i][j] = 0.f;

  const int arow = t >> 1, acol = (t & 1) * 4;
  const float* aptr = A + (long)(m0 + arow) * K + acol;

  const float* bptr;
  int brow_s, bcol_s;
  if (BL == 0) {
    if (TN == 128) { brow_s = t >> 1; bcol_s = (t & 1) * 4; }
    else           { brow_s = t >> 2; bcol_s = (t & 3) * 2; }
    bptr = B + (long)(n0 + brow_s) * K + bcol_s;
  } else { brow_s = t >> 5; bcol_s = (t & 31) * 4; bptr = B + (long)brow_s * N + n0 + bcol_s; }

  float4 av = *(const float4*)(aptr);
  float4 bv4; float2 bv2;
  if (BL == 0) {
    if (TN == 128) bv4 = *(const float4*)(bptr);
    else           bv2 = *(const float2*)(bptr);
  } else bv4 = *(const float4*)(bptr);

  for (int k0 = 0; k0 < K; k0 += 8) {
    __syncthreads();
    As[acol+0][arow] = av.x; As[acol+1][arow] = av.y;
    As[acol+2][arow] = av.z; As[acol+3][arow] = av.w;
    if (BL == 0) {
      if (TN == 128) {
        Bs[bcol_s+0][brow_s] = bv4.x; Bs[bcol_s+1][brow_s] = bv4.y;
        Bs[bcol_s+2][brow_s] = bv4.z; Bs[bcol_s+3][brow_s] = bv4.w;
      } else {
        Bs[bcol_s+0][brow_s] = bv2.x; Bs[bcol_s+1][brow_s] = bv2.y;
      }
    } else {
      *(float4*)&Bs[brow_s][bcol_s] = bv4;
    }
    __syncthreads();
    if (k0 + 8 < K) {
      av = *(const float4*)(aptr + k0 + 8);
      if (BL == 0) {
        if (TN == 128) bv4 = *(const float4*)(bptr + k0 + 8);
        else           bv2 = *(const float2*)(bptr + k0 + 8);
      } else bv4 = *(const float4*)(bptr + (long)(k0+8) * N);
    }
#pragma unroll
    for (int kk = 0; kk < 8; ++kk) {
      float4 a0 = *(const float4*)&As[kk][ty*4];
      float4 a1 = *(const float4*)&As[kk][64 + ty*4];
      float ar[8] = {a0.x,a0.y,a0.z,a0.w, a1.x,a1.y,a1.z,a1.w};
      float br[NJ*4];
#pragma unroll
      for (int jh = 0; jh < NJ; ++jh) {
        float4 b0 = *(const float4*)&Bs[kk][jh*64 + tx*4];
        br[jh*4+0]=b0.x; br[jh*4+1]=b0.y; br[jh*4+2]=b0.z; br[jh*4+3]=b0.w;
      }
#pragma unroll
      for (int i = 0; i < 8; ++i)
#pragma unroll
        for (int j = 0; j < NJ*4; ++j) acc[i][j] = fmaf(ar[i], br[j], acc[i][j]);
    }
  }

#pragma unroll
  for (int ih = 0; ih < 2; ++ih)
#pragma unroll
  for (int i = 0; i < 4; ++i) {
    const int row = ih*64 + ty*4 + i;
    const int rm = m0 + row;
    long orow = rm;
    if (OREMAP) orow = (long)(rm & (NB-1)) * S_LEN + (rm >> 3);
#pragma unroll
    for (int jh = 0; jh < NJ; ++jh) {
      const int cn = n0 + jh*64 + tx*4;
      float4 v;
      v.x = acc[ih*4+i][jh*4+0];
      v.y = acc[ih*4+i][jh*4+1];
      v.z = acc[ih*4+i][jh*4+2];
      v.w = acc[ih*4+i][jh*4+3];
      if (BIAS) {
        float4 bb = *(const float4*)(bias + cn);
        v.x += bb.x; v.y += bb.y; v.z += bb.z; v.w += bb.w;
      }
      if (RES) {
        float4 rr = *(const float4*)(Rsrc + (long)rm*ldr + cn);
        v.x += rr.x; v.y += rr.y; v.z += rr.z; v.w += rr.w;
      }
      if (RELU) {
        v.x = fmaxf(v.x, 0.f); v.y = fmaxf(v.y, 0.f);
        v.z = fmaxf(v.z, 0.f); v.w = fmaxf(v.w, 0.f);
      }
      *(float4*)(C + orow*(long)ldc + cn) = v;
    }
  }
}

// ---------------------------------------------------------------------------
// fp16 MFMA GEMM: C[M,N] = A[M,K] @ W[N,K]^T (+bias/res/relu). A,W are fp32 in
// global, converted to fp16 in registers during staging. 128x128 tile, BK=64,
// 4 waves each owning 64x64 via 4x4 frags of mfma_f32_16x16x32_f16.
// LDS XOR-swizzle (byte ^= (row&7)<<4) on both write and read.
// SOFTA: A row r read from phys row (r&7)*S_LEN+(r>>3), transformed
// exp(a - stats[2p]) * stats[2p+1]  (softmax over logits rows).
// ---------------------------------------------------------------------------
template<bool BIAS, bool RES, bool RELU, bool SOFTA>
__global__ __launch_bounds__(256)
void hgemm_k(const float* __restrict__ A, const float* __restrict__ W,
             const float* __restrict__ bias, const float* __restrict__ Rsrc, int ldr,
             float* __restrict__ C, int ldc, int M, int N, int K,
             const float* __restrict__ stats)
{
  __shared__ __align__(16) _Float16 Asm[128*64];
  __shared__ __align__(16) _Float16 Bsm[128*64];
  const int t = threadIdx.x;
  const int m0 = blockIdx.y * 128, n0 = blockIdx.x * 128;

  const int srow = t >> 1, shalf = t & 1;
  const int atok = m0 + srow;
  long aphys = atok;
  if (SOFTA) aphys = (long)(atok & (NB-1)) * S_LEN + (atok >> 3);
  const float* aptr = A + aphys * (long)K + shalf*32;
  const float* bptr = W + (long)(n0 + srow) * K + shalf*32;
  float sm_m = 0.f, sm_inv = 0.f;
  if (SOFTA) { sm_m = stats[2*aphys]; sm_inv = stats[2*aphys+1]; }

  const int lane = t & 63, wave = t >> 6;
  const int wm = wave >> 1, wn = wave & 1;
  const int lr = lane & 15, lk = lane >> 4;

  f32x4 acc[4][4];
#pragma unroll
  for (int mi = 0; mi < 4; ++mi)
#pragma unroll
    for (int ni = 0; ni < 4; ++ni)
#pragma unroll
      for (int e = 0; e < 4; ++e) acc[mi][ni][e] = 0.f;

  float4 a4[8], b4[8];
#pragma unroll
  for (int j = 0; j < 8; ++j) {
    a4[j] = *(const float4*)(aptr + j*4);
    b4[j] = *(const float4*)(bptr + j*4);
  }

  for (int k0 = 0; k0 < K; k0 += 64) {
    __syncthreads();
    if (SOFTA) {
#pragma unroll
      for (int j = 0; j < 8; ++j) {
        a4[j].x = expf(a4[j].x - sm_m) * sm_inv;
        a4[j].y = expf(a4[j].y - sm_m) * sm_inv;
        a4[j].z = expf(a4[j].z - sm_m) * sm_inv;
        a4[j].w = expf(a4[j].w - sm_m) * sm_inv;
      }
    }
#pragma unroll
    for (int c2 = 0; c2 < 4; ++c2) {
      f16x8 ha, hb;
      ha[0] = (_Float16)a4[2*c2].x;   ha[1] = (_Float16)a4[2*c2].y;
      ha[2] = (_Float16)a4[2*c2].z;   ha[3] = (_Float16)a4[2*c2].w;
      ha[4] = (_Float16)a4[2*c2+1].x; ha[5] = (_Float16)a4[2*c2+1].y;
      ha[6] = (_Float16)a4[2*c2+1].z; ha[7] = (_Float16)a4[2*c2+1].w;
      hb[0] = (_Float16)b4[2*c2].x;   hb[1] = (_Float16)b4[2*c2].y;
      hb[2] = (_Float16)b4[2*c2].z;   hb[3] = (_Float16)b4[2*c2].w;
      hb[4] = (_Float16)b4[2*c2+1].x; hb[5] = (_Float16)b4[2*c2+1].y;
      hb[6] = (_Float16)b4[2*c2+1].z; hb[7] = (_Float16)b4[2*c2+1].w;
      const int byteoff = shalf*64 + c2*16;
      const int sw = byteoff ^ ((srow & 7) << 4);
      *(f16x8*)((char*)Asm + srow*128 + sw) = ha;
      *(f16x8*)((char*)Bsm + srow*128 + sw) = hb;
    }
    __syncthreads();
    if (k0 + 64 < K) {
#pragma unroll
      for (int j = 0; j < 8; ++j) {
        a4[j] = *(const float4*)(aptr + k0 + 64 + j*4);
        b4[j] = *(const float4*)(bptr + k0 + 64 + j*4);
      }
    }
#pragma unroll
    for (int kk = 0; kk < 2; ++kk) {
      f16x8 af[4], bf[4];
#pragma unroll
      for (int mi = 0; mi < 4; ++mi) {
        const int r = wm*64 + mi*16 + lr;
        const int bo = (lk*16 + kk*64) ^ ((r & 7) << 4);
        af[mi] = *(const f16x8*)((const char*)Asm + r*128 + bo);
      }
#pragma unroll
      for (int ni = 0; ni < 4; ++ni) {
        const int r = wn*64 + ni*16 + lr;
        const int bo = (lk*16 + kk*64) ^ ((r & 7) << 4);
        bf[ni] = *(const f16x8*)((const char*)Bsm + r*128 + bo);
      }
#pragma unroll
      for (int mi = 0; mi < 4; ++mi)
#pragma unroll
        for (int ni = 0; ni < 4; ++ni)
          acc[mi][ni] = __builtin_amdgcn_mfma_f32_16x16x32_f16(af[mi], bf[ni], acc[mi][ni], 0, 0, 0);
    }
  }

  float bvv[4];
  if (BIAS) {
#pragma unroll
    for (int ni = 0; ni < 4; ++ni) bvv[ni] = bias[n0 + wn*64 + ni*16 + lr];
  }
#pragma unroll
  for (int mi = 0; mi < 4; ++mi)
#pragma unroll
  for (int i = 0; i < 4; ++i) {
    const int row = m0 + wm*64 + mi*16 + lk*4 + i;
#pragma unroll
    for (int ni = 0; ni < 4; ++ni) {
      const int col = n0 + wn*64 + ni*16 + lr;
      float v = acc[mi][ni][i];
      if (BIAS) v += bvv[ni];
      if (RES)  v += Rsrc[(long)row*ldr + col];
      if (RELU) v = fmaxf(v, 0.f);
      C[(long)row*ldc + col] = v;
    }
  }
}

// ---------------------------------------------------------------------------
// Fused flash-style fp32 attention (unchanged from round 0).
// ---------------------------------------------------------------------------
__global__ __launch_bounds__(256)
void attn_k(const float* __restrict__ Qp, int ldq,
            const float* __restrict__ Kp, int ldk,
            const float* __restrict__ Vp, int ldv,
            float* __restrict__ Op, int ldo)
{
  __shared__ float qsT[64][68];
  __shared__ float kps[64][68];
  __shared__ float vs [64][68];
  const int t  = threadIdx.x;
  const int b  = blockIdx.y >> 3, hd = blockIdx.y & 7;
  const int s0 = blockIdx.x * 64;
  const int qoff = hd * DH;
  const int tx = t & 15, ty = t >> 4;
  const int lr = t >> 2;
  const int ld0 = (t & 3) * 4;

  {
    const float* qrow = Qp + ((long)(s0 + lr) * NB + b) * ldq + qoff;
#pragma unroll
    for (int rep = 0; rep < 4; ++rep) {
      const int d = ld0 + rep*16;
      float4 v = *(const float4*)(qrow + d);
      qsT[d+0][lr]=v.x; qsT[d+1][lr]=v.y; qsT[d+2][lr]=v.z; qsT[d+3][lr]=v.w;
    }
  }
  float m_run[4], l_run[4], accv[4][4];
#pragma unroll
  for (int i = 0; i < 4; ++i) {
    m_run[i] = -INFINITY; l_run[i] = 0.f;
#pragma unroll
    for (int j = 0; j < 4; ++j) accv[i][j] = 0.f;
  }
  __syncthreads();

  for (int t0 = 0; t0 < S_LEN; t0 += 64) {
    {
      const float* krow = Kp + ((long)(t0 + lr) * NB + b) * ldk + qoff;
      const float* vrow = Vp + ((long)(t0 + lr) * NB + b) * ldv + qoff;
#pragma unroll
      for (int rep = 0; rep < 4; ++rep) {
        const int d = ld0 + rep*16;
        float4 kv4 = *(const float4*)(krow + d);
        kps[d+0][lr]=kv4.x; kps[d+1][lr]=kv4.y; kps[d+2][lr]=kv4.z; kps[d+3][lr]=kv4.w;
        float4 vv4 = *(const float4*)(vrow + d);
        *(float4*)&vs[lr][d] = vv4;
      }
    }
    __syncthreads();
    float sc[4][4];
#pragma unroll
    for (int i = 0; i < 4; ++i)
#pragma unroll
      for (int j = 0; j < 4; ++j) sc[i][j] = 0.f;
#pragma unroll 8
    for (int d = 0; d < 64; ++d) {
      float4 qa = *(const float4*)&qsT[d][ty*4];
      float4 kb = *(const float4*)&kps[d][tx*4];
      float aa[4] = {qa.x,qa.y,qa.z,qa.w};
      float bb[4] = {kb.x,kb.y,kb.z,kb.w};
#pragma unroll
      for (int i = 0; i < 4; ++i)
#pragma unroll
        for (int j = 0; j < 4; ++j) sc[i][j] = fmaf(aa[i], bb[j], sc[i][j]);
    }
    float pm[4];
#pragma unroll
    for (int i = 0; i < 4; ++i) {
#pragma unroll
      for (int j = 0; j < 4; ++j) sc[i][j] *= 0.125f;
      pm[i] = fmaxf(fmaxf(sc[i][0], sc[i][1]), fmaxf(sc[i][2], sc[i][3]));
    }
#pragma unroll
    for (int off = 1; off < 16; off <<= 1)
#pragma unroll
      for (int i = 0; i < 4; ++i) pm[i] = fmaxf(pm[i], __shfl_xor(pm[i], off));
    float rs[4];
#pragma unroll
    for (int i = 0; i < 4; ++i) {
      const float mnew = fmaxf(m_run[i], pm[i]);
      const float corr = expf(m_run[i] - mnew);
      m_run[i] = mnew;
      l_run[i] *= corr;
      float lsum = 0.f;
#pragma unroll
      for (int j = 0; j < 4; ++j) { sc[i][j] = expf(sc[i][j] - mnew); lsum += sc[i][j]; }
      rs[i] = lsum;
#pragma unroll
      for (int j = 0; j < 4; ++j) accv[i][j] *= corr;
    }
#pragma unroll
    for (int off = 1; off < 16; off <<= 1)
#pragma unroll
      for (int i = 0; i < 4; ++i) rs[i] += __shfl_xor(rs[i], off);
#pragma unroll
    for (int i = 0; i < 4; ++i) l_run[i] += rs[i];
    __syncthreads();
#pragma unroll
    for (int i = 0; i < 4; ++i)
#pragma unroll
      for (int j = 0; j < 4; ++j) kps[tx*4+j][ty*4+i] = sc[i][j];
    __syncthreads();
#pragma unroll 8
    for (int tt = 0; tt < 64; ++tt) {
      float4 pr = *(const float4*)&kps[tt][ty*4];
      float4 vv = *(const float4*)&vs[tt][tx*4];
      float pa[4] = {pr.x,pr.y,pr.z,pr.w};
      float vb[4] = {vv.x,vv.y,vv.z,vv.w};
#pragma unroll
      for (int i = 0; i < 4; ++i)
#pragma unroll
        for (int j = 0; j < 4; ++j) accv[i][j] = fmaf(pa[i], vb[j], accv[i][j]);
    }
    __syncthreads();
  }
#pragma unroll
  for (int i = 0; i < 4; ++i) {
    const float inv = 1.0f / l_run[i];
    float* op = Op + ((long)(s0 + ty*4 + i) * NB + b) * ldo + qoff + tx*4;
    float4 v;
    v.x = accv[i][0]*inv; v.y = accv[i][1]*inv; v.z = accv[i][2]*inv; v.w = accv[i][3]*inv;
    *(float4*)op = v;
  }
}

// ---------------------------------------------------------------------------
// LayerNorm over c=512, one wave per row.
// ---------------------------------------------------------------------------
__global__ __launch_bounds__(256)
void ln_k(const float* __restrict__ X, const float* __restrict__ g,
          const float* __restrict__ bb, float* __restrict__ Y)
{
  const int t = threadIdx.x;
  const int lane = t & 63;
  const long row = (long)blockIdx.x * 4 + (t >> 6);
  const float* xr = X + row * CDIM;
  float4 v0 = *(const float4*)(xr + lane*4);
  float4 v1 = *(const float4*)(xr + 256 + lane*4);
  float s = v0.x+v0.y+v0.z+v0.w + v1.x+v1.y+v1.z+v1.w;
#pragma unroll
  for (int off = 1; off < 64; off <<= 1) s += __shfl_xor(s, off);
  const float mean = s * (1.0f/512.0f);
  float d[8] = {v0.x-mean, v0.y-mean, v0.z-mean, v0.w-mean,
                v1.x-mean, v1.y-mean, v1.z-mean, v1.w-mean};
  float sq = d[0]*d[0]+d[1]*d[1]+d[2]*d[2]+d[3]*d[3]
           + d[4]*d[4]+d[5]*d[5]+d[6]*d[6]+d[7]*d[7];
#pragma unroll
  for (int off = 1; off < 64; off <<= 1) sq += __shfl_xor(sq, off);
  const float inv = 1.0f / sqrtf(sq * (1.0f/512.0f) + 1e-5f);
  float4 g0 = *(const float4*)(g + lane*4);
  float4 g1 = *(const float4*)(g + 256 + lane*4);
  float4 b0 = *(const float4*)(bb + lane*4);
  float4 b1 = *(const float4*)(bb + 256 + lane*4);
  float4 o0, o1;
  o0.x = d[0]*inv*g0.x + b0.x; o0.y = d[1]*inv*g0.y + b0.y;
  o0.z = d[2]*inv*g0.z + b0.z; o0.w = d[3]*inv*g0.w + b0.w;
  o1.x = d[4]*inv*g1.x + b1.x; o1.y = d[5]*inv*g1.y + b1.y;
  o1.z = d[6]*inv*g1.z + b1.z; o1.w = d[7]*inv*g1.w + b1.w;
  *(float4*)(Y + row*CDIM + lane*4) = o0;
  *(float4*)(Y + row*CDIM + 256 + lane*4) = o1;
}

// ---------------------------------------------------------------------------
// Pack x (N,C,H,W) -> enc_flat (S,n,c) and posisted = enc_flat + PE2D.
// ---------------------------------------------------------------------------
__global__ void pack_pe_k(const float* __restrict__ x, float* __restrict__ encf,
                          float* __restrict__ posd)
{
  __shared__ float tl[32][33];
  const int b = blockIdx.z;
  const int s0 = blockIdx.x*32, c0 = blockIdx.y*32;
#pragma unroll
  for (int i = 0; i < 4; ++i) {
    int ci = threadIdx.y + i*8;
    tl[ci][threadIdx.x] = x[((long)b*CDIM + c0+ci)*S_LEN + s0 + threadIdx.x];
  }
  __syncthreads();
#pragma unroll
  for (int i = 0; i < 4; ++i) {
    int si = threadIdx.y + i*8;
    int s = s0 + si;
    int ch = c0 + threadIdx.x;
    float val = tl[threadIdx.x][si];
    long o = ((long)s*NB + b)*CDIM + ch;
    encf[o] = val;
    int pos = (ch < 256) ? (s & 31) : (s >> 5);
    int j = (ch & 255) >> 1;
    float dv = expf((float)(2*j) * (-9.210340371976184f / 256.0f));
    float ang = (float)pos * dv;
    float pe = (ch & 1) ? cosf(ang) : sinf(ang);
    posd[o] = val + pe;
  }
}

// (S,n,c) token-major -> (n,c,S) output layout
__global__ void tpose_k(const float* __restrict__ in, float* __restrict__ out)
{
  __shared__ float tl[32][33];
  const int b = blockIdx.z;
  const int s0 = blockIdx.x*32, c0 = blockIdx.y*32;
#pragma unroll
  for (int i = 0; i < 4; ++i) {
    int si = threadIdx.y + i*8;
    tl[si][threadIdx.x] = in[((long)(s0+si)*NB + b)*CDIM + c0 + threadIdx.x];
  }
  __syncthreads();
#pragma unroll
  for (int i = 0; i < 4; ++i) {
    int ci = threadIdx.y + i*8;
    out[((long)b*CDIM + c0+ci)*S_LEN + s0 + threadIdx.x] = tl[threadIdx.x][ci];
  }
}

// cb_w (c,K) -> cbT (K,c)
__global__ void cbt_k(const float* __restrict__ cb, float* __restrict__ cbT)
{
  __shared__ float tl[32][33];
  const int k0 = blockIdx.x*32, c0 = blockIdx.y*32;
#pragma unroll
  for (int i = 0; i < 4; ++i) {
    int ci = threadIdx.y + i*8;
    tl[ci][threadIdx.x] = cb[(long)(c0+ci)*KCB + k0 + threadIdx.x];
  }
  __syncthreads();
#pragma unroll
  for (int i = 0; i < 4; ++i) {
    int ki = threadIdx.y + i*8;
    cbT[(long)(k0+ki)*CDIM + c0 + threadIdx.x] = tl[threadIdx.x][ki];
  }
}

// Per-token row of logits: max, argmax (np first-occurrence), 1/sum(exp).
__global__ __launch_bounds__(256)
void simstats_k(const float* __restrict__ logits, float* __restrict__ stats,
                int* __restrict__ codes_tok, float* __restrict__ codes_out)
{
  const long phys = blockIdx.x;
  const float* rowp = logits + phys * KCB;
  const int t = threadIdx.x;
  float vals[16];
#pragma unroll
  for (int rep = 0; rep < 4; ++rep) {
    float4 v = *(const float4*)(rowp + rep*1024 + t*4);
    vals[rep*4+0]=v.x; vals[rep*4+1]=v.y; vals[rep*4+2]=v.z; vals[rep*4+3]=v.w;
  }
  float mv = -INFINITY; int mi = 0;
#pragma unroll
  for (int rep = 0; rep < 4; ++rep)
#pragma unroll
    for (int j = 0; j < 4; ++j) {
      float xv = vals[rep*4+j];
      int ix = rep*1024 + t*4 + j;
      if (xv > mv) { mv = xv; mi = ix; }
    }
  const int lane = t & 63, wid = t >> 6;
#pragma unroll
  for (int off = 1; off < 64; off <<= 1) {
    float ov = __shfl_xor(mv, off);
    int   oi = __shfl_xor(mi, off);
    if (ov > mv || (ov == mv && oi < mi)) { mv = ov; mi = oi; }
  }
  __shared__ float smax[4]; __shared__ int sidx[4]; __shared__ float ssum[4];
  __shared__ float fm; __shared__ int fi;
  if (lane == 0) { smax[wid] = mv; sidx[wid] = mi; }
  __syncthreads();
  if (t == 0) {
    float bm = smax[0]; int bi = sidx[0];
    for (int wq = 1; wq < 4; ++wq)
      if (smax[wq] > bm || (smax[wq] == bm && sidx[wq] < bi)) { bm = smax[wq]; bi = sidx[wq]; }
    fm = bm; fi = bi;
  }
  __syncthreads();
  const float Mx = fm;
  float se = 0.f;
#pragma unroll
  for (int q = 0; q < 16; ++q) se += expf(vals[q] - Mx);
#pragma unroll
  for (int off = 1; off < 64; off <<= 1) se += __shfl_xor(se, off);
  if (lane == 0) ssum[wid] = se;
  __syncthreads();
  if (t == 0) {
    float tot = ssum[0]+ssum[1]+ssum[2]+ssum[3];
    stats[2*phys]   = Mx;
    stats[2*phys+1] = 1.0f / tot;
    int b = (int)(phys >> 10), s = (int)(phys & 1023);
    codes_tok[s*NB + b] = fi;
    codes_out[phys] = (float)fi;
  }
}

// quant = (hard - soft) + soft, also emit hard
__global__ __launch_bounds__(128)
void quant_k(const float* __restrict__ soft, const int* __restrict__ codes_tok,
             const float* __restrict__ cbT, float* __restrict__ quant,
             float* __restrict__ hardb)
{
  const int r = blockIdx.x;
  const int code = codes_tok[r];
  const int c = threadIdx.x * 4;
  float4 h  = *(const float4*)(cbT + (long)code*CDIM + c);
  float4 sf = *(const float4*)(soft + (long)r*CDIM + c);
  float4 q;
  q.x = (h.x - sf.x) + sf.x; q.y = (h.y - sf.y) + sf.y;
  q.z = (h.z - sf.z) + sf.z; q.w = (h.w - sf.w) + sf.w;
  *(float4*)(quant + (long)r*CDIM + c) = q;
  *(float4*)(hardb + (long)r*CDIM + c) = h;
}

// Detect the storage format of the bool mask buffer.
__global__ void maskdetect_k(const void* __restrict__ mask, int* __restrict__ flag)
{
  const unsigned int* wds = (const unsigned int*)mask;
  int t = threadIdx.x;
  int okI = 1, okF = 1, okL = 1;
  for (int i = t; i < 2048; i += 256) {
    unsigned int u = wds[i];
    if (u > 1u) okI = 0;
    if (u != 0u && u != 0x3F800000u) okF = 0;
    if ((i & 1) ? (u != 0u) : (u > 1u)) okL = 0;
  }
  __shared__ int sI, sF, sL;
  if (t == 0) { sI = 1; sF = 1; sL = 1; }
  __syncthreads();
  if (!okI) atomicAnd(&sI, 0);
  if (!okF) atomicAnd(&sF, 0);
  if (!okL) atomicAnd(&sL, 0);
  __syncthreads();
  if (t == 0) {
    int f;
    if (sI && sL) f = 3;
    else if (sI)  f = 1;
    else if (sF)  f = 2;
    else          f = 0;
    *flag = f;
  }
}

// mixed = mask ? enc_flat : post
__global__ __launch_bounds__(256)
void mixed_k(const float* __restrict__ encf, const float* __restrict__ post,
             const void* __restrict__ mask, const int* __restrict__ flag,
             float* __restrict__ outx)
{
  long gid = (long)blockIdx.x * blockDim.x + threadIdx.x;
  int r = (int)(gid >> 7);
  int c = (int)(gid & 127) * 4;
  int f = *flag;
  bool mv;
  if (f == 0)      mv = ((const unsigned char*)mask)[r] != 0;
  else if (f == 1) mv = ((const int*)mask)[r] != 0;
  else if (f == 3) mv = ((const long long*)mask)[r] != 0;
  else             mv = ((const float*)mask)[r] != 0.0f;
  const float* src = mv ? encf : post;
  *(float4*)(outx + (long)r*CDIM + c) = *(const float4*)(src + (long)r*CDIM + c);
}

// ---------------------------------------------------------------------------
// Host-side wrappers
// ---------------------------------------------------------------------------
static void gemm_qkv_f32(hipStream_t st, const float* A, const float* W, const float* bias,
                         float* C, int N) {
  sgemm_k<128,0,true,false,false,false><<<dim3(N/128, NTOK/128), 256, 0, st>>>(
      A, W, bias, nullptr, 0, C, N, NTOK, N, CDIM);
}
static void gemm64_b(hipStream_t st, const float* A, const float* W, const float* bias,
                     float* C) {
  sgemm_k<64,0,true,false,false,false><<<dim3(CDIM/64, NTOK/128), 256, 0, st>>>(
      A, W, bias, nullptr, 0, C, CDIM, NTOK, CDIM, CDIM);
}
static void gemm64_br(hipStream_t st, const float* A, const float* W, const float* bias,
                      const float* R, float* C) {
  sgemm_k<64,0,true,true,false,false><<<dim3(CDIM/64, NTOK/128), 256, 0, st>>>(
      A, W, bias, R, CDIM, C, CDIM, NTOK, CDIM, CDIM);
}
static void gemm64_brelu(hipStream_t st, const float* A, const float* W, const float* bias,
                         float* C) {
  sgemm_k<64,0,true,false,true,false><<<dim3(CDIM/64, NTOK/128), 256, 0, st>>>(
      A, W, bias, nullptr, 0, C, CDIM, NTOK, CDIM, CDIM);
}
static void hgemm_b(hipStream_t st, const float* A, const float* W, const float* bias,
                    float* C, int N, int K) {
  hgemm_k<true,false,false,false><<<dim3(N/128, NTOK/128), 256, 0, st>>>(
      A, W, bias, nullptr, 0, C, N, NTOK, N, K, nullptr);
}
static void hgemm_br(hipStream_t st, const float* A, const float* W, const float* bias,
                     const float* R, float* C) {
  hgemm_k<true,true,false,false><<<dim3(CDIM/128, NTOK/128), 256, 0, st>>>(
      A, W, bias, R, CDIM, C, CDIM, NTOK, CDIM, CDIM, nullptr);
}
static void hgemm_brelu(hipStream_t st, const float* A, const float* W, const float* bias,
                        float* C) {
  hgemm_k<true,false,true,false><<<dim3(CDIM/128, NTOK/128), 256, 0, st>>>(
      A, W, bias, nullptr, 0, C, CDIM, NTOK, CDIM, CDIM, nullptr);
}

extern "C" void kernel_launch(void* const* d_in, const int* in_sizes, int n_in,
                              void* d_out, int out_size, void* d_ws, size_t ws_size,
                              hipStream_t stream)
{
  const float* x       = (const float*)d_in[0];
  const float* pre_w   = (const float*)d_in[1];
  const float* pre_b   = (const float*)d_in[2];
  const float* post_w  = (const float*)d_in[3];
  const float* post_b  = (const float*)d_in[4];
  const float* cb_w    = (const float*)d_in[5];
  const float* e_qkv_w = (const float*)d_in[6];
  const float* e_qkv_b = (const float*)d_in[7];
  const float* e_o_w   = (const float*)d_in[8];
  const float* e_o_b   = (const float*)d_in[9];
  const float* e_ln1_w = (const float*)d_in[10];
  const float* e_ln1_b = (const float*)d_in[11];
  const float* e_ln2_w = (const float*)d_in[12];
  const float* e_ln2_b = (const float*)d_in[13];
  const float* e_f1_w  = (const float*)d_in[14];
  const float* e_f1_b  = (const float*)d_in[15];
  const float* e_f2_w  = (const float*)d_in[16];
  const float* e_f2_b  = (const float*)d_in[17];
  const float* d_sqkv_w= (const float*)d_in[18];
  const float* d_sqkv_b= (const float*)d_in[19];
  const float* d_so_w  = (const float*)d_in[20];
  const float* d_so_b  = (const float*)d_in[21];
  const float* d_cqkv_w= (const float*)d_in[22];
  const float* d_cqkv_b= (const float*)d_in[23];
  const float* d_co_w  = (const float*)d_in[24];
  const float* d_co_b  = (const float*)d_in[25];
  const float* d_ln1w  = (const float*)d_in[26];
  const float* d_ln1b  = (const float*)d_in[27];
  const float* d_ln2w  = (const float*)d_in[28];
  const float* d_ln2b  = (const float*)d_in[29];
  const float* d_ln3w  = (const float*)d_in[30];
  const float* d_ln3b  = (const float*)d_in[31];
  const float* d_f1w   = (const float*)d_in[32];
  const float* d_f1b   = (const float*)d_in[33];
  const float* d_f2w   = (const float*)d_in[34];
  const float* d_f2b   = (const float*)d_in[35];
  const void*  mask    = d_in[36];

  float* out = (float*)d_out;
  float* o_quant  = out;
  float* o_high   = out + 4194304;
  float* o_softs  = out + 8388608;
  float* o_hards  = out + 12582912;
  float* o_codes  = out + 16777216;
  float* o_logits = out + 16785408;

  float* ws    = (float*)d_ws;
  float* ENC   = ws;
  float* Xb    = ws + TOKC;
  float* T1    = ws + 2*TOKC;
  float* T2    = ws + 3*TOKC;
  float* QKV   = ws + 4*TOKC;
  float* MEMB  = ws + 7*TOKC;
  float* CBT   = ws + 8*TOKC;
  float* STATS = CBT + (long)KCB*CDIM;
  int*   CODES = (int*)(STATS + 2*NTOK);
  int*   FLAG  = CODES + NTOK;
  float* HARDB = QKV;
  float* QUANT = QKV + TOKC;

  const size_t NEED = (size_t)(8*TOKC + (long)KCB*CDIM + 2*NTOK + NTOK + 16) * 4;
  if (ws_size < NEED) return;

  const int M = NTOK;
  dim3 tgrid(S_LEN/32, CDIM/32, NB), tblk(32, 8);

  pack_pe_k<<<tgrid, tblk, 0, stream>>>(x, ENC, Xb);
  cbt_k<<<dim3(KCB/32, CDIM/32), tblk, 0, stream>>>(cb_w, CBT);
  maskdetect_k<<<1, 256, 0, stream>>>(mask, FLAG);

  // -------- encoder (fp32, argmax-critical) --------
  for (int i = 0; i < NLAYER; ++i) {
    gemm_qkv_f32(stream, Xb, e_qkv_w + (long)i*3*CDIM*CDIM, e_qkv_b + i*3*CDIM, QKV, 3*CDIM);
    attn_k<<<dim3(S_LEN/64, NB*8), 256, 0, stream>>>(QKV, 3*CDIM, QKV+CDIM, 3*CDIM, QKV+2*CDIM, 3*CDIM, T1, CDIM);
    gemm64_br(stream, T1, e_o_w + (long)i*CDIM*CDIM, e_o_b + i*CDIM, Xb, T2);
    ln_k<<<M/4, 256, 0, stream>>>(T2, e_ln1_w + i*CDIM, e_ln1_b + i*CDIM, T1);
    gemm64_brelu(stream, T1, e_f1_w + (long)i*CDIM*CDIM, e_f1_b + i*CDIM, QKV);
    gemm64_br(stream, QKV, e_f2_w + (long)i*CDIM*CDIM, e_f2_b + i*CDIM, T1, T2);
    ln_k<<<M/4, 256, 0, stream>>>(T2, e_ln2_w + i*CDIM, e_ln2_b + i*CDIM, Xb);
  }

  // -------- codebook / quantizer --------
  gemm64_b(stream, Xb, pre_w, pre_b, T1);                                    // pre (fp32)
  tpose_k<<<tgrid, tblk, 0, stream>>>(T1, o_high);
  sgemm_k<128,1,false,false,false,true><<<dim3(KCB/128, M/128), 256, 0, stream>>>(
      T1, cb_w, nullptr, nullptr, 0, o_logits, KCB, M, KCB, CDIM);           // sim (fp32)
  simstats_k<<<NTOK, 256, 0, stream>>>(o_logits, STATS, CODES, o_codes);
  hgemm_k<false,false,false,true><<<dim3(CDIM/128, M/128), 256, 0, stream>>>(
      o_logits, cb_w, nullptr, nullptr, 0, T2, CDIM, M, CDIM, KCB, STATS);   // soft (f16)
  tpose_k<<<tgrid, tblk, 0, stream>>>(T2, o_softs);
  quant_k<<<NTOK, 128, 0, stream>>>(T2, CODES, CBT, QUANT, HARDB);
  tpose_k<<<tgrid, tblk, 0, stream>>>(HARDB, o_hards);
  hgemm_b(stream, QUANT, post_w, post_b, MEMB, CDIM, CDIM);                  // post (f16)
  mixed_k<<<4096, 256, 0, stream>>>(ENC, MEMB, mask, FLAG, Xb);

  // -------- decoder (f16 MFMA GEMMs) --------
  for (int i = 0; i < NLAYER; ++i) {
    hgemm_b(stream, Xb, d_sqkv_w + (long)i*3*CDIM*CDIM, d_sqkv_b + i*3*CDIM, QKV, 3*CDIM, CDIM);
    attn_k<<<dim3(S_LEN/64, NB*8), 256, 0, stream>>>(QKV, 3*CDIM, QKV+CDIM, 3*CDIM, QKV+2*CDIM, 3*CDIM, T1, CDIM);
    hgemm_br(stream, T1, d_so_w + (long)i*CDIM*CDIM, d_so_b + i*CDIM, Xb, T2);
    ln_k<<<M/4, 256, 0, stream>>>(T2, d_ln1w + i*CDIM, d_ln1b + i*CDIM, Xb);
    hgemm_b(stream, Xb, d_cqkv_w + (long)i*3*CDIM*CDIM, d_cqkv_b + i*3*CDIM, QKV, CDIM, CDIM);
    hgemm_k<true,false,false,false><<<dim3(2*CDIM/128, M/128), 256, 0, stream>>>(
        MEMB, d_cqkv_w + (long)i*3*CDIM*CDIM + (long)CDIM*CDIM,
        d_cqkv_b + i*3*CDIM + CDIM, nullptr, 0, QKV + TOKC, 2*CDIM, M, 2*CDIM, CDIM, nullptr);
    attn_k<<<dim3(S_LEN/64, NB*8), 256, 0, stream>>>(QKV, CDIM, QKV+TOKC, 2*CDIM, QKV+TOKC+CDIM, 2*CDIM, T1, CDIM);
    hgemm_br(stream, T1, d_co_w + (long)i*CDIM*CDIM, d_co_b + i*CDIM, Xb, T2);
    ln_k<<<M/4, 256, 0, stream>>>(T2, d_ln2w + i*CDIM, d_ln2b + i*CDIM, Xb);
    hgemm_brelu(stream, Xb, d_f1w + (long)i*CDIM*CDIM, d_f1b + i*CDIM, QKV);
    hgemm_br(stream, QKV, d_f2w + (long)i*CDIM*CDIM, d_f2b + i*CDIM, Xb, T2);
    ln_k<<<M/4, 256, 0, stream>>>(T2, d_ln3w + i*CDIM, d_ln3b + i*CDIM, Xb);
  }
  tpose_k<<<tgrid, tblk, 0, stream>>>(Xb, o_quant);
}

// Round 3
// 5173.788 us; speedup vs baseline: 2.4229x; 1.7926x over previous
//
#include <hip/hip_runtime.h>
#include <math.h>

#define S_LEN 1024
#define NB 8
#define CDIM 512
#define KCB 4096
#define DH 64
#define NLAYER 6
#define NTOK (S_LEN*NB)
#define TOKC ((long)NTOK*CDIM)

typedef __attribute__((ext_vector_type(8))) _Float16 f16x8;
typedef __attribute__((ext_vector_type(2))) _Float16 f16x2;
typedef __attribute__((ext_vector_type(4))) float f32x4;

// ---------------------------------------------------------------------------
// MFMA GEMM: C[M,N] = A[M,K] @ W[N,K]^T (+bias/res/relu). fp32 in global.
// SPLIT=0: plain fp16 (tolerant outputs). SPLIT=1: hi/lo split-fp16 -> ~fp32
// accuracy via 4 MFMAs per fragment pair (argmax-critical encoder chain).
// 128x128 tile, BK=64, 4 waves, mfma_f32_16x16x32_f16, XOR-swizzled LDS.
// SOFTA: A row r read from phys row (r&7)*S_LEN+(r>>3), exp(a-m)*inv applied.
// OREMAP: output row (s*NB+b) -> (b*S_LEN+s).
// ---------------------------------------------------------------------------
template<int SPLIT, bool BIAS, bool RES, bool RELU, bool SOFTA, bool OREMAP>
__global__ __launch_bounds__(256)
void hgemm_k(const float* __restrict__ A, const float* __restrict__ W,
             const float* __restrict__ bias, const float* __restrict__ Rsrc, int ldr,
             float* __restrict__ C, int ldc, int M, int N, int K,
             const float* __restrict__ stats)
{
  __shared__ __align__(16) _Float16 Ah[128*64];
  __shared__ __align__(16) _Float16 Bh[128*64];
  __shared__ __align__(16) _Float16 Al[SPLIT ? 128*64 : 8];
  __shared__ __align__(16) _Float16 Bl[SPLIT ? 128*64 : 8];
  const int t = threadIdx.x;
  const int m0 = blockIdx.y * 128, n0 = blockIdx.x * 128;

  const int srow = t >> 1, shalf = t & 1;
  const int atok = m0 + srow;
  long aphys = atok;
  if (SOFTA) aphys = (long)(atok & (NB-1)) * S_LEN + (atok >> 3);
  const float* aptr = A + aphys * (long)K + shalf*32;
  const float* bptr = W + (long)(n0 + srow) * K + shalf*32;
  float sm_m = 0.f, sm_inv = 0.f;
  if (SOFTA) { sm_m = stats[2*aphys]; sm_inv = stats[2*aphys+1]; }

  const int lane = t & 63, wave = t >> 6;
  const int wm = wave >> 1, wn = wave & 1;
  const int lr = lane & 15, lk = lane >> 4;

  f32x4 acc[4][4];
#pragma unroll
  for (int mi = 0; mi < 4; ++mi)
#pragma unroll
    for (int ni = 0; ni < 4; ++ni)
#pragma unroll
      for (int e = 0; e < 4; ++e) acc[mi][ni][e] = 0.f;

  float4 a4[8], b4[8];
#pragma unroll
  for (int j = 0; j < 8; ++j) {
    a4[j] = *(const float4*)(aptr + j*4);
    b4[j] = *(const float4*)(bptr + j*4);
  }

  for (int k0 = 0; k0 < K; k0 += 64) {
    __syncthreads();
    if (SOFTA) {
#pragma unroll
      for (int j = 0; j < 8; ++j) {
        a4[j].x = expf(a4[j].x - sm_m) * sm_inv;
        a4[j].y = expf(a4[j].y - sm_m) * sm_inv;
        a4[j].z = expf(a4[j].z - sm_m) * sm_inv;
        a4[j].w = expf(a4[j].w - sm_m) * sm_inv;
      }
    }
    {
      const float* af = (const float*)a4;
      const float* bf = (const float*)b4;
#pragma unroll
      for (int c2 = 0; c2 < 4; ++c2) {
        f16x8 ha, hb, la, lb;
#pragma unroll
        for (int j = 0; j < 8; ++j) {
          float xa = af[c2*8+j], xb = bf[c2*8+j];
          _Float16 hia = (_Float16)xa, hib = (_Float16)xb;
          ha[j] = hia; hb[j] = hib;
          if (SPLIT) { la[j] = (_Float16)(xa - (float)hia); lb[j] = (_Float16)(xb - (float)hib); }
        }
        const int sw = (shalf*64 + c2*16) ^ ((srow & 7) << 4);
        *(f16x8*)((char*)Ah + srow*128 + sw) = ha;
        *(f16x8*)((char*)Bh + srow*128 + sw) = hb;
        if (SPLIT) {
          *(f16x8*)((char*)Al + srow*128 + sw) = la;
          *(f16x8*)((char*)Bl + srow*128 + sw) = lb;
        }
      }
    }
    __syncthreads();
    if (k0 + 64 < K) {
#pragma unroll
      for (int j = 0; j < 8; ++j) {
        a4[j] = *(const float4*)(aptr + k0 + 64 + j*4);
        b4[j] = *(const float4*)(bptr + k0 + 64 + j*4);
      }
    }
#pragma unroll
    for (int kk = 0; kk < 2; ++kk) {
      f16x8 afh[4], bfh[4], afl[4], bfl[4];
#pragma unroll
      for (int mi = 0; mi < 4; ++mi) {
        const int r = wm*64 + mi*16 + lr;
        const int bo = (lk*16 + kk*64) ^ ((r & 7) << 4);
        afh[mi] = *(const f16x8*)((const char*)Ah + r*128 + bo);
        if (SPLIT) afl[mi] = *(const f16x8*)((const char*)Al + r*128 + bo);
      }
#pragma unroll
      for (int ni = 0; ni < 4; ++ni) {
        const int r = wn*64 + ni*16 + lr;
        const int bo = (lk*16 + kk*64) ^ ((r & 7) << 4);
        bfh[ni] = *(const f16x8*)((const char*)Bh + r*128 + bo);
        if (SPLIT) bfl[ni] = *(const f16x8*)((const char*)Bl + r*128 + bo);
      }
#pragma unroll
      for (int mi = 0; mi < 4; ++mi)
#pragma unroll
        for (int ni = 0; ni < 4; ++ni) {
          acc[mi][ni] = __builtin_amdgcn_mfma_f32_16x16x32_f16(afh[mi], bfh[ni], acc[mi][ni], 0, 0, 0);
          if (SPLIT) {
            acc[mi][ni] = __builtin_amdgcn_mfma_f32_16x16x32_f16(afh[mi], bfl[ni], acc[mi][ni], 0, 0, 0);
            acc[mi][ni] = __builtin_amdgcn_mfma_f32_16x16x32_f16(afl[mi], bfh[ni], acc[mi][ni], 0, 0, 0);
            acc[mi][ni] = __builtin_amdgcn_mfma_f32_16x16x32_f16(afl[mi], bfl[ni], acc[mi][ni], 0, 0, 0);
          }
        }
    }
  }

  float bvv[4];
  if (BIAS) {
#pragma unroll
    for (int ni = 0; ni < 4; ++ni) bvv[ni] = bias[n0 + wn*64 + ni*16 + lr];
  }
#pragma unroll
  for (int mi = 0; mi < 4; ++mi)
#pragma unroll
  for (int i = 0; i < 4; ++i) {
    const int rm = m0 + wm*64 + mi*16 + lk*4 + i;
    long orow = rm;
    if (OREMAP) orow = (long)(rm & (NB-1)) * S_LEN + (rm >> 3);
#pragma unroll
    for (int ni = 0; ni < 4; ++ni) {
      const int col = n0 + wn*64 + ni*16 + lr;
      float v = acc[mi][ni][i];
      if (BIAS) v += bvv[ni];
      if (RES)  v += Rsrc[(long)rm*ldr + col];
      if (RELU) v = fmaxf(v, 0.f);
      C[orow*(long)ldc + col] = v;
    }
  }
}

// ---------------------------------------------------------------------------
// MFMA flash attention. Block = 128 q rows x one (b,head); 4 waves x 32 rows.
// SPLIT=1: hi/lo split-fp16 (4 MFMAs/pair) for the argmax-critical encoder.
// Q staged once in LDS then held in registers; its LDS buffer is reused as
// the per-wave P buffer. K staged [key][d]; V staged transposed [d][key].
// All LDS XOR-swizzled (byte ^= (row&7)<<4).
// ---------------------------------------------------------------------------
template<int SPLIT>
__global__ __launch_bounds__(256)
void mattn_k(const float* __restrict__ Qp, int ldq,
             const float* __restrict__ Kp, int ldk,
             const float* __restrict__ Vp, int ldv,
             float* __restrict__ Op, int ldo)
{
  __shared__ __align__(16) char QP[SPLIT ? 32768 : 16384];  // Q then P
  __shared__ __align__(16) _Float16 Kh[64*64];
  __shared__ __align__(16) _Float16 Vh[64*64];
  __shared__ __align__(16) _Float16 Kl[SPLIT ? 64*64 : 8];
  __shared__ __align__(16) _Float16 Vl[SPLIT ? 64*64 : 8];

  const int t = threadIdx.x;
  const int b = blockIdx.y >> 3, hd = blockIdx.y & 7;
  const int s0 = blockIdx.x * 128;
  const int qoff = hd * DH;
  const int wave = t >> 6, lane = t & 63;
  const int lr = lane & 15, lk = lane >> 4;

  // ---- stage Q (once) ----
  {
    const int row = t >> 1, sh = t & 1;
    const float* qrow = Qp + ((long)(s0 + row) * NB + b) * ldq + qoff + sh*32;
    float4 q4[8];
#pragma unroll
    for (int j = 0; j < 8; ++j) q4[j] = *(const float4*)(qrow + j*4);
    const float* qf = (const float*)q4;
#pragma unroll
    for (int c2 = 0; c2 < 4; ++c2) {
      f16x8 h, l;
#pragma unroll
      for (int j = 0; j < 8; ++j) {
        float xv = qf[c2*8+j];
        _Float16 hh = (_Float16)xv;
        h[j] = hh;
        if (SPLIT) l[j] = (_Float16)(xv - (float)hh);
      }
      const int sw = (sh*64 + c2*16) ^ ((row & 7) << 4);
      *(f16x8*)(QP + row*128 + sw) = h;
      if (SPLIT) *(f16x8*)(QP + 16384 + row*128 + sw) = l;
    }
  }
  __syncthreads();

  f16x8 qa[2][2], qal[2][2];
#pragma unroll
  for (int mi = 0; mi < 2; ++mi)
#pragma unroll
    for (int kk = 0; kk < 2; ++kk) {
      const int r = wave*32 + mi*16 + lr;
      const int bo = (lk*16 + kk*64) ^ ((r & 7) << 4);
      qa[mi][kk] = *(const f16x8*)(QP + r*128 + bo);
      if (SPLIT) qal[mi][kk] = *(const f16x8*)(QP + 16384 + r*128 + bo);
    }

  float m_run[2][4], l_run[2][4];
  f32x4 oacc[2][4];
#pragma unroll
  for (int mi = 0; mi < 2; ++mi)
#pragma unroll
    for (int i = 0; i < 4; ++i) {
      m_run[mi][i] = -INFINITY; l_run[mi][i] = 0.f;
#pragma unroll
      for (int ni = 0; ni < 4; ++ni) oacc[mi][ni][i] = 0.f;
    }

  char* Pw  = QP + wave*4096;
  char* Pwl = QP + 16384 + wave*4096;

  for (int t0 = 0; t0 < S_LEN; t0 += 64) {
    __syncthreads();   // all waves done with Kh/Vh (and Q-frag reads, first iter)
    // ---- stage K [key][d] ----
    {
      const int row = t >> 2, qd = t & 3;
      const float* krow = Kp + ((long)(t0 + row) * NB + b) * ldk + qoff + qd*16;
      float4 k4[4];
#pragma unroll
      for (int j = 0; j < 4; ++j) k4[j] = *(const float4*)(krow + j*4);
      const float* kf = (const float*)k4;
#pragma unroll
      for (int c = 0; c < 2; ++c) {
        f16x8 h, l;
#pragma unroll
        for (int j = 0; j < 8; ++j) {
          float xv = kf[c*8+j];
          _Float16 hh = (_Float16)xv;
          h[j] = hh;
          if (SPLIT) l[j] = (_Float16)(xv - (float)hh);
        }
        const int sw = (qd*32 + c*16) ^ ((row & 7) << 4);
        *(f16x8*)((char*)Kh + row*128 + sw) = h;
        if (SPLIT) *(f16x8*)((char*)Kl + row*128 + sw) = l;
      }
    }
    // ---- stage V transposed [d][key] ----
    {
      const int tp = t & 31, dc = t >> 5;
      const float* v0 = Vp + ((long)(t0 + 2*tp) * NB + b) * ldv + qoff + dc*8;
      const float* v1 = v0 + (long)NB * ldv;
      float4 va[2], vb2[2];
      va[0] = *(const float4*)(v0); va[1] = *(const float4*)(v0 + 4);
      vb2[0] = *(const float4*)(v1); vb2[1] = *(const float4*)(v1 + 4);
      const float* f0 = (const float*)va;
      const float* f1 = (const float*)vb2;
#pragma unroll
      for (int j = 0; j < 8; ++j) {
        const int dd = dc*8 + j;
        _Float16 h0 = (_Float16)f0[j], h1 = (_Float16)f1[j];
        f16x2 hv = {h0, h1};
        const int sw = (tp*4) ^ ((dd & 7) << 4);
        *(f16x2*)((char*)Vh + dd*128 + sw) = hv;
        if (SPLIT) {
          f16x2 lv = {(_Float16)(f0[j] - (float)h0), (_Float16)(f1[j] - (float)h1)};
          *(f16x2*)((char*)Vl + dd*128 + sw) = lv;
        }
      }
    }
    __syncthreads();

    // ---- S = Q K^T ----
    f32x4 s[2][4];
#pragma unroll
    for (int mi = 0; mi < 2; ++mi)
#pragma unroll
      for (int ni = 0; ni < 4; ++ni)
#pragma unroll
        for (int e = 0; e < 4; ++e) s[mi][ni][e] = 0.f;
#pragma unroll
    for (int kk = 0; kk < 2; ++kk) {
      f16x8 kb[4], kbl[4];
#pragma unroll
      for (int ni = 0; ni < 4; ++ni) {
        const int r = ni*16 + lr;
        const int bo = (lk*16 + kk*64) ^ ((r & 7) << 4);
        kb[ni] = *(const f16x8*)((const char*)Kh + r*128 + bo);
        if (SPLIT) kbl[ni] = *(const f16x8*)((const char*)Kl + r*128 + bo);
      }
#pragma unroll
      for (int mi = 0; mi < 2; ++mi)
#pragma unroll
        for (int ni = 0; ni < 4; ++ni) {
          s[mi][ni] = __builtin_amdgcn_mfma_f32_16x16x32_f16(qa[mi][kk], kb[ni], s[mi][ni], 0, 0, 0);
          if (SPLIT) {
            s[mi][ni] = __builtin_amdgcn_mfma_f32_16x16x32_f16(qa[mi][kk], kbl[ni], s[mi][ni], 0, 0, 0);
            s[mi][ni] = __builtin_amdgcn_mfma_f32_16x16x32_f16(qal[mi][kk], kb[ni], s[mi][ni], 0, 0, 0);
            s[mi][ni] = __builtin_amdgcn_mfma_f32_16x16x32_f16(qal[mi][kk], kbl[ni], s[mi][ni], 0, 0, 0);
          }
        }
    }
#pragma unroll
    for (int mi = 0; mi < 2; ++mi)
#pragma unroll
      for (int ni = 0; ni < 4; ++ni)
#pragma unroll
        for (int e = 0; e < 4; ++e) s[mi][ni][e] *= 0.125f;

    // ---- online softmax (rows spread over 16-lane groups) ----
#pragma unroll
    for (int mi = 0; mi < 2; ++mi) {
      float rm[4];
#pragma unroll
      for (int i = 0; i < 4; ++i)
        rm[i] = fmaxf(fmaxf(s[mi][0][i], s[mi][1][i]), fmaxf(s[mi][2][i], s[mi][3][i]));
#pragma unroll
      for (int off = 1; off < 16; off <<= 1)
#pragma unroll
        for (int i = 0; i < 4; ++i) rm[i] = fmaxf(rm[i], __shfl_xor(rm[i], off));
      float rs[4], corr[4];
#pragma unroll
      for (int i = 0; i < 4; ++i) {
        const float mnew = fmaxf(m_run[mi][i], rm[i]);
        corr[i] = expf(m_run[mi][i] - mnew);
        m_run[mi][i] = mnew;
        float lsum = 0.f;
#pragma unroll
        for (int ni = 0; ni < 4; ++ni) {
          float p = expf(s[mi][ni][i] - mnew);
          s[mi][ni][i] = p; lsum += p;
        }
        rs[i] = lsum;
      }
#pragma unroll
      for (int off = 1; off < 16; off <<= 1)
#pragma unroll
        for (int i = 0; i < 4; ++i) rs[i] += __shfl_xor(rs[i], off);
#pragma unroll
      for (int i = 0; i < 4; ++i) {
        l_run[mi][i] = l_run[mi][i]*corr[i] + rs[i];
#pragma unroll
        for (int ni = 0; ni < 4; ++ni) oacc[mi][ni][i] *= corr[i];
      }
    }

    // ---- P -> LDS (wave-private region) ----
#pragma unroll
    for (int mi = 0; mi < 2; ++mi)
#pragma unroll
      for (int ni = 0; ni < 4; ++ni)
#pragma unroll
        for (int i = 0; i < 4; ++i) {
          const int row = mi*16 + lk*4 + i;
          const int col = ni*16 + lr;
          const int ad = row*128 + ((col*2) ^ ((row & 7) << 4));
          float pv = s[mi][ni][i];
          _Float16 ph = (_Float16)pv;
          *(_Float16*)(Pw + ad) = ph;
          if (SPLIT) *(_Float16*)(Pwl + ad) = (_Float16)(pv - (float)ph);
        }

    // ---- O += P V ----
#pragma unroll
    for (int kk = 0; kk < 2; ++kk) {
      f16x8 vb[4], vbl[4], pa[2], pal[2];
#pragma unroll
      for (int ni = 0; ni < 4; ++ni) {
        const int r = ni*16 + lr;
        const int bo = (lk*16 + kk*64) ^ ((r & 7) << 4);
        vb[ni] = *(const f16x8*)((const char*)Vh + r*128 + bo);
        if (SPLIT) vbl[ni] = *(const f16x8*)((const char*)Vl + r*128 + bo);
      }
#pragma unroll
      for (int mi = 0; mi < 2; ++mi) {
        const int r = mi*16 + lr;
        const int bo = (lk*16 + kk*64) ^ ((r & 7) << 4);
        pa[mi] = *(const f16x8*)(Pw + r*128 + bo);
        if (SPLIT) pal[mi] = *(const f16x8*)(Pwl + r*128 + bo);
      }
#pragma unroll
      for (int mi = 0; mi < 2; ++mi)
#pragma unroll
        for (int ni = 0; ni < 4; ++ni) {
          oacc[mi][ni] = __builtin_amdgcn_mfma_f32_16x16x32_f16(pa[mi], vb[ni], oacc[mi][ni], 0, 0, 0);
          if (SPLIT) {
            oacc[mi][ni] = __builtin_amdgcn_mfma_f32_16x16x32_f16(pa[mi], vbl[ni], oacc[mi][ni], 0, 0, 0);
            oacc[mi][ni] = __builtin_amdgcn_mfma_f32_16x16x32_f16(pal[mi], vb[ni], oacc[mi][ni], 0, 0, 0);
            oacc[mi][ni] = __builtin_amdgcn_mfma_f32_16x16x32_f16(pal[mi], vbl[ni], oacc[mi][ni], 0, 0, 0);
          }
        }
    }
  }

#pragma unroll
  for (int mi = 0; mi < 2; ++mi)
#pragma unroll
    for (int i = 0; i < 4; ++i) {
      const float inv = 1.0f / l_run[mi][i];
      const int q = s0 + wave*32 + mi*16 + lk*4 + i;
      float* orow = Op + ((long)q * NB + b) * ldo + qoff;
#pragma unroll
      for (int ni = 0; ni < 4; ++ni) orow[ni*16 + lr] = oacc[mi][ni][i] * inv;
    }
}

// ---------------------------------------------------------------------------
// LayerNorm over c=512, one wave per row.
// ---------------------------------------------------------------------------
__global__ __launch_bounds__(256)
void ln_k(const float* __restrict__ X, const float* __restrict__ g,
          const float* __restrict__ bb, float* __restrict__ Y)
{
  const int t = threadIdx.x;
  const int lane = t & 63;
  const long row = (long)blockIdx.x * 4 + (t >> 6);
  const float* xr = X + row * CDIM;
  float4 v0 = *(const float4*)(xr + lane*4);
  float4 v1 = *(const float4*)(xr + 256 + lane*4);
  float s = v0.x+v0.y+v0.z+v0.w + v1.x+v1.y+v1.z+v1.w;
#pragma unroll
  for (int off = 1; off < 64; off <<= 1) s += __shfl_xor(s, off);
  const float mean = s * (1.0f/512.0f);
  float d[8] = {v0.x-mean, v0.y-mean, v0.z-mean, v0.w-mean,
                v1.x-mean, v1.y-mean, v1.z-mean, v1.w-mean};
  float sq = d[0]*d[0]+d[1]*d[1]+d[2]*d[2]+d[3]*d[3]
           + d[4]*d[4]+d[5]*d[5]+d[6]*d[6]+d[7]*d[7];
#pragma unroll
  for (int off = 1; off < 64; off <<= 1) sq += __shfl_xor(sq, off);
  const float inv = 1.0f / sqrtf(sq * (1.0f/512.0f) + 1e-5f);
  float4 g0 = *(const float4*)(g + lane*4);
  float4 g1 = *(const float4*)(g + 256 + lane*4);
  float4 b0 = *(const float4*)(bb + lane*4);
  float4 b1 = *(const float4*)(bb + 256 + lane*4);
  float4 o0, o1;
  o0.x = d[0]*inv*g0.x + b0.x; o0.y = d[1]*inv*g0.y + b0.y;
  o0.z = d[2]*inv*g0.z + b0.z; o0.w = d[3]*inv*g0.w + b0.w;
  o1.x = d[4]*inv*g1.x + b1.x; o1.y = d[5]*inv*g1.y + b1.y;
  o1.z = d[6]*inv*g1.z + b1.z; o1.w = d[7]*inv*g1.w + b1.w;
  *(float4*)(Y + row*CDIM + lane*4) = o0;
  *(float4*)(Y + row*CDIM + 256 + lane*4) = o1;
}

// ---------------------------------------------------------------------------
// Pack x (N,C,H,W) -> enc_flat (S,n,c) and posisted = enc_flat + PE2D.
// ---------------------------------------------------------------------------
__global__ void pack_pe_k(const float* __restrict__ x, float* __restrict__ encf,
                          float* __restrict__ posd)
{
  __shared__ float tl[32][33];
  const int b = blockIdx.z;
  const int s0 = blockIdx.x*32, c0 = blockIdx.y*32;
#pragma unroll
  for (int i = 0; i < 4; ++i) {
    int ci = threadIdx.y + i*8;
    tl[ci][threadIdx.x] = x[((long)b*CDIM + c0+ci)*S_LEN + s0 + threadIdx.x];
  }
  __syncthreads();
#pragma unroll
  for (int i = 0; i < 4; ++i) {
    int si = threadIdx.y + i*8;
    int s = s0 + si;
    int ch = c0 + threadIdx.x;
    float val = tl[threadIdx.x][si];
    long o = ((long)s*NB + b)*CDIM + ch;
    encf[o] = val;
    int pos = (ch < 256) ? (s & 31) : (s >> 5);
    int j = (ch & 255) >> 1;
    float dv = expf((float)(2*j) * (-9.210340371976184f / 256.0f));
    float ang = (float)pos * dv;
    float pe = (ch & 1) ? cosf(ang) : sinf(ang);
    posd[o] = val + pe;
  }
}

// (S,n,c) token-major -> (n,c,S) output layout
__global__ void tpose_k(const float* __restrict__ in, float* __restrict__ out)
{
  __shared__ float tl[32][33];
  const int b = blockIdx.z;
  const int s0 = blockIdx.x*32, c0 = blockIdx.y*32;
#pragma unroll
  for (int i = 0; i < 4; ++i) {
    int si = threadIdx.y + i*8;
    tl[si][threadIdx.x] = in[((long)(s0+si)*NB + b)*CDIM + c0 + threadIdx.x];
  }
  __syncthreads();
#pragma unroll
  for (int i = 0; i < 4; ++i) {
    int ci = threadIdx.y + i*8;
    out[((long)b*CDIM + c0+ci)*S_LEN + s0 + threadIdx.x] = tl[threadIdx.x][ci];
  }
}

// cb_w (c,K) -> cbT (K,c)
__global__ void cbt_k(const float* __restrict__ cb, float* __restrict__ cbT)
{
  __shared__ float tl[32][33];
  const int k0 = blockIdx.x*32, c0 = blockIdx.y*32;
#pragma unroll
  for (int i = 0; i < 4; ++i) {
    int ci = threadIdx.y + i*8;
    tl[ci][threadIdx.x] = cb[(long)(c0+ci)*KCB + k0 + threadIdx.x];
  }
  __syncthreads();
#pragma unroll
  for (int i = 0; i < 4; ++i) {
    int ki = threadIdx.y + i*8;
    cbT[(long)(k0+ki)*CDIM + c0 + threadIdx.x] = tl[threadIdx.x][ki];
  }
}

// Per-token row of logits: max, argmax (np first-occurrence), 1/sum(exp).
__global__ __launch_bounds__(256)
void simstats_k(const float* __restrict__ logits, float* __restrict__ stats,
                int* __restrict__ codes_tok, float* __restrict__ codes_out)
{
  const long phys = blockIdx.x;
  const float* rowp = logits + phys * KCB;
  const int t = threadIdx.x;
  float vals[16];
#pragma unroll
  for (int rep = 0; rep < 4; ++rep) {
    float4 v = *(const float4*)(rowp + rep*1024 + t*4);
    vals[rep*4+0]=v.x; vals[rep*4+1]=v.y; vals[rep*4+2]=v.z; vals[rep*4+3]=v.w;
  }
  float mv = -INFINITY; int mi = 0;
#pragma unroll
  for (int rep = 0; rep < 4; ++rep)
#pragma unroll
    for (int j = 0; j < 4; ++j) {
      float xv = vals[rep*4+j];
      int ix = rep*1024 + t*4 + j;
      if (xv > mv) { mv = xv; mi = ix; }
    }
  const int lane = t & 63, wid = t >> 6;
#pragma unroll
  for (int off = 1; off < 64; off <<= 1) {
    float ov = __shfl_xor(mv, off);
    int   oi = __shfl_xor(mi, off);
    if (ov > mv || (ov == mv && oi < mi)) { mv = ov; mi = oi; }
  }
  __shared__ float smax[4]; __shared__ int sidx[4]; __shared__ float ssum[4];
  __shared__ float fm; __shared__ int fi;
  if (lane == 0) { smax[wid] = mv; sidx[wid] = mi; }
  __syncthreads();
  if (t == 0) {
    float bm = smax[0]; int bi = sidx[0];
    for (int wq = 1; wq < 4; ++wq)
      if (smax[wq] > bm || (smax[wq] == bm && sidx[wq] < bi)) { bm = smax[wq]; bi = sidx[wq]; }
    fm = bm; fi = bi;
  }
  __syncthreads();
  const float Mx = fm;
  float se = 0.f;
#pragma unroll
  for (int q = 0; q < 16; ++q) se += expf(vals[q] - Mx);
#pragma unroll
  for (int off = 1; off < 64; off <<= 1) se += __shfl_xor(se, off);
  if (lane == 0) ssum[wid] = se;
  __syncthreads();
  if (t == 0) {
    float tot = ssum[0]+ssum[1]+ssum[2]+ssum[3];
    stats[2*phys]   = Mx;
    stats[2*phys+1] = 1.0f / tot;
    int b = (int)(phys >> 10), s = (int)(phys & 1023);
    codes_tok[s*NB + b] = fi;
    codes_out[phys] = (float)fi;
  }
}

// quant = (hard - soft) + soft, also emit hard
__global__ __launch_bounds__(128)
void quant_k(const float* __restrict__ soft, const int* __restrict__ codes_tok,
             const float* __restrict__ cbT, float* __restrict__ quant,
             float* __restrict__ hardb)
{
  const int r = blockIdx.x;
  const int code = codes_tok[r];
  const int c = threadIdx.x * 4;
  float4 h  = *(const float4*)(cbT + (long)code*CDIM + c);
  float4 sf = *(const float4*)(soft + (long)r*CDIM + c);
  float4 q;
  q.x = (h.x - sf.x) + sf.x; q.y = (h.y - sf.y) + sf.y;
  q.z = (h.z - sf.z) + sf.z; q.w = (h.w - sf.w) + sf.w;
  *(float4*)(quant + (long)r*CDIM + c) = q;
  *(float4*)(hardb + (long)r*CDIM + c) = h;
}

// Detect the storage format of the bool mask buffer.
__global__ void maskdetect_k(const void* __restrict__ mask, int* __restrict__ flag)
{
  const unsigned int* wds = (const unsigned int*)mask;
  int t = threadIdx.x;
  int okI = 1, okF = 1, okL = 1;
  for (int i = t; i < 2048; i += 256) {
    unsigned int u = wds[i];
    if (u > 1u) okI = 0;
    if (u != 0u && u != 0x3F800000u) okF = 0;
    if ((i & 1) ? (u != 0u) : (u > 1u)) okL = 0;
  }
  __shared__ int sI, sF, sL;
  if (t == 0) { sI = 1; sF = 1; sL = 1; }
  __syncthreads();
  if (!okI) atomicAnd(&sI, 0);
  if (!okF) atomicAnd(&sF, 0);
  if (!okL) atomicAnd(&sL, 0);
  __syncthreads();
  if (t == 0) {
    int f;
    if (sI && sL) f = 3;
    else if (sI)  f = 1;
    else if (sF)  f = 2;
    else          f = 0;
    *flag = f;
  }
}

// mixed = mask ? enc_flat : post
__global__ __launch_bounds__(256)
void mixed_k(const float* __restrict__ encf, const float* __restrict__ post,
             const void* __restrict__ mask, const int* __restrict__ flag,
             float* __restrict__ outx)
{
  long gid = (long)blockIdx.x * blockDim.x + threadIdx.x;
  int r = (int)(gid >> 7);
  int c = (int)(gid & 127) * 4;
  int f = *flag;
  bool mv;
  if (f == 0)      mv = ((const unsigned char*)mask)[r] != 0;
  else if (f == 1) mv = ((const int*)mask)[r] != 0;
  else if (f == 3) mv = ((const long long*)mask)[r] != 0;
  else             mv = ((const float*)mask)[r] != 0.0f;
  const float* src = mv ? encf : post;
  *(float4*)(outx + (long)r*CDIM + c) = *(const float4*)(src + (long)r*CDIM + c);
}

// ---------------------------------------------------------------------------
// Host-side wrappers
// ---------------------------------------------------------------------------
// split (encoder chain)
static void sg_b(hipStream_t st, const float* A, const float* W, const float* bias,
                 float* C, int N) {
  hgemm_k<1,true,false,false,false,false><<<dim3(N/128, NTOK/128), 256, 0, st>>>(
      A, W, bias, nullptr, 0, C, N, NTOK, N, CDIM, nullptr);
}
static void sg_br(hipStream_t st, const float* A, const float* W, const float* bias,
                  const float* R, float* C) {
  hgemm_k<1,true,true,false,false,false><<<dim3(CDIM/128, NTOK/128), 256, 0, st>>>(
      A, W, bias, R, CDIM, C, CDIM, NTOK, CDIM, CDIM, nullptr);
}
static void sg_brelu(hipStream_t st, const float* A, const float* W, const float* bias,
                     float* C) {
  hgemm_k<1,true,false,true,false,false><<<dim3(CDIM/128, NTOK/128), 256, 0, st>>>(
      A, W, bias, nullptr, 0, C, CDIM, NTOK, CDIM, CDIM, nullptr);
}
// plain fp16 (decoder / tolerant)
static void hg_b(hipStream_t st, const float* A, const float* W, const float* bias,
                 float* C, int N, int K) {
  hgemm_k<0,true,false,false,false,false><<<dim3(N/128, NTOK/128), 256, 0, st>>>(
      A, W, bias, nullptr, 0, C, N, NTOK, N, K, nullptr);
}
static void hg_br(hipStream_t st, const float* A, const float* W, const float* bias,
                  const float* R, float* C) {
  hgemm_k<0,true,true,false,false,false><<<dim3(CDIM/128, NTOK/128), 256, 0, st>>>(
      A, W, bias, R, CDIM, C, CDIM, NTOK, CDIM, CDIM, nullptr);
}
static void hg_brelu(hipStream_t st, const float* A, const float* W, const float* bias,
                     float* C) {
  hgemm_k<0,true,false,true,false,false><<<dim3(CDIM/128, NTOK/128), 256, 0, st>>>(
      A, W, bias, nullptr, 0, C, CDIM, NTOK, CDIM, CDIM, nullptr);
}

extern "C" void kernel_launch(void* const* d_in, const int* in_sizes, int n_in,
                              void* d_out, int out_size, void* d_ws, size_t ws_size,
                              hipStream_t stream)
{
  const float* x       = (const float*)d_in[0];
  const float* pre_w   = (const float*)d_in[1];
  const float* pre_b   = (const float*)d_in[2];
  const float* post_w  = (const float*)d_in[3];
  const float* post_b  = (const float*)d_in[4];
  const float* cb_w    = (const float*)d_in[5];
  const float* e_qkv_w = (const float*)d_in[6];
  const float* e_qkv_b = (const float*)d_in[7];
  const float* e_o_w   = (const float*)d_in[8];
  const float* e_o_b   = (const float*)d_in[9];
  const float* e_ln1_w = (const float*)d_in[10];
  const float* e_ln1_b = (const float*)d_in[11];
  const float* e_ln2_w = (const float*)d_in[12];
  const float* e_ln2_b = (const float*)d_in[13];
  const float* e_f1_w  = (const float*)d_in[14];
  const float* e_f1_b  = (const float*)d_in[15];
  const float* e_f2_w  = (const float*)d_in[16];
  const float* e_f2_b  = (const float*)d_in[17];
  const float* d_sqkv_w= (const float*)d_in[18];
  const float* d_sqkv_b= (const float*)d_in[19];
  const float* d_so_w  = (const float*)d_in[20];
  const float* d_so_b  = (const float*)d_in[21];
  const float* d_cqkv_w= (const float*)d_in[22];
  const float* d_cqkv_b= (const float*)d_in[23];
  const float* d_co_w  = (const float*)d_in[24];
  const float* d_co_b  = (const float*)d_in[25];
  const float* d_ln1w  = (const float*)d_in[26];
  const float* d_ln1b  = (const float*)d_in[27];
  const float* d_ln2w  = (const float*)d_in[28];
  const float* d_ln2b  = (const float*)d_in[29];
  const float* d_ln3w  = (const float*)d_in[30];
  const float* d_ln3b  = (const float*)d_in[31];
  const float* d_f1w   = (const float*)d_in[32];
  const float* d_f1b   = (const float*)d_in[33];
  const float* d_f2w   = (const float*)d_in[34];
  const float* d_f2b   = (const float*)d_in[35];
  const void*  mask    = d_in[36];

  float* out = (float*)d_out;
  float* o_quant  = out;
  float* o_high   = out + 4194304;
  float* o_softs  = out + 8388608;
  float* o_hards  = out + 12582912;
  float* o_codes  = out + 16777216;
  float* o_logits = out + 16785408;

  float* ws    = (float*)d_ws;
  float* ENC   = ws;
  float* Xb    = ws + TOKC;
  float* T1    = ws + 2*TOKC;
  float* T2    = ws + 3*TOKC;
  float* QKV   = ws + 4*TOKC;
  float* MEMB  = ws + 7*TOKC;
  float* CBT   = ws + 8*TOKC;
  float* STATS = CBT + (long)KCB*CDIM;
  int*   CODES = (int*)(STATS + 2*NTOK);
  int*   FLAG  = CODES + NTOK;
  float* HARDB = QKV;
  float* QUANT = QKV + TOKC;

  const size_t NEED = (size_t)(8*TOKC + (long)KCB*CDIM + 2*NTOK + NTOK + 16) * 4;
  if (ws_size < NEED) return;

  const int M = NTOK;
  dim3 tgrid(S_LEN/32, CDIM/32, NB), tblk(32, 8);
  dim3 agrid(S_LEN/128, NB*8);

  pack_pe_k<<<tgrid, tblk, 0, stream>>>(x, ENC, Xb);
  cbt_k<<<dim3(KCB/32, CDIM/32), tblk, 0, stream>>>(cb_w, CBT);
  maskdetect_k<<<1, 256, 0, stream>>>(mask, FLAG);

  // -------- encoder (split-fp16 MFMA, argmax-critical) --------
  for (int i = 0; i < NLAYER; ++i) {
    sg_b(stream, Xb, e_qkv_w + (long)i*3*CDIM*CDIM, e_qkv_b + i*3*CDIM, QKV, 3*CDIM);
    mattn_k<1><<<agrid, 256, 0, stream>>>(QKV, 3*CDIM, QKV+CDIM, 3*CDIM, QKV+2*CDIM, 3*CDIM, T1, CDIM);
    sg_br(stream, T1, e_o_w + (long)i*CDIM*CDIM, e_o_b + i*CDIM, Xb, T2);
    ln_k<<<M/4, 256, 0, stream>>>(T2, e_ln1_w + i*CDIM, e_ln1_b + i*CDIM, T1);
    sg_brelu(stream, T1, e_f1_w + (long)i*CDIM*CDIM, e_f1_b + i*CDIM, QKV);
    sg_br(stream, QKV, e_f2_w + (long)i*CDIM*CDIM, e_f2_b + i*CDIM, T1, T2);
    ln_k<<<M/4, 256, 0, stream>>>(T2, e_ln2_w + i*CDIM, e_ln2_b + i*CDIM, Xb);
  }

  // -------- codebook / quantizer --------
  sg_b(stream, Xb, pre_w, pre_b, T1, CDIM);                                  // pre (split)
  tpose_k<<<tgrid, tblk, 0, stream>>>(T1, o_high);
  hgemm_k<1,false,false,false,false,true><<<dim3(KCB/128, M/128), 256, 0, stream>>>(
      T1, CBT, nullptr, nullptr, 0, o_logits, KCB, M, KCB, CDIM, nullptr);   // sim (split)
  simstats_k<<<NTOK, 256, 0, stream>>>(o_logits, STATS, CODES, o_codes);
  hgemm_k<0,false,false,false,true,false><<<dim3(CDIM/128, M/128), 256, 0, stream>>>(
      o_logits, cb_w, nullptr, nullptr, 0, T2, CDIM, M, CDIM, KCB, STATS);   // soft (f16)
  tpose_k<<<tgrid, tblk, 0, stream>>>(T2, o_softs);
  quant_k<<<NTOK, 128, 0, stream>>>(T2, CODES, CBT, QUANT, HARDB);
  tpose_k<<<tgrid, tblk, 0, stream>>>(HARDB, o_hards);
  hg_b(stream, QUANT, post_w, post_b, MEMB, CDIM, CDIM);                     // post (f16)
  mixed_k<<<4096, 256, 0, stream>>>(ENC, MEMB, mask, FLAG, Xb);

  // -------- decoder (f16 MFMA) --------
  for (int i = 0; i < NLAYER; ++i) {
    hg_b(stream, Xb, d_sqkv_w + (long)i*3*CDIM*CDIM, d_sqkv_b + i*3*CDIM, QKV, 3*CDIM, CDIM);
    mattn_k<0><<<agrid, 256, 0, stream>>>(QKV, 3*CDIM, QKV+CDIM, 3*CDIM, QKV+2*CDIM, 3*CDIM, T1, CDIM);
    hg_br(stream, T1, d_so_w + (long)i*CDIM*CDIM, d_so_b + i*CDIM, Xb, T2);
    ln_k<<<M/4, 256, 0, stream>>>(T2, d_ln1w + i*CDIM, d_ln1b + i*CDIM, Xb);
    hg_b(stream, Xb, d_cqkv_w + (long)i*3*CDIM*CDIM, d_cqkv_b + i*3*CDIM, QKV, CDIM, CDIM);
    hgemm_k<0,true,false,false,false,false><<<dim3(2*CDIM/128, M/128), 256, 0, stream>>>(
        MEMB, d_cqkv_w + (long)i*3*CDIM*CDIM + (long)CDIM*CDIM,
        d_cqkv_b + i*3*CDIM + CDIM, nullptr, 0, QKV + TOKC, 2*CDIM, M, 2*CDIM, CDIM, nullptr);
    mattn_k<0><<<agrid, 256, 0, stream>>>(QKV, CDIM, QKV+TOKC, 2*CDIM, QKV+TOKC+CDIM, 2*CDIM, T1, CDIM);
    hg_br(stream, T1, d_co_w + (long)i*CDIM*CDIM, d_co_b + i*CDIM, Xb, T2);
    ln_k<<<M/4, 256, 0, stream>>>(T2, d_ln2w + i*CDIM, d_ln2b + i*CDIM, Xb);
    hg_brelu(stream, Xb, d_f1w + (long)i*CDIM*CDIM, d_f1b + i*CDIM, QKV);
    hg_br(stream, QKV, d_f2w + (long)i*CDIM*CDIM, d_f2b + i*CDIM, Xb, T2);
    ln_k<<<M/4, 256, 0, stream>>>(T2, d_ln3w + i*CDIM, d_ln3b + i*CDIM, Xb);
  }
  tpose_k<<<tgrid, tblk, 0, stream>>>(Xb, o_quant);
}

// Round 4
// 5145.030 us; speedup vs baseline: 2.4365x; 1.0056x over previous
//
#include <hip/hip_runtime.h>
#include <math.h>

#define S_LEN 1024
#define NB 8
#define CDIM 512
#define KCB 4096
#define DH 64
#define NLAYER 6
#define NTOK (S_LEN*NB)
#define TOKC ((long)NTOK*CDIM)

typedef __attribute__((ext_vector_type(8))) _Float16 f16x8;
typedef __attribute__((ext_vector_type(4))) _Float16 f16x4;
typedef __attribute__((ext_vector_type(2))) _Float16 f16x2;
typedef __attribute__((ext_vector_type(4))) float f32x4;

// ---------------------------------------------------------------------------
// MFMA GEMM: C[M,N] = A[M,K] @ W[N,K]^T (+bias/res/relu).
// TM in {64,128} (M-tile); N-tile fixed 128. 4 waves: (wm,wn) own
// (TM/2)x64 each, MI = TM/32 m-fragments. BK=64, mfma_f32_16x16x32_f16.
// SPLIT=1: hi/lo split-fp16, 3 MFMAs/pair (hh, h*lo, lo*h) ~ fp32 accuracy.
// F16IN=1: A and W already _Float16 in global (soft path), SPLIT must be 0.
// OREMAP: output row (s*NB+b) -> (b*S_LEN+s)  (sim -> logits layout).
// LDS XOR-swizzled: byte ^= (row&7)<<4.
// ---------------------------------------------------------------------------
template<int TM, int SPLIT, int F16IN, bool BIAS, bool RES, bool RELU, bool OREMAP>
__global__ __launch_bounds__(256)
void hgemm_k(const void* __restrict__ Av, const void* __restrict__ Wv,
             const float* __restrict__ bias, const float* __restrict__ Rsrc, int ldr,
             float* __restrict__ C, int ldc, int M, int N, int K)
{
  constexpr int MI = TM / 32;
  constexpr int ATPR = 256 / TM;     // threads per A row (2 or 4)
  constexpr int ACOL = 64 / ATPR;    // elems per thread (32 or 16)
  __shared__ __align__(16) _Float16 Ah[TM*64];
  __shared__ __align__(16) _Float16 Bh[128*64];
  __shared__ __align__(16) _Float16 Al[SPLIT ? TM*64 : 8];
  __shared__ __align__(16) _Float16 Bl[SPLIT ? 128*64 : 8];
  const int t = threadIdx.x;
  const int m0 = blockIdx.y * TM, n0 = blockIdx.x * 128;

  const int arow = t / ATPR, apart = t % ATPR;
  const int brow = t >> 1, bpart = t & 1;

  const float*    Af = (const float*)Av;
  const _Float16* Axh = (const _Float16*)Av;
  const float*    Wf = (const float*)Wv;
  const _Float16* Wxh = (const _Float16*)Wv;
  const long aoff = (long)(m0 + arow) * K + apart * ACOL;
  const long boff = (long)(n0 + brow) * K + bpart * 32;

  const int lane = t & 63, wave = t >> 6;
  const int wm = wave >> 1, wn = wave & 1;
  const int lr = lane & 15, lk = lane >> 4;

  f32x4 acc[MI][4];
#pragma unroll
  for (int mi = 0; mi < MI; ++mi)
#pragma unroll
    for (int ni = 0; ni < 4; ++ni)
#pragma unroll
      for (int e = 0; e < 4; ++e) acc[mi][ni][e] = 0.f;

  float4 a4[ACOL/4], b4[8];
  f16x8  a16[ACOL/8], b16[4];
  if (F16IN) {
#pragma unroll
    for (int g = 0; g < ACOL/8; ++g) a16[g] = *(const f16x8*)(Axh + aoff + g*8);
#pragma unroll
    for (int g = 0; g < 4; ++g) b16[g] = *(const f16x8*)(Wxh + boff + g*8);
  } else {
#pragma unroll
    for (int j = 0; j < ACOL/4; ++j) a4[j] = *(const float4*)(Af + aoff + j*4);
#pragma unroll
    for (int j = 0; j < 8; ++j) b4[j] = *(const float4*)(Wf + boff + j*4);
  }

  for (int k0 = 0; k0 < K; k0 += 64) {
    __syncthreads();
    if (F16IN) {
#pragma unroll
      for (int g = 0; g < ACOL/8; ++g) {
        const int sw = (apart*ACOL*2 + g*16) ^ ((arow & 7) << 4);
        *(f16x8*)((char*)Ah + arow*128 + sw) = a16[g];
      }
#pragma unroll
      for (int g = 0; g < 4; ++g) {
        const int sw = (bpart*64 + g*16) ^ ((brow & 7) << 4);
        *(f16x8*)((char*)Bh + brow*128 + sw) = b16[g];
      }
    } else {
      const float* af = (const float*)a4;
#pragma unroll
      for (int g = 0; g < ACOL/8; ++g) {
        f16x8 h, l;
#pragma unroll
        for (int j = 0; j < 8; ++j) {
          float xv = af[g*8+j];
          _Float16 hh = (_Float16)xv;
          h[j] = hh;
          if (SPLIT) l[j] = (_Float16)(xv - (float)hh);
        }
        const int sw = (apart*ACOL*2 + g*16) ^ ((arow & 7) << 4);
        *(f16x8*)((char*)Ah + arow*128 + sw) = h;
        if (SPLIT) *(f16x8*)((char*)Al + arow*128 + sw) = l;
      }
      const float* bf = (const float*)b4;
#pragma unroll
      for (int g = 0; g < 4; ++g) {
        f16x8 h, l;
#pragma unroll
        for (int j = 0; j < 8; ++j) {
          float xv = bf[g*8+j];
          _Float16 hh = (_Float16)xv;
          h[j] = hh;
          if (SPLIT) l[j] = (_Float16)(xv - (float)hh);
        }
        const int sw = (bpart*64 + g*16) ^ ((brow & 7) << 4);
        *(f16x8*)((char*)Bh + brow*128 + sw) = h;
        if (SPLIT) *(f16x8*)((char*)Bl + brow*128 + sw) = l;
      }
    }
    __syncthreads();
    if (k0 + 64 < K) {
      if (F16IN) {
#pragma unroll
        for (int g = 0; g < ACOL/8; ++g) a16[g] = *(const f16x8*)(Axh + aoff + k0 + 64 + g*8);
#pragma unroll
        for (int g = 0; g < 4; ++g) b16[g] = *(const f16x8*)(Wxh + boff + k0 + 64 + g*8);
      } else {
#pragma unroll
        for (int j = 0; j < ACOL/4; ++j) a4[j] = *(const float4*)(Af + aoff + k0 + 64 + j*4);
#pragma unroll
        for (int j = 0; j < 8; ++j) b4[j] = *(const float4*)(Wf + boff + k0 + 64 + j*4);
      }
    }
#pragma unroll
    for (int kk = 0; kk < 2; ++kk) {
      f16x8 afh[MI], bfh[4], afl[MI], bfl[4];
#pragma unroll
      for (int mi = 0; mi < MI; ++mi) {
        const int r = wm*(TM/2) + mi*16 + lr;
        const int bo = (lk*16 + kk*64) ^ ((r & 7) << 4);
        afh[mi] = *(const f16x8*)((const char*)Ah + r*128 + bo);
        if (SPLIT) afl[mi] = *(const f16x8*)((const char*)Al + r*128 + bo);
      }
#pragma unroll
      for (int ni = 0; ni < 4; ++ni) {
        const int r = wn*64 + ni*16 + lr;
        const int bo = (lk*16 + kk*64) ^ ((r & 7) << 4);
        bfh[ni] = *(const f16x8*)((const char*)Bh + r*128 + bo);
        if (SPLIT) bfl[ni] = *(const f16x8*)((const char*)Bl + r*128 + bo);
      }
#pragma unroll
      for (int mi = 0; mi < MI; ++mi)
#pragma unroll
        for (int ni = 0; ni < 4; ++ni) {
          acc[mi][ni] = __builtin_amdgcn_mfma_f32_16x16x32_f16(afh[mi], bfh[ni], acc[mi][ni], 0, 0, 0);
          if (SPLIT) {
            acc[mi][ni] = __builtin_amdgcn_mfma_f32_16x16x32_f16(afh[mi], bfl[ni], acc[mi][ni], 0, 0, 0);
            acc[mi][ni] = __builtin_amdgcn_mfma_f32_16x16x32_f16(afl[mi], bfh[ni], acc[mi][ni], 0, 0, 0);
          }
        }
    }
  }

  float bvv[4];
  if (BIAS) {
#pragma unroll
    for (int ni = 0; ni < 4; ++ni) bvv[ni] = bias[n0 + wn*64 + ni*16 + lr];
  }
#pragma unroll
  for (int mi = 0; mi < MI; ++mi)
#pragma unroll
  for (int i = 0; i < 4; ++i) {
    const int rm = m0 + wm*(TM/2) + mi*16 + lk*4 + i;
    long orow = rm;
    if (OREMAP) orow = (long)(rm & (NB-1)) * S_LEN + (rm >> 3);
#pragma unroll
    for (int ni = 0; ni < 4; ++ni) {
      const int col = n0 + wn*64 + ni*16 + lr;
      float v = acc[mi][ni][i];
      if (BIAS) v += bvv[ni];
      if (RES)  v += Rsrc[(long)rm*ldr + col];
      if (RELU) v = fmaxf(v, 0.f);
      C[orow*(long)ldc + col] = v;
    }
  }
}

// ---------------------------------------------------------------------------
// MFMA flash attention. Block = 128 q rows x one (b,head); 4 waves x 32 rows.
// SPLIT=1: hi/lo split-fp16, 3 MFMAs/pair (lo*lo dropped).
// ---------------------------------------------------------------------------
template<int SPLIT>
__global__ __launch_bounds__(256)
void mattn_k(const float* __restrict__ Qp, int ldq,
             const float* __restrict__ Kp, int ldk,
             const float* __restrict__ Vp, int ldv,
             float* __restrict__ Op, int ldo)
{
  __shared__ __align__(16) char QP[SPLIT ? 32768 : 16384];  // Q then P
  __shared__ __align__(16) _Float16 Kh[64*64];
  __shared__ __align__(16) _Float16 Vh[64*64];
  __shared__ __align__(16) _Float16 Kl[SPLIT ? 64*64 : 8];
  __shared__ __align__(16) _Float16 Vl[SPLIT ? 64*64 : 8];

  const int t = threadIdx.x;
  const int b = blockIdx.y >> 3, hd = blockIdx.y & 7;
  const int s0 = blockIdx.x * 128;
  const int qoff = hd * DH;
  const int wave = t >> 6, lane = t & 63;
  const int lr = lane & 15, lk = lane >> 4;

  // ---- stage Q (once) ----
  {
    const int row = t >> 1, sh = t & 1;
    const float* qrow = Qp + ((long)(s0 + row) * NB + b) * ldq + qoff + sh*32;
    float4 q4[8];
#pragma unroll
    for (int j = 0; j < 8; ++j) q4[j] = *(const float4*)(qrow + j*4);
    const float* qf = (const float*)q4;
#pragma unroll
    for (int c2 = 0; c2 < 4; ++c2) {
      f16x8 h, l;
#pragma unroll
      for (int j = 0; j < 8; ++j) {
        float xv = qf[c2*8+j];
        _Float16 hh = (_Float16)xv;
        h[j] = hh;
        if (SPLIT) l[j] = (_Float16)(xv - (float)hh);
      }
      const int sw = (sh*64 + c2*16) ^ ((row & 7) << 4);
      *(f16x8*)(QP + row*128 + sw) = h;
      if (SPLIT) *(f16x8*)(QP + 16384 + row*128 + sw) = l;
    }
  }
  __syncthreads();

  f16x8 qa[2][2], qal[2][2];
#pragma unroll
  for (int mi = 0; mi < 2; ++mi)
#pragma unroll
    for (int kk = 0; kk < 2; ++kk) {
      const int r = wave*32 + mi*16 + lr;
      const int bo = (lk*16 + kk*64) ^ ((r & 7) << 4);
      qa[mi][kk] = *(const f16x8*)(QP + r*128 + bo);
      if (SPLIT) qal[mi][kk] = *(const f16x8*)(QP + 16384 + r*128 + bo);
    }

  float m_run[2][4], l_run[2][4];
  f32x4 oacc[2][4];
#pragma unroll
  for (int mi = 0; mi < 2; ++mi)
#pragma unroll
    for (int i = 0; i < 4; ++i) {
      m_run[mi][i] = -INFINITY; l_run[mi][i] = 0.f;
#pragma unroll
      for (int ni = 0; ni < 4; ++ni) oacc[mi][ni][i] = 0.f;
    }

  char* Pw  = QP + wave*4096;
  char* Pwl = QP + 16384 + wave*4096;

  for (int t0 = 0; t0 < S_LEN; t0 += 64) {
    __syncthreads();
    // ---- stage K [key][d] ----
    {
      const int row = t >> 2, qd = t & 3;
      const float* krow = Kp + ((long)(t0 + row) * NB + b) * ldk + qoff + qd*16;
      float4 k4[4];
#pragma unroll
      for (int j = 0; j < 4; ++j) k4[j] = *(const float4*)(krow + j*4);
      const float* kf = (const float*)k4;
#pragma unroll
      for (int c = 0; c < 2; ++c) {
        f16x8 h, l;
#pragma unroll
        for (int j = 0; j < 8; ++j) {
          float xv = kf[c*8+j];
          _Float16 hh = (_Float16)xv;
          h[j] = hh;
          if (SPLIT) l[j] = (_Float16)(xv - (float)hh);
        }
        const int sw = (qd*32 + c*16) ^ ((row & 7) << 4);
        *(f16x8*)((char*)Kh + row*128 + sw) = h;
        if (SPLIT) *(f16x8*)((char*)Kl + row*128 + sw) = l;
      }
    }
    // ---- stage V transposed [d][key] ----
    {
      const int tp = t & 31, dc = t >> 5;
      const float* v0 = Vp + ((long)(t0 + 2*tp) * NB + b) * ldv + qoff + dc*8;
      const float* v1 = v0 + (long)NB * ldv;
      float4 va[2], vb2[2];
      va[0] = *(const float4*)(v0); va[1] = *(const float4*)(v0 + 4);
      vb2[0] = *(const float4*)(v1); vb2[1] = *(const float4*)(v1 + 4);
      const float* f0 = (const float*)va;
      const float* f1 = (const float*)vb2;
#pragma unroll
      for (int j = 0; j < 8; ++j) {
        const int dd = dc*8 + j;
        _Float16 h0 = (_Float16)f0[j], h1 = (_Float16)f1[j];
        f16x2 hv = {h0, h1};
        const int sw = (tp*4) ^ ((dd & 7) << 4);
        *(f16x2*)((char*)Vh + dd*128 + sw) = hv;
        if (SPLIT) {
          f16x2 lv = {(_Float16)(f0[j] - (float)h0), (_Float16)(f1[j] - (float)h1)};
          *(f16x2*)((char*)Vl + dd*128 + sw) = lv;
        }
      }
    }
    __syncthreads();

    // ---- S = Q K^T ----
    f32x4 s[2][4];
#pragma unroll
    for (int mi = 0; mi < 2; ++mi)
#pragma unroll
      for (int ni = 0; ni < 4; ++ni)
#pragma unroll
        for (int e = 0; e < 4; ++e) s[mi][ni][e] = 0.f;
#pragma unroll
    for (int kk = 0; kk < 2; ++kk) {
      f16x8 kb[4], kbl[4];
#pragma unroll
      for (int ni = 0; ni < 4; ++ni) {
        const int r = ni*16 + lr;
        const int bo = (lk*16 + kk*64) ^ ((r & 7) << 4);
        kb[ni] = *(const f16x8*)((const char*)Kh + r*128 + bo);
        if (SPLIT) kbl[ni] = *(const f16x8*)((const char*)Kl + r*128 + bo);
      }
#pragma unroll
      for (int mi = 0; mi < 2; ++mi)
#pragma unroll
        for (int ni = 0; ni < 4; ++ni) {
          s[mi][ni] = __builtin_amdgcn_mfma_f32_16x16x32_f16(qa[mi][kk], kb[ni], s[mi][ni], 0, 0, 0);
          if (SPLIT) {
            s[mi][ni] = __builtin_amdgcn_mfma_f32_16x16x32_f16(qa[mi][kk], kbl[ni], s[mi][ni], 0, 0, 0);
            s[mi][ni] = __builtin_amdgcn_mfma_f32_16x16x32_f16(qal[mi][kk], kb[ni], s[mi][ni], 0, 0, 0);
          }
        }
    }
#pragma unroll
    for (int mi = 0; mi < 2; ++mi)
#pragma unroll
      for (int ni = 0; ni < 4; ++ni)
#pragma unroll
        for (int e = 0; e < 4; ++e) s[mi][ni][e] *= 0.125f;

    // ---- online softmax ----
#pragma unroll
    for (int mi = 0; mi < 2; ++mi) {
      float rm[4];
#pragma unroll
      for (int i = 0; i < 4; ++i)
        rm[i] = fmaxf(fmaxf(s[mi][0][i], s[mi][1][i]), fmaxf(s[mi][2][i], s[mi][3][i]));
#pragma unroll
      for (int off = 1; off < 16; off <<= 1)
#pragma unroll
        for (int i = 0; i < 4; ++i) rm[i] = fmaxf(rm[i], __shfl_xor(rm[i], off));
      float rs[4], corr[4];
#pragma unroll
      for (int i = 0; i < 4; ++i) {
        const float mnew = fmaxf(m_run[mi][i], rm[i]);
        corr[i] = expf(m_run[mi][i] - mnew);
        m_run[mi][i] = mnew;
        float lsum = 0.f;
#pragma unroll
        for (int ni = 0; ni < 4; ++ni) {
          float p = expf(s[mi][ni][i] - mnew);
          s[mi][ni][i] = p; lsum += p;
        }
        rs[i] = lsum;
      }
#pragma unroll
      for (int off = 1; off < 16; off <<= 1)
#pragma unroll
        for (int i = 0; i < 4; ++i) rs[i] += __shfl_xor(rs[i], off);
#pragma unroll
      for (int i = 0; i < 4; ++i) {
        l_run[mi][i] = l_run[mi][i]*corr[i] + rs[i];
#pragma unroll
        for (int ni = 0; ni < 4; ++ni) oacc[mi][ni][i] *= corr[i];
      }
    }

    // ---- P -> LDS (wave-private) ----
#pragma unroll
    for (int mi = 0; mi < 2; ++mi)
#pragma unroll
      for (int ni = 0; ni < 4; ++ni)
#pragma unroll
        for (int i = 0; i < 4; ++i) {
          const int row = mi*16 + lk*4 + i;
          const int col = ni*16 + lr;
          const int ad = row*128 + ((col*2) ^ ((row & 7) << 4));
          float pv = s[mi][ni][i];
          _Float16 ph = (_Float16)pv;
          *(_Float16*)(Pw + ad) = ph;
          if (SPLIT) *(_Float16*)(Pwl + ad) = (_Float16)(pv - (float)ph);
        }

    // ---- O += P V ----
#pragma unroll
    for (int kk = 0; kk < 2; ++kk) {
      f16x8 vb[4], vbl[4], pa[2], pal[2];
#pragma unroll
      for (int ni = 0; ni < 4; ++ni) {
        const int r = ni*16 + lr;
        const int bo = (lk*16 + kk*64) ^ ((r & 7) << 4);
        vb[ni] = *(const f16x8*)((const char*)Vh + r*128 + bo);
        if (SPLIT) vbl[ni] = *(const f16x8*)((const char*)Vl + r*128 + bo);
      }
#pragma unroll
      for (int mi = 0; mi < 2; ++mi) {
        const int r = mi*16 + lr;
        const int bo = (lk*16 + kk*64) ^ ((r & 7) << 4);
        pa[mi] = *(const f16x8*)(Pw + r*128 + bo);
        if (SPLIT) pal[mi] = *(const f16x8*)(Pwl + r*128 + bo);
      }
#pragma unroll
      for (int mi = 0; mi < 2; ++mi)
#pragma unroll
        for (int ni = 0; ni < 4; ++ni) {
          oacc[mi][ni] = __builtin_amdgcn_mfma_f32_16x16x32_f16(pa[mi], vb[ni], oacc[mi][ni], 0, 0, 0);
          if (SPLIT) {
            oacc[mi][ni] = __builtin_amdgcn_mfma_f32_16x16x32_f16(pa[mi], vbl[ni], oacc[mi][ni], 0, 0, 0);
            oacc[mi][ni] = __builtin_amdgcn_mfma_f32_16x16x32_f16(pal[mi], vb[ni], oacc[mi][ni], 0, 0, 0);
          }
        }
    }
  }

#pragma unroll
  for (int mi = 0; mi < 2; ++mi)
#pragma unroll
    for (int i = 0; i < 4; ++i) {
      const float inv = 1.0f / l_run[mi][i];
      const int q = s0 + wave*32 + mi*16 + lk*4 + i;
      float* orow = Op + ((long)q * NB + b) * ldo + qoff;
#pragma unroll
      for (int ni = 0; ni < 4; ++ni) orow[ni*16 + lr] = oacc[mi][ni][i] * inv;
    }
}

// ---------------------------------------------------------------------------
// LayerNorm over c=512, one wave per row.
// ---------------------------------------------------------------------------
__global__ __launch_bounds__(256)
void ln_k(const float* __restrict__ X, const float* __restrict__ g,
          const float* __restrict__ bb, float* __restrict__ Y)
{
  const int t = threadIdx.x;
  const int lane = t & 63;
  const long row = (long)blockIdx.x * 4 + (t >> 6);
  const float* xr = X + row * CDIM;
  float4 v0 = *(const float4*)(xr + lane*4);
  float4 v1 = *(const float4*)(xr + 256 + lane*4);
  float s = v0.x+v0.y+v0.z+v0.w + v1.x+v1.y+v1.z+v1.w;
#pragma unroll
  for (int off = 1; off < 64; off <<= 1) s += __shfl_xor(s, off);
  const float mean = s * (1.0f/512.0f);
  float d[8] = {v0.x-mean, v0.y-mean, v0.z-mean, v0.w-mean,
                v1.x-mean, v1.y-mean, v1.z-mean, v1.w-mean};
  float sq = d[0]*d[0]+d[1]*d[1]+d[2]*d[2]+d[3]*d[3]
           + d[4]*d[4]+d[5]*d[5]+d[6]*d[6]+d[7]*d[7];
#pragma unroll
  for (int off = 1; off < 64; off <<= 1) sq += __shfl_xor(sq, off);
  const float inv = 1.0f / sqrtf(sq * (1.0f/512.0f) + 1e-5f);
  float4 g0 = *(const float4*)(g + lane*4);
  float4 g1 = *(const float4*)(g + 256 + lane*4);
  float4 b0 = *(const float4*)(bb + lane*4);
  float4 b1 = *(const float4*)(bb + 256 + lane*4);
  float4 o0, o1;
  o0.x = d[0]*inv*g0.x + b0.x; o0.y = d[1]*inv*g0.y + b0.y;
  o0.z = d[2]*inv*g0.z + b0.z; o0.w = d[3]*inv*g0.w + b0.w;
  o1.x = d[4]*inv*g1.x + b1.x; o1.y = d[5]*inv*g1.y + b1.y;
  o1.z = d[6]*inv*g1.z + b1.z; o1.w = d[7]*inv*g1.w + b1.w;
  *(float4*)(Y + row*CDIM + lane*4) = o0;
  *(float4*)(Y + row*CDIM + 256 + lane*4) = o1;
}

// ---------------------------------------------------------------------------
// Pack x (N,C,H,W) -> enc_flat (S,n,c) and posisted = enc_flat + PE2D.
// ---------------------------------------------------------------------------
__global__ void pack_pe_k(const float* __restrict__ x, float* __restrict__ encf,
                          float* __restrict__ posd)
{
  __shared__ float tl[32][33];
  const int b = blockIdx.z;
  const int s0 = blockIdx.x*32, c0 = blockIdx.y*32;
#pragma unroll
  for (int i = 0; i < 4; ++i) {
    int ci = threadIdx.y + i*8;
    tl[ci][threadIdx.x] = x[((long)b*CDIM + c0+ci)*S_LEN + s0 + threadIdx.x];
  }
  __syncthreads();
#pragma unroll
  for (int i = 0; i < 4; ++i) {
    int si = threadIdx.y + i*8;
    int s = s0 + si;
    int ch = c0 + threadIdx.x;
    float val = tl[threadIdx.x][si];
    long o = ((long)s*NB + b)*CDIM + ch;
    encf[o] = val;
    int pos = (ch < 256) ? (s & 31) : (s >> 5);
    int j = (ch & 255) >> 1;
    float dv = expf((float)(2*j) * (-9.210340371976184f / 256.0f));
    float ang = (float)pos * dv;
    float pe = (ch & 1) ? cosf(ang) : sinf(ang);
    posd[o] = val + pe;
  }
}

// (S,n,c) token-major -> (n,c,S) output layout
__global__ void tpose_k(const float* __restrict__ in, float* __restrict__ out)
{
  __shared__ float tl[32][33];
  const int b = blockIdx.z;
  const int s0 = blockIdx.x*32, c0 = blockIdx.y*32;
#pragma unroll
  for (int i = 0; i < 4; ++i) {
    int si = threadIdx.y + i*8;
    tl[si][threadIdx.x] = in[((long)(s0+si)*NB + b)*CDIM + c0 + threadIdx.x];
  }
  __syncthreads();
#pragma unroll
  for (int i = 0; i < 4; ++i) {
    int ci = threadIdx.y + i*8;
    out[((long)b*CDIM + c0+ci)*S_LEN + s0 + threadIdx.x] = tl[threadIdx.x][ci];
  }
}

// cb_w (c,K) -> cbT (K,c)
__global__ void cbt_k(const float* __restrict__ cb, float* __restrict__ cbT)
{
  __shared__ float tl[32][33];
  const int k0 = blockIdx.x*32, c0 = blockIdx.y*32;
#pragma unroll
  for (int i = 0; i < 4; ++i) {
    int ci = threadIdx.y + i*8;
    tl[ci][threadIdx.x] = cb[(long)(c0+ci)*KCB + k0 + threadIdx.x];
  }
  __syncthreads();
#pragma unroll
  for (int i = 0; i < 4; ++i) {
    int ki = threadIdx.y + i*8;
    cbT[(long)(k0+ki)*CDIM + c0 + threadIdx.x] = tl[threadIdx.x][ki];
  }
}

// fp32 -> fp16 elementwise (cb_w -> CBH), 8 per thread
__global__ __launch_bounds__(256)
void conv16_k(const float* __restrict__ in, _Float16* __restrict__ out)
{
  const long i = ((long)blockIdx.x * 256 + threadIdx.x) * 8;
  float4 v0 = *(const float4*)(in + i);
  float4 v1 = *(const float4*)(in + i + 4);
  f16x8 h;
  h[0]=(_Float16)v0.x; h[1]=(_Float16)v0.y; h[2]=(_Float16)v0.z; h[3]=(_Float16)v0.w;
  h[4]=(_Float16)v1.x; h[5]=(_Float16)v1.y; h[6]=(_Float16)v1.z; h[7]=(_Float16)v1.w;
  *(f16x8*)(out + i) = h;
}

// Per-token row of logits: argmax (np first-occurrence) + write P (fp16)
// P[tok = s*NB+b][k] = exp(v - max) / sum.
__global__ __launch_bounds__(256)
void simstats_k(const float* __restrict__ logits, _Float16* __restrict__ Pbuf,
                int* __restrict__ codes_tok, float* __restrict__ codes_out)
{
  const long phys = blockIdx.x;
  const float* rowp = logits + phys * KCB;
  const int t = threadIdx.x;
  float vals[16];
#pragma unroll
  for (int rep = 0; rep < 4; ++rep) {
    float4 v = *(const float4*)(rowp + rep*1024 + t*4);
    vals[rep*4+0]=v.x; vals[rep*4+1]=v.y; vals[rep*4+2]=v.z; vals[rep*4+3]=v.w;
  }
  float mv = -INFINITY; int mi = 0;
#pragma unroll
  for (int rep = 0; rep < 4; ++rep)
#pragma unroll
    for (int j = 0; j < 4; ++j) {
      float xv = vals[rep*4+j];
      int ix = rep*1024 + t*4 + j;
      if (xv > mv) { mv = xv; mi = ix; }
    }
  const int lane = t & 63, wid = t >> 6;
#pragma unroll
  for (int off = 1; off < 64; off <<= 1) {
    float ov = __shfl_xor(mv, off);
    int   oi = __shfl_xor(mi, off);
    if (ov > mv || (ov == mv && oi < mi)) { mv = ov; mi = oi; }
  }
  __shared__ float smax[4]; __shared__ int sidx[4]; __shared__ float ssum[4];
  __shared__ float fm; __shared__ int fi; __shared__ float sinv;
  if (lane == 0) { smax[wid] = mv; sidx[wid] = mi; }
  __syncthreads();
  if (t == 0) {
    float bm = smax[0]; int bi = sidx[0];
    for (int wq = 1; wq < 4; ++wq)
      if (smax[wq] > bm || (smax[wq] == bm && sidx[wq] < bi)) { bm = smax[wq]; bi = sidx[wq]; }
    fm = bm; fi = bi;
  }
  __syncthreads();
  const float Mx = fm;
  float se = 0.f;
#pragma unroll
  for (int q = 0; q < 16; ++q) se += expf(vals[q] - Mx);
#pragma unroll
  for (int off = 1; off < 64; off <<= 1) se += __shfl_xor(se, off);
  if (lane == 0) ssum[wid] = se;
  __syncthreads();
  const int b = (int)(phys >> 10), s = (int)(phys & 1023);
  if (t == 0) {
    float tot = ssum[0]+ssum[1]+ssum[2]+ssum[3];
    sinv = 1.0f / tot;
    codes_tok[s*NB + b] = fi;
    codes_out[phys] = (float)fi;
  }
  __syncthreads();
  const float inv = sinv;
  _Float16* prow = Pbuf + ((long)s*NB + b) * KCB;
#pragma unroll
  for (int rep = 0; rep < 4; ++rep) {
    f16x4 pv;
#pragma unroll
    for (int j = 0; j < 4; ++j) pv[j] = (_Float16)(expf(vals[rep*4+j] - Mx) * inv);
    *(f16x4*)(prow + rep*1024 + t*4) = pv;
  }
}

// quant = (hard - soft) + soft, also emit hard
__global__ __launch_bounds__(128)
void quant_k(const float* __restrict__ soft, const int* __restrict__ codes_tok,
             const float* __restrict__ cbT, float* __restrict__ quant,
             float* __restrict__ hardb)
{
  const int r = blockIdx.x;
  const int code = codes_tok[r];
  const int c = threadIdx.x * 4;
  float4 h  = *(const float4*)(cbT + (long)code*CDIM + c);
  float4 sf = *(const float4*)(soft + (long)r*CDIM + c);
  float4 q;
  q.x = (h.x - sf.x) + sf.x; q.y = (h.y - sf.y) + sf.y;
  q.z = (h.z - sf.z) + sf.z; q.w = (h.w - sf.w) + sf.w;
  *(float4*)(quant + (long)r*CDIM + c) = q;
  *(float4*)(hardb + (long)r*CDIM + c) = h;
}

// Detect the storage format of the bool mask buffer.
__global__ void maskdetect_k(const void* __restrict__ mask, int* __restrict__ flag)
{
  const unsigned int* wds = (const unsigned int*)mask;
  int t = threadIdx.x;
  int okI = 1, okF = 1, okL = 1;
  for (int i = t; i < 2048; i += 256) {
    unsigned int u = wds[i];
    if (u > 1u) okI = 0;
    if (u != 0u && u != 0x3F800000u) okF = 0;
    if ((i & 1) ? (u != 0u) : (u > 1u)) okL = 0;
  }
  __shared__ int sI, sF, sL;
  if (t == 0) { sI = 1; sF = 1; sL = 1; }
  __syncthreads();
  if (!okI) atomicAnd(&sI, 0);
  if (!okF) atomicAnd(&sF, 0);
  if (!okL) atomicAnd(&sL, 0);
  __syncthreads();
  if (t == 0) {
    int f;
    if (sI && sL) f = 3;
    else if (sI)  f = 1;
    else if (sF)  f = 2;
    else          f = 0;
    *flag = f;
  }
}

// mixed = mask ? enc_flat : post
__global__ __launch_bounds__(256)
void mixed_k(const float* __restrict__ encf, const float* __restrict__ post,
             const void* __restrict__ mask, const int* __restrict__ flag,
             float* __restrict__ outx)
{
  long gid = (long)blockIdx.x * blockDim.x + threadIdx.x;
  int r = (int)(gid >> 7);
  int c = (int)(gid & 127) * 4;
  int f = *flag;
  bool mv;
  if (f == 0)      mv = ((const unsigned char*)mask)[r] != 0;
  else if (f == 1) mv = ((const int*)mask)[r] != 0;
  else if (f == 3) mv = ((const long long*)mask)[r] != 0;
  else             mv = ((const float*)mask)[r] != 0.0f;
  const float* src = mv ? encf : post;
  *(float4*)(outx + (long)r*CDIM + c) = *(const float4*)(src + (long)r*CDIM + c);
}

// ---------------------------------------------------------------------------
// Host-side wrappers
// ---------------------------------------------------------------------------
// split (encoder chain)
static void sg_b(hipStream_t st, const float* A, const float* W, const float* bias,
                 float* C, int N) {            // TM=128, for N>=1024
  hgemm_k<128,1,0,true,false,false,false><<<dim3(N/128, NTOK/128), 256, 0, st>>>(
      A, W, bias, nullptr, 0, C, N, NTOK, N, CDIM);
}
static void sg64_b(hipStream_t st, const float* A, const float* W, const float* bias,
                   float* C) {
  hgemm_k<64,1,0,true,false,false,false><<<dim3(CDIM/128, NTOK/64), 256, 0, st>>>(
      A, W, bias, nullptr, 0, C, CDIM, NTOK, CDIM, CDIM);
}
static void sg64_br(hipStream_t st, const float* A, const float* W, const float* bias,
                    const float* R, float* C) {
  hgemm_k<64,1,0,true,true,false,false><<<dim3(CDIM/128, NTOK/64), 256, 0, st>>>(
      A, W, bias, R, CDIM, C, CDIM, NTOK, CDIM, CDIM);
}
static void sg64_brelu(hipStream_t st, const float* A, const float* W, const float* bias,
                       float* C) {
  hgemm_k<64,1,0,true,false,true,false><<<dim3(CDIM/128, NTOK/64), 256, 0, st>>>(
      A, W, bias, nullptr, 0, C, CDIM, NTOK, CDIM, CDIM);
}
// plain fp16 (decoder / tolerant)
static void hg_b(hipStream_t st, const float* A, const float* W, const float* bias,
                 float* C, int N, int K) {     // TM=128, for N>=1024
  hgemm_k<128,0,0,true,false,false,false><<<dim3(N/128, NTOK/128), 256, 0, st>>>(
      A, W, bias, nullptr, 0, C, N, NTOK, N, K);
}
static void hg64_b(hipStream_t st, const float* A, const float* W, const float* bias,
                   float* C) {
  hgemm_k<64,0,0,true,false,false,false><<<dim3(CDIM/128, NTOK/64), 256, 0, st>>>(
      A, W, bias, nullptr, 0, C, CDIM, NTOK, CDIM, CDIM);
}
static void hg64_br(hipStream_t st, const float* A, const float* W, const float* bias,
                    const float* R, float* C) {
  hgemm_k<64,0,0,true,true,false,false><<<dim3(CDIM/128, NTOK/64), 256, 0, st>>>(
      A, W, bias, R, CDIM, C, CDIM, NTOK, CDIM, CDIM);
}
static void hg64_brelu(hipStream_t st, const float* A, const float* W, const float* bias,
                       float* C) {
  hgemm_k<64,0,0,true,false,true,false><<<dim3(CDIM/128, NTOK/64), 256, 0, st>>>(
      A, W, bias, nullptr, 0, C, CDIM, NTOK, CDIM, CDIM);
}

extern "C" void kernel_launch(void* const* d_in, const int* in_sizes, int n_in,
                              void* d_out, int out_size, void* d_ws, size_t ws_size,
                              hipStream_t stream)
{
  const float* x       = (const float*)d_in[0];
  const float* pre_w   = (const float*)d_in[1];
  const float* pre_b   = (const float*)d_in[2];
  const float* post_w  = (const float*)d_in[3];
  const float* post_b  = (const float*)d_in[4];
  const float* cb_w    = (const float*)d_in[5];
  const float* e_qkv_w = (const float*)d_in[6];
  const float* e_qkv_b = (const float*)d_in[7];
  const float* e_o_w   = (const float*)d_in[8];
  const float* e_o_b   = (const float*)d_in[9];
  const float* e_ln1_w = (const float*)d_in[10];
  const float* e_ln1_b = (const float*)d_in[11];
  const float* e_ln2_w = (const float*)d_in[12];
  const float* e_ln2_b = (const float*)d_in[13];
  const float* e_f1_w  = (const float*)d_in[14];
  const float* e_f1_b  = (const float*)d_in[15];
  const float* e_f2_w  = (const float*)d_in[16];
  const float* e_f2_b  = (const float*)d_in[17];
  const float* d_sqkv_w= (const float*)d_in[18];
  const float* d_sqkv_b= (const float*)d_in[19];
  const float* d_so_w  = (const float*)d_in[20];
  const float* d_so_b  = (const float*)d_in[21];
  const float* d_cqkv_w= (const float*)d_in[22];
  const float* d_cqkv_b= (const float*)d_in[23];
  const float* d_co_w  = (const float*)d_in[24];
  const float* d_co_b  = (const float*)d_in[25];
  const float* d_ln1w  = (const float*)d_in[26];
  const float* d_ln1b  = (const float*)d_in[27];
  const float* d_ln2w  = (const float*)d_in[28];
  const float* d_ln2b  = (const float*)d_in[29];
  const float* d_ln3w  = (const float*)d_in[30];
  const float* d_ln3b  = (const float*)d_in[31];
  const float* d_f1w   = (const float*)d_in[32];
  const float* d_f1b   = (const float*)d_in[33];
  const float* d_f2w   = (const float*)d_in[34];
  const float* d_f2b   = (const float*)d_in[35];
  const void*  mask    = d_in[36];

  float* out = (float*)d_out;
  float* o_quant  = out;
  float* o_high   = out + 4194304;
  float* o_softs  = out + 8388608;
  float* o_hards  = out + 12582912;
  float* o_codes  = out + 16777216;
  float* o_logits = out + 16785408;

  float* ws    = (float*)d_ws;
  float* ENC   = ws;
  float* Xb    = ws + TOKC;
  float* T1    = ws + 2*TOKC;
  float* T2    = ws + 3*TOKC;
  float* QKV   = ws + 4*TOKC;
  float* MEMB  = ws + 7*TOKC;
  float* CBT   = ws + 8*TOKC;
  int*   CODES = (int*)(CBT + (long)KCB*CDIM);
  int*   FLAG  = CODES + NTOK;
  float* HARDB = QKV;
  float* QUANT = QKV + TOKC;
  _Float16* PBUF = (_Float16*)QKV;           // 8192*4096 halves == 4*TOKC floats
  _Float16* CBH  = (_Float16*)T1;            // aliases T1 (dead during soft)

  const size_t NEED = (size_t)(8*TOKC + (long)KCB*CDIM + 2*NTOK + NTOK + 16) * 4;
  if (ws_size < NEED) return;

  const int M = NTOK;
  dim3 tgrid(S_LEN/32, CDIM/32, NB), tblk(32, 8);
  dim3 agrid(S_LEN/128, NB*8);

  pack_pe_k<<<tgrid, tblk, 0, stream>>>(x, ENC, Xb);
  cbt_k<<<dim3(KCB/32, CDIM/32), tblk, 0, stream>>>(cb_w, CBT);
  maskdetect_k<<<1, 256, 0, stream>>>(mask, FLAG);

  // -------- encoder (split-fp16 MFMA, argmax-critical) --------
  for (int i = 0; i < NLAYER; ++i) {
    sg_b(stream, Xb, e_qkv_w + (long)i*3*CDIM*CDIM, e_qkv_b + i*3*CDIM, QKV, 3*CDIM);
    mattn_k<1><<<agrid, 256, 0, stream>>>(QKV, 3*CDIM, QKV+CDIM, 3*CDIM, QKV+2*CDIM, 3*CDIM, T1, CDIM);
    sg64_br(stream, T1, e_o_w + (long)i*CDIM*CDIM, e_o_b + i*CDIM, Xb, T2);
    ln_k<<<M/4, 256, 0, stream>>>(T2, e_ln1_w + i*CDIM, e_ln1_b + i*CDIM, T1);
    sg64_brelu(stream, T1, e_f1_w + (long)i*CDIM*CDIM, e_f1_b + i*CDIM, QKV);
    sg64_br(stream, QKV, e_f2_w + (long)i*CDIM*CDIM, e_f2_b + i*CDIM, T1, T2);
    ln_k<<<M/4, 256, 0, stream>>>(T2, e_ln2_w + i*CDIM, e_ln2_b + i*CDIM, Xb);
  }

  // -------- codebook / quantizer --------
  sg64_b(stream, Xb, pre_w, pre_b, T1);                                      // pre (split)
  tpose_k<<<tgrid, tblk, 0, stream>>>(T1, o_high);
  hgemm_k<128,1,0,false,false,false,true><<<dim3(KCB/128, M/128), 256, 0, stream>>>(
      T1, CBT, nullptr, nullptr, 0, o_logits, KCB, M, KCB, CDIM);            // sim (split)
  conv16_k<<<(CDIM*(long)KCB)/(256*8), 256, 0, stream>>>(cb_w, CBH);
  simstats_k<<<NTOK, 256, 0, stream>>>(o_logits, PBUF, CODES, o_codes);
  hgemm_k<64,0,1,false,false,false,false><<<dim3(CDIM/128, M/64), 256, 0, stream>>>(
      PBUF, CBH, nullptr, nullptr, 0, T2, CDIM, M, CDIM, KCB);               // soft (fp16 in)
  tpose_k<<<tgrid, tblk, 0, stream>>>(T2, o_softs);
  quant_k<<<NTOK, 128, 0, stream>>>(T2, CODES, CBT, QUANT, HARDB);
  tpose_k<<<tgrid, tblk, 0, stream>>>(HARDB, o_hards);
  hg64_b(stream, QUANT, post_w, post_b, MEMB);                               // post (f16)
  mixed_k<<<4096, 256, 0, stream>>>(ENC, MEMB, mask, FLAG, Xb);

  // -------- decoder (f16 MFMA) --------
  for (int i = 0; i < NLAYER; ++i) {
    hg_b(stream, Xb, d_sqkv_w + (long)i*3*CDIM*CDIM, d_sqkv_b + i*3*CDIM, QKV, 3*CDIM, CDIM);
    mattn_k<0><<<agrid, 256, 0, stream>>>(QKV, 3*CDIM, QKV+CDIM, 3*CDIM, QKV+2*CDIM, 3*CDIM, T1, CDIM);
    hg64_br(stream, T1, d_so_w + (long)i*CDIM*CDIM, d_so_b + i*CDIM, Xb, T2);
    ln_k<<<M/4, 256, 0, stream>>>(T2, d_ln1w + i*CDIM, d_ln1b + i*CDIM, Xb);
    hg64_b(stream, Xb, d_cqkv_w + (long)i*3*CDIM*CDIM, d_cqkv_b + i*3*CDIM, QKV);
    hg_b(stream, MEMB, d_cqkv_w + (long)i*3*CDIM*CDIM + (long)CDIM*CDIM,
         d_cqkv_b + i*3*CDIM + CDIM, QKV + TOKC, 2*CDIM, CDIM);
    mattn_k<0><<<agrid, 256, 0, stream>>>(QKV, CDIM, QKV+TOKC, 2*CDIM, QKV+TOKC+CDIM, 2*CDIM, T1, CDIM);
    hg64_br(stream, T1, d_co_w + (long)i*CDIM*CDIM, d_co_b + i*CDIM, Xb, T2);
    ln_k<<<M/4, 256, 0, stream>>>(T2, d_ln2w + i*CDIM, d_ln2b + i*CDIM, Xb);
    hg64_brelu(stream, Xb, d_f1w + (long)i*CDIM*CDIM, d_f1b + i*CDIM, QKV);
    hg64_br(stream, QKV, d_f2w + (long)i*CDIM*CDIM, d_f2b + i*CDIM, Xb, T2);
    ln_k<<<M/4, 256, 0, stream>>>(T2, d_ln3w + i*CDIM, d_ln3b + i*CDIM, Xb);
  }
  tpose_k<<<tgrid, tblk, 0, stream>>>(Xb, o_quant);
}

// Round 5
// 4562.107 us; speedup vs baseline: 2.7478x; 1.1278x over previous
//
#include <hip/hip_runtime.h>
#include <math.h>

#define S_LEN 1024
#define NB 8
#define CDIM 512
#define KCB 4096
#define DH 64
#define NLAYER 6
#define NTOK (S_LEN*NB)
#define TOKC ((long)NTOK*CDIM)

typedef __attribute__((ext_vector_type(8))) _Float16 f16x8;
typedef __attribute__((ext_vector_type(4))) _Float16 f16x4;
typedef __attribute__((ext_vector_type(2))) _Float16 f16x2;
typedef __attribute__((ext_vector_type(4))) float f32x4;

// ---------------------------------------------------------------------------
// MFMA GEMM: C[M,N] = A[M,K] @ W[N,K]^T (+bias/res/relu).
// TM in {64,128}; N-tile 128. BK=64, mfma_f32_16x16x32_f16, XOR-swizzled LDS.
// SPLIT=1: hi/lo split-fp16, 3 MFMAs/pair (~fp32 accuracy).
// F16IN=1: A,W already fp16 (soft path).
// E16=1: epilogue writes fp16 hi (Ch) and, if SPLIT, lo (Cl) instead of fp32 C.
// OREMAP: output row (s*NB+b) -> (b*S_LEN+s).
// ---------------------------------------------------------------------------
template<int TM, int SPLIT, int F16IN, bool BIAS, bool RES, bool RELU, bool OREMAP, bool E16>
__global__ __launch_bounds__(256)
void hgemm_k(const void* __restrict__ Av, const void* __restrict__ Wv,
             const float* __restrict__ bias, const float* __restrict__ Rsrc, int ldr,
             float* __restrict__ C, int ldc, int M, int N, int K,
             _Float16* __restrict__ Ch16, _Float16* __restrict__ Cl16)
{
  constexpr int MI = TM / 32;
  constexpr int ATPR = 256 / TM;
  constexpr int ACOL = 64 / ATPR;
  __shared__ __align__(16) _Float16 Ah[TM*64];
  __shared__ __align__(16) _Float16 Bh[128*64];
  __shared__ __align__(16) _Float16 Al[SPLIT ? TM*64 : 8];
  __shared__ __align__(16) _Float16 Bl[SPLIT ? 128*64 : 8];
  const int t = threadIdx.x;
  const int m0 = blockIdx.y * TM, n0 = blockIdx.x * 128;

  const int arow = t / ATPR, apart = t % ATPR;
  const int brow = t >> 1, bpart = t & 1;

  const float*    Af = (const float*)Av;
  const _Float16* Axh = (const _Float16*)Av;
  const float*    Wf = (const float*)Wv;
  const _Float16* Wxh = (const _Float16*)Wv;
  const long aoff = (long)(m0 + arow) * K + apart * ACOL;
  const long boff = (long)(n0 + brow) * K + bpart * 32;

  const int lane = t & 63, wave = t >> 6;
  const int wm = wave >> 1, wn = wave & 1;
  const int lr = lane & 15, lk = lane >> 4;

  f32x4 acc[MI][4];
#pragma unroll
  for (int mi = 0; mi < MI; ++mi)
#pragma unroll
    for (int ni = 0; ni < 4; ++ni)
#pragma unroll
      for (int e = 0; e < 4; ++e) acc[mi][ni][e] = 0.f;

  float4 a4[ACOL/4], b4[8];
  f16x8  a16[ACOL/8], b16[4];
  if (F16IN) {
#pragma unroll
    for (int g = 0; g < ACOL/8; ++g) a16[g] = *(const f16x8*)(Axh + aoff + g*8);
#pragma unroll
    for (int g = 0; g < 4; ++g) b16[g] = *(const f16x8*)(Wxh + boff + g*8);
  } else {
#pragma unroll
    for (int j = 0; j < ACOL/4; ++j) a4[j] = *(const float4*)(Af + aoff + j*4);
#pragma unroll
    for (int j = 0; j < 8; ++j) b4[j] = *(const float4*)(Wf + boff + j*4);
  }

  for (int k0 = 0; k0 < K; k0 += 64) {
    __syncthreads();
    if (F16IN) {
#pragma unroll
      for (int g = 0; g < ACOL/8; ++g) {
        const int sw = (apart*ACOL*2 + g*16) ^ ((arow & 7) << 4);
        *(f16x8*)((char*)Ah + arow*128 + sw) = a16[g];
      }
#pragma unroll
      for (int g = 0; g < 4; ++g) {
        const int sw = (bpart*64 + g*16) ^ ((brow & 7) << 4);
        *(f16x8*)((char*)Bh + brow*128 + sw) = b16[g];
      }
    } else {
      const float* af = (const float*)a4;
#pragma unroll
      for (int g = 0; g < ACOL/8; ++g) {
        f16x8 h, l;
#pragma unroll
        for (int j = 0; j < 8; ++j) {
          float xv = af[g*8+j];
          _Float16 hh = (_Float16)xv;
          h[j] = hh;
          if (SPLIT) l[j] = (_Float16)(xv - (float)hh);
        }
        const int sw = (apart*ACOL*2 + g*16) ^ ((arow & 7) << 4);
        *(f16x8*)((char*)Ah + arow*128 + sw) = h;
        if (SPLIT) *(f16x8*)((char*)Al + arow*128 + sw) = l;
      }
      const float* bf = (const float*)b4;
#pragma unroll
      for (int g = 0; g < 4; ++g) {
        f16x8 h, l;
#pragma unroll
        for (int j = 0; j < 8; ++j) {
          float xv = bf[g*8+j];
          _Float16 hh = (_Float16)xv;
          h[j] = hh;
          if (SPLIT) l[j] = (_Float16)(xv - (float)hh);
        }
        const int sw = (bpart*64 + g*16) ^ ((brow & 7) << 4);
        *(f16x8*)((char*)Bh + brow*128 + sw) = h;
        if (SPLIT) *(f16x8*)((char*)Bl + brow*128 + sw) = l;
      }
    }
    __syncthreads();
    if (k0 + 64 < K) {
      if (F16IN) {
#pragma unroll
        for (int g = 0; g < ACOL/8; ++g) a16[g] = *(const f16x8*)(Axh + aoff + k0 + 64 + g*8);
#pragma unroll
        for (int g = 0; g < 4; ++g) b16[g] = *(const f16x8*)(Wxh + boff + k0 + 64 + g*8);
      } else {
#pragma unroll
        for (int j = 0; j < ACOL/4; ++j) a4[j] = *(const float4*)(Af + aoff + k0 + 64 + j*4);
#pragma unroll
        for (int j = 0; j < 8; ++j) b4[j] = *(const float4*)(Wf + boff + k0 + 64 + j*4);
      }
    }
#pragma unroll
    for (int kk = 0; kk < 2; ++kk) {
      f16x8 afh[MI], bfh[4], afl[MI], bfl[4];
#pragma unroll
      for (int mi = 0; mi < MI; ++mi) {
        const int r = wm*(TM/2) + mi*16 + lr;
        const int bo = (lk*16 + kk*64) ^ ((r & 7) << 4);
        afh[mi] = *(const f16x8*)((const char*)Ah + r*128 + bo);
        if (SPLIT) afl[mi] = *(const f16x8*)((const char*)Al + r*128 + bo);
      }
#pragma unroll
      for (int ni = 0; ni < 4; ++ni) {
        const int r = wn*64 + ni*16 + lr;
        const int bo = (lk*16 + kk*64) ^ ((r & 7) << 4);
        bfh[ni] = *(const f16x8*)((const char*)Bh + r*128 + bo);
        if (SPLIT) bfl[ni] = *(const f16x8*)((const char*)Bl + r*128 + bo);
      }
#pragma unroll
      for (int mi = 0; mi < MI; ++mi)
#pragma unroll
        for (int ni = 0; ni < 4; ++ni) {
          acc[mi][ni] = __builtin_amdgcn_mfma_f32_16x16x32_f16(afh[mi], bfh[ni], acc[mi][ni], 0, 0, 0);
          if (SPLIT) {
            acc[mi][ni] = __builtin_amdgcn_mfma_f32_16x16x32_f16(afh[mi], bfl[ni], acc[mi][ni], 0, 0, 0);
            acc[mi][ni] = __builtin_amdgcn_mfma_f32_16x16x32_f16(afl[mi], bfh[ni], acc[mi][ni], 0, 0, 0);
          }
        }
    }
  }

  float bvv[4];
  if (BIAS) {
#pragma unroll
    for (int ni = 0; ni < 4; ++ni) bvv[ni] = bias[n0 + wn*64 + ni*16 + lr];
  }
#pragma unroll
  for (int mi = 0; mi < MI; ++mi)
#pragma unroll
  for (int i = 0; i < 4; ++i) {
    const int rm = m0 + wm*(TM/2) + mi*16 + lk*4 + i;
    long orow = rm;
    if (OREMAP) orow = (long)(rm & (NB-1)) * S_LEN + (rm >> 3);
#pragma unroll
    for (int ni = 0; ni < 4; ++ni) {
      const int col = n0 + wn*64 + ni*16 + lr;
      float v = acc[mi][ni][i];
      if (BIAS) v += bvv[ni];
      if (RES)  v += Rsrc[(long)rm*ldr + col];
      if (RELU) v = fmaxf(v, 0.f);
      if (E16) {
        _Float16 hv = (_Float16)v;
        Ch16[(long)rm*ldc + col] = hv;
        if (SPLIT) Cl16[(long)rm*ldc + col] = (_Float16)(v - (float)hv);
      } else {
        C[orow*(long)ldc + col] = v;
      }
    }
  }
}

// ---------------------------------------------------------------------------
// MFMA flash attention, fp16 hi/lo inputs (pre-converted by GEMM epilogue).
// Block = 128 q rows x one (b,head); 4 waves x 32 rows. Q fragments loaded
// directly from global (MFMA fragment layout is contiguous f16x8). Q pre-
// scaled by 0.125 (exact). K staged [key][d]; V staged transposed [d][key].
// SPLIT=1: 3 MFMAs/pair. LDS XOR-swizzled.
// ---------------------------------------------------------------------------
template<int SPLIT>
__global__ __launch_bounds__(256)
void mattn_k(const _Float16* __restrict__ Qh, const _Float16* __restrict__ Ql, int ldq,
             const _Float16* __restrict__ Kh, const _Float16* __restrict__ Kl, int ldk,
             const _Float16* __restrict__ Vh, const _Float16* __restrict__ Vl, int ldv,
             float* __restrict__ Op, int ldo)
{
  __shared__ __align__(16) char Pb[SPLIT ? 32768 : 16384];
  __shared__ __align__(16) char Kb[SPLIT ? 16384 : 8192];
  __shared__ __align__(16) char Vb[SPLIT ? 16384 : 8192];

  const int t = threadIdx.x;
  const int b = blockIdx.y >> 3, hd = blockIdx.y & 7;
  const int s0 = blockIdx.x * 128;
  const int qoff = hd * DH;
  const int wave = t >> 6, lane = t & 63;
  const int lr = lane & 15, lk = lane >> 4;

  // ---- Q fragments direct from global, pre-scaled by 1/8 (exact) ----
  f16x8 qa[2][2], qal[2][2];
#pragma unroll
  for (int mi = 0; mi < 2; ++mi)
#pragma unroll
    for (int kk = 0; kk < 2; ++kk) {
      const int q = s0 + wave*32 + mi*16 + lr;
      const long base = ((long)q*NB + b)*ldq + qoff + kk*32 + lk*8;
      f16x8 v = *(const f16x8*)(Qh + base);
#pragma unroll
      for (int e = 0; e < 8; ++e) v[e] = v[e] * (_Float16)0.125f;
      qa[mi][kk] = v;
      if (SPLIT) {
        f16x8 w = *(const f16x8*)(Ql + base);
#pragma unroll
        for (int e = 0; e < 8; ++e) w[e] = w[e] * (_Float16)0.125f;
        qal[mi][kk] = w;
      }
    }

  float m_run[2][4], l_run[2][4];
  f32x4 oacc[2][4];
#pragma unroll
  for (int mi = 0; mi < 2; ++mi)
#pragma unroll
    for (int i = 0; i < 4; ++i) {
      m_run[mi][i] = -INFINITY; l_run[mi][i] = 0.f;
#pragma unroll
      for (int ni = 0; ni < 4; ++ni) oacc[mi][ni][i] = 0.f;
    }

  char* Pw  = Pb + wave*4096;
  char* Pwl = Pb + 16384 + wave*4096;
  char* Klo = Kb + 8192;
  char* Vlo = Vb + 8192;

  for (int t0 = 0; t0 < S_LEN; t0 += 64) {
    __syncthreads();
    // ---- stage K [key][d] ----
    {
      const int row = t >> 2, qd = t & 3;
      const long base = ((long)(t0 + row)*NB + b)*ldk + qoff + qd*16;
      f16x8 h0 = *(const f16x8*)(Kh + base);
      f16x8 h1 = *(const f16x8*)(Kh + base + 8);
      const int sw0 = (qd*32) ^ ((row & 7) << 4);
      const int sw1 = (qd*32 + 16) ^ ((row & 7) << 4);
      *(f16x8*)(Kb + row*128 + sw0) = h0;
      *(f16x8*)(Kb + row*128 + sw1) = h1;
      if (SPLIT) {
        f16x8 l0 = *(const f16x8*)(Kl + base);
        f16x8 l1 = *(const f16x8*)(Kl + base + 8);
        *(f16x8*)(Klo + row*128 + sw0) = l0;
        *(f16x8*)(Klo + row*128 + sw1) = l1;
      }
    }
    // ---- stage V transposed [d][key] ----
    {
      const int tp = t & 31, dc = t >> 5;
      const long base = ((long)(t0 + 2*tp)*NB + b)*ldv + qoff + dc*8;
      f16x8 a = *(const f16x8*)(Vh + base);
      f16x8 c = *(const f16x8*)(Vh + base + (long)NB*ldv);
#pragma unroll
      for (int j = 0; j < 8; ++j) {
        const int dd = dc*8 + j;
        f16x2 hv = {a[j], c[j]};
        *(f16x2*)(Vb + dd*128 + ((tp*4) ^ ((dd & 7) << 4))) = hv;
      }
      if (SPLIT) {
        f16x8 la = *(const f16x8*)(Vl + base);
        f16x8 lc = *(const f16x8*)(Vl + base + (long)NB*ldv);
#pragma unroll
        for (int j = 0; j < 8; ++j) {
          const int dd = dc*8 + j;
          f16x2 lv = {la[j], lc[j]};
          *(f16x2*)(Vlo + dd*128 + ((tp*4) ^ ((dd & 7) << 4))) = lv;
        }
      }
    }
    __syncthreads();

    // ---- S = Q K^T ----
    f32x4 s[2][4];
#pragma unroll
    for (int mi = 0; mi < 2; ++mi)
#pragma unroll
      for (int ni = 0; ni < 4; ++ni)
#pragma unroll
        for (int e = 0; e < 4; ++e) s[mi][ni][e] = 0.f;
#pragma unroll
    for (int kk = 0; kk < 2; ++kk) {
      f16x8 kb[4], kbl[4];
#pragma unroll
      for (int ni = 0; ni < 4; ++ni) {
        const int r = ni*16 + lr;
        const int bo = (lk*16 + kk*64) ^ ((r & 7) << 4);
        kb[ni] = *(const f16x8*)(Kb + r*128 + bo);
        if (SPLIT) kbl[ni] = *(const f16x8*)(Klo + r*128 + bo);
      }
#pragma unroll
      for (int mi = 0; mi < 2; ++mi)
#pragma unroll
        for (int ni = 0; ni < 4; ++ni) {
          s[mi][ni] = __builtin_amdgcn_mfma_f32_16x16x32_f16(qa[mi][kk], kb[ni], s[mi][ni], 0, 0, 0);
          if (SPLIT) {
            s[mi][ni] = __builtin_amdgcn_mfma_f32_16x16x32_f16(qa[mi][kk], kbl[ni], s[mi][ni], 0, 0, 0);
            s[mi][ni] = __builtin_amdgcn_mfma_f32_16x16x32_f16(qal[mi][kk], kb[ni], s[mi][ni], 0, 0, 0);
          }
        }
    }

    // ---- online softmax ----
#pragma unroll
    for (int mi = 0; mi < 2; ++mi) {
      float rm[4];
#pragma unroll
      for (int i = 0; i < 4; ++i)
        rm[i] = fmaxf(fmaxf(s[mi][0][i], s[mi][1][i]), fmaxf(s[mi][2][i], s[mi][3][i]));
#pragma unroll
      for (int off = 1; off < 16; off <<= 1)
#pragma unroll
        for (int i = 0; i < 4; ++i) rm[i] = fmaxf(rm[i], __shfl_xor(rm[i], off));
      float rs[4], corr[4];
#pragma unroll
      for (int i = 0; i < 4; ++i) {
        const float mnew = fmaxf(m_run[mi][i], rm[i]);
        corr[i] = __expf(m_run[mi][i] - mnew);
        m_run[mi][i] = mnew;
        float lsum = 0.f;
#pragma unroll
        for (int ni = 0; ni < 4; ++ni) {
          float p = __expf(s[mi][ni][i] - mnew);
          s[mi][ni][i] = p; lsum += p;
        }
        rs[i] = lsum;
      }
#pragma unroll
      for (int off = 1; off < 16; off <<= 1)
#pragma unroll
        for (int i = 0; i < 4; ++i) rs[i] += __shfl_xor(rs[i], off);
#pragma unroll
      for (int i = 0; i < 4; ++i) {
        l_run[mi][i] = l_run[mi][i]*corr[i] + rs[i];
#pragma unroll
        for (int ni = 0; ni < 4; ++ni) oacc[mi][ni][i] *= corr[i];
      }
    }

    // ---- P -> LDS (wave-private) ----
#pragma unroll
    for (int mi = 0; mi < 2; ++mi)
#pragma unroll
      for (int ni = 0; ni < 4; ++ni)
#pragma unroll
        for (int i = 0; i < 4; ++i) {
          const int row = mi*16 + lk*4 + i;
          const int col = ni*16 + lr;
          const int ad = row*128 + ((col*2) ^ ((row & 7) << 4));
          float pv = s[mi][ni][i];
          _Float16 ph = (_Float16)pv;
          *(_Float16*)(Pw + ad) = ph;
          if (SPLIT) *(_Float16*)(Pwl + ad) = (_Float16)(pv - (float)ph);
        }

    // ---- O += P V ----
#pragma unroll
    for (int kk = 0; kk < 2; ++kk) {
      f16x8 vb[4], vbl[4], pa[2], pal[2];
#pragma unroll
      for (int ni = 0; ni < 4; ++ni) {
        const int r = ni*16 + lr;
        const int bo = (lk*16 + kk*64) ^ ((r & 7) << 4);
        vb[ni] = *(const f16x8*)(Vb + r*128 + bo);
        if (SPLIT) vbl[ni] = *(const f16x8*)(Vlo + r*128 + bo);
      }
#pragma unroll
      for (int mi = 0; mi < 2; ++mi) {
        const int r = mi*16 + lr;
        const int bo = (lk*16 + kk*64) ^ ((r & 7) << 4);
        pa[mi] = *(const f16x8*)(Pw + r*128 + bo);
        if (SPLIT) pal[mi] = *(const f16x8*)(Pwl + r*128 + bo);
      }
#pragma unroll
      for (int mi = 0; mi < 2; ++mi)
#pragma unroll
        for (int ni = 0; ni < 4; ++ni) {
          oacc[mi][ni] = __builtin_amdgcn_mfma_f32_16x16x32_f16(pa[mi], vb[ni], oacc[mi][ni], 0, 0, 0);
          if (SPLIT) {
            oacc[mi][ni] = __builtin_amdgcn_mfma_f32_16x16x32_f16(pa[mi], vbl[ni], oacc[mi][ni], 0, 0, 0);
            oacc[mi][ni] = __builtin_amdgcn_mfma_f32_16x16x32_f16(pal[mi], vb[ni], oacc[mi][ni], 0, 0, 0);
          }
        }
    }
  }

#pragma unroll
  for (int mi = 0; mi < 2; ++mi)
#pragma unroll
    for (int i = 0; i < 4; ++i) {
      const float inv = 1.0f / l_run[mi][i];
      const int q = s0 + wave*32 + mi*16 + lk*4 + i;
      float* orow = Op + ((long)q * NB + b) * ldo + qoff;
#pragma unroll
      for (int ni = 0; ni < 4; ++ni) orow[ni*16 + lr] = oacc[mi][ni][i] * inv;
    }
}

// ---------------------------------------------------------------------------
// LayerNorm over c=512, one wave per row.
// ---------------------------------------------------------------------------
__global__ __launch_bounds__(256)
void ln_k(const float* __restrict__ X, const float* __restrict__ g,
          const float* __restrict__ bb, float* __restrict__ Y)
{
  const int t = threadIdx.x;
  const int lane = t & 63;
  const long row = (long)blockIdx.x * 4 + (t >> 6);
  const float* xr = X + row * CDIM;
  float4 v0 = *(const float4*)(xr + lane*4);
  float4 v1 = *(const float4*)(xr + 256 + lane*4);
  float s = v0.x+v0.y+v0.z+v0.w + v1.x+v1.y+v1.z+v1.w;
#pragma unroll
  for (int off = 1; off < 64; off <<= 1) s += __shfl_xor(s, off);
  const float mean = s * (1.0f/512.0f);
  float d[8] = {v0.x-mean, v0.y-mean, v0.z-mean, v0.w-mean,
                v1.x-mean, v1.y-mean, v1.z-mean, v1.w-mean};
  float sq = d[0]*d[0]+d[1]*d[1]+d[2]*d[2]+d[3]*d[3]
           + d[4]*d[4]+d[5]*d[5]+d[6]*d[6]+d[7]*d[7];
#pragma unroll
  for (int off = 1; off < 64; off <<= 1) sq += __shfl_xor(sq, off);
  const float inv = 1.0f / sqrtf(sq * (1.0f/512.0f) + 1e-5f);
  float4 g0 = *(const float4*)(g + lane*4);
  float4 g1 = *(const float4*)(g + 256 + lane*4);
  float4 b0 = *(const float4*)(bb + lane*4);
  float4 b1 = *(const float4*)(bb + 256 + lane*4);
  float4 o0, o1;
  o0.x = d[0]*inv*g0.x + b0.x; o0.y = d[1]*inv*g0.y + b0.y;
  o0.z = d[2]*inv*g0.z + b0.z; o0.w = d[3]*inv*g0.w + b0.w;
  o1.x = d[4]*inv*g1.x + b1.x; o1.y = d[5]*inv*g1.y + b1.y;
  o1.z = d[6]*inv*g1.z + b1.z; o1.w = d[7]*inv*g1.w + b1.w;
  *(float4*)(Y + row*CDIM + lane*4) = o0;
  *(float4*)(Y + row*CDIM + 256 + lane*4) = o1;
}

// ---------------------------------------------------------------------------
// Pack x (N,C,H,W) -> enc_flat (S,n,c) and posisted = enc_flat + PE2D.
// ---------------------------------------------------------------------------
__global__ void pack_pe_k(const float* __restrict__ x, float* __restrict__ encf,
                          float* __restrict__ posd)
{
  __shared__ float tl[32][33];
  const int b = blockIdx.z;
  const int s0 = blockIdx.x*32, c0 = blockIdx.y*32;
#pragma unroll
  for (int i = 0; i < 4; ++i) {
    int ci = threadIdx.y + i*8;
    tl[ci][threadIdx.x] = x[((long)b*CDIM + c0+ci)*S_LEN + s0 + threadIdx.x];
  }
  __syncthreads();
#pragma unroll
  for (int i = 0; i < 4; ++i) {
    int si = threadIdx.y + i*8;
    int s = s0 + si;
    int ch = c0 + threadIdx.x;
    float val = tl[threadIdx.x][si];
    long o = ((long)s*NB + b)*CDIM + ch;
    encf[o] = val;
    int pos = (ch < 256) ? (s & 31) : (s >> 5);
    int j = (ch & 255) >> 1;
    float dv = expf((float)(2*j) * (-9.210340371976184f / 256.0f));
    float ang = (float)pos * dv;
    float pe = (ch & 1) ? cosf(ang) : sinf(ang);
    posd[o] = val + pe;
  }
}

// (S,n,c) token-major -> (n,c,S) output layout
__global__ void tpose_k(const float* __restrict__ in, float* __restrict__ out)
{
  __shared__ float tl[32][33];
  const int b = blockIdx.z;
  const int s0 = blockIdx.x*32, c0 = blockIdx.y*32;
#pragma unroll
  for (int i = 0; i < 4; ++i) {
    int si = threadIdx.y + i*8;
    tl[si][threadIdx.x] = in[((long)(s0+si)*NB + b)*CDIM + c0 + threadIdx.x];
  }
  __syncthreads();
#pragma unroll
  for (int i = 0; i < 4; ++i) {
    int ci = threadIdx.y + i*8;
    out[((long)b*CDIM + c0+ci)*S_LEN + s0 + threadIdx.x] = tl[threadIdx.x][ci];
  }
}

// cb_w (c,K) -> cbT (K,c)
__global__ void cbt_k(const float* __restrict__ cb, float* __restrict__ cbT)
{
  __shared__ float tl[32][33];
  const int k0 = blockIdx.x*32, c0 = blockIdx.y*32;
#pragma unroll
  for (int i = 0; i < 4; ++i) {
    int ci = threadIdx.y + i*8;
    tl[ci][threadIdx.x] = cb[(long)(c0+ci)*KCB + k0 + threadIdx.x];
  }
  __syncthreads();
#pragma unroll
  for (int i = 0; i < 4; ++i) {
    int ki = threadIdx.y + i*8;
    cbT[(long)(k0+ki)*CDIM + c0 + threadIdx.x] = tl[threadIdx.x][ki];
  }
}

// fp32 -> fp16 elementwise (cb_w -> CBH), 8 per thread
__global__ __launch_bounds__(256)
void conv16_k(const float* __restrict__ in, _Float16* __restrict__ out)
{
  const long i = ((long)blockIdx.x * 256 + threadIdx.x) * 8;
  float4 v0 = *(const float4*)(in + i);
  float4 v1 = *(const float4*)(in + i + 4);
  f16x8 h;
  h[0]=(_Float16)v0.x; h[1]=(_Float16)v0.y; h[2]=(_Float16)v0.z; h[3]=(_Float16)v0.w;
  h[4]=(_Float16)v1.x; h[5]=(_Float16)v1.y; h[6]=(_Float16)v1.z; h[7]=(_Float16)v1.w;
  *(f16x8*)(out + i) = h;
}

// Per-token row of logits: argmax (np first-occurrence) + write P (fp16)
__global__ __launch_bounds__(256)
void simstats_k(const float* __restrict__ logits, _Float16* __restrict__ Pbuf,
                int* __restrict__ codes_tok, float* __restrict__ codes_out)
{
  const long phys = blockIdx.x;
  const float* rowp = logits + phys * KCB;
  const int t = threadIdx.x;
  float vals[16];
#pragma unroll
  for (int rep = 0; rep < 4; ++rep) {
    float4 v = *(const float4*)(rowp + rep*1024 + t*4);
    vals[rep*4+0]=v.x; vals[rep*4+1]=v.y; vals[rep*4+2]=v.z; vals[rep*4+3]=v.w;
  }
  float mv = -INFINITY; int mi = 0;
#pragma unroll
  for (int rep = 0; rep < 4; ++rep)
#pragma unroll
    for (int j = 0; j < 4; ++j) {
      float xv = vals[rep*4+j];
      int ix = rep*1024 + t*4 + j;
      if (xv > mv) { mv = xv; mi = ix; }
    }
  const int lane = t & 63, wid = t >> 6;
#pragma unroll
  for (int off = 1; off < 64; off <<= 1) {
    float ov = __shfl_xor(mv, off);
    int   oi = __shfl_xor(mi, off);
    if (ov > mv || (ov == mv && oi < mi)) { mv = ov; mi = oi; }
  }
  __shared__ float smax[4]; __shared__ int sidx[4]; __shared__ float ssum[4];
  __shared__ float fm; __shared__ int fi; __shared__ float sinv;
  if (lane == 0) { smax[wid] = mv; sidx[wid] = mi; }
  __syncthreads();
  if (t == 0) {
    float bm = smax[0]; int bi = sidx[0];
    for (int wq = 1; wq < 4; ++wq)
      if (smax[wq] > bm || (smax[wq] == bm && sidx[wq] < bi)) { bm = smax[wq]; bi = sidx[wq]; }
    fm = bm; fi = bi;
  }
  __syncthreads();
  const float Mx = fm;
  float se = 0.f;
#pragma unroll
  for (int q = 0; q < 16; ++q) se += __expf(vals[q] - Mx);
#pragma unroll
  for (int off = 1; off < 64; off <<= 1) se += __shfl_xor(se, off);
  if (lane == 0) ssum[wid] = se;
  __syncthreads();
  const int b = (int)(phys >> 10), s = (int)(phys & 1023);
  if (t == 0) {
    float tot = ssum[0]+ssum[1]+ssum[2]+ssum[3];
    sinv = 1.0f / tot;
    codes_tok[s*NB + b] = fi;
    codes_out[phys] = (float)fi;
  }
  __syncthreads();
  const float inv = sinv;
  _Float16* prow = Pbuf + ((long)s*NB + b) * KCB;
#pragma unroll
  for (int rep = 0; rep < 4; ++rep) {
    f16x4 pv;
#pragma unroll
    for (int j = 0; j < 4; ++j) pv[j] = (_Float16)(__expf(vals[rep*4+j] - Mx) * inv);
    *(f16x4*)(prow + rep*1024 + t*4) = pv;
  }
}

// quant = (hard - soft) + soft, also emit hard
__global__ __launch_bounds__(128)
void quant_k(const float* __restrict__ soft, const int* __restrict__ codes_tok,
             const float* __restrict__ cbT, float* __restrict__ quant,
             float* __restrict__ hardb)
{
  const int r = blockIdx.x;
  const int code = codes_tok[r];
  const int c = threadIdx.x * 4;
  float4 h  = *(const float4*)(cbT + (long)code*CDIM + c);
  float4 sf = *(const float4*)(soft + (long)r*CDIM + c);
  float4 q;
  q.x = (h.x - sf.x) + sf.x; q.y = (h.y - sf.y) + sf.y;
  q.z = (h.z - sf.z) + sf.z; q.w = (h.w - sf.w) + sf.w;
  *(float4*)(quant + (long)r*CDIM + c) = q;
  *(float4*)(hardb + (long)r*CDIM + c) = h;
}

// Detect the storage format of the bool mask buffer.
__global__ void maskdetect_k(const void* __restrict__ mask, int* __restrict__ flag)
{
  const unsigned int* wds = (const unsigned int*)mask;
  int t = threadIdx.x;
  int okI = 1, okF = 1, okL = 1;
  for (int i = t; i < 2048; i += 256) {
    unsigned int u = wds[i];
    if (u > 1u) okI = 0;
    if (u != 0u && u != 0x3F800000u) okF = 0;
    if ((i & 1) ? (u != 0u) : (u > 1u)) okL = 0;
  }
  __shared__ int sI, sF, sL;
  if (t == 0) { sI = 1; sF = 1; sL = 1; }
  __syncthreads();
  if (!okI) atomicAnd(&sI, 0);
  if (!okF) atomicAnd(&sF, 0);
  if (!okL) atomicAnd(&sL, 0);
  __syncthreads();
  if (t == 0) {
    int f;
    if (sI && sL) f = 3;
    else if (sI)  f = 1;
    else if (sF)  f = 2;
    else          f = 0;
    *flag = f;
  }
}

// mixed = mask ? enc_flat : post
__global__ __launch_bounds__(256)
void mixed_k(const float* __restrict__ encf, const float* __restrict__ post,
             const void* __restrict__ mask, const int* __restrict__ flag,
             float* __restrict__ outx)
{
  long gid = (long)blockIdx.x * blockDim.x + threadIdx.x;
  int r = (int)(gid >> 7);
  int c = (int)(gid & 127) * 4;
  int f = *flag;
  bool mv;
  if (f == 0)      mv = ((const unsigned char*)mask)[r] != 0;
  else if (f == 1) mv = ((const int*)mask)[r] != 0;
  else if (f == 3) mv = ((const long long*)mask)[r] != 0;
  else             mv = ((const float*)mask)[r] != 0.0f;
  const float* src = mv ? encf : post;
  *(float4*)(outx + (long)r*CDIM + c) = *(const float4*)(src + (long)r*CDIM + c);
}

// ---------------------------------------------------------------------------
// Host-side wrappers (fp32-out GEMMs)
// ---------------------------------------------------------------------------
static void sg64_b(hipStream_t st, const float* A, const float* W, const float* bias,
                   float* C) {
  hgemm_k<64,1,0,true,false,false,false,false><<<dim3(CDIM/128, NTOK/64), 256, 0, st>>>(
      A, W, bias, nullptr, 0, C, CDIM, NTOK, CDIM, CDIM, nullptr, nullptr);
}
static void sg64_br(hipStream_t st, const float* A, const float* W, const float* bias,
                    const float* R, float* C) {
  hgemm_k<64,1,0,true,true,false,false,false><<<dim3(CDIM/128, NTOK/64), 256, 0, st>>>(
      A, W, bias, R, CDIM, C, CDIM, NTOK, CDIM, CDIM, nullptr, nullptr);
}
static void sg64_brelu(hipStream_t st, const float* A, const float* W, const float* bias,
                       float* C) {
  hgemm_k<64,1,0,true,false,true,false,false><<<dim3(CDIM/128, NTOK/64), 256, 0, st>>>(
      A, W, bias, nullptr, 0, C, CDIM, NTOK, CDIM, CDIM, nullptr, nullptr);
}
static void hg64_b(hipStream_t st, const float* A, const float* W, const float* bias,
                   float* C) {
  hgemm_k<64,0,0,true,false,false,false,false><<<dim3(CDIM/128, NTOK/64), 256, 0, st>>>(
      A, W, bias, nullptr, 0, C, CDIM, NTOK, CDIM, CDIM, nullptr, nullptr);
}
static void hg64_br(hipStream_t st, const float* A, const float* W, const float* bias,
                    const float* R, float* C) {
  hgemm_k<64,0,0,true,true,false,false,false><<<dim3(CDIM/128, NTOK/64), 256, 0, st>>>(
      A, W, bias, R, CDIM, C, CDIM, NTOK, CDIM, CDIM, nullptr, nullptr);
}
static void hg64_brelu(hipStream_t st, const float* A, const float* W, const float* bias,
                       float* C) {
  hgemm_k<64,0,0,true,false,true,false,false><<<dim3(CDIM/128, NTOK/64), 256, 0, st>>>(
      A, W, bias, nullptr, 0, C, CDIM, NTOK, CDIM, CDIM, nullptr, nullptr);
}

extern "C" void kernel_launch(void* const* d_in, const int* in_sizes, int n_in,
                              void* d_out, int out_size, void* d_ws, size_t ws_size,
                              hipStream_t stream)
{
  const float* x       = (const float*)d_in[0];
  const float* pre_w   = (const float*)d_in[1];
  const float* pre_b   = (const float*)d_in[2];
  const float* post_w  = (const float*)d_in[3];
  const float* post_b  = (const float*)d_in[4];
  const float* cb_w    = (const float*)d_in[5];
  const float* e_qkv_w = (const float*)d_in[6];
  const float* e_qkv_b = (const float*)d_in[7];
  const float* e_o_w   = (const float*)d_in[8];
  const float* e_o_b   = (const float*)d_in[9];
  const float* e_ln1_w = (const float*)d_in[10];
  const float* e_ln1_b = (const float*)d_in[11];
  const float* e_ln2_w = (const float*)d_in[12];
  const float* e_ln2_b = (const float*)d_in[13];
  const float* e_f1_w  = (const float*)d_in[14];
  const float* e_f1_b  = (const float*)d_in[15];
  const float* e_f2_w  = (const float*)d_in[16];
  const float* e_f2_b  = (const float*)d_in[17];
  const float* d_sqkv_w= (const float*)d_in[18];
  const float* d_sqkv_b= (const float*)d_in[19];
  const float* d_so_w  = (const float*)d_in[20];
  const float* d_so_b  = (const float*)d_in[21];
  const float* d_cqkv_w= (const float*)d_in[22];
  const float* d_cqkv_b= (const float*)d_in[23];
  const float* d_co_w  = (const float*)d_in[24];
  const float* d_co_b  = (const float*)d_in[25];
  const float* d_ln1w  = (const float*)d_in[26];
  const float* d_ln1b  = (const float*)d_in[27];
  const float* d_ln2w  = (const float*)d_in[28];
  const float* d_ln2b  = (const float*)d_in[29];
  const float* d_ln3w  = (const float*)d_in[30];
  const float* d_ln3b  = (const float*)d_in[31];
  const float* d_f1w   = (const float*)d_in[32];
  const float* d_f1b   = (const float*)d_in[33];
  const float* d_f2w   = (const float*)d_in[34];
  const float* d_f2b   = (const float*)d_in[35];
  const void*  mask    = d_in[36];

  float* out = (float*)d_out;
  float* o_quant  = out;
  float* o_high   = out + 4194304;
  float* o_softs  = out + 8388608;
  float* o_hards  = out + 12582912;
  float* o_codes  = out + 16777216;
  float* o_logits = out + 16785408;

  float* ws    = (float*)d_ws;
  float* ENC   = ws;
  float* Xb    = ws + TOKC;
  float* T1    = ws + 2*TOKC;
  float* T2    = ws + 3*TOKC;
  float* QKV   = ws + 4*TOKC;
  float* MEMB  = ws + 7*TOKC;
  float* CBT   = ws + 8*TOKC;
  int*   CODES = (int*)(CBT + (long)KCB*CDIM);
  int*   FLAG  = CODES + NTOK;
  float* HARDB = QKV;
  float* QUANT = QKV + TOKC;
  _Float16* PBUF = (_Float16*)QKV;
  _Float16* CBH  = (_Float16*)T1;
  _Float16* QKVh = (_Float16*)QKV;                    // [NTOK][3C] halves
  _Float16* QKVl = QKVh + (long)NTOK*3*CDIM;          // lo part (encoder only)
  _Float16* CQh  = (_Float16*)QKV;                    // decoder cross Q [NTOK][C]
  _Float16* KVh  = (_Float16*)(QKV + TOKC);           // decoder cross KV [NTOK][2C]

  const size_t NEED = (size_t)(8*TOKC + (long)KCB*CDIM + 2*NTOK + NTOK + 16) * 4;
  if (ws_size < NEED) return;

  const int M = NTOK;
  dim3 tgrid(S_LEN/32, CDIM/32, NB), tblk(32, 8);
  dim3 agrid(S_LEN/128, NB*8);

  pack_pe_k<<<tgrid, tblk, 0, stream>>>(x, ENC, Xb);
  cbt_k<<<dim3(KCB/32, CDIM/32), tblk, 0, stream>>>(cb_w, CBT);
  maskdetect_k<<<1, 256, 0, stream>>>(mask, FLAG);

  // -------- encoder (split-fp16 MFMA, argmax-critical) --------
  for (int i = 0; i < NLAYER; ++i) {
    hgemm_k<128,1,0,true,false,false,false,true><<<dim3(3*CDIM/128, M/128), 256, 0, stream>>>(
        Xb, e_qkv_w + (long)i*3*CDIM*CDIM, e_qkv_b + i*3*CDIM, nullptr, 0,
        nullptr, 3*CDIM, M, 3*CDIM, CDIM, QKVh, QKVl);
    mattn_k<1><<<agrid, 256, 0, stream>>>(QKVh, QKVl, 3*CDIM,
        QKVh+CDIM, QKVl+CDIM, 3*CDIM, QKVh+2*CDIM, QKVl+2*CDIM, 3*CDIM, T1, CDIM);
    sg64_br(stream, T1, e_o_w + (long)i*CDIM*CDIM, e_o_b + i*CDIM, Xb, T2);
    ln_k<<<M/4, 256, 0, stream>>>(T2, e_ln1_w + i*CDIM, e_ln1_b + i*CDIM, T1);
    sg64_brelu(stream, T1, e_f1_w + (long)i*CDIM*CDIM, e_f1_b + i*CDIM, T2);
    sg64_br(stream, T2, e_f2_w + (long)i*CDIM*CDIM, e_f2_b + i*CDIM, T1, T2);
    ln_k<<<M/4, 256, 0, stream>>>(T2, e_ln2_w + i*CDIM, e_ln2_b + i*CDIM, Xb);
  }

  // -------- codebook / quantizer --------
  sg64_b(stream, Xb, pre_w, pre_b, T1);                                      // pre (split)
  tpose_k<<<tgrid, tblk, 0, stream>>>(T1, o_high);
  hgemm_k<128,1,0,false,false,false,true,false><<<dim3(KCB/128, M/128), 256, 0, stream>>>(
      T1, CBT, nullptr, nullptr, 0, o_logits, KCB, M, KCB, CDIM, nullptr, nullptr); // sim
  conv16_k<<<(CDIM*(long)KCB)/(256*8), 256, 0, stream>>>(cb_w, CBH);
  simstats_k<<<NTOK, 256, 0, stream>>>(o_logits, PBUF, CODES, o_codes);
  hgemm_k<64,0,1,false,false,false,false,false><<<dim3(CDIM/128, M/64), 256, 0, stream>>>(
      PBUF, CBH, nullptr, nullptr, 0, T2, CDIM, M, CDIM, KCB, nullptr, nullptr);    // soft
  tpose_k<<<tgrid, tblk, 0, stream>>>(T2, o_softs);
  quant_k<<<NTOK, 128, 0, stream>>>(T2, CODES, CBT, QUANT, HARDB);
  tpose_k<<<tgrid, tblk, 0, stream>>>(HARDB, o_hards);
  hg64_b(stream, QUANT, post_w, post_b, MEMB);                               // post (f16)
  mixed_k<<<4096, 256, 0, stream>>>(ENC, MEMB, mask, FLAG, Xb);

  // -------- decoder (f16 MFMA) --------
  for (int i = 0; i < NLAYER; ++i) {
    hgemm_k<128,0,0,true,false,false,false,true><<<dim3(3*CDIM/128, M/128), 256, 0, stream>>>(
        Xb, d_sqkv_w + (long)i*3*CDIM*CDIM, d_sqkv_b + i*3*CDIM, nullptr, 0,
        nullptr, 3*CDIM, M, 3*CDIM, CDIM, QKVh, nullptr);
    mattn_k<0><<<agrid, 256, 0, stream>>>(QKVh, nullptr, 3*CDIM,
        QKVh+CDIM, nullptr, 3*CDIM, QKVh+2*CDIM, nullptr, 3*CDIM, T1, CDIM);
    hg64_br(stream, T1, d_so_w + (long)i*CDIM*CDIM, d_so_b + i*CDIM, Xb, T2);
    ln_k<<<M/4, 256, 0, stream>>>(T2, d_ln1w + i*CDIM, d_ln1b + i*CDIM, Xb);
    hgemm_k<64,0,0,true,false,false,false,true><<<dim3(CDIM/128, M/64), 256, 0, stream>>>(
        Xb, d_cqkv_w + (long)i*3*CDIM*CDIM, d_cqkv_b + i*3*CDIM, nullptr, 0,
        nullptr, CDIM, M, CDIM, CDIM, CQh, nullptr);
    hgemm_k<128,0,0,true,false,false,false,true><<<dim3(2*CDIM/128, M/128), 256, 0, stream>>>(
        MEMB, d_cqkv_w + (long)i*3*CDIM*CDIM + (long)CDIM*CDIM,
        d_cqkv_b + i*3*CDIM + CDIM, nullptr, 0,
        nullptr, 2*CDIM, M, 2*CDIM, CDIM, KVh, nullptr);
    mattn_k<0><<<agrid, 256, 0, stream>>>(CQh, nullptr, CDIM,
        KVh, nullptr, 2*CDIM, KVh+CDIM, nullptr, 2*CDIM, T1, CDIM);
    hg64_br(stream, T1, d_co_w + (long)i*CDIM*CDIM, d_co_b + i*CDIM, Xb, T2);
    ln_k<<<M/4, 256, 0, stream>>>(T2, d_ln2w + i*CDIM, d_ln2b + i*CDIM, Xb);
    hg64_brelu(stream, Xb, d_f1w + (long)i*CDIM*CDIM, d_f1b + i*CDIM, T2);
    hg64_br(stream, T2, d_f2w + (long)i*CDIM*CDIM, d_f2b + i*CDIM, Xb, T2);
    ln_k<<<M/4, 256, 0, stream>>>(T2, d_ln3w + i*CDIM, d_ln3b + i*CDIM, Xb);
  }
  tpose_k<<<tgrid, tblk, 0, stream>>>(Xb, o_quant);
}

// Round 6
// 4312.067 us; speedup vs baseline: 2.9071x; 1.0580x over previous
//
#include <hip/hip_runtime.h>
#include <math.h>

#define S_LEN 1024
#define NB 8
#define CDIM 512
#define KCB 4096
#define DH 64
#define NLAYER 6
#define NTOK (S_LEN*NB)
#define TOKC ((long)NTOK*CDIM)

typedef __attribute__((ext_vector_type(8))) _Float16 f16x8;
typedef __attribute__((ext_vector_type(4))) _Float16 f16x4;
typedef __attribute__((ext_vector_type(2))) _Float16 f16x2;
typedef __attribute__((ext_vector_type(4))) float f32x4;

// ---------------------------------------------------------------------------
// MFMA GEMM: C[M,N] = A[M,K] @ W[N,K]^T (+bias/res/relu).
// TM in {64,128}; N-tile 128. BK=64, mfma_f32_16x16x32_f16, XOR-swizzled LDS.
// SPLIT=1: hi/lo split-fp16, 3 MFMAs/pair (~fp32 accuracy).
// F16IN=1: A,W fp16 (plain). F16IN=2: A,W split fp16 hi/lo (Avl/Wvl), SPLIT=1.
// E16: epilogue writes fp16 hi (Ch16) (+lo Cl16 if SPLIT); also fp32 C if C!=0.
// OREMAP: output row (s*NB+b) -> (b*S_LEN+s).
// ---------------------------------------------------------------------------
template<int TM, int SPLIT, int F16IN, bool BIAS, bool RES, bool RELU, bool OREMAP, bool E16>
__global__ __launch_bounds__(256)
void hgemm_k(const void* __restrict__ Av, const void* __restrict__ Wv,
             const float* __restrict__ bias, const float* __restrict__ Rsrc, int ldr,
             float* __restrict__ C, int ldc, int M, int N, int K,
             _Float16* __restrict__ Ch16, _Float16* __restrict__ Cl16,
             const void* __restrict__ Avl, const void* __restrict__ Wvl)
{
  constexpr int MI = TM / 32;
  constexpr int ATPR = 256 / TM;
  constexpr int ACOL = 64 / ATPR;
  __shared__ __align__(16) _Float16 Ah[TM*64];
  __shared__ __align__(16) _Float16 Bh[128*64];
  __shared__ __align__(16) _Float16 Al[SPLIT ? TM*64 : 8];
  __shared__ __align__(16) _Float16 Bl[SPLIT ? 128*64 : 8];
  const int t = threadIdx.x;
  const int m0 = blockIdx.y * TM, n0 = blockIdx.x * 128;

  const int arow = t / ATPR, apart = t % ATPR;
  const int brow = t >> 1, bpart = t & 1;

  const float*    Af  = (const float*)Av;
  const _Float16* Axh = (const _Float16*)Av;
  const _Float16* Axl = (const _Float16*)Avl;
  const float*    Wf  = (const float*)Wv;
  const _Float16* Wxh = (const _Float16*)Wv;
  const _Float16* Wxl = (const _Float16*)Wvl;
  const long aoff = (long)(m0 + arow) * K + apart * ACOL;
  const long boff = (long)(n0 + brow) * K + bpart * 32;

  const int lane = t & 63, wave = t >> 6;
  const int wm = wave >> 1, wn = wave & 1;
  const int lr = lane & 15, lk = lane >> 4;

  f32x4 acc[MI][4];
#pragma unroll
  for (int mi = 0; mi < MI; ++mi)
#pragma unroll
    for (int ni = 0; ni < 4; ++ni)
#pragma unroll
      for (int e = 0; e < 4; ++e) acc[mi][ni][e] = 0.f;

  float4 a4[ACOL/4], b4[8];
  f16x8  a16[ACOL/8], b16[4];
  f16x8  a16l[F16IN==2 ? ACOL/8 : 1], b16l[F16IN==2 ? 4 : 1];
  if (F16IN) {
#pragma unroll
    for (int g = 0; g < ACOL/8; ++g) a16[g] = *(const f16x8*)(Axh + aoff + g*8);
#pragma unroll
    for (int g = 0; g < 4; ++g) b16[g] = *(const f16x8*)(Wxh + boff + g*8);
    if (F16IN == 2) {
#pragma unroll
      for (int g = 0; g < ACOL/8; ++g) a16l[g] = *(const f16x8*)(Axl + aoff + g*8);
#pragma unroll
      for (int g = 0; g < 4; ++g) b16l[g] = *(const f16x8*)(Wxl + boff + g*8);
    }
  } else {
#pragma unroll
    for (int j = 0; j < ACOL/4; ++j) a4[j] = *(const float4*)(Af + aoff + j*4);
#pragma unroll
    for (int j = 0; j < 8; ++j) b4[j] = *(const float4*)(Wf + boff + j*4);
  }

  for (int k0 = 0; k0 < K; k0 += 64) {
    __syncthreads();
    if (F16IN) {
#pragma unroll
      for (int g = 0; g < ACOL/8; ++g) {
        const int sw = (apart*ACOL*2 + g*16) ^ ((arow & 7) << 4);
        *(f16x8*)((char*)Ah + arow*128 + sw) = a16[g];
        if (F16IN == 2) *(f16x8*)((char*)Al + arow*128 + sw) = a16l[g];
      }
#pragma unroll
      for (int g = 0; g < 4; ++g) {
        const int sw = (bpart*64 + g*16) ^ ((brow & 7) << 4);
        *(f16x8*)((char*)Bh + brow*128 + sw) = b16[g];
        if (F16IN == 2) *(f16x8*)((char*)Bl + brow*128 + sw) = b16l[g];
      }
    } else {
      const float* af = (const float*)a4;
#pragma unroll
      for (int g = 0; g < ACOL/8; ++g) {
        f16x8 h, l;
#pragma unroll
        for (int j = 0; j < 8; ++j) {
          float xv = af[g*8+j];
          _Float16 hh = (_Float16)xv;
          h[j] = hh;
          if (SPLIT) l[j] = (_Float16)(xv - (float)hh);
        }
        const int sw = (apart*ACOL*2 + g*16) ^ ((arow & 7) << 4);
        *(f16x8*)((char*)Ah + arow*128 + sw) = h;
        if (SPLIT) *(f16x8*)((char*)Al + arow*128 + sw) = l;
      }
      const float* bf = (const float*)b4;
#pragma unroll
      for (int g = 0; g < 4; ++g) {
        f16x8 h, l;
#pragma unroll
        for (int j = 0; j < 8; ++j) {
          float xv = bf[g*8+j];
          _Float16 hh = (_Float16)xv;
          h[j] = hh;
          if (SPLIT) l[j] = (_Float16)(xv - (float)hh);
        }
        const int sw = (bpart*64 + g*16) ^ ((brow & 7) << 4);
        *(f16x8*)((char*)Bh + brow*128 + sw) = h;
        if (SPLIT) *(f16x8*)((char*)Bl + brow*128 + sw) = l;
      }
    }
    __syncthreads();
    if (k0 + 64 < K) {
      if (F16IN) {
#pragma unroll
        for (int g = 0; g < ACOL/8; ++g) a16[g] = *(const f16x8*)(Axh + aoff + k0 + 64 + g*8);
#pragma unroll
        for (int g = 0; g < 4; ++g) b16[g] = *(const f16x8*)(Wxh + boff + k0 + 64 + g*8);
        if (F16IN == 2) {
#pragma unroll
          for (int g = 0; g < ACOL/8; ++g) a16l[g] = *(const f16x8*)(Axl + aoff + k0 + 64 + g*8);
#pragma unroll
          for (int g = 0; g < 4; ++g) b16l[g] = *(const f16x8*)(Wxl + boff + k0 + 64 + g*8);
        }
      } else {
#pragma unroll
        for (int j = 0; j < ACOL/4; ++j) a4[j] = *(const float4*)(Af + aoff + k0 + 64 + j*4);
#pragma unroll
        for (int j = 0; j < 8; ++j) b4[j] = *(const float4*)(Wf + boff + k0 + 64 + j*4);
      }
    }
#pragma unroll
    for (int kk = 0; kk < 2; ++kk) {
      f16x8 afh[MI], bfh[4], afl[MI], bfl[4];
#pragma unroll
      for (int mi = 0; mi < MI; ++mi) {
        const int r = wm*(TM/2) + mi*16 + lr;
        const int bo = (lk*16 + kk*64) ^ ((r & 7) << 4);
        afh[mi] = *(const f16x8*)((const char*)Ah + r*128 + bo);
        if (SPLIT) afl[mi] = *(const f16x8*)((const char*)Al + r*128 + bo);
      }
#pragma unroll
      for (int ni = 0; ni < 4; ++ni) {
        const int r = wn*64 + ni*16 + lr;
        const int bo = (lk*16 + kk*64) ^ ((r & 7) << 4);
        bfh[ni] = *(const f16x8*)((const char*)Bh + r*128 + bo);
        if (SPLIT) bfl[ni] = *(const f16x8*)((const char*)Bl + r*128 + bo);
      }
#pragma unroll
      for (int mi = 0; mi < MI; ++mi)
#pragma unroll
        for (int ni = 0; ni < 4; ++ni) {
          acc[mi][ni] = __builtin_amdgcn_mfma_f32_16x16x32_f16(afh[mi], bfh[ni], acc[mi][ni], 0, 0, 0);
          if (SPLIT) {
            acc[mi][ni] = __builtin_amdgcn_mfma_f32_16x16x32_f16(afh[mi], bfl[ni], acc[mi][ni], 0, 0, 0);
            acc[mi][ni] = __builtin_amdgcn_mfma_f32_16x16x32_f16(afl[mi], bfh[ni], acc[mi][ni], 0, 0, 0);
          }
        }
    }
  }

  float bvv[4];
  if (BIAS) {
#pragma unroll
    for (int ni = 0; ni < 4; ++ni) bvv[ni] = bias[n0 + wn*64 + ni*16 + lr];
  }
#pragma unroll
  for (int mi = 0; mi < MI; ++mi)
#pragma unroll
  for (int i = 0; i < 4; ++i) {
    const int rm = m0 + wm*(TM/2) + mi*16 + lk*4 + i;
    long orow = rm;
    if (OREMAP) orow = (long)(rm & (NB-1)) * S_LEN + (rm >> 3);
#pragma unroll
    for (int ni = 0; ni < 4; ++ni) {
      const int col = n0 + wn*64 + ni*16 + lr;
      float v = acc[mi][ni][i];
      if (BIAS) v += bvv[ni];
      if (RES)  v += Rsrc[(long)rm*ldr + col];
      if (RELU) v = fmaxf(v, 0.f);
      if (E16) {
        _Float16 hv = (_Float16)v;
        Ch16[(long)rm*ldc + col] = hv;
        if (SPLIT) Cl16[(long)rm*ldc + col] = (_Float16)(v - (float)hv);
        if (C != nullptr) C[orow*(long)ldc + col] = v;
      } else {
        C[orow*(long)ldc + col] = v;
      }
    }
  }
}

// ---------------------------------------------------------------------------
// MFMA flash attention, fp16 hi/lo inputs. 128 q rows x (b,head); 4 waves.
// K/V staged via register prefetch: tile t+1 global loads issued right after
// tile t's LDS writes, hiding load latency under compute. LDS XOR-swizzled.
// SPLIT=1: 3 MFMAs/pair. Q pre-scaled by 1/8 (exact).
// ---------------------------------------------------------------------------
template<int SPLIT>
__global__ __launch_bounds__(256)
void mattn_k(const _Float16* __restrict__ Qh, const _Float16* __restrict__ Ql, int ldq,
             const _Float16* __restrict__ Kh, const _Float16* __restrict__ Kl, int ldk,
             const _Float16* __restrict__ Vh, const _Float16* __restrict__ Vl, int ldv,
             float* __restrict__ Op, int ldo)
{
  __shared__ __align__(16) char Pb[SPLIT ? 32768 : 16384];
  __shared__ __align__(16) char Kb[SPLIT ? 16384 : 8192];
  __shared__ __align__(16) char Vb[SPLIT ? 16384 : 8192];

  const int t = threadIdx.x;
  const int b = blockIdx.y >> 3, hd = blockIdx.y & 7;
  const int s0 = blockIdx.x * 128;
  const int qoff = hd * DH;
  const int wave = t >> 6, lane = t & 63;
  const int lr = lane & 15, lk = lane >> 4;
  const int krow = t >> 2, kqd = t & 3;
  const int vtp = t & 31, vdc = t >> 5;

  // ---- Q fragments direct from global, pre-scaled by 1/8 (exact) ----
  f16x8 qa[2][2], qal[2][2];
#pragma unroll
  for (int mi = 0; mi < 2; ++mi)
#pragma unroll
    for (int kk = 0; kk < 2; ++kk) {
      const int q = s0 + wave*32 + mi*16 + lr;
      const long base = ((long)q*NB + b)*ldq + qoff + kk*32 + lk*8;
      f16x8 v = *(const f16x8*)(Qh + base);
#pragma unroll
      for (int e = 0; e < 8; ++e) v[e] = v[e] * (_Float16)0.125f;
      qa[mi][kk] = v;
      if (SPLIT) {
        f16x8 w = *(const f16x8*)(Ql + base);
#pragma unroll
        for (int e = 0; e < 8; ++e) w[e] = w[e] * (_Float16)0.125f;
        qal[mi][kk] = w;
      }
    }

  float m_run[2][4], l_run[2][4];
  f32x4 oacc[2][4];
#pragma unroll
  for (int mi = 0; mi < 2; ++mi)
#pragma unroll
    for (int i = 0; i < 4; ++i) {
      m_run[mi][i] = -INFINITY; l_run[mi][i] = 0.f;
#pragma unroll
      for (int ni = 0; ni < 4; ++ni) oacc[mi][ni][i] = 0.f;
    }

  char* Pw  = Pb + wave*4096;
  char* Pwl = Pb + 16384 + wave*4096;
  char* Klo = Kb + 8192;
  char* Vlo = Vb + 8192;

  // ---- prologue: load tile 0 into regs ----
  f16x8 kr0, kr1, krl0, krl1, vr0, vr1, vrl0, vrl1;
  {
    const long kb = ((long)krow*NB + b)*ldk + qoff + kqd*16;
    kr0 = *(const f16x8*)(Kh + kb);
    kr1 = *(const f16x8*)(Kh + kb + 8);
    if (SPLIT) { krl0 = *(const f16x8*)(Kl + kb); krl1 = *(const f16x8*)(Kl + kb + 8); }
    const long vb = ((long)(2*vtp)*NB + b)*ldv + qoff + vdc*8;
    vr0 = *(const f16x8*)(Vh + vb);
    vr1 = *(const f16x8*)(Vh + vb + (long)NB*ldv);
    if (SPLIT) { vrl0 = *(const f16x8*)(Vl + vb); vrl1 = *(const f16x8*)(Vl + vb + (long)NB*ldv); }
  }

  for (int t0 = 0; t0 < S_LEN; t0 += 64) {
    __syncthreads();
    // ---- LDS writes from regs ----
    {
      const int sw0 = (kqd*32) ^ ((krow & 7) << 4);
      const int sw1 = (kqd*32 + 16) ^ ((krow & 7) << 4);
      *(f16x8*)(Kb + krow*128 + sw0) = kr0;
      *(f16x8*)(Kb + krow*128 + sw1) = kr1;
      if (SPLIT) {
        *(f16x8*)(Klo + krow*128 + sw0) = krl0;
        *(f16x8*)(Klo + krow*128 + sw1) = krl1;
      }
#pragma unroll
      for (int j = 0; j < 8; ++j) {
        const int dd = vdc*8 + j;
        f16x2 hv = {vr0[j], vr1[j]};
        *(f16x2*)(Vb + dd*128 + ((vtp*4) ^ ((dd & 7) << 4))) = hv;
        if (SPLIT) {
          f16x2 lv = {vrl0[j], vrl1[j]};
          *(f16x2*)(Vlo + dd*128 + ((vtp*4) ^ ((dd & 7) << 4))) = lv;
        }
      }
    }
    // ---- prefetch tile t0+64 into regs (hidden under compute) ----
    if (t0 + 64 < S_LEN) {
      const long kb = ((long)(t0 + 64 + krow)*NB + b)*ldk + qoff + kqd*16;
      kr0 = *(const f16x8*)(Kh + kb);
      kr1 = *(const f16x8*)(Kh + kb + 8);
      if (SPLIT) { krl0 = *(const f16x8*)(Kl + kb); krl1 = *(const f16x8*)(Kl + kb + 8); }
      const long vb = ((long)(t0 + 64 + 2*vtp)*NB + b)*ldv + qoff + vdc*8;
      vr0 = *(const f16x8*)(Vh + vb);
      vr1 = *(const f16x8*)(Vh + vb + (long)NB*ldv);
      if (SPLIT) { vrl0 = *(const f16x8*)(Vl + vb); vrl1 = *(const f16x8*)(Vl + vb + (long)NB*ldv); }
    }
    __syncthreads();

    // ---- S = Q K^T ----
    f32x4 s[2][4];
#pragma unroll
    for (int mi = 0; mi < 2; ++mi)
#pragma unroll
      for (int ni = 0; ni < 4; ++ni)
#pragma unroll
        for (int e = 0; e < 4; ++e) s[mi][ni][e] = 0.f;
#pragma unroll
    for (int kk = 0; kk < 2; ++kk) {
      f16x8 kb[4], kbl[4];
#pragma unroll
      for (int ni = 0; ni < 4; ++ni) {
        const int r = ni*16 + lr;
        const int bo = (lk*16 + kk*64) ^ ((r & 7) << 4);
        kb[ni] = *(const f16x8*)(Kb + r*128 + bo);
        if (SPLIT) kbl[ni] = *(const f16x8*)(Klo + r*128 + bo);
      }
#pragma unroll
      for (int mi = 0; mi < 2; ++mi)
#pragma unroll
        for (int ni = 0; ni < 4; ++ni) {
          s[mi][ni] = __builtin_amdgcn_mfma_f32_16x16x32_f16(qa[mi][kk], kb[ni], s[mi][ni], 0, 0, 0);
          if (SPLIT) {
            s[mi][ni] = __builtin_amdgcn_mfma_f32_16x16x32_f16(qa[mi][kk], kbl[ni], s[mi][ni], 0, 0, 0);
            s[mi][ni] = __builtin_amdgcn_mfma_f32_16x16x32_f16(qal[mi][kk], kb[ni], s[mi][ni], 0, 0, 0);
          }
        }
    }

    // ---- online softmax ----
#pragma unroll
    for (int mi = 0; mi < 2; ++mi) {
      float rm[4];
#pragma unroll
      for (int i = 0; i < 4; ++i)
        rm[i] = fmaxf(fmaxf(s[mi][0][i], s[mi][1][i]), fmaxf(s[mi][2][i], s[mi][3][i]));
#pragma unroll
      for (int off = 1; off < 16; off <<= 1)
#pragma unroll
        for (int i = 0; i < 4; ++i) rm[i] = fmaxf(rm[i], __shfl_xor(rm[i], off));
      float rs[4], corr[4];
#pragma unroll
      for (int i = 0; i < 4; ++i) {
        const float mnew = fmaxf(m_run[mi][i], rm[i]);
        corr[i] = __expf(m_run[mi][i] - mnew);
        m_run[mi][i] = mnew;
        float lsum = 0.f;
#pragma unroll
        for (int ni = 0; ni < 4; ++ni) {
          float p = __expf(s[mi][ni][i] - mnew);
          s[mi][ni][i] = p; lsum += p;
        }
        rs[i] = lsum;
      }
#pragma unroll
      for (int off = 1; off < 16; off <<= 1)
#pragma unroll
        for (int i = 0; i < 4; ++i) rs[i] += __shfl_xor(rs[i], off);
#pragma unroll
      for (int i = 0; i < 4; ++i) {
        l_run[mi][i] = l_run[mi][i]*corr[i] + rs[i];
#pragma unroll
        for (int ni = 0; ni < 4; ++ni) oacc[mi][ni][i] *= corr[i];
      }
    }

    // ---- P -> LDS (wave-private) ----
#pragma unroll
    for (int mi = 0; mi < 2; ++mi)
#pragma unroll
      for (int ni = 0; ni < 4; ++ni)
#pragma unroll
        for (int i = 0; i < 4; ++i) {
          const int row = mi*16 + lk*4 + i;
          const int col = ni*16 + lr;
          const int ad = row*128 + ((col*2) ^ ((row & 7) << 4));
          float pv = s[mi][ni][i];
          _Float16 ph = (_Float16)pv;
          *(_Float16*)(Pw + ad) = ph;
          if (SPLIT) *(_Float16*)(Pwl + ad) = (_Float16)(pv - (float)ph);
        }

    // ---- O += P V ----
#pragma unroll
    for (int kk = 0; kk < 2; ++kk) {
      f16x8 vb[4], vbl[4], pa[2], pal[2];
#pragma unroll
      for (int ni = 0; ni < 4; ++ni) {
        const int r = ni*16 + lr;
        const int bo = (lk*16 + kk*64) ^ ((r & 7) << 4);
        vb[ni] = *(const f16x8*)(Vb + r*128 + bo);
        if (SPLIT) vbl[ni] = *(const f16x8*)(Vlo + r*128 + bo);
      }
#pragma unroll
      for (int mi = 0; mi < 2; ++mi) {
        const int r = mi*16 + lr;
        const int bo = (lk*16 + kk*64) ^ ((r & 7) << 4);
        pa[mi] = *(const f16x8*)(Pw + r*128 + bo);
        if (SPLIT) pal[mi] = *(const f16x8*)(Pwl + r*128 + bo);
      }
#pragma unroll
      for (int mi = 0; mi < 2; ++mi)
#pragma unroll
        for (int ni = 0; ni < 4; ++ni) {
          oacc[mi][ni] = __builtin_amdgcn_mfma_f32_16x16x32_f16(pa[mi], vb[ni], oacc[mi][ni], 0, 0, 0);
          if (SPLIT) {
            oacc[mi][ni] = __builtin_amdgcn_mfma_f32_16x16x32_f16(pa[mi], vbl[ni], oacc[mi][ni], 0, 0, 0);
            oacc[mi][ni] = __builtin_amdgcn_mfma_f32_16x16x32_f16(pal[mi], vb[ni], oacc[mi][ni], 0, 0, 0);
          }
        }
    }
  }

#pragma unroll
  for (int mi = 0; mi < 2; ++mi)
#pragma unroll
    for (int i = 0; i < 4; ++i) {
      const float inv = 1.0f / l_run[mi][i];
      const int q = s0 + wave*32 + mi*16 + lk*4 + i;
      float* orow = Op + ((long)q * NB + b) * ldo + qoff;
#pragma unroll
      for (int ni = 0; ni < 4; ++ni) orow[ni*16 + lr] = oacc[mi][ni][i] * inv;
    }
}

// ---------------------------------------------------------------------------
// LayerNorm over c=512, one wave per row.
// ---------------------------------------------------------------------------
__global__ __launch_bounds__(256)
void ln_k(const float* __restrict__ X, const float* __restrict__ g,
          const float* __restrict__ bb, float* __restrict__ Y)
{
  const int t = threadIdx.x;
  const int lane = t & 63;
  const long row = (long)blockIdx.x * 4 + (t >> 6);
  const float* xr = X + row * CDIM;
  float4 v0 = *(const float4*)(xr + lane*4);
  float4 v1 = *(const float4*)(xr + 256 + lane*4);
  float s = v0.x+v0.y+v0.z+v0.w + v1.x+v1.y+v1.z+v1.w;
#pragma unroll
  for (int off = 1; off < 64; off <<= 1) s += __shfl_xor(s, off);
  const float mean = s * (1.0f/512.0f);
  float d[8] = {v0.x-mean, v0.y-mean, v0.z-mean, v0.w-mean,
                v1.x-mean, v1.y-mean, v1.z-mean, v1.w-mean};
  float sq = d[0]*d[0]+d[1]*d[1]+d[2]*d[2]+d[3]*d[3]
           + d[4]*d[4]+d[5]*d[5]+d[6]*d[6]+d[7]*d[7];
#pragma unroll
  for (int off = 1; off < 64; off <<= 1) sq += __shfl_xor(sq, off);
  const float inv = 1.0f / sqrtf(sq * (1.0f/512.0f) + 1e-5f);
  float4 g0 = *(const float4*)(g + lane*4);
  float4 g1 = *(const float4*)(g + 256 + lane*4);
  float4 b0 = *(const float4*)(bb + lane*4);
  float4 b1 = *(const float4*)(bb + 256 + lane*4);
  float4 o0, o1;
  o0.x = d[0]*inv*g0.x + b0.x; o0.y = d[1]*inv*g0.y + b0.y;
  o0.z = d[2]*inv*g0.z + b0.z; o0.w = d[3]*inv*g0.w + b0.w;
  o1.x = d[4]*inv*g1.x + b1.x; o1.y = d[5]*inv*g1.y + b1.y;
  o1.z = d[6]*inv*g1.z + b1.z; o1.w = d[7]*inv*g1.w + b1.w;
  *(float4*)(Y + row*CDIM + lane*4) = o0;
  *(float4*)(Y + row*CDIM + 256 + lane*4) = o1;
}

// ---------------------------------------------------------------------------
// Pack x (N,C,H,W) -> enc_flat (S,n,c) and posisted = enc_flat + PE2D.
// ---------------------------------------------------------------------------
__global__ void pack_pe_k(const float* __restrict__ x, float* __restrict__ encf,
                          float* __restrict__ posd)
{
  __shared__ float tl[32][33];
  const int b = blockIdx.z;
  const int s0 = blockIdx.x*32, c0 = blockIdx.y*32;
#pragma unroll
  for (int i = 0; i < 4; ++i) {
    int ci = threadIdx.y + i*8;
    tl[ci][threadIdx.x] = x[((long)b*CDIM + c0+ci)*S_LEN + s0 + threadIdx.x];
  }
  __syncthreads();
#pragma unroll
  for (int i = 0; i < 4; ++i) {
    int si = threadIdx.y + i*8;
    int s = s0 + si;
    int ch = c0 + threadIdx.x;
    float val = tl[threadIdx.x][si];
    long o = ((long)s*NB + b)*CDIM + ch;
    encf[o] = val;
    int pos = (ch < 256) ? (s & 31) : (s >> 5);
    int j = (ch & 255) >> 1;
    float dv = expf((float)(2*j) * (-9.210340371976184f / 256.0f));
    float ang = (float)pos * dv;
    float pe = (ch & 1) ? cosf(ang) : sinf(ang);
    posd[o] = val + pe;
  }
}

// (S,n,c) token-major -> (n,c,S) output layout
__global__ void tpose_k(const float* __restrict__ in, float* __restrict__ out)
{
  __shared__ float tl[32][33];
  const int b = blockIdx.z;
  const int s0 = blockIdx.x*32, c0 = blockIdx.y*32;
#pragma unroll
  for (int i = 0; i < 4; ++i) {
    int si = threadIdx.y + i*8;
    tl[si][threadIdx.x] = in[((long)(s0+si)*NB + b)*CDIM + c0 + threadIdx.x];
  }
  __syncthreads();
#pragma unroll
  for (int i = 0; i < 4; ++i) {
    int ci = threadIdx.y + i*8;
    out[((long)b*CDIM + c0+ci)*S_LEN + s0 + threadIdx.x] = tl[threadIdx.x][ci];
  }
}

// cb_w (c,K) -> transposed split-fp16 codebook [K][c] hi/lo
__global__ void cbt16_k(const float* __restrict__ cb,
                        _Float16* __restrict__ outh, _Float16* __restrict__ outl)
{
  __shared__ float tl[32][33];
  const int k0 = blockIdx.x*32, c0 = blockIdx.y*32;
#pragma unroll
  for (int i = 0; i < 4; ++i) {
    int ci = threadIdx.y + i*8;
    tl[ci][threadIdx.x] = cb[(long)(c0+ci)*KCB + k0 + threadIdx.x];
  }
  __syncthreads();
#pragma unroll
  for (int i = 0; i < 4; ++i) {
    int ki = threadIdx.y + i*8;
    float v = tl[threadIdx.x][ki];
    _Float16 h = (_Float16)v;
    outh[(long)(k0+ki)*CDIM + c0 + threadIdx.x] = h;
    outl[(long)(k0+ki)*CDIM + c0 + threadIdx.x] = (_Float16)(v - (float)h);
  }
}

// fp32 -> fp16 elementwise (cb_w -> CBH), 8 per thread
__global__ __launch_bounds__(256)
void conv16_k(const float* __restrict__ in, _Float16* __restrict__ out)
{
  const long i = ((long)blockIdx.x * 256 + threadIdx.x) * 8;
  float4 v0 = *(const float4*)(in + i);
  float4 v1 = *(const float4*)(in + i + 4);
  f16x8 h;
  h[0]=(_Float16)v0.x; h[1]=(_Float16)v0.y; h[2]=(_Float16)v0.z; h[3]=(_Float16)v0.w;
  h[4]=(_Float16)v1.x; h[5]=(_Float16)v1.y; h[6]=(_Float16)v1.z; h[7]=(_Float16)v1.w;
  *(f16x8*)(out + i) = h;
}

// Per-token row of logits: argmax (np first-occurrence) + write P (fp16)
__global__ __launch_bounds__(256)
void simstats_k(const float* __restrict__ logits, _Float16* __restrict__ Pbuf,
                int* __restrict__ codes_tok, float* __restrict__ codes_out)
{
  const long phys = blockIdx.x;
  const float* rowp = logits + phys * KCB;
  const int t = threadIdx.x;
  float vals[16];
#pragma unroll
  for (int rep = 0; rep < 4; ++rep) {
    float4 v = *(const float4*)(rowp + rep*1024 + t*4);
    vals[rep*4+0]=v.x; vals[rep*4+1]=v.y; vals[rep*4+2]=v.z; vals[rep*4+3]=v.w;
  }
  float mv = -INFINITY; int mi = 0;
#pragma unroll
  for (int rep = 0; rep < 4; ++rep)
#pragma unroll
    for (int j = 0; j < 4; ++j) {
      float xv = vals[rep*4+j];
      int ix = rep*1024 + t*4 + j;
      if (xv > mv) { mv = xv; mi = ix; }
    }
  const int lane = t & 63, wid = t >> 6;
#pragma unroll
  for (int off = 1; off < 64; off <<= 1) {
    float ov = __shfl_xor(mv, off);
    int   oi = __shfl_xor(mi, off);
    if (ov > mv || (ov == mv && oi < mi)) { mv = ov; mi = oi; }
  }
  __shared__ float smax[4]; __shared__ int sidx[4]; __shared__ float ssum[4];
  __shared__ float fm; __shared__ int fi; __shared__ float sinv;
  if (lane == 0) { smax[wid] = mv; sidx[wid] = mi; }
  __syncthreads();
  if (t == 0) {
    float bm = smax[0]; int bi = sidx[0];
    for (int wq = 1; wq < 4; ++wq)
      if (smax[wq] > bm || (smax[wq] == bm && sidx[wq] < bi)) { bm = smax[wq]; bi = sidx[wq]; }
    fm = bm; fi = bi;
  }
  __syncthreads();
  const float Mx = fm;
  float se = 0.f;
#pragma unroll
  for (int q = 0; q < 16; ++q) se += __expf(vals[q] - Mx);
#pragma unroll
  for (int off = 1; off < 64; off <<= 1) se += __shfl_xor(se, off);
  if (lane == 0) ssum[wid] = se;
  __syncthreads();
  const int b = (int)(phys >> 10), s = (int)(phys & 1023);
  if (t == 0) {
    float tot = ssum[0]+ssum[1]+ssum[2]+ssum[3];
    sinv = 1.0f / tot;
    codes_tok[s*NB + b] = fi;
    codes_out[phys] = (float)fi;
  }
  __syncthreads();
  const float inv = sinv;
  _Float16* prow = Pbuf + ((long)s*NB + b) * KCB;
#pragma unroll
  for (int rep = 0; rep < 4; ++rep) {
    f16x4 pv;
#pragma unroll
    for (int j = 0; j < 4; ++j) pv[j] = (_Float16)(__expf(vals[rep*4+j] - Mx) * inv);
    *(f16x4*)(prow + rep*1024 + t*4) = pv;
  }
}

// quant = (hard - soft) + soft, also emit hard. hard gathered from split cb.
__global__ __launch_bounds__(128)
void quant_k(const float* __restrict__ soft, const int* __restrict__ codes_tok,
             const _Float16* __restrict__ cbh, const _Float16* __restrict__ cbl,
             float* __restrict__ quant, float* __restrict__ hardb)
{
  const int r = blockIdx.x;
  const int code = codes_tok[r];
  const int c = threadIdx.x * 4;
  f16x4 hh = *(const f16x4*)(cbh + (long)code*CDIM + c);
  f16x4 hl = *(const f16x4*)(cbl + (long)code*CDIM + c);
  float4 sf = *(const float4*)(soft + (long)r*CDIM + c);
  float4 h, q;
  h.x = (float)hh[0] + (float)hl[0]; h.y = (float)hh[1] + (float)hl[1];
  h.z = (float)hh[2] + (float)hl[2]; h.w = (float)hh[3] + (float)hl[3];
  q.x = (h.x - sf.x) + sf.x; q.y = (h.y - sf.y) + sf.y;
  q.z = (h.z - sf.z) + sf.z; q.w = (h.w - sf.w) + sf.w;
  *(float4*)(quant + (long)r*CDIM + c) = q;
  *(float4*)(hardb + (long)r*CDIM + c) = h;
}

// Detect the storage format of the bool mask buffer.
__global__ void maskdetect_k(const void* __restrict__ mask, int* __restrict__ flag)
{
  const unsigned int* wds = (const unsigned int*)mask;
  int t = threadIdx.x;
  int okI = 1, okF = 1, okL = 1;
  for (int i = t; i < 2048; i += 256) {
    unsigned int u = wds[i];
    if (u > 1u) okI = 0;
    if (u != 0u && u != 0x3F800000u) okF = 0;
    if ((i & 1) ? (u != 0u) : (u > 1u)) okL = 0;
  }
  __shared__ int sI, sF, sL;
  if (t == 0) { sI = 1; sF = 1; sL = 1; }
  __syncthreads();
  if (!okI) atomicAnd(&sI, 0);
  if (!okF) atomicAnd(&sF, 0);
  if (!okL) atomicAnd(&sL, 0);
  __syncthreads();
  if (t == 0) {
    int f;
    if (sI && sL) f = 3;
    else if (sI)  f = 1;
    else if (sF)  f = 2;
    else          f = 0;
    *flag = f;
  }
}

// mixed = mask ? enc_flat : post
__global__ __launch_bounds__(256)
void mixed_k(const float* __restrict__ encf, const float* __restrict__ post,
             const void* __restrict__ mask, const int* __restrict__ flag,
             float* __restrict__ outx)
{
  long gid = (long)blockIdx.x * blockDim.x + threadIdx.x;
  int r = (int)(gid >> 7);
  int c = (int)(gid & 127) * 4;
  int f = *flag;
  bool mv;
  if (f == 0)      mv = ((const unsigned char*)mask)[r] != 0;
  else if (f == 1) mv = ((const int*)mask)[r] != 0;
  else if (f == 3) mv = ((const long long*)mask)[r] != 0;
  else             mv = ((const float*)mask)[r] != 0.0f;
  const float* src = mv ? encf : post;
  *(float4*)(outx + (long)r*CDIM + c) = *(const float4*)(src + (long)r*CDIM + c);
}

// ---------------------------------------------------------------------------
// Host-side wrappers
// ---------------------------------------------------------------------------
static void sg64_b(hipStream_t st, const float* A, const float* W, const float* bias,
                   float* C) {
  hgemm_k<64,1,0,true,false,false,false,false><<<dim3(CDIM/128, NTOK/64), 256, 0, st>>>(
      A, W, bias, nullptr, 0, C, CDIM, NTOK, CDIM, CDIM, nullptr, nullptr, nullptr, nullptr);
}
static void sg64_br(hipStream_t st, const float* A, const float* W, const float* bias,
                    const float* R, float* C) {
  hgemm_k<64,1,0,true,true,false,false,false><<<dim3(CDIM/128, NTOK/64), 256, 0, st>>>(
      A, W, bias, R, CDIM, C, CDIM, NTOK, CDIM, CDIM, nullptr, nullptr, nullptr, nullptr);
}
static void sg64_brelu(hipStream_t st, const float* A, const float* W, const float* bias,
                       float* C) {
  hgemm_k<64,1,0,true,false,true,false,false><<<dim3(CDIM/128, NTOK/64), 256, 0, st>>>(
      A, W, bias, nullptr, 0, C, CDIM, NTOK, CDIM, CDIM, nullptr, nullptr, nullptr, nullptr);
}
static void hg64_b(hipStream_t st, const float* A, const float* W, const float* bias,
                   float* C) {
  hgemm_k<64,0,0,true,false,false,false,false><<<dim3(CDIM/128, NTOK/64), 256, 0, st>>>(
      A, W, bias, nullptr, 0, C, CDIM, NTOK, CDIM, CDIM, nullptr, nullptr, nullptr, nullptr);
}
static void hg64_br(hipStream_t st, const float* A, const float* W, const float* bias,
                    const float* R, float* C) {
  hgemm_k<64,0,0,true,true,false,false,false><<<dim3(CDIM/128, NTOK/64), 256, 0, st>>>(
      A, W, bias, R, CDIM, C, CDIM, NTOK, CDIM, CDIM, nullptr, nullptr, nullptr, nullptr);
}
static void hg64_brelu(hipStream_t st, const float* A, const float* W, const float* bias,
                       float* C) {
  hgemm_k<64,0,0,true,false,true,false,false><<<dim3(CDIM/128, NTOK/64), 256, 0, st>>>(
      A, W, bias, nullptr, 0, C, CDIM, NTOK, CDIM, CDIM, nullptr, nullptr, nullptr, nullptr);
}

extern "C" void kernel_launch(void* const* d_in, const int* in_sizes, int n_in,
                              void* d_out, int out_size, void* d_ws, size_t ws_size,
                              hipStream_t stream)
{
  const float* x       = (const float*)d_in[0];
  const float* pre_w   = (const float*)d_in[1];
  const float* pre_b   = (const float*)d_in[2];
  const float* post_w  = (const float*)d_in[3];
  const float* post_b  = (const float*)d_in[4];
  const float* cb_w    = (const float*)d_in[5];
  const float* e_qkv_w = (const float*)d_in[6];
  const float* e_qkv_b = (const float*)d_in[7];
  const float* e_o_w   = (const float*)d_in[8];
  const float* e_o_b   = (const float*)d_in[9];
  const float* e_ln1_w = (const float*)d_in[10];
  const float* e_ln1_b = (const float*)d_in[11];
  const float* e_ln2_w = (const float*)d_in[12];
  const float* e_ln2_b = (const float*)d_in[13];
  const float* e_f1_w  = (const float*)d_in[14];
  const float* e_f1_b  = (const float*)d_in[15];
  const float* e_f2_w  = (const float*)d_in[16];
  const float* e_f2_b  = (const float*)d_in[17];
  const float* d_sqkv_w= (const float*)d_in[18];
  const float* d_sqkv_b= (const float*)d_in[19];
  const float* d_so_w  = (const float*)d_in[20];
  const float* d_so_b  = (const float*)d_in[21];
  const float* d_cqkv_w= (const float*)d_in[22];
  const float* d_cqkv_b= (const float*)d_in[23];
  const float* d_co_w  = (const float*)d_in[24];
  const float* d_co_b  = (const float*)d_in[25];
  const float* d_ln1w  = (const float*)d_in[26];
  const float* d_ln1b  = (const float*)d_in[27];
  const float* d_ln2w  = (const float*)d_in[28];
  const float* d_ln2b  = (const float*)d_in[29];
  const float* d_ln3w  = (const float*)d_in[30];
  const float* d_ln3b  = (const float*)d_in[31];
  const float* d_f1w   = (const float*)d_in[32];
  const float* d_f1b   = (const float*)d_in[33];
  const float* d_f2w   = (const float*)d_in[34];
  const float* d_f2b   = (const float*)d_in[35];
  const void*  mask    = d_in[36];

  float* out = (float*)d_out;
  float* o_quant  = out;
  float* o_high   = out + 4194304;
  float* o_softs  = out + 8388608;
  float* o_hards  = out + 12582912;
  float* o_codes  = out + 16777216;
  float* o_logits = out + 16785408;

  float* ws    = (float*)d_ws;
  float* ENC   = ws;
  float* Xb    = ws + TOKC;
  float* T1    = ws + 2*TOKC;
  float* T2    = ws + 3*TOKC;
  float* QKV   = ws + 4*TOKC;
  float* MEMB  = ws + 7*TOKC;
  float* CBREG = ws + 8*TOKC;                         // KCB*CDIM floats
  int*   CODES = (int*)(CBREG + (long)KCB*CDIM);
  int*   FLAG  = CODES + NTOK;
  float* HARDB = QKV;
  float* QUANT = QKV + TOKC;
  _Float16* PBUF = (_Float16*)QKV;
  _Float16* CBH  = (_Float16*)T1;                     // plain fp16 cb_w (c,K)
  _Float16* QKVh = (_Float16*)QKV;                    // [NTOK][3C] halves
  _Float16* QKVl = QKVh + (long)NTOK*3*CDIM;
  _Float16* CQh  = (_Float16*)QKV;
  _Float16* KVh  = (_Float16*)(QKV + TOKC);
  _Float16* CBT16h = (_Float16*)CBREG;                // [K][c] hi
  _Float16* CBT16l = CBT16h + (long)KCB*CDIM;         // [K][c] lo
  _Float16* PREH = (_Float16*)T2;                     // pre in split fp16
  _Float16* PREL = PREH + TOKC;

  const size_t NEED = (size_t)(8*TOKC + (long)KCB*CDIM + 2*NTOK + NTOK + 16) * 4;
  if (ws_size < NEED) return;

  const int M = NTOK;
  dim3 tgrid(S_LEN/32, CDIM/32, NB), tblk(32, 8);
  dim3 agrid(S_LEN/128, NB*8);

  pack_pe_k<<<tgrid, tblk, 0, stream>>>(x, ENC, Xb);
  cbt16_k<<<dim3(KCB/32, CDIM/32), tblk, 0, stream>>>(cb_w, CBT16h, CBT16l);
  maskdetect_k<<<1, 256, 0, stream>>>(mask, FLAG);

  // -------- encoder (split-fp16 MFMA, argmax-critical) --------
  for (int i = 0; i < NLAYER; ++i) {
    hgemm_k<128,1,0,true,false,false,false,true><<<dim3(3*CDIM/128, M/128), 256, 0, stream>>>(
        Xb, e_qkv_w + (long)i*3*CDIM*CDIM, e_qkv_b + i*3*CDIM, nullptr, 0,
        nullptr, 3*CDIM, M, 3*CDIM, CDIM, QKVh, QKVl, nullptr, nullptr);
    mattn_k<1><<<agrid, 256, 0, stream>>>(QKVh, QKVl, 3*CDIM,
        QKVh+CDIM, QKVl+CDIM, 3*CDIM, QKVh+2*CDIM, QKVl+2*CDIM, 3*CDIM, T1, CDIM);
    sg64_br(stream, T1, e_o_w + (long)i*CDIM*CDIM, e_o_b + i*CDIM, Xb, T2);
    ln_k<<<M/4, 256, 0, stream>>>(T2, e_ln1_w + i*CDIM, e_ln1_b + i*CDIM, T1);
    sg64_brelu(stream, T1, e_f1_w + (long)i*CDIM*CDIM, e_f1_b + i*CDIM, T2);
    sg64_br(stream, T2, e_f2_w + (long)i*CDIM*CDIM, e_f2_b + i*CDIM, T1, T2);
    ln_k<<<M/4, 256, 0, stream>>>(T2, e_ln2_w + i*CDIM, e_ln2_b + i*CDIM, Xb);
  }

  // -------- codebook / quantizer --------
  // pre: fp32 out (T1) + split fp16 out (PREH/PREL in T2)
  hgemm_k<64,1,0,true,false,false,false,true><<<dim3(CDIM/128, M/64), 256, 0, stream>>>(
      Xb, pre_w, pre_b, nullptr, 0, T1, CDIM, M, CDIM, CDIM, PREH, PREL, nullptr, nullptr);
  tpose_k<<<tgrid, tblk, 0, stream>>>(T1, o_high);
  // sim: pure split-fp16 inputs (bit-identical to in-kernel conversion)
  hgemm_k<128,1,2,false,false,false,true,false><<<dim3(KCB/128, M/128), 256, 0, stream>>>(
      PREH, CBT16h, nullptr, nullptr, 0, o_logits, KCB, M, KCB, CDIM,
      nullptr, nullptr, PREL, CBT16l);
  conv16_k<<<(CDIM*(long)KCB)/(256*8), 256, 0, stream>>>(cb_w, CBH);
  simstats_k<<<NTOK, 256, 0, stream>>>(o_logits, PBUF, CODES, o_codes);
  hgemm_k<64,0,1,false,false,false,false,false><<<dim3(CDIM/128, M/64), 256, 0, stream>>>(
      PBUF, CBH, nullptr, nullptr, 0, T2, CDIM, M, CDIM, KCB,
      nullptr, nullptr, nullptr, nullptr);                                   // soft
  tpose_k<<<tgrid, tblk, 0, stream>>>(T2, o_softs);
  quant_k<<<NTOK, 128, 0, stream>>>(T2, CODES, CBT16h, CBT16l, QUANT, HARDB);
  tpose_k<<<tgrid, tblk, 0, stream>>>(HARDB, o_hards);
  hg64_b(stream, QUANT, post_w, post_b, MEMB);                               // post
  mixed_k<<<4096, 256, 0, stream>>>(ENC, MEMB, mask, FLAG, Xb);

  // -------- decoder (f16 MFMA) --------
  for (int i = 0; i < NLAYER; ++i) {
    hgemm_k<128,0,0,true,false,false,false,true><<<dim3(3*CDIM/128, M/128), 256, 0, stream>>>(
        Xb, d_sqkv_w + (long)i*3*CDIM*CDIM, d_sqkv_b + i*3*CDIM, nullptr, 0,
        nullptr, 3*CDIM, M, 3*CDIM, CDIM, QKVh, nullptr, nullptr, nullptr);
    mattn_k<0><<<agrid, 256, 0, stream>>>(QKVh, nullptr, 3*CDIM,
        QKVh+CDIM, nullptr, 3*CDIM, QKVh+2*CDIM, nullptr, 3*CDIM, T1, CDIM);
    hg64_br(stream, T1, d_so_w + (long)i*CDIM*CDIM, d_so_b + i*CDIM, Xb, T2);
    ln_k<<<M/4, 256, 0, stream>>>(T2, d_ln1w + i*CDIM, d_ln1b + i*CDIM, Xb);
    hgemm_k<64,0,0,true,false,false,false,true><<<dim3(CDIM/128, M/64), 256, 0, stream>>>(
        Xb, d_cqkv_w + (long)i*3*CDIM*CDIM, d_cqkv_b + i*3*CDIM, nullptr, 0,
        nullptr, CDIM, M, CDIM, CDIM, CQh, nullptr, nullptr, nullptr);
    hgemm_k<128,0,0,true,false,false,false,true><<<dim3(2*CDIM/128, M/128), 256, 0, stream>>>(
        MEMB, d_cqkv_w + (long)i*3*CDIM*CDIM + (long)CDIM*CDIM,
        d_cqkv_b + i*3*CDIM + CDIM, nullptr, 0,
        nullptr, 2*CDIM, M, 2*CDIM, CDIM, KVh, nullptr, nullptr, nullptr);
    mattn_k<0><<<agrid, 256, 0, stream>>>(CQh, nullptr, CDIM,
        KVh, nullptr, 2*CDIM, KVh+CDIM, nullptr, 2*CDIM, T1, CDIM);
    hg64_br(stream, T1, d_co_w + (long)i*CDIM*CDIM, d_co_b + i*CDIM, Xb, T2);
    ln_k<<<M/4, 256, 0, stream>>>(T2, d_ln2w + i*CDIM, d_ln2b + i*CDIM, Xb);
    hg64_brelu(stream, Xb, d_f1w + (long)i*CDIM*CDIM, d_f1b + i*CDIM, T2);
    hg64_br(stream, T2, d_f2w + (long)i*CDIM*CDIM, d_f2b + i*CDIM, Xb, T2);
    ln_k<<<M/4, 256, 0, stream>>>(T2, d_ln3w + i*CDIM, d_ln3b + i*CDIM, Xb);
  }
  tpose_k<<<tgrid, tblk, 0, stream>>>(Xb, o_quant);
}

// Round 9
// 4299.046 us; speedup vs baseline: 2.9159x; 1.0030x over previous
//
#include <hip/hip_runtime.h>
#include <math.h>

#define S_LEN 1024
#define NB 8
#define CDIM 512
#define KCB 4096
#define DH 64
#define NLAYER 6
#define NTOK (S_LEN*NB)
#define TOKC ((long)NTOK*CDIM)

typedef __attribute__((ext_vector_type(8))) _Float16 f16x8;
typedef __attribute__((ext_vector_type(4))) _Float16 f16x4;
typedef __attribute__((ext_vector_type(2))) _Float16 f16x2;
typedef __attribute__((ext_vector_type(4))) float f32x4;

// ---------------------------------------------------------------------------
// MFMA GEMM: C[M,N] = A[M,K] @ W[N,K]^T (+bias/res/relu).
// TM in {64,128}; N-tile 128. BK=64, mfma_f32_16x16x32_f16, XOR-swizzled LDS.
// SPLIT=1: hi/lo split-fp16, 3 MFMAs/pair (~fp32 accuracy).
// F16IN=1: A,W fp16 (plain). F16IN=2: A,W split fp16 hi/lo (Avl/Wvl), SPLIT=1.
// E16: epilogue writes fp16 hi (Ch16) (+lo Cl16 if SPLIT); also fp32 C if C!=0.
// OREMAP: output row (s*NB+b) -> (b*S_LEN+s).
// NOTE: A and C must NOT alias (blocks of one dispatch race) — enforced in
// kernel_launch buffer routing.
// ---------------------------------------------------------------------------
template<int TM, int SPLIT, int F16IN, bool BIAS, bool RES, bool RELU, bool OREMAP, bool E16>
__global__ __launch_bounds__(256)
void hgemm_k(const void* __restrict__ Av, const void* __restrict__ Wv,
             const float* __restrict__ bias, const float* __restrict__ Rsrc, int ldr,
             float* __restrict__ C, int ldc, int M, int N, int K,
             _Float16* __restrict__ Ch16, _Float16* __restrict__ Cl16,
             const void* __restrict__ Avl, const void* __restrict__ Wvl)
{
  constexpr int MI = TM / 32;
  constexpr int ATPR = 256 / TM;
  constexpr int ACOL = 64 / ATPR;
  __shared__ __align__(16) _Float16 Ah[TM*64];
  __shared__ __align__(16) _Float16 Bh[128*64];
  __shared__ __align__(16) _Float16 Al[SPLIT ? TM*64 : 8];
  __shared__ __align__(16) _Float16 Bl[SPLIT ? 128*64 : 8];
  const int t = threadIdx.x;
  const int m0 = blockIdx.y * TM, n0 = blockIdx.x * 128;

  const int arow = t / ATPR, apart = t % ATPR;
  const int brow = t >> 1, bpart = t & 1;

  const float*    Af  = (const float*)Av;
  const _Float16* Axh = (const _Float16*)Av;
  const _Float16* Axl = (const _Float16*)Avl;
  const float*    Wf  = (const float*)Wv;
  const _Float16* Wxh = (const _Float16*)Wv;
  const _Float16* Wxl = (const _Float16*)Wvl;
  const long aoff = (long)(m0 + arow) * K + apart * ACOL;
  const long boff = (long)(n0 + brow) * K + bpart * 32;

  const int lane = t & 63, wave = t >> 6;
  const int wm = wave >> 1, wn = wave & 1;
  const int lr = lane & 15, lk = lane >> 4;

  f32x4 acc[MI][4];
#pragma unroll
  for (int mi = 0; mi < MI; ++mi)
#pragma unroll
    for (int ni = 0; ni < 4; ++ni)
#pragma unroll
      for (int e = 0; e < 4; ++e) acc[mi][ni][e] = 0.f;

  float4 a4[ACOL/4], b4[8];
  f16x8  a16[ACOL/8], b16[4];
  f16x8  a16l[F16IN==2 ? ACOL/8 : 1], b16l[F16IN==2 ? 4 : 1];
  if (F16IN) {
#pragma unroll
    for (int g = 0; g < ACOL/8; ++g) a16[g] = *(const f16x8*)(Axh + aoff + g*8);
#pragma unroll
    for (int g = 0; g < 4; ++g) b16[g] = *(const f16x8*)(Wxh + boff + g*8);
    if (F16IN == 2) {
#pragma unroll
      for (int g = 0; g < ACOL/8; ++g) a16l[g] = *(const f16x8*)(Axl + aoff + g*8);
#pragma unroll
      for (int g = 0; g < 4; ++g) b16l[g] = *(const f16x8*)(Wxl + boff + g*8);
    }
  } else {
#pragma unroll
    for (int j = 0; j < ACOL/4; ++j) a4[j] = *(const float4*)(Af + aoff + j*4);
#pragma unroll
    for (int j = 0; j < 8; ++j) b4[j] = *(const float4*)(Wf + boff + j*4);
  }

  for (int k0 = 0; k0 < K; k0 += 64) {
    __syncthreads();
    if (F16IN) {
#pragma unroll
      for (int g = 0; g < ACOL/8; ++g) {
        const int sw = (apart*ACOL*2 + g*16) ^ ((arow & 7) << 4);
        *(f16x8*)((char*)Ah + arow*128 + sw) = a16[g];
        if (F16IN == 2) *(f16x8*)((char*)Al + arow*128 + sw) = a16l[g];
      }
#pragma unroll
      for (int g = 0; g < 4; ++g) {
        const int sw = (bpart*64 + g*16) ^ ((brow & 7) << 4);
        *(f16x8*)((char*)Bh + brow*128 + sw) = b16[g];
        if (F16IN == 2) *(f16x8*)((char*)Bl + brow*128 + sw) = b16l[g];
      }
    } else {
      const float* af = (const float*)a4;
#pragma unroll
      for (int g = 0; g < ACOL/8; ++g) {
        f16x8 h, l;
#pragma unroll
        for (int j = 0; j < 8; ++j) {
          float xv = af[g*8+j];
          _Float16 hh = (_Float16)xv;
          h[j] = hh;
          if (SPLIT) l[j] = (_Float16)(xv - (float)hh);
        }
        const int sw = (apart*ACOL*2 + g*16) ^ ((arow & 7) << 4);
        *(f16x8*)((char*)Ah + arow*128 + sw) = h;
        if (SPLIT) *(f16x8*)((char*)Al + arow*128 + sw) = l;
      }
      const float* bf = (const float*)b4;
#pragma unroll
      for (int g = 0; g < 4; ++g) {
        f16x8 h, l;
#pragma unroll
        for (int j = 0; j < 8; ++j) {
          float xv = bf[g*8+j];
          _Float16 hh = (_Float16)xv;
          h[j] = hh;
          if (SPLIT) l[j] = (_Float16)(xv - (float)hh);
        }
        const int sw = (bpart*64 + g*16) ^ ((brow & 7) << 4);
        *(f16x8*)((char*)Bh + brow*128 + sw) = h;
        if (SPLIT) *(f16x8*)((char*)Bl + brow*128 + sw) = l;
      }
    }
    __syncthreads();
    if (k0 + 64 < K) {
      if (F16IN) {
#pragma unroll
        for (int g = 0; g < ACOL/8; ++g) a16[g] = *(const f16x8*)(Axh + aoff + k0 + 64 + g*8);
#pragma unroll
        for (int g = 0; g < 4; ++g) b16[g] = *(const f16x8*)(Wxh + boff + k0 + 64 + g*8);
        if (F16IN == 2) {
#pragma unroll
          for (int g = 0; g < ACOL/8; ++g) a16l[g] = *(const f16x8*)(Axl + aoff + k0 + 64 + g*8);
#pragma unroll
          for (int g = 0; g < 4; ++g) b16l[g] = *(const f16x8*)(Wxl + boff + k0 + 64 + g*8);
        }
      } else {
#pragma unroll
        for (int j = 0; j < ACOL/4; ++j) a4[j] = *(const float4*)(Af + aoff + k0 + 64 + j*4);
#pragma unroll
        for (int j = 0; j < 8; ++j) b4[j] = *(const float4*)(Wf + boff + k0 + 64 + j*4);
      }
    }
#pragma unroll
    for (int kk = 0; kk < 2; ++kk) {
      f16x8 afh[MI], bfh[4], afl[MI], bfl[4];
#pragma unroll
      for (int mi = 0; mi < MI; ++mi) {
        const int r = wm*(TM/2) + mi*16 + lr;
        const int bo = (lk*16 + kk*64) ^ ((r & 7) << 4);
        afh[mi] = *(const f16x8*)((const char*)Ah + r*128 + bo);
        if (SPLIT) afl[mi] = *(const f16x8*)((const char*)Al + r*128 + bo);
      }
#pragma unroll
      for (int ni = 0; ni < 4; ++ni) {
        const int r = wn*64 + ni*16 + lr;
        const int bo = (lk*16 + kk*64) ^ ((r & 7) << 4);
        bfh[ni] = *(const f16x8*)((const char*)Bh + r*128 + bo);
        if (SPLIT) bfl[ni] = *(const f16x8*)((const char*)Bl + r*128 + bo);
      }
#pragma unroll
      for (int mi = 0; mi < MI; ++mi)
#pragma unroll
        for (int ni = 0; ni < 4; ++ni) {
          acc[mi][ni] = __builtin_amdgcn_mfma_f32_16x16x32_f16(afh[mi], bfh[ni], acc[mi][ni], 0, 0, 0);
          if (SPLIT) {
            acc[mi][ni] = __builtin_amdgcn_mfma_f32_16x16x32_f16(afh[mi], bfl[ni], acc[mi][ni], 0, 0, 0);
            acc[mi][ni] = __builtin_amdgcn_mfma_f32_16x16x32_f16(afl[mi], bfh[ni], acc[mi][ni], 0, 0, 0);
          }
        }
    }
  }

  float bvv[4];
  if (BIAS) {
#pragma unroll
    for (int ni = 0; ni < 4; ++ni) bvv[ni] = bias[n0 + wn*64 + ni*16 + lr];
  }
#pragma unroll
  for (int mi = 0; mi < MI; ++mi)
#pragma unroll
  for (int i = 0; i < 4; ++i) {
    const int rm = m0 + wm*(TM/2) + mi*16 + lk*4 + i;
    long orow = rm;
    if (OREMAP) orow = (long)(rm & (NB-1)) * S_LEN + (rm >> 3);
#pragma unroll
    for (int ni = 0; ni < 4; ++ni) {
      const int col = n0 + wn*64 + ni*16 + lr;
      float v = acc[mi][ni][i];
      if (BIAS) v += bvv[ni];
      if (RES)  v += Rsrc[(long)rm*ldr + col];
      if (RELU) v = fmaxf(v, 0.f);
      if (E16) {
        _Float16 hv = (_Float16)v;
        Ch16[(long)rm*ldc + col] = hv;
        if (SPLIT) Cl16[(long)rm*ldc + col] = (_Float16)(v - (float)hv);
        if (C != nullptr) C[orow*(long)ldc + col] = v;
      } else {
        C[orow*(long)ldc + col] = v;
      }
    }
  }
}

// ---------------------------------------------------------------------------
// MFMA flash attention, fp16 hi/lo inputs. 128 q rows x (b,head); 4 waves.
// K/V staged via register prefetch: tile t+1 global loads issued right after
// tile t's LDS writes, hiding load latency under compute. LDS XOR-swizzled.
// SPLIT=1: 3 MFMAs/pair. Q pre-scaled by 1/8 (exact).
// (Round-5 verified version: f16x2 V-stage, unconditional rescale.)
// ---------------------------------------------------------------------------
template<int SPLIT>
__global__ __launch_bounds__(256)
void mattn_k(const _Float16* __restrict__ Qh, const _Float16* __restrict__ Ql, int ldq,
             const _Float16* __restrict__ Kh, const _Float16* __restrict__ Kl, int ldk,
             const _Float16* __restrict__ Vh, const _Float16* __restrict__ Vl, int ldv,
             float* __restrict__ Op, int ldo)
{
  __shared__ __align__(16) char Pb[SPLIT ? 32768 : 16384];
  __shared__ __align__(16) char Kb[SPLIT ? 16384 : 8192];
  __shared__ __align__(16) char Vb[SPLIT ? 16384 : 8192];

  const int t = threadIdx.x;
  const int b = blockIdx.y >> 3, hd = blockIdx.y & 7;
  const int s0 = blockIdx.x * 128;
  const int qoff = hd * DH;
  const int wave = t >> 6, lane = t & 63;
  const int lr = lane & 15, lk = lane >> 4;
  const int krow = t >> 2, kqd = t & 3;
  const int vtp = t & 31, vdc = t >> 5;

  // ---- Q fragments direct from global, pre-scaled by 1/8 (exact) ----
  f16x8 qa[2][2], qal[2][2];
#pragma unroll
  for (int mi = 0; mi < 2; ++mi)
#pragma unroll
    for (int kk = 0; kk < 2; ++kk) {
      const int q = s0 + wave*32 + mi*16 + lr;
      const long base = ((long)q*NB + b)*ldq + qoff + kk*32 + lk*8;
      f16x8 v = *(const f16x8*)(Qh + base);
#pragma unroll
      for (int e = 0; e < 8; ++e) v[e] = v[e] * (_Float16)0.125f;
      qa[mi][kk] = v;
      if (SPLIT) {
        f16x8 w = *(const f16x8*)(Ql + base);
#pragma unroll
        for (int e = 0; e < 8; ++e) w[e] = w[e] * (_Float16)0.125f;
        qal[mi][kk] = w;
      }
    }

  float m_run[2][4], l_run[2][4];
  f32x4 oacc[2][4];
#pragma unroll
  for (int mi = 0; mi < 2; ++mi)
#pragma unroll
    for (int i = 0; i < 4; ++i) {
      m_run[mi][i] = -INFINITY; l_run[mi][i] = 0.f;
#pragma unroll
      for (int ni = 0; ni < 4; ++ni) oacc[mi][ni][i] = 0.f;
    }

  char* Pw  = Pb + wave*4096;
  char* Pwl = Pb + 16384 + wave*4096;
  char* Klo = Kb + 8192;
  char* Vlo = Vb + 8192;

  // ---- prologue: load tile 0 into regs ----
  f16x8 kr0, kr1, krl0, krl1, vr0, vr1, vrl0, vrl1;
  {
    const long kb = ((long)krow*NB + b)*ldk + qoff + kqd*16;
    kr0 = *(const f16x8*)(Kh + kb);
    kr1 = *(const f16x8*)(Kh + kb + 8);
    if (SPLIT) { krl0 = *(const f16x8*)(Kl + kb); krl1 = *(const f16x8*)(Kl + kb + 8); }
    const long vb = ((long)(2*vtp)*NB + b)*ldv + qoff + vdc*8;
    vr0 = *(const f16x8*)(Vh + vb);
    vr1 = *(const f16x8*)(Vh + vb + (long)NB*ldv);
    if (SPLIT) { vrl0 = *(const f16x8*)(Vl + vb); vrl1 = *(const f16x8*)(Vl + vb + (long)NB*ldv); }
  }

  for (int t0 = 0; t0 < S_LEN; t0 += 64) {
    __syncthreads();
    // ---- LDS writes from regs ----
    {
      const int sw0 = (kqd*32) ^ ((krow & 7) << 4);
      const int sw1 = (kqd*32 + 16) ^ ((krow & 7) << 4);
      *(f16x8*)(Kb + krow*128 + sw0) = kr0;
      *(f16x8*)(Kb + krow*128 + sw1) = kr1;
      if (SPLIT) {
        *(f16x8*)(Klo + krow*128 + sw0) = krl0;
        *(f16x8*)(Klo + krow*128 + sw1) = krl1;
      }
#pragma unroll
      for (int j = 0; j < 8; ++j) {
        const int dd = vdc*8 + j;
        f16x2 hv = {vr0[j], vr1[j]};
        *(f16x2*)(Vb + dd*128 + ((vtp*4) ^ ((dd & 7) << 4))) = hv;
        if (SPLIT) {
          f16x2 lv = {vrl0[j], vrl1[j]};
          *(f16x2*)(Vlo + dd*128 + ((vtp*4) ^ ((dd & 7) << 4))) = lv;
        }
      }
    }
    // ---- prefetch tile t0+64 into regs (hidden under compute) ----
    if (t0 + 64 < S_LEN) {
      const long kb = ((long)(t0 + 64 + krow)*NB + b)*ldk + qoff + kqd*16;
      kr0 = *(const f16x8*)(Kh + kb);
      kr1 = *(const f16x8*)(Kh + kb + 8);
      if (SPLIT) { krl0 = *(const f16x8*)(Kl + kb); krl1 = *(const f16x8*)(Kl + kb + 8); }
      const long vb = ((long)(t0 + 64 + 2*vtp)*NB + b)*ldv + qoff + vdc*8;
      vr0 = *(const f16x8*)(Vh + vb);
      vr1 = *(const f16x8*)(Vh + vb + (long)NB*ldv);
      if (SPLIT) { vrl0 = *(const f16x8*)(Vl + vb); vrl1 = *(const f16x8*)(Vl + vb + (long)NB*ldv); }
    }
    __syncthreads();

    // ---- S = Q K^T ----
    f32x4 s[2][4];
#pragma unroll
    for (int mi = 0; mi < 2; ++mi)
#pragma unroll
      for (int ni = 0; ni < 4; ++ni)
#pragma unroll
        for (int e = 0; e < 4; ++e) s[mi][ni][e] = 0.f;
#pragma unroll
    for (int kk = 0; kk < 2; ++kk) {
      f16x8 kb[4], kbl[4];
#pragma unroll
      for (int ni = 0; ni < 4; ++ni) {
        const int r = ni*16 + lr;
        const int bo = (lk*16 + kk*64) ^ ((r & 7) << 4);
        kb[ni] = *(const f16x8*)(Kb + r*128 + bo);
        if (SPLIT) kbl[ni] = *(const f16x8*)(Klo + r*128 + bo);
      }
#pragma unroll
      for (int mi = 0; mi < 2; ++mi)
#pragma unroll
        for (int ni = 0; ni < 4; ++ni) {
          s[mi][ni] = __builtin_amdgcn_mfma_f32_16x16x32_f16(qa[mi][kk], kb[ni], s[mi][ni], 0, 0, 0);
          if (SPLIT) {
            s[mi][ni] = __builtin_amdgcn_mfma_f32_16x16x32_f16(qa[mi][kk], kbl[ni], s[mi][ni], 0, 0, 0);
            s[mi][ni] = __builtin_amdgcn_mfma_f32_16x16x32_f16(qal[mi][kk], kb[ni], s[mi][ni], 0, 0, 0);
          }
        }
    }

    // ---- online softmax (unconditional rescale; round-5 verified) ----
#pragma unroll
    for (int mi = 0; mi < 2; ++mi) {
      float rm[4];
#pragma unroll
      for (int i = 0; i < 4; ++i)
        rm[i] = fmaxf(fmaxf(s[mi][0][i], s[mi][1][i]), fmaxf(s[mi][2][i], s[mi][3][i]));
#pragma unroll
      for (int off = 1; off < 16; off <<= 1)
#pragma unroll
        for (int i = 0; i < 4; ++i) rm[i] = fmaxf(rm[i], __shfl_xor(rm[i], off));
      float rs[4], corr[4];
#pragma unroll
      for (int i = 0; i < 4; ++i) {
        const float mnew = fmaxf(m_run[mi][i], rm[i]);
        corr[i] = __expf(m_run[mi][i] - mnew);
        m_run[mi][i] = mnew;
        float lsum = 0.f;
#pragma unroll
        for (int ni = 0; ni < 4; ++ni) {
          float p = __expf(s[mi][ni][i] - mnew);
          s[mi][ni][i] = p; lsum += p;
        }
        rs[i] = lsum;
      }
#pragma unroll
      for (int off = 1; off < 16; off <<= 1)
#pragma unroll
        for (int i = 0; i < 4; ++i) rs[i] += __shfl_xor(rs[i], off);
#pragma unroll
      for (int i = 0; i < 4; ++i) {
        l_run[mi][i] = l_run[mi][i]*corr[i] + rs[i];
#pragma unroll
        for (int ni = 0; ni < 4; ++ni) oacc[mi][ni][i] *= corr[i];
      }
    }

    // ---- P -> LDS (wave-private) ----
#pragma unroll
    for (int mi = 0; mi < 2; ++mi)
#pragma unroll
      for (int ni = 0; ni < 4; ++ni)
#pragma unroll
        for (int i = 0; i < 4; ++i) {
          const int row = mi*16 + lk*4 + i;
          const int col = ni*16 + lr;
          const int ad = row*128 + ((col*2) ^ ((row & 7) << 4));
          float pv = s[mi][ni][i];
          _Float16 ph = (_Float16)pv;
          *(_Float16*)(Pw + ad) = ph;
          if (SPLIT) *(_Float16*)(Pwl + ad) = (_Float16)(pv - (float)ph);
        }

    // ---- O += P V ----
#pragma unroll
    for (int kk = 0; kk < 2; ++kk) {
      f16x8 vb[4], vbl[4], pa[2], pal[2];
#pragma unroll
      for (int ni = 0; ni < 4; ++ni) {
        const int r = ni*16 + lr;
        const int bo = (lk*16 + kk*64) ^ ((r & 7) << 4);
        vb[ni] = *(const f16x8*)(Vb + r*128 + bo);
        if (SPLIT) vbl[ni] = *(const f16x8*)(Vlo + r*128 + bo);
      }
#pragma unroll
      for (int mi = 0; mi < 2; ++mi) {
        const int r = mi*16 + lr;
        const int bo = (lk*16 + kk*64) ^ ((r & 7) << 4);
        pa[mi] = *(const f16x8*)(Pw + r*128 + bo);
        if (SPLIT) pal[mi] = *(const f16x8*)(Pwl + r*128 + bo);
      }
#pragma unroll
      for (int mi = 0; mi < 2; ++mi)
#pragma unroll
        for (int ni = 0; ni < 4; ++ni) {
          oacc[mi][ni] = __builtin_amdgcn_mfma_f32_16x16x32_f16(pa[mi], vb[ni], oacc[mi][ni], 0, 0, 0);
          if (SPLIT) {
            oacc[mi][ni] = __builtin_amdgcn_mfma_f32_16x16x32_f16(pa[mi], vbl[ni], oacc[mi][ni], 0, 0, 0);
            oacc[mi][ni] = __builtin_amdgcn_mfma_f32_16x16x32_f16(pal[mi], vb[ni], oacc[mi][ni], 0, 0, 0);
          }
        }
    }
  }

#pragma unroll
  for (int mi = 0; mi < 2; ++mi)
#pragma unroll
    for (int i = 0; i < 4; ++i) {
      const float inv = 1.0f / l_run[mi][i];
      const int q = s0 + wave*32 + mi*16 + lk*4 + i;
      float* orow = Op + ((long)q * NB + b) * ldo + qoff;
#pragma unroll
      for (int ni = 0; ni < 4; ++ni) orow[ni*16 + lr] = oacc[mi][ni][i] * inv;
    }
}

// ---------------------------------------------------------------------------
// LayerNorm over c=512, one wave per row.
// ---------------------------------------------------------------------------
__global__ __launch_bounds__(256)
void ln_k(const float* __restrict__ X, const float* __restrict__ g,
          const float* __restrict__ bb, float* __restrict__ Y)
{
  const int t = threadIdx.x;
  const int lane = t & 63;
  const long row = (long)blockIdx.x * 4 + (t >> 6);
  const float* xr = X + row * CDIM;
  float4 v0 = *(const float4*)(xr + lane*4);
  float4 v1 = *(const float4*)(xr + 256 + lane*4);
  float s = v0.x+v0.y+v0.z+v0.w + v1.x+v1.y+v1.z+v1.w;
#pragma unroll
  for (int off = 1; off < 64; off <<= 1) s += __shfl_xor(s, off);
  const float mean = s * (1.0f/512.0f);
  float d[8] = {v0.x-mean, v0.y-mean, v0.z-mean, v0.w-mean,
                v1.x-mean, v1.y-mean, v1.z-mean, v1.w-mean};
  float sq = d[0]*d[0]+d[1]*d[1]+d[2]*d[2]+d[3]*d[3]
           + d[4]*d[4]+d[5]*d[5]+d[6]*d[6]+d[7]*d[7];
#pragma unroll
  for (int off = 1; off < 64; off <<= 1) sq += __shfl_xor(sq, off);
  const float inv = 1.0f / sqrtf(sq * (1.0f/512.0f) + 1e-5f);
  float4 g0 = *(const float4*)(g + lane*4);
  float4 g1 = *(const float4*)(g + 256 + lane*4);
  float4 b0 = *(const float4*)(bb + lane*4);
  float4 b1 = *(const float4*)(bb + 256 + lane*4);
  float4 o0, o1;
  o0.x = d[0]*inv*g0.x + b0.x; o0.y = d[1]*inv*g0.y + b0.y;
  o0.z = d[2]*inv*g0.z + b0.z; o0.w = d[3]*inv*g0.w + b0.w;
  o1.x = d[4]*inv*g1.x + b1.x; o1.y = d[5]*inv*g1.y + b1.y;
  o1.z = d[6]*inv*g1.z + b1.z; o1.w = d[7]*inv*g1.w + b1.w;
  *(float4*)(Y + row*CDIM + lane*4) = o0;
  *(float4*)(Y + row*CDIM + 256 + lane*4) = o1;
}

// ---------------------------------------------------------------------------
// Pack x (N,C,H,W) -> enc_flat (S,n,c) and posisted = enc_flat + PE2D.
// ---------------------------------------------------------------------------
__global__ void pack_pe_k(const float* __restrict__ x, float* __restrict__ encf,
                          float* __restrict__ posd)
{
  __shared__ float tl[32][33];
  const int b = blockIdx.z;
  const int s0 = blockIdx.x*32, c0 = blockIdx.y*32;
#pragma unroll
  for (int i = 0; i < 4; ++i) {
    int ci = threadIdx.y + i*8;
    tl[ci][threadIdx.x] = x[((long)b*CDIM + c0+ci)*S_LEN + s0 + threadIdx.x];
  }
  __syncthreads();
#pragma unroll
  for (int i = 0; i < 4; ++i) {
    int si = threadIdx.y + i*8;
    int s = s0 + si;
    int ch = c0 + threadIdx.x;
    float val = tl[threadIdx.x][si];
    long o = ((long)s*NB + b)*CDIM + ch;
    encf[o] = val;
    int pos = (ch < 256) ? (s & 31) : (s >> 5);
    int j = (ch & 255) >> 1;
    float dv = expf((float)(2*j) * (-9.210340371976184f / 256.0f));
    float ang = (float)pos * dv;
    float pe = (ch & 1) ? cosf(ang) : sinf(ang);
    posd[o] = val + pe;
  }
}

// (S,n,c) token-major -> (n,c,S) output layout
__global__ void tpose_k(const float* __restrict__ in, float* __restrict__ out)
{
  __shared__ float tl[32][33];
  const int b = blockIdx.z;
  const int s0 = blockIdx.x*32, c0 = blockIdx.y*32;
#pragma unroll
  for (int i = 0; i < 4; ++i) {
    int si = threadIdx.y + i*8;
    tl[si][threadIdx.x] = in[((long)(s0+si)*NB + b)*CDIM + c0 + threadIdx.x];
  }
  __syncthreads();
#pragma unroll
  for (int i = 0; i < 4; ++i) {
    int ci = threadIdx.y + i*8;
    out[((long)b*CDIM + c0+ci)*S_LEN + s0 + threadIdx.x] = tl[threadIdx.x][ci];
  }
}

// cb_w (c,K) -> transposed split-fp16 codebook [K][c] hi/lo
__global__ void cbt16_k(const float* __restrict__ cb,
                        _Float16* __restrict__ outh, _Float16* __restrict__ outl)
{
  __shared__ float tl[32][33];
  const int k0 = blockIdx.x*32, c0 = blockIdx.y*32;
#pragma unroll
  for (int i = 0; i < 4; ++i) {
    int ci = threadIdx.y + i*8;
    tl[ci][threadIdx.x] = cb[(long)(c0+ci)*KCB + k0 + threadIdx.x];
  }
  __syncthreads();
#pragma unroll
  for (int i = 0; i < 4; ++i) {
    int ki = threadIdx.y + i*8;
    float v = tl[threadIdx.x][ki];
    _Float16 h = (_Float16)v;
    outh[(long)(k0+ki)*CDIM + c0 + threadIdx.x] = h;
    outl[(long)(k0+ki)*CDIM + c0 + threadIdx.x] = (_Float16)(v - (float)h);
  }
}

// fp32 -> fp16 elementwise (cb_w -> CBH), 8 per thread
__global__ __launch_bounds__(256)
void conv16_k(const float* __restrict__ in, _Float16* __restrict__ out)
{
  const long i = ((long)blockIdx.x * 256 + threadIdx.x) * 8;
  float4 v0 = *(const float4*)(in + i);
  float4 v1 = *(const float4*)(in + i + 4);
  f16x8 h;
  h[0]=(_Float16)v0.x; h[1]=(_Float16)v0.y; h[2]=(_Float16)v0.z; h[3]=(_Float16)v0.w;
  h[4]=(_Float16)v1.x; h[5]=(_Float16)v1.y; h[6]=(_Float16)v1.z; h[7]=(_Float16)v1.w;
  *(f16x8*)(out + i) = h;
}

// Per-token row of logits: argmax (np first-occurrence) + write P (fp16)
__global__ __launch_bounds__(256)
void simstats_k(const float* __restrict__ logits, _Float16* __restrict__ Pbuf,
                int* __restrict__ codes_tok, float* __restrict__ codes_out)
{
  const long phys = blockIdx.x;
  const float* rowp = logits + phys * KCB;
  const int t = threadIdx.x;
  float vals[16];
#pragma unroll
  for (int rep = 0; rep < 4; ++rep) {
    float4 v = *(const float4*)(rowp + rep*1024 + t*4);
    vals[rep*4+0]=v.x; vals[rep*4+1]=v.y; vals[rep*4+2]=v.z; vals[rep*4+3]=v.w;
  }
  float mv = -INFINITY; int mi = 0;
#pragma unroll
  for (int rep = 0; rep < 4; ++rep)
#pragma unroll
    for (int j = 0; j < 4; ++j) {
      float xv = vals[rep*4+j];
      int ix = rep*1024 + t*4 + j;
      if (xv > mv) { mv = xv; mi = ix; }
    }
  const int lane = t & 63, wid = t >> 6;
#pragma unroll
  for (int off = 1; off < 64; off <<= 1) {
    float ov = __shfl_xor(mv, off);
    int   oi = __shfl_xor(mi, off);
    if (ov > mv || (ov == mv && oi < mi)) { mv = ov; mi = oi; }
  }
  __shared__ float smax[4]; __shared__ int sidx[4]; __shared__ float ssum[4];
  __shared__ float fm; __shared__ int fi; __shared__ float sinv;
  if (lane == 0) { smax[wid] = mv; sidx[wid] = mi; }
  __syncthreads();
  if (t == 0) {
    float bm = smax[0]; int bi = sidx[0];
    for (int wq = 1; wq < 4; ++wq)
      if (smax[wq] > bm || (smax[wq] == bm && sidx[wq] < bi)) { bm = smax[wq]; bi = sidx[wq]; }
    fm = bm; fi = bi;
  }
  __syncthreads();
  const float Mx = fm;
  float se = 0.f;
#pragma unroll
  for (int q = 0; q < 16; ++q) se += __expf(vals[q] - Mx);
#pragma unroll
  for (int off = 1; off < 64; off <<= 1) se += __shfl_xor(se, off);
  if (lane == 0) ssum[wid] = se;
  __syncthreads();
  const int b = (int)(phys >> 10), s = (int)(phys & 1023);
  if (t == 0) {
    float tot = ssum[0]+ssum[1]+ssum[2]+ssum[3];
    sinv = 1.0f / tot;
    codes_tok[s*NB + b] = fi;
    codes_out[phys] = (float)fi;
  }
  __syncthreads();
  const float inv = sinv;
  _Float16* prow = Pbuf + ((long)s*NB + b) * KCB;
#pragma unroll
  for (int rep = 0; rep < 4; ++rep) {
    f16x4 pv;
#pragma unroll
    for (int j = 0; j < 4; ++j) pv[j] = (_Float16)(__expf(vals[rep*4+j] - Mx) * inv);
    *(f16x4*)(prow + rep*1024 + t*4) = pv;
  }
}

// quant = (hard - soft) + soft, also emit hard. hard gathered from split cb.
__global__ __launch_bounds__(128)
void quant_k(const float* __restrict__ soft, const int* __restrict__ codes_tok,
             const _Float16* __restrict__ cbh, const _Float16* __restrict__ cbl,
             float* __restrict__ quant, float* __restrict__ hardb)
{
  const int r = blockIdx.x;
  const int code = codes_tok[r];
  const int c = threadIdx.x * 4;
  f16x4 hh = *(const f16x4*)(cbh + (long)code*CDIM + c);
  f16x4 hl = *(const f16x4*)(cbl + (long)code*CDIM + c);
  float4 sf = *(const float4*)(soft + (long)r*CDIM + c);
  float4 h, q;
  h.x = (float)hh[0] + (float)hl[0]; h.y = (float)hh[1] + (float)hl[1];
  h.z = (float)hh[2] + (float)hl[2]; h.w = (float)hh[3] + (float)hl[3];
  q.x = (h.x - sf.x) + sf.x; q.y = (h.y - sf.y) + sf.y;
  q.z = (h.z - sf.z) + sf.z; q.w = (h.w - sf.w) + sf.w;
  *(float4*)(quant + (long)r*CDIM + c) = q;
  *(float4*)(hardb + (long)r*CDIM + c) = h;
}

// Detect the storage format of the bool mask buffer.
__global__ void maskdetect_k(const void* __restrict__ mask, int* __restrict__ flag)
{
  const unsigned int* wds = (const unsigned int*)mask;
  int t = threadIdx.x;
  int okI = 1, okF = 1, okL = 1;
  for (int i = t; i < 2048; i += 256) {
    unsigned int u = wds[i];
    if (u > 1u) okI = 0;
    if (u != 0u && u != 0x3F800000u) okF = 0;
    if ((i & 1) ? (u != 0u) : (u > 1u)) okL = 0;
  }
  __shared__ int sI, sF, sL;
  if (t == 0) { sI = 1; sF = 1; sL = 1; }
  __syncthreads();
  if (!okI) atomicAnd(&sI, 0);
  if (!okF) atomicAnd(&sF, 0);
  if (!okL) atomicAnd(&sL, 0);
  __syncthreads();
  if (t == 0) {
    int f;
    if (sI && sL) f = 3;
    else if (sI)  f = 1;
    else if (sF)  f = 2;
    else          f = 0;
    *flag = f;
  }
}

// mixed = mask ? enc_flat : post
__global__ __launch_bounds__(256)
void mixed_k(const float* __restrict__ encf, const float* __restrict__ post,
             const void* __restrict__ mask, const int* __restrict__ flag,
             float* __restrict__ outx)
{
  long gid = (long)blockIdx.x * blockDim.x + threadIdx.x;
  int r = (int)(gid >> 7);
  int c = (int)(gid & 127) * 4;
  int f = *flag;
  bool mv;
  if (f == 0)      mv = ((const unsigned char*)mask)[r] != 0;
  else if (f == 1) mv = ((const int*)mask)[r] != 0;
  else if (f == 3) mv = ((const long long*)mask)[r] != 0;
  else             mv = ((const float*)mask)[r] != 0.0f;
  const float* src = mv ? encf : post;
  *(float4*)(outx + (long)r*CDIM + c) = *(const float4*)(src + (long)r*CDIM + c);
}

// ---------------------------------------------------------------------------
// Host-side wrappers
// ---------------------------------------------------------------------------
static void sg64_br(hipStream_t st, const float* A, const float* W, const float* bias,
                    const float* R, float* C) {
  hgemm_k<64,1,0,true,true,false,false,false><<<dim3(CDIM/128, NTOK/64), 256, 0, st>>>(
      A, W, bias, R, CDIM, C, CDIM, NTOK, CDIM, CDIM, nullptr, nullptr, nullptr, nullptr);
}
static void sg64_brelu(hipStream_t st, const float* A, const float* W, const float* bias,
                       float* C) {
  hgemm_k<64,1,0,true,false,true,false,false><<<dim3(CDIM/128, NTOK/64), 256, 0, st>>>(
      A, W, bias, nullptr, 0, C, CDIM, NTOK, CDIM, CDIM, nullptr, nullptr, nullptr, nullptr);
}
static void hg64_b(hipStream_t st, const float* A, const float* W, const float* bias,
                   float* C) {
  hgemm_k<64,0,0,true,false,false,false,false><<<dim3(CDIM/128, NTOK/64), 256, 0, st>>>(
      A, W, bias, nullptr, 0, C, CDIM, NTOK, CDIM, CDIM, nullptr, nullptr, nullptr, nullptr);
}
static void hg64_br(hipStream_t st, const float* A, const float* W, const float* bias,
                    const float* R, float* C) {
  hgemm_k<64,0,0,true,true,false,false,false><<<dim3(CDIM/128, NTOK/64), 256, 0, st>>>(
      A, W, bias, R, CDIM, C, CDIM, NTOK, CDIM, CDIM, nullptr, nullptr, nullptr, nullptr);
}
static void hg64_brelu(hipStream_t st, const float* A, const float* W, const float* bias,
                       float* C) {
  hgemm_k<64,0,0,true,false,true,false,false><<<dim3(CDIM/128, NTOK/64), 256, 0, st>>>(
      A, W, bias, nullptr, 0, C, CDIM, NTOK, CDIM, CDIM, nullptr, nullptr, nullptr, nullptr);
}

extern "C" void kernel_launch(void* const* d_in, const int* in_sizes, int n_in,
                              void* d_out, int out_size, void* d_ws, size_t ws_size,
                              hipStream_t stream)
{
  const float* x       = (const float*)d_in[0];
  const float* pre_w   = (const float*)d_in[1];
  const float* pre_b   = (const float*)d_in[2];
  const float* post_w  = (const float*)d_in[3];
  const float* post_b  = (const float*)d_in[4];
  const float* cb_w    = (const float*)d_in[5];
  const float* e_qkv_w = (const float*)d_in[6];
  const float* e_qkv_b = (const float*)d_in[7];
  const float* e_o_w   = (const float*)d_in[8];
  const float* e_o_b   = (const float*)d_in[9];
  const float* e_ln1_w = (const float*)d_in[10];
  const float* e_ln1_b = (const float*)d_in[11];
  const float* e_ln2_w = (const float*)d_in[12];
  const float* e_ln2_b = (const float*)d_in[13];
  const float* e_f1_w  = (const float*)d_in[14];
  const float* e_f1_b  = (const float*)d_in[15];
  const float* e_f2_w  = (const float*)d_in[16];
  const float* e_f2_b  = (const float*)d_in[17];
  const float* d_sqkv_w= (const float*)d_in[18];
  const float* d_sqkv_b= (const float*)d_in[19];
  const float* d_so_w  = (const float*)d_in[20];
  const float* d_so_b  = (const float*)d_in[21];
  const float* d_cqkv_w= (const float*)d_in[22];
  const float* d_cqkv_b= (const float*)d_in[23];
  const float* d_co_w  = (const float*)d_in[24];
  const float* d_co_b  = (const float*)d_in[25];
  const float* d_ln1w  = (const float*)d_in[26];
  const float* d_ln1b  = (const float*)d_in[27];
  const float* d_ln2w  = (const float*)d_in[28];
  const float* d_ln2b  = (const float*)d_in[29];
  const float* d_ln3w  = (const float*)d_in[30];
  const float* d_ln3b  = (const float*)d_in[31];
  const float* d_f1w   = (const float*)d_in[32];
  const float* d_f1b   = (const float*)d_in[33];
  const float* d_f2w   = (const float*)d_in[34];
  const float* d_f2b   = (const float*)d_in[35];
  const void*  mask    = d_in[36];

  float* out = (float*)d_out;
  float* o_quant  = out;
  float* o_high   = out + 4194304;
  float* o_softs  = out + 8388608;
  float* o_hards  = out + 12582912;
  float* o_codes  = out + 16777216;
  float* o_logits = out + 16785408;

  float* ws    = (float*)d_ws;
  float* ENC   = ws;
  float* Xb    = ws + TOKC;
  float* T1    = ws + 2*TOKC;
  float* T2    = ws + 3*TOKC;
  float* QKV   = ws + 4*TOKC;
  float* MEMB  = ws + 7*TOKC;
  float* CBREG = ws + 8*TOKC;                         // KCB*CDIM floats
  int*   CODES = (int*)(CBREG + (long)KCB*CDIM);
  int*   FLAG  = CODES + NTOK;
  float* HARDB = QKV;
  float* QUANT = QKV + TOKC;
  _Float16* PBUF = (_Float16*)QKV;
  _Float16* CBH  = (_Float16*)T1;                     // plain fp16 cb_w (c,K)
  _Float16* QKVh = (_Float16*)QKV;                    // [NTOK][3C] halves
  _Float16* QKVl = QKVh + (long)NTOK*3*CDIM;
  _Float16* CQh  = (_Float16*)QKV;
  _Float16* KVh  = (_Float16*)(QKV + TOKC);
  _Float16* CBT16h = (_Float16*)CBREG;                // [K][c] hi
  _Float16* CBT16l = CBT16h + (long)KCB*CDIM;         // [K][c] lo
  _Float16* PREH = (_Float16*)T2;                     // pre in split fp16
  _Float16* PREL = PREH + TOKC;

  const size_t NEED = (size_t)(8*TOKC + (long)KCB*CDIM + 2*NTOK + NTOK + 16) * 4;
  if (ws_size < NEED) return;

  const int M = NTOK;
  dim3 tgrid(S_LEN/32, CDIM/32, NB), tblk(32, 8);
  dim3 agrid(S_LEN/128, NB*8);

  pack_pe_k<<<tgrid, tblk, 0, stream>>>(x, ENC, Xb);
  cbt16_k<<<dim3(KCB/32, CDIM/32), tblk, 0, stream>>>(cb_w, CBT16h, CBT16l);
  maskdetect_k<<<1, 256, 0, stream>>>(mask, FLAG);

  // -------- encoder (split-fp16 MFMA, argmax-critical) --------
  // FFN hidden routed via QKV scratch so GEMM A never aliases GEMM C.
  for (int i = 0; i < NLAYER; ++i) {
    hgemm_k<128,1,0,true,false,false,false,true><<<dim3(3*CDIM/128, M/128), 256, 0, stream>>>(
        Xb, e_qkv_w + (long)i*3*CDIM*CDIM, e_qkv_b + i*3*CDIM, nullptr, 0,
        nullptr, 3*CDIM, M, 3*CDIM, CDIM, QKVh, QKVl, nullptr, nullptr);
    mattn_k<1><<<agrid, 256, 0, stream>>>(QKVh, QKVl, 3*CDIM,
        QKVh+CDIM, QKVl+CDIM, 3*CDIM, QKVh+2*CDIM, QKVl+2*CDIM, 3*CDIM, T1, CDIM);
    sg64_br(stream, T1, e_o_w + (long)i*CDIM*CDIM, e_o_b + i*CDIM, Xb, T2);
    ln_k<<<M/4, 256, 0, stream>>>(T2, e_ln1_w + i*CDIM, e_ln1_b + i*CDIM, T1);
    sg64_brelu(stream, T1, e_f1_w + (long)i*CDIM*CDIM, e_f1_b + i*CDIM, QKV);
    sg64_br(stream, QKV, e_f2_w + (long)i*CDIM*CDIM, e_f2_b + i*CDIM, T1, T2);
    ln_k<<<M/4, 256, 0, stream>>>(T2, e_ln2_w + i*CDIM, e_ln2_b + i*CDIM, Xb);
  }

  // -------- codebook / quantizer --------
  hgemm_k<64,1,0,true,false,false,false,true><<<dim3(CDIM/128, M/64), 256, 0, stream>>>(
      Xb, pre_w, pre_b, nullptr, 0, T1, CDIM, M, CDIM, CDIM, PREH, PREL, nullptr, nullptr);
  tpose_k<<<tgrid, tblk, 0, stream>>>(T1, o_high);
  hgemm_k<128,1,2,false,false,false,true,false><<<dim3(KCB/128, M/128), 256, 0, stream>>>(
      PREH, CBT16h, nullptr, nullptr, 0, o_logits, KCB, M, KCB, CDIM,
      nullptr, nullptr, PREL, CBT16l);
  conv16_k<<<(CDIM*(long)KCB)/(256*8), 256, 0, stream>>>(cb_w, CBH);
  simstats_k<<<NTOK, 256, 0, stream>>>(o_logits, PBUF, CODES, o_codes);
  hgemm_k<64,0,1,false,false,false,false,false><<<dim3(CDIM/128, M/64), 256, 0, stream>>>(
      PBUF, CBH, nullptr, nullptr, 0, T2, CDIM, M, CDIM, KCB,
      nullptr, nullptr, nullptr, nullptr);                                   // soft
  tpose_k<<<tgrid, tblk, 0, stream>>>(T2, o_softs);
  quant_k<<<NTOK, 128, 0, stream>>>(T2, CODES, CBT16h, CBT16l, QUANT, HARDB);
  tpose_k<<<tgrid, tblk, 0, stream>>>(HARDB, o_hards);
  hg64_b(stream, QUANT, post_w, post_b, MEMB);                               // post
  mixed_k<<<4096, 256, 0, stream>>>(ENC, MEMB, mask, FLAG, Xb);

  // -------- decoder (f16 MFMA) --------
  // FFN hidden routed via T1 so GEMM A never aliases GEMM C.
  for (int i = 0; i < NLAYER; ++i) {
    hgemm_k<128,0,0,true,false,false,false,true><<<dim3(3*CDIM/128, M/128), 256, 0, stream>>>(
        Xb, d_sqkv_w + (long)i*3*CDIM*CDIM, d_sqkv_b + i*3*CDIM, nullptr, 0,
        nullptr, 3*CDIM, M, 3*CDIM, CDIM, QKVh, nullptr, nullptr, nullptr);
    mattn_k<0><<<agrid, 256, 0, stream>>>(QKVh, nullptr, 3*CDIM,
        QKVh+CDIM, nullptr, 3*CDIM, QKVh+2*CDIM, nullptr, 3*CDIM, T1, CDIM);
    hg64_br(stream, T1, d_so_w + (long)i*CDIM*CDIM, d_so_b + i*CDIM, Xb, T2);
    ln_k<<<M/4, 256, 0, stream>>>(T2, d_ln1w + i*CDIM, d_ln1b + i*CDIM, Xb);
    hgemm_k<64,0,0,true,false,false,false,true><<<dim3(CDIM/128, M/64), 256, 0, stream>>>(
        Xb, d_cqkv_w + (long)i*3*CDIM*CDIM, d_cqkv_b + i*3*CDIM, nullptr, 0,
        nullptr, CDIM, M, CDIM, CDIM, CQh, nullptr, nullptr, nullptr);
    hgemm_k<128,0,0,true,false,false,false,true><<<dim3(2*CDIM/128, M/128), 256, 0, stream>>>(
        MEMB, d_cqkv_w + (long)i*3*CDIM*CDIM + (long)CDIM*CDIM,
        d_cqkv_b + i*3*CDIM + CDIM, nullptr, 0,
        nullptr, 2*CDIM, M, 2*CDIM, CDIM, KVh, nullptr, nullptr, nullptr);
    mattn_k<0><<<agrid, 256, 0, stream>>>(CQh, nullptr, CDIM,
        KVh, nullptr, 2*CDIM, KVh+CDIM, nullptr, 2*CDIM, T1, CDIM);
    hg64_br(stream, T1, d_co_w + (long)i*CDIM*CDIM, d_co_b + i*CDIM, Xb, T2);
    ln_k<<<M/4, 256, 0, stream>>>(T2, d_ln2w + i*CDIM, d_ln2b + i*CDIM, Xb);
    hg64_brelu(stream, Xb, d_f1w + (long)i*CDIM*CDIM, d_f1b + i*CDIM, T1);
    hg64_br(stream, T1, d_f2w + (long)i*CDIM*CDIM, d_f2b + i*CDIM, Xb, T2);
    ln_k<<<M/4, 256, 0, stream>>>(T2, d_ln3w + i*CDIM, d_ln3b + i*CDIM, Xb);
  }
  tpose_k<<<tgrid, tblk, 0, stream>>>(Xb, o_quant);
}

// Round 10
// 4125.942 us; speedup vs baseline: 3.0383x; 1.0420x over previous
//
#include <hip/hip_runtime.h>
#include <math.h>

#define S_LEN 1024
#define NB 8
#define CDIM 512
#define KCB 4096
#define DH 64
#define NLAYER 6
#define NTOK (S_LEN*NB)
#define TOKC ((long)NTOK*CDIM)

typedef __attribute__((ext_vector_type(8))) _Float16 f16x8;
typedef __attribute__((ext_vector_type(4))) _Float16 f16x4;
typedef __attribute__((ext_vector_type(2))) _Float16 f16x2;
typedef __attribute__((ext_vector_type(4))) float f32x4;

// ---------------------------------------------------------------------------
// MFMA GEMM: C[M,N] = A[M,K] @ W[N,K]^T (+bias/res/relu).
// TM in {64,128}; N-tile 128. BK=64, mfma_f32_16x16x32_f16, XOR-swizzled LDS.
// SPLIT=1: hi/lo split-fp16, 3 MFMAs/pair (~fp32 accuracy).
// F16IN=1: A,W fp16 (plain). F16IN=2: A,W split fp16 hi/lo (Avl/Wvl), SPLIT=1.
// E16: epilogue writes fp16 hi (Ch16) (+lo Cl16 if SPLIT); also fp32 C if C!=0.
// OREMAP: output row (s*NB+b) -> (b*S_LEN+s).
// NOTE: A and C must NOT alias (blocks of one dispatch race) — enforced in
// kernel_launch buffer routing.
// ---------------------------------------------------------------------------
template<int TM, int SPLIT, int F16IN, bool BIAS, bool RES, bool RELU, bool OREMAP, bool E16>
__global__ __launch_bounds__(256)
void hgemm_k(const void* __restrict__ Av, const void* __restrict__ Wv,
             const float* __restrict__ bias, const float* __restrict__ Rsrc, int ldr,
             float* __restrict__ C, int ldc, int M, int N, int K,
             _Float16* __restrict__ Ch16, _Float16* __restrict__ Cl16,
             const void* __restrict__ Avl, const void* __restrict__ Wvl)
{
  constexpr int MI = TM / 32;
  constexpr int ATPR = 256 / TM;
  constexpr int ACOL = 64 / ATPR;
  __shared__ __align__(16) _Float16 Ah[TM*64];
  __shared__ __align__(16) _Float16 Bh[128*64];
  __shared__ __align__(16) _Float16 Al[SPLIT ? TM*64 : 8];
  __shared__ __align__(16) _Float16 Bl[SPLIT ? 128*64 : 8];
  const int t = threadIdx.x;
  const int m0 = blockIdx.y * TM, n0 = blockIdx.x * 128;

  const int arow = t / ATPR, apart = t % ATPR;
  const int brow = t >> 1, bpart = t & 1;

  const float*    Af  = (const float*)Av;
  const _Float16* Axh = (const _Float16*)Av;
  const _Float16* Axl = (const _Float16*)Avl;
  const float*    Wf  = (const float*)Wv;
  const _Float16* Wxh = (const _Float16*)Wv;
  const _Float16* Wxl = (const _Float16*)Wvl;
  const long aoff = (long)(m0 + arow) * K + apart * ACOL;
  const long boff = (long)(n0 + brow) * K + bpart * 32;

  const int lane = t & 63, wave = t >> 6;
  const int wm = wave >> 1, wn = wave & 1;
  const int lr = lane & 15, lk = lane >> 4;

  f32x4 acc[MI][4];
#pragma unroll
  for (int mi = 0; mi < MI; ++mi)
#pragma unroll
    for (int ni = 0; ni < 4; ++ni)
#pragma unroll
      for (int e = 0; e < 4; ++e) acc[mi][ni][e] = 0.f;

  float4 a4[ACOL/4], b4[8];
  f16x8  a16[ACOL/8], b16[4];
  f16x8  a16l[F16IN==2 ? ACOL/8 : 1], b16l[F16IN==2 ? 4 : 1];
  if (F16IN) {
#pragma unroll
    for (int g = 0; g < ACOL/8; ++g) a16[g] = *(const f16x8*)(Axh + aoff + g*8);
#pragma unroll
    for (int g = 0; g < 4; ++g) b16[g] = *(const f16x8*)(Wxh + boff + g*8);
    if (F16IN == 2) {
#pragma unroll
      for (int g = 0; g < ACOL/8; ++g) a16l[g] = *(const f16x8*)(Axl + aoff + g*8);
#pragma unroll
      for (int g = 0; g < 4; ++g) b16l[g] = *(const f16x8*)(Wxl + boff + g*8);
    }
  } else {
#pragma unroll
    for (int j = 0; j < ACOL/4; ++j) a4[j] = *(const float4*)(Af + aoff + j*4);
#pragma unroll
    for (int j = 0; j < 8; ++j) b4[j] = *(const float4*)(Wf + boff + j*4);
  }

  for (int k0 = 0; k0 < K; k0 += 64) {
    __syncthreads();
    if (F16IN) {
#pragma unroll
      for (int g = 0; g < ACOL/8; ++g) {
        const int sw = (apart*ACOL*2 + g*16) ^ ((arow & 7) << 4);
        *(f16x8*)((char*)Ah + arow*128 + sw) = a16[g];
        if (F16IN == 2) *(f16x8*)((char*)Al + arow*128 + sw) = a16l[g];
      }
#pragma unroll
      for (int g = 0; g < 4; ++g) {
        const int sw = (bpart*64 + g*16) ^ ((brow & 7) << 4);
        *(f16x8*)((char*)Bh + brow*128 + sw) = b16[g];
        if (F16IN == 2) *(f16x8*)((char*)Bl + brow*128 + sw) = b16l[g];
      }
    } else {
      const float* af = (const float*)a4;
#pragma unroll
      for (int g = 0; g < ACOL/8; ++g) {
        f16x8 h, l;
#pragma unroll
        for (int j = 0; j < 8; ++j) {
          float xv = af[g*8+j];
          _Float16 hh = (_Float16)xv;
          h[j] = hh;
          if (SPLIT) l[j] = (_Float16)(xv - (float)hh);
        }
        const int sw = (apart*ACOL*2 + g*16) ^ ((arow & 7) << 4);
        *(f16x8*)((char*)Ah + arow*128 + sw) = h;
        if (SPLIT) *(f16x8*)((char*)Al + arow*128 + sw) = l;
      }
      const float* bf = (const float*)b4;
#pragma unroll
      for (int g = 0; g < 4; ++g) {
        f16x8 h, l;
#pragma unroll
        for (int j = 0; j < 8; ++j) {
          float xv = bf[g*8+j];
          _Float16 hh = (_Float16)xv;
          h[j] = hh;
          if (SPLIT) l[j] = (_Float16)(xv - (float)hh);
        }
        const int sw = (bpart*64 + g*16) ^ ((brow & 7) << 4);
        *(f16x8*)((char*)Bh + brow*128 + sw) = h;
        if (SPLIT) *(f16x8*)((char*)Bl + brow*128 + sw) = l;
      }
    }
    __syncthreads();
    if (k0 + 64 < K) {
      if (F16IN) {
#pragma unroll
        for (int g = 0; g < ACOL/8; ++g) a16[g] = *(const f16x8*)(Axh + aoff + k0 + 64 + g*8);
#pragma unroll
        for (int g = 0; g < 4; ++g) b16[g] = *(const f16x8*)(Wxh + boff + k0 + 64 + g*8);
        if (F16IN == 2) {
#pragma unroll
          for (int g = 0; g < ACOL/8; ++g) a16l[g] = *(const f16x8*)(Axl + aoff + k0 + 64 + g*8);
#pragma unroll
          for (int g = 0; g < 4; ++g) b16l[g] = *(const f16x8*)(Wxl + boff + k0 + 64 + g*8);
        }
      } else {
#pragma unroll
        for (int j = 0; j < ACOL/4; ++j) a4[j] = *(const float4*)(Af + aoff + k0 + 64 + j*4);
#pragma unroll
        for (int j = 0; j < 8; ++j) b4[j] = *(const float4*)(Wf + boff + k0 + 64 + j*4);
      }
    }
#pragma unroll
    for (int kk = 0; kk < 2; ++kk) {
      f16x8 afh[MI], bfh[4], afl[MI], bfl[4];
#pragma unroll
      for (int mi = 0; mi < MI; ++mi) {
        const int r = wm*(TM/2) + mi*16 + lr;
        const int bo = (lk*16 + kk*64) ^ ((r & 7) << 4);
        afh[mi] = *(const f16x8*)((const char*)Ah + r*128 + bo);
        if (SPLIT) afl[mi] = *(const f16x8*)((const char*)Al + r*128 + bo);
      }
#pragma unroll
      for (int ni = 0; ni < 4; ++ni) {
        const int r = wn*64 + ni*16 + lr;
        const int bo = (lk*16 + kk*64) ^ ((r & 7) << 4);
        bfh[ni] = *(const f16x8*)((const char*)Bh + r*128 + bo);
        if (SPLIT) bfl[ni] = *(const f16x8*)((const char*)Bl + r*128 + bo);
      }
#pragma unroll
      for (int mi = 0; mi < MI; ++mi)
#pragma unroll
        for (int ni = 0; ni < 4; ++ni) {
          acc[mi][ni] = __builtin_amdgcn_mfma_f32_16x16x32_f16(afh[mi], bfh[ni], acc[mi][ni], 0, 0, 0);
          if (SPLIT) {
            acc[mi][ni] = __builtin_amdgcn_mfma_f32_16x16x32_f16(afh[mi], bfl[ni], acc[mi][ni], 0, 0, 0);
            acc[mi][ni] = __builtin_amdgcn_mfma_f32_16x16x32_f16(afl[mi], bfh[ni], acc[mi][ni], 0, 0, 0);
          }
        }
    }
  }

  float bvv[4];
  if (BIAS) {
#pragma unroll
    for (int ni = 0; ni < 4; ++ni) bvv[ni] = bias[n0 + wn*64 + ni*16 + lr];
  }
#pragma unroll
  for (int mi = 0; mi < MI; ++mi)
#pragma unroll
  for (int i = 0; i < 4; ++i) {
    const int rm = m0 + wm*(TM/2) + mi*16 + lk*4 + i;
    long orow = rm;
    if (OREMAP) orow = (long)(rm & (NB-1)) * S_LEN + (rm >> 3);
#pragma unroll
    for (int ni = 0; ni < 4; ++ni) {
      const int col = n0 + wn*64 + ni*16 + lr;
      float v = acc[mi][ni][i];
      if (BIAS) v += bvv[ni];
      if (RES)  v += Rsrc[(long)rm*ldr + col];
      if (RELU) v = fmaxf(v, 0.f);
      if (E16) {
        _Float16 hv = (_Float16)v;
        Ch16[(long)rm*ldc + col] = hv;
        if (SPLIT) Cl16[(long)rm*ldc + col] = (_Float16)(v - (float)hv);
        if (C != nullptr) C[orow*(long)ldc + col] = v;
      } else {
        C[orow*(long)ldc + col] = v;
      }
    }
  }
}

// ---------------------------------------------------------------------------
// MFMA flash attention, fp16 hi/lo inputs. 128 q rows x (b,head); 4 waves.
// K/V staged via register prefetch. LDS XOR-swizzled. SPLIT=1: 3 MFMAs/pair.
// Q pre-scaled by 1/8 (exact). OSPLIT=1: epilogue emits split fp16 hi/lo
// (bit-identical to a downstream conversion of the fp32 value).
// ---------------------------------------------------------------------------
template<int SPLIT, int OSPLIT>
__global__ __launch_bounds__(256)
void mattn_k(const _Float16* __restrict__ Qh, const _Float16* __restrict__ Ql, int ldq,
             const _Float16* __restrict__ Kh, const _Float16* __restrict__ Kl, int ldk,
             const _Float16* __restrict__ Vh, const _Float16* __restrict__ Vl, int ldv,
             float* __restrict__ Op, int ldo,
             _Float16* __restrict__ Oh, _Float16* __restrict__ Ol)
{
  __shared__ __align__(16) char Pb[SPLIT ? 32768 : 16384];
  __shared__ __align__(16) char Kb[SPLIT ? 16384 : 8192];
  __shared__ __align__(16) char Vb[SPLIT ? 16384 : 8192];

  const int t = threadIdx.x;
  const int b = blockIdx.y >> 3, hd = blockIdx.y & 7;
  const int s0 = blockIdx.x * 128;
  const int qoff = hd * DH;
  const int wave = t >> 6, lane = t & 63;
  const int lr = lane & 15, lk = lane >> 4;
  const int krow = t >> 2, kqd = t & 3;
  const int vtp = t & 31, vdc = t >> 5;

  f16x8 qa[2][2], qal[2][2];
#pragma unroll
  for (int mi = 0; mi < 2; ++mi)
#pragma unroll
    for (int kk = 0; kk < 2; ++kk) {
      const int q = s0 + wave*32 + mi*16 + lr;
      const long base = ((long)q*NB + b)*ldq + qoff + kk*32 + lk*8;
      f16x8 v = *(const f16x8*)(Qh + base);
#pragma unroll
      for (int e = 0; e < 8; ++e) v[e] = v[e] * (_Float16)0.125f;
      qa[mi][kk] = v;
      if (SPLIT) {
        f16x8 w = *(const f16x8*)(Ql + base);
#pragma unroll
        for (int e = 0; e < 8; ++e) w[e] = w[e] * (_Float16)0.125f;
        qal[mi][kk] = w;
      }
    }

  float m_run[2][4], l_run[2][4];
  f32x4 oacc[2][4];
#pragma unroll
  for (int mi = 0; mi < 2; ++mi)
#pragma unroll
    for (int i = 0; i < 4; ++i) {
      m_run[mi][i] = -INFINITY; l_run[mi][i] = 0.f;
#pragma unroll
      for (int ni = 0; ni < 4; ++ni) oacc[mi][ni][i] = 0.f;
    }

  char* Pw  = Pb + wave*4096;
  char* Pwl = Pb + 16384 + wave*4096;
  char* Klo = Kb + 8192;
  char* Vlo = Vb + 8192;

  f16x8 kr0, kr1, krl0, krl1, vr0, vr1, vrl0, vrl1;
  {
    const long kb = ((long)krow*NB + b)*ldk + qoff + kqd*16;
    kr0 = *(const f16x8*)(Kh + kb);
    kr1 = *(const f16x8*)(Kh + kb + 8);
    if (SPLIT) { krl0 = *(const f16x8*)(Kl + kb); krl1 = *(const f16x8*)(Kl + kb + 8); }
    const long vb = ((long)(2*vtp)*NB + b)*ldv + qoff + vdc*8;
    vr0 = *(const f16x8*)(Vh + vb);
    vr1 = *(const f16x8*)(Vh + vb + (long)NB*ldv);
    if (SPLIT) { vrl0 = *(const f16x8*)(Vl + vb); vrl1 = *(const f16x8*)(Vl + vb + (long)NB*ldv); }
  }

  for (int t0 = 0; t0 < S_LEN; t0 += 64) {
    __syncthreads();
    {
      const int sw0 = (kqd*32) ^ ((krow & 7) << 4);
      const int sw1 = (kqd*32 + 16) ^ ((krow & 7) << 4);
      *(f16x8*)(Kb + krow*128 + sw0) = kr0;
      *(f16x8*)(Kb + krow*128 + sw1) = kr1;
      if (SPLIT) {
        *(f16x8*)(Klo + krow*128 + sw0) = krl0;
        *(f16x8*)(Klo + krow*128 + sw1) = krl1;
      }
#pragma unroll
      for (int j = 0; j < 8; ++j) {
        const int dd = vdc*8 + j;
        f16x2 hv = {vr0[j], vr1[j]};
        *(f16x2*)(Vb + dd*128 + ((vtp*4) ^ ((dd & 7) << 4))) = hv;
        if (SPLIT) {
          f16x2 lv = {vrl0[j], vrl1[j]};
          *(f16x2*)(Vlo + dd*128 + ((vtp*4) ^ ((dd & 7) << 4))) = lv;
        }
      }
    }
    if (t0 + 64 < S_LEN) {
      const long kb = ((long)(t0 + 64 + krow)*NB + b)*ldk + qoff + kqd*16;
      kr0 = *(const f16x8*)(Kh + kb);
      kr1 = *(const f16x8*)(Kh + kb + 8);
      if (SPLIT) { krl0 = *(const f16x8*)(Kl + kb); krl1 = *(const f16x8*)(Kl + kb + 8); }
      const long vb = ((long)(t0 + 64 + 2*vtp)*NB + b)*ldv + qoff + vdc*8;
      vr0 = *(const f16x8*)(Vh + vb);
      vr1 = *(const f16x8*)(Vh + vb + (long)NB*ldv);
      if (SPLIT) { vrl0 = *(const f16x8*)(Vl + vb); vrl1 = *(const f16x8*)(Vl + vb + (long)NB*ldv); }
    }
    __syncthreads();

    // ---- S = Q K^T ----
    f32x4 s[2][4];
#pragma unroll
    for (int mi = 0; mi < 2; ++mi)
#pragma unroll
      for (int ni = 0; ni < 4; ++ni)
#pragma unroll
        for (int e = 0; e < 4; ++e) s[mi][ni][e] = 0.f;
#pragma unroll
    for (int kk = 0; kk < 2; ++kk) {
      f16x8 kb[4], kbl[4];
#pragma unroll
      for (int ni = 0; ni < 4; ++ni) {
        const int r = ni*16 + lr;
        const int bo = (lk*16 + kk*64) ^ ((r & 7) << 4);
        kb[ni] = *(const f16x8*)(Kb + r*128 + bo);
        if (SPLIT) kbl[ni] = *(const f16x8*)(Klo + r*128 + bo);
      }
#pragma unroll
      for (int mi = 0; mi < 2; ++mi)
#pragma unroll
        for (int ni = 0; ni < 4; ++ni) {
          s[mi][ni] = __builtin_amdgcn_mfma_f32_16x16x32_f16(qa[mi][kk], kb[ni], s[mi][ni], 0, 0, 0);
          if (SPLIT) {
            s[mi][ni] = __builtin_amdgcn_mfma_f32_16x16x32_f16(qa[mi][kk], kbl[ni], s[mi][ni], 0, 0, 0);
            s[mi][ni] = __builtin_amdgcn_mfma_f32_16x16x32_f16(qal[mi][kk], kb[ni], s[mi][ni], 0, 0, 0);
          }
        }
    }

    // ---- online softmax ----
#pragma unroll
    for (int mi = 0; mi < 2; ++mi) {
      float rm[4];
#pragma unroll
      for (int i = 0; i < 4; ++i)
        rm[i] = fmaxf(fmaxf(s[mi][0][i], s[mi][1][i]), fmaxf(s[mi][2][i], s[mi][3][i]));
#pragma unroll
      for (int off = 1; off < 16; off <<= 1)
#pragma unroll
        for (int i = 0; i < 4; ++i) rm[i] = fmaxf(rm[i], __shfl_xor(rm[i], off));
      float rs[4], corr[4];
#pragma unroll
      for (int i = 0; i < 4; ++i) {
        const float mnew = fmaxf(m_run[mi][i], rm[i]);
        corr[i] = __expf(m_run[mi][i] - mnew);
        m_run[mi][i] = mnew;
        float lsum = 0.f;
#pragma unroll
        for (int ni = 0; ni < 4; ++ni) {
          float p = __expf(s[mi][ni][i] - mnew);
          s[mi][ni][i] = p; lsum += p;
        }
        rs[i] = lsum;
      }
#pragma unroll
      for (int off = 1; off < 16; off <<= 1)
#pragma unroll
        for (int i = 0; i < 4; ++i) rs[i] += __shfl_xor(rs[i], off);
#pragma unroll
      for (int i = 0; i < 4; ++i) {
        l_run[mi][i] = l_run[mi][i]*corr[i] + rs[i];
#pragma unroll
        for (int ni = 0; ni < 4; ++ni) oacc[mi][ni][i] *= corr[i];
      }
    }

    // ---- P -> LDS (wave-private) ----
#pragma unroll
    for (int mi = 0; mi < 2; ++mi)
#pragma unroll
      for (int ni = 0; ni < 4; ++ni)
#pragma unroll
        for (int i = 0; i < 4; ++i) {
          const int row = mi*16 + lk*4 + i;
          const int col = ni*16 + lr;
          const int ad = row*128 + ((col*2) ^ ((row & 7) << 4));
          float pv = s[mi][ni][i];
          _Float16 ph = (_Float16)pv;
          *(_Float16*)(Pw + ad) = ph;
          if (SPLIT) *(_Float16*)(Pwl + ad) = (_Float16)(pv - (float)ph);
        }

    // ---- O += P V ----
#pragma unroll
    for (int kk = 0; kk < 2; ++kk) {
      f16x8 vb[4], vbl[4], pa[2], pal[2];
#pragma unroll
      for (int ni = 0; ni < 4; ++ni) {
        const int r = ni*16 + lr;
        const int bo = (lk*16 + kk*64) ^ ((r & 7) << 4);
        vb[ni] = *(const f16x8*)(Vb + r*128 + bo);
        if (SPLIT) vbl[ni] = *(const f16x8*)(Vlo + r*128 + bo);
      }
#pragma unroll
      for (int mi = 0; mi < 2; ++mi) {
        const int r = mi*16 + lr;
        const int bo = (lk*16 + kk*64) ^ ((r & 7) << 4);
        pa[mi] = *(const f16x8*)(Pw + r*128 + bo);
        if (SPLIT) pal[mi] = *(const f16x8*)(Pwl + r*128 + bo);
      }
#pragma unroll
      for (int mi = 0; mi < 2; ++mi)
#pragma unroll
        for (int ni = 0; ni < 4; ++ni) {
          oacc[mi][ni] = __builtin_amdgcn_mfma_f32_16x16x32_f16(pa[mi], vb[ni], oacc[mi][ni], 0, 0, 0);
          if (SPLIT) {
            oacc[mi][ni] = __builtin_amdgcn_mfma_f32_16x16x32_f16(pa[mi], vbl[ni], oacc[mi][ni], 0, 0, 0);
            oacc[mi][ni] = __builtin_amdgcn_mfma_f32_16x16x32_f16(pal[mi], vb[ni], oacc[mi][ni], 0, 0, 0);
          }
        }
    }
  }

#pragma unroll
  for (int mi = 0; mi < 2; ++mi)
#pragma unroll
    for (int i = 0; i < 4; ++i) {
      const float inv = 1.0f / l_run[mi][i];
      const int q = s0 + wave*32 + mi*16 + lk*4 + i;
      const long base = ((long)q * NB + b) * ldo + qoff;
#pragma unroll
      for (int ni = 0; ni < 4; ++ni) {
        float v = oacc[mi][ni][i] * inv;
        if (OSPLIT) {
          _Float16 h = (_Float16)v;
          Oh[base + ni*16 + lr] = h;
          Ol[base + ni*16 + lr] = (_Float16)(v - (float)h);
        } else {
          Op[base + ni*16 + lr] = v;
        }
      }
    }
}

// ---------------------------------------------------------------------------
// LayerNorm over c=512, one wave per row. ES=1: also emit split fp16 hi/lo.
// ---------------------------------------------------------------------------
template<int ES>
__global__ __launch_bounds__(256)
void ln_k(const float* __restrict__ X, const float* __restrict__ g,
          const float* __restrict__ bb, float* __restrict__ Y,
          _Float16* __restrict__ Yh, _Float16* __restrict__ Yl)
{
  const int t = threadIdx.x;
  const int lane = t & 63;
  const long row = (long)blockIdx.x * 4 + (t >> 6);
  const float* xr = X + row * CDIM;
  float4 v0 = *(const float4*)(xr + lane*4);
  float4 v1 = *(const float4*)(xr + 256 + lane*4);
  float s = v0.x+v0.y+v0.z+v0.w + v1.x+v1.y+v1.z+v1.w;
#pragma unroll
  for (int off = 1; off < 64; off <<= 1) s += __shfl_xor(s, off);
  const float mean = s * (1.0f/512.0f);
  float d[8] = {v0.x-mean, v0.y-mean, v0.z-mean, v0.w-mean,
                v1.x-mean, v1.y-mean, v1.z-mean, v1.w-mean};
  float sq = d[0]*d[0]+d[1]*d[1]+d[2]*d[2]+d[3]*d[3]
           + d[4]*d[4]+d[5]*d[5]+d[6]*d[6]+d[7]*d[7];
#pragma unroll
  for (int off = 1; off < 64; off <<= 1) sq += __shfl_xor(sq, off);
  const float inv = 1.0f / sqrtf(sq * (1.0f/512.0f) + 1e-5f);
  float4 g0 = *(const float4*)(g + lane*4);
  float4 g1 = *(const float4*)(g + 256 + lane*4);
  float4 b0 = *(const float4*)(bb + lane*4);
  float4 b1 = *(const float4*)(bb + 256 + lane*4);
  float o[8];
  o[0] = d[0]*inv*g0.x + b0.x; o[1] = d[1]*inv*g0.y + b0.y;
  o[2] = d[2]*inv*g0.z + b0.z; o[3] = d[3]*inv*g0.w + b0.w;
  o[4] = d[4]*inv*g1.x + b1.x; o[5] = d[5]*inv*g1.y + b1.y;
  o[6] = d[6]*inv*g1.z + b1.z; o[7] = d[7]*inv*g1.w + b1.w;
  *(float4*)(Y + row*CDIM + lane*4) = *(float4*)&o[0];
  *(float4*)(Y + row*CDIM + 256 + lane*4) = *(float4*)&o[4];
  if (ES) {
    f16x4 h0, h1, l0, l1;
#pragma unroll
    for (int j = 0; j < 4; ++j) {
      _Float16 h = (_Float16)o[j];     h0[j] = h; l0[j] = (_Float16)(o[j] - (float)h);
      _Float16 k = (_Float16)o[4+j];   h1[j] = k; l1[j] = (_Float16)(o[4+j] - (float)k);
    }
    *(f16x4*)(Yh + row*CDIM + lane*4) = h0;
    *(f16x4*)(Yh + row*CDIM + 256 + lane*4) = h1;
    *(f16x4*)(Yl + row*CDIM + lane*4) = l0;
    *(f16x4*)(Yl + row*CDIM + 256 + lane*4) = l1;
  }
}

// ---------------------------------------------------------------------------
// Pack x (N,C,H,W) -> enc_flat (S,n,c); posisted fp32 + split fp16 hi/lo.
// ---------------------------------------------------------------------------
__global__ void pack_pe_k(const float* __restrict__ x, float* __restrict__ encf,
                          float* __restrict__ posd,
                          _Float16* __restrict__ posh, _Float16* __restrict__ posl)
{
  __shared__ float tl[32][33];
  const int b = blockIdx.z;
  const int s0 = blockIdx.x*32, c0 = blockIdx.y*32;
#pragma unroll
  for (int i = 0; i < 4; ++i) {
    int ci = threadIdx.y + i*8;
    tl[ci][threadIdx.x] = x[((long)b*CDIM + c0+ci)*S_LEN + s0 + threadIdx.x];
  }
  __syncthreads();
#pragma unroll
  for (int i = 0; i < 4; ++i) {
    int si = threadIdx.y + i*8;
    int s = s0 + si;
    int ch = c0 + threadIdx.x;
    float val = tl[threadIdx.x][si];
    long o = ((long)s*NB + b)*CDIM + ch;
    encf[o] = val;
    int pos = (ch < 256) ? (s & 31) : (s >> 5);
    int j = (ch & 255) >> 1;
    float dv = expf((float)(2*j) * (-9.210340371976184f / 256.0f));
    float ang = (float)pos * dv;
    float pe = (ch & 1) ? cosf(ang) : sinf(ang);
    float pv = val + pe;
    posd[o] = pv;
    _Float16 h = (_Float16)pv;
    posh[o] = h;
    posl[o] = (_Float16)(pv - (float)h);
  }
}

// (S,n,c) token-major -> (n,c,S) output layout
__global__ void tpose_k(const float* __restrict__ in, float* __restrict__ out)
{
  __shared__ float tl[32][33];
  const int b = blockIdx.z;
  const int s0 = blockIdx.x*32, c0 = blockIdx.y*32;
#pragma unroll
  for (int i = 0; i < 4; ++i) {
    int si = threadIdx.y + i*8;
    tl[si][threadIdx.x] = in[((long)(s0+si)*NB + b)*CDIM + c0 + threadIdx.x];
  }
  __syncthreads();
#pragma unroll
  for (int i = 0; i < 4; ++i) {
    int ci = threadIdx.y + i*8;
    out[((long)b*CDIM + c0+ci)*S_LEN + s0 + threadIdx.x] = tl[threadIdx.x][ci];
  }
}

// cb_w (c,K) -> transposed split-fp16 codebook [K][c] hi/lo
__global__ void cbt16_k(const float* __restrict__ cb,
                        _Float16* __restrict__ outh, _Float16* __restrict__ outl)
{
  __shared__ float tl[32][33];
  const int k0 = blockIdx.x*32, c0 = blockIdx.y*32;
#pragma unroll
  for (int i = 0; i < 4; ++i) {
    int ci = threadIdx.y + i*8;
    tl[ci][threadIdx.x] = cb[(long)(c0+ci)*KCB + k0 + threadIdx.x];
  }
  __syncthreads();
#pragma unroll
  for (int i = 0; i < 4; ++i) {
    int ki = threadIdx.y + i*8;
    float v = tl[threadIdx.x][ki];
    _Float16 h = (_Float16)v;
    outh[(long)(k0+ki)*CDIM + c0 + threadIdx.x] = h;
    outl[(long)(k0+ki)*CDIM + c0 + threadIdx.x] = (_Float16)(v - (float)h);
  }
}

// fp32 -> fp16 elementwise, 8 per thread
__global__ __launch_bounds__(256)
void conv16_k(const float* __restrict__ in, _Float16* __restrict__ out)
{
  const long i = ((long)blockIdx.x * 256 + threadIdx.x) * 8;
  float4 v0 = *(const float4*)(in + i);
  float4 v1 = *(const float4*)(in + i + 4);
  f16x8 h;
  h[0]=(_Float16)v0.x; h[1]=(_Float16)v0.y; h[2]=(_Float16)v0.z; h[3]=(_Float16)v0.w;
  h[4]=(_Float16)v1.x; h[5]=(_Float16)v1.y; h[6]=(_Float16)v1.z; h[7]=(_Float16)v1.w;
  *(f16x8*)(out + i) = h;
}

// fp32 -> split fp16 hi/lo, 8 per thread
__global__ __launch_bounds__(256)
void convsplit_k(const float* __restrict__ in, _Float16* __restrict__ oh,
                 _Float16* __restrict__ ol)
{
  const long i = ((long)blockIdx.x * 256 + threadIdx.x) * 8;
  float4 v0 = *(const float4*)(in + i);
  float4 v1 = *(const float4*)(in + i + 4);
  float vv[8] = {v0.x,v0.y,v0.z,v0.w,v1.x,v1.y,v1.z,v1.w};
  f16x8 h, l;
#pragma unroll
  for (int j = 0; j < 8; ++j) {
    _Float16 hh = (_Float16)vv[j];
    h[j] = hh;
    l[j] = (_Float16)(vv[j] - (float)hh);
  }
  *(f16x8*)(oh + i) = h;
  *(f16x8*)(ol + i) = l;
}

// Per-token row of logits: argmax (np first-occurrence) + write P (fp16)
__global__ __launch_bounds__(256)
void simstats_k(const float* __restrict__ logits, _Float16* __restrict__ Pbuf,
                int* __restrict__ codes_tok, float* __restrict__ codes_out)
{
  const long phys = blockIdx.x;
  const float* rowp = logits + phys * KCB;
  const int t = threadIdx.x;
  float vals[16];
#pragma unroll
  for (int rep = 0; rep < 4; ++rep) {
    float4 v = *(const float4*)(rowp + rep*1024 + t*4);
    vals[rep*4+0]=v.x; vals[rep*4+1]=v.y; vals[rep*4+2]=v.z; vals[rep*4+3]=v.w;
  }
  float mv = -INFINITY; int mi = 0;
#pragma unroll
  for (int rep = 0; rep < 4; ++rep)
#pragma unroll
    for (int j = 0; j < 4; ++j) {
      float xv = vals[rep*4+j];
      int ix = rep*1024 + t*4 + j;
      if (xv > mv) { mv = xv; mi = ix; }
    }
  const int lane = t & 63, wid = t >> 6;
#pragma unroll
  for (int off = 1; off < 64; off <<= 1) {
    float ov = __shfl_xor(mv, off);
    int   oi = __shfl_xor(mi, off);
    if (ov > mv || (ov == mv && oi < mi)) { mv = ov; mi = oi; }
  }
  __shared__ float smax[4]; __shared__ int sidx[4]; __shared__ float ssum[4];
  __shared__ float fm; __shared__ int fi; __shared__ float sinv;
  if (lane == 0) { smax[wid] = mv; sidx[wid] = mi; }
  __syncthreads();
  if (t == 0) {
    float bm = smax[0]; int bi = sidx[0];
    for (int wq = 1; wq < 4; ++wq)
      if (smax[wq] > bm || (smax[wq] == bm && sidx[wq] < bi)) { bm = smax[wq]; bi = sidx[wq]; }
    fm = bm; fi = bi;
  }
  __syncthreads();
  const float Mx = fm;
  float se = 0.f;
#pragma unroll
  for (int q = 0; q < 16; ++q) se += __expf(vals[q] - Mx);
#pragma unroll
  for (int off = 1; off < 64; off <<= 1) se += __shfl_xor(se, off);
  if (lane == 0) ssum[wid] = se;
  __syncthreads();
  const int b = (int)(phys >> 10), s = (int)(phys & 1023);
  if (t == 0) {
    float tot = ssum[0]+ssum[1]+ssum[2]+ssum[3];
    sinv = 1.0f / tot;
    codes_tok[s*NB + b] = fi;
    codes_out[phys] = (float)fi;
  }
  __syncthreads();
  const float inv = sinv;
  _Float16* prow = Pbuf + ((long)s*NB + b) * KCB;
#pragma unroll
  for (int rep = 0; rep < 4; ++rep) {
    f16x4 pv;
#pragma unroll
    for (int j = 0; j < 4; ++j) pv[j] = (_Float16)(__expf(vals[rep*4+j] - Mx) * inv);
    *(f16x4*)(prow + rep*1024 + t*4) = pv;
  }
}

// quant = (hard - soft) + soft, also emit hard. hard gathered from split cb.
__global__ __launch_bounds__(128)
void quant_k(const float* __restrict__ soft, const int* __restrict__ codes_tok,
             const _Float16* __restrict__ cbh, const _Float16* __restrict__ cbl,
             float* __restrict__ quant, float* __restrict__ hardb)
{
  const int r = blockIdx.x;
  const int code = codes_tok[r];
  const int c = threadIdx.x * 4;
  f16x4 hh = *(const f16x4*)(cbh + (long)code*CDIM + c);
  f16x4 hl = *(const f16x4*)(cbl + (long)code*CDIM + c);
  float4 sf = *(const float4*)(soft + (long)r*CDIM + c);
  float4 h, q;
  h.x = (float)hh[0] + (float)hl[0]; h.y = (float)hh[1] + (float)hl[1];
  h.z = (float)hh[2] + (float)hl[2]; h.w = (float)hh[3] + (float)hl[3];
  q.x = (h.x - sf.x) + sf.x; q.y = (h.y - sf.y) + sf.y;
  q.z = (h.z - sf.z) + sf.z; q.w = (h.w - sf.w) + sf.w;
  *(float4*)(quant + (long)r*CDIM + c) = q;
  *(float4*)(hardb + (long)r*CDIM + c) = h;
}

// Detect the storage format of the bool mask buffer.
__global__ void maskdetect_k(const void* __restrict__ mask, int* __restrict__ flag)
{
  const unsigned int* wds = (const unsigned int*)mask;
  int t = threadIdx.x;
  int okI = 1, okF = 1, okL = 1;
  for (int i = t; i < 2048; i += 256) {
    unsigned int u = wds[i];
    if (u > 1u) okI = 0;
    if (u != 0u && u != 0x3F800000u) okF = 0;
    if ((i & 1) ? (u != 0u) : (u > 1u)) okL = 0;
  }
  __shared__ int sI, sF, sL;
  if (t == 0) { sI = 1; sF = 1; sL = 1; }
  __syncthreads();
  if (!okI) atomicAnd(&sI, 0);
  if (!okF) atomicAnd(&sF, 0);
  if (!okL) atomicAnd(&sL, 0);
  __syncthreads();
  if (t == 0) {
    int f;
    if (sI && sL) f = 3;
    else if (sI)  f = 1;
    else if (sF)  f = 2;
    else          f = 0;
    *flag = f;
  }
}

// mixed = mask ? enc_flat : post
__global__ __launch_bounds__(256)
void mixed_k(const float* __restrict__ encf, const float* __restrict__ post,
             const void* __restrict__ mask, const int* __restrict__ flag,
             float* __restrict__ outx)
{
  long gid = (long)blockIdx.x * blockDim.x + threadIdx.x;
  int r = (int)(gid >> 7);
  int c = (int)(gid & 127) * 4;
  int f = *flag;
  bool mv;
  if (f == 0)      mv = ((const unsigned char*)mask)[r] != 0;
  else if (f == 1) mv = ((const int*)mask)[r] != 0;
  else if (f == 3) mv = ((const long long*)mask)[r] != 0;
  else             mv = ((const float*)mask)[r] != 0.0f;
  const float* src = mv ? encf : post;
  *(float4*)(outx + (long)r*CDIM + c) = *(const float4*)(src + (long)r*CDIM + c);
}

// ---------------------------------------------------------------------------
// Host-side wrappers (decoder, plain fp16 path — unchanged)
// ---------------------------------------------------------------------------
static void hg64_b(hipStream_t st, const float* A, const float* W, const float* bias,
                   float* C) {
  hgemm_k<64,0,0,true,false,false,false,false><<<dim3(CDIM/128, NTOK/64), 256, 0, st>>>(
      A, W, bias, nullptr, 0, C, CDIM, NTOK, CDIM, CDIM, nullptr, nullptr, nullptr, nullptr);
}
static void hg64_br(hipStream_t st, const float* A, const float* W, const float* bias,
                    const float* R, float* C) {
  hgemm_k<64,0,0,true,true,false,false,false><<<dim3(CDIM/128, NTOK/64), 256, 0, st>>>(
      A, W, bias, R, CDIM, C, CDIM, NTOK, CDIM, CDIM, nullptr, nullptr, nullptr, nullptr);
}
static void hg64_brelu(hipStream_t st, const float* A, const float* W, const float* bias,
                       float* C) {
  hgemm_k<64,0,0,true,false,true,false,false><<<dim3(CDIM/128, NTOK/64), 256, 0, st>>>(
      A, W, bias, nullptr, 0, C, CDIM, NTOK, CDIM, CDIM, nullptr, nullptr, nullptr, nullptr);
}

extern "C" void kernel_launch(void* const* d_in, const int* in_sizes, int n_in,
                              void* d_out, int out_size, void* d_ws, size_t ws_size,
                              hipStream_t stream)
{
  const float* x       = (const float*)d_in[0];
  const float* pre_w   = (const float*)d_in[1];
  const float* pre_b   = (const float*)d_in[2];
  const float* post_w  = (const float*)d_in[3];
  const float* post_b  = (const float*)d_in[4];
  const float* cb_w    = (const float*)d_in[5];
  const float* e_qkv_w = (const float*)d_in[6];
  const float* e_qkv_b = (const float*)d_in[7];
  const float* e_o_w   = (const float*)d_in[8];
  const float* e_o_b   = (const float*)d_in[9];
  const float* e_ln1_w = (const float*)d_in[10];
  const float* e_ln1_b = (const float*)d_in[11];
  const float* e_ln2_w = (const float*)d_in[12];
  const float* e_ln2_b = (const float*)d_in[13];
  const float* e_f1_w  = (const float*)d_in[14];
  const float* e_f1_b  = (const float*)d_in[15];
  const float* e_f2_w  = (const float*)d_in[16];
  const float* e_f2_b  = (const float*)d_in[17];
  const float* d_sqkv_w= (const float*)d_in[18];
  const float* d_sqkv_b= (const float*)d_in[19];
  const float* d_so_w  = (const float*)d_in[20];
  const float* d_so_b  = (const float*)d_in[21];
  const float* d_cqkv_w= (const float*)d_in[22];
  const float* d_cqkv_b= (const float*)d_in[23];
  const float* d_co_w  = (const float*)d_in[24];
  const float* d_co_b  = (const float*)d_in[25];
  const float* d_ln1w  = (const float*)d_in[26];
  const float* d_ln1b  = (const float*)d_in[27];
  const float* d_ln2w  = (const float*)d_in[28];
  const float* d_ln2b  = (const float*)d_in[29];
  const float* d_ln3w  = (const float*)d_in[30];
  const float* d_ln3b  = (const float*)d_in[31];
  const float* d_f1w   = (const float*)d_in[32];
  const float* d_f1b   = (const float*)d_in[33];
  const float* d_f2w   = (const float*)d_in[34];
  const float* d_f2b   = (const float*)d_in[35];
  const void*  mask    = d_in[36];

  float* out = (float*)d_out;
  float* o_quant  = out;
  float* o_high   = out + 4194304;
  float* o_softs  = out + 8388608;
  float* o_hards  = out + 12582912;
  float* o_codes  = out + 16777216;
  float* o_logits = out + 16785408;

  float* ws    = (float*)d_ws;
  float* ENC   = ws;
  float* Xb    = ws + TOKC;
  float* T1    = ws + 2*TOKC;
  float* T2    = ws + 3*TOKC;
  float* QKV   = ws + 4*TOKC;
  float* MEMB  = ws + 7*TOKC;
  float* CBREG = ws + 8*TOKC;                         // KCB*CDIM floats
  int*   CODES = (int*)(CBREG + (long)KCB*CDIM);
  int*   FLAG  = CODES + NTOK;
  float* HARDB = QKV;
  float* QUANT = QKV + TOKC;
  _Float16* PBUF = (_Float16*)QKV;
  _Float16* CBH  = (_Float16*)T1;                     // plain fp16 cb_w (c,K)
  _Float16* QKVh = (_Float16*)QKV;                    // [NTOK][3C] halves
  _Float16* QKVl = QKVh + (long)NTOK*3*CDIM;
  _Float16* CQh  = (_Float16*)QKV;
  _Float16* KVh  = (_Float16*)(QKV + TOKC);
  _Float16* CBT16h = (_Float16*)CBREG;                // [K][c] hi
  _Float16* CBT16l = CBT16h + (long)KCB*CDIM;         // [K][c] lo
  _Float16* PREH = (_Float16*)T2;                     // pre in split fp16
  _Float16* PREL = PREH + TOKC;

  // ---- encoder scratch inside o_logits (dead until sim GEMM rewrites it) ----
  const long WQSZ = (long)6*3*CDIM*CDIM;   // 4,718,592
  const long WSSZ = (long)6*CDIM*CDIM;     // 1,572,864
  _Float16* SCR  = (_Float16*)o_logits;
  _Float16* WQH = SCR;            _Float16* WQL = WQH + WQSZ;
  _Float16* WOH = WQL + WQSZ;     _Float16* WOL = WOH + WSSZ;
  _Float16* WF1H= WOL + WSSZ;     _Float16* WF1L= WF1H + WSSZ;
  _Float16* WF2H= WF1L + WSSZ;    _Float16* WF2L= WF2H + WSSZ;
  _Float16* WPH = WF2L + WSSZ;    _Float16* WPL = WPH + (long)CDIM*CDIM;
  _Float16* XH  = WPL + (long)CDIM*CDIM;  _Float16* XL  = XH + TOKC;
  _Float16* AH  = XL + TOKC;      _Float16* AL  = AH + TOKC;
  _Float16* L1H = AL + TOKC;      _Float16* L1L = L1H + TOKC;
  _Float16* H1H = L1L + TOKC;     _Float16* H1L = H1H + TOKC;

  const size_t NEED = (size_t)(8*TOKC + (long)KCB*CDIM + 2*NTOK + NTOK + 16) * 4;
  if (ws_size < NEED) return;

  const int M = NTOK;
  dim3 tgrid(S_LEN/32, CDIM/32, NB), tblk(32, 8);
  dim3 agrid(S_LEN/128, NB*8);

  pack_pe_k<<<tgrid, tblk, 0, stream>>>(x, ENC, Xb, XH, XL);
  cbt16_k<<<dim3(KCB/32, CDIM/32), tblk, 0, stream>>>(cb_w, CBT16h, CBT16l);
  maskdetect_k<<<1, 256, 0, stream>>>(mask, FLAG);
  // one-time encoder weight split conversions (bit-identical to per-tile)
  convsplit_k<<<(int)(WQSZ/2048), 256, 0, stream>>>(e_qkv_w, WQH, WQL);
  convsplit_k<<<(int)(WSSZ/2048), 256, 0, stream>>>(e_o_w,  WOH,  WOL);
  convsplit_k<<<(int)(WSSZ/2048), 256, 0, stream>>>(e_f1_w, WF1H, WF1L);
  convsplit_k<<<(int)(WSSZ/2048), 256, 0, stream>>>(e_f2_w, WF2H, WF2L);
  convsplit_k<<<(int)(((long)CDIM*CDIM)/2048), 256, 0, stream>>>(pre_w, WPH, WPL);

  // -------- encoder (split-fp16 MFMA, producer-converted inputs) --------
  for (int i = 0; i < NLAYER; ++i) {
    hgemm_k<128,1,2,true,false,false,false,true><<<dim3(3*CDIM/128, M/128), 256, 0, stream>>>(
        XH, WQH + (long)i*3*CDIM*CDIM, e_qkv_b + i*3*CDIM, nullptr, 0,
        nullptr, 3*CDIM, M, 3*CDIM, CDIM, QKVh, QKVl, XL, WQL + (long)i*3*CDIM*CDIM);
    mattn_k<1,1><<<agrid, 256, 0, stream>>>(QKVh, QKVl, 3*CDIM,
        QKVh+CDIM, QKVl+CDIM, 3*CDIM, QKVh+2*CDIM, QKVl+2*CDIM, 3*CDIM,
        nullptr, CDIM, AH, AL);
    hgemm_k<64,1,2,true,true,false,false,false><<<dim3(CDIM/128, M/64), 256, 0, stream>>>(
        AH, WOH + (long)i*CDIM*CDIM, e_o_b + i*CDIM, Xb, CDIM,
        T2, CDIM, M, CDIM, CDIM, nullptr, nullptr, AL, WOL + (long)i*CDIM*CDIM);
    ln_k<1><<<M/4, 256, 0, stream>>>(T2, e_ln1_w + i*CDIM, e_ln1_b + i*CDIM, T1, L1H, L1L);
    hgemm_k<64,1,2,true,false,true,false,true><<<dim3(CDIM/128, M/64), 256, 0, stream>>>(
        L1H, WF1H + (long)i*CDIM*CDIM, e_f1_b + i*CDIM, nullptr, 0,
        nullptr, CDIM, M, CDIM, CDIM, H1H, H1L, L1L, WF1L + (long)i*CDIM*CDIM);
    hgemm_k<64,1,2,true,true,false,false,false><<<dim3(CDIM/128, M/64), 256, 0, stream>>>(
        H1H, WF2H + (long)i*CDIM*CDIM, e_f2_b + i*CDIM, T1, CDIM,
        T2, CDIM, M, CDIM, CDIM, nullptr, nullptr, H1L, WF2L + (long)i*CDIM*CDIM);
    ln_k<1><<<M/4, 256, 0, stream>>>(T2, e_ln2_w + i*CDIM, e_ln2_b + i*CDIM, Xb, XH, XL);
  }

  // -------- codebook / quantizer --------
  hgemm_k<64,1,2,true,false,false,false,true><<<dim3(CDIM/128, M/64), 256, 0, stream>>>(
      XH, WPH, pre_b, nullptr, 0, T1, CDIM, M, CDIM, CDIM, PREH, PREL, XL, WPL);
  tpose_k<<<tgrid, tblk, 0, stream>>>(T1, o_high);
  hgemm_k<128,1,2,false,false,false,true,false><<<dim3(KCB/128, M/128), 256, 0, stream>>>(
      PREH, CBT16h, nullptr, nullptr, 0, o_logits, KCB, M, KCB, CDIM,
      nullptr, nullptr, PREL, CBT16l);
  conv16_k<<<(CDIM*(long)KCB)/(256*8), 256, 0, stream>>>(cb_w, CBH);
  simstats_k<<<NTOK, 256, 0, stream>>>(o_logits, PBUF, CODES, o_codes);
  hgemm_k<64,0,1,false,false,false,false,false><<<dim3(CDIM/128, M/64), 256, 0, stream>>>(
      PBUF, CBH, nullptr, nullptr, 0, T2, CDIM, M, CDIM, KCB,
      nullptr, nullptr, nullptr, nullptr);                                   // soft
  tpose_k<<<tgrid, tblk, 0, stream>>>(T2, o_softs);
  quant_k<<<NTOK, 128, 0, stream>>>(T2, CODES, CBT16h, CBT16l, QUANT, HARDB);
  tpose_k<<<tgrid, tblk, 0, stream>>>(HARDB, o_hards);
  hg64_b(stream, QUANT, post_w, post_b, MEMB);                               // post
  mixed_k<<<4096, 256, 0, stream>>>(ENC, MEMB, mask, FLAG, Xb);

  // -------- decoder (f16 MFMA, unchanged) --------
  for (int i = 0; i < NLAYER; ++i) {
    hgemm_k<128,0,0,true,false,false,false,true><<<dim3(3*CDIM/128, M/128), 256, 0, stream>>>(
        Xb, d_sqkv_w + (long)i*3*CDIM*CDIM, d_sqkv_b + i*3*CDIM, nullptr, 0,
        nullptr, 3*CDIM, M, 3*CDIM, CDIM, QKVh, nullptr, nullptr, nullptr);
    mattn_k<0,0><<<agrid, 256, 0, stream>>>(QKVh, nullptr, 3*CDIM,
        QKVh+CDIM, nullptr, 3*CDIM, QKVh+2*CDIM, nullptr, 3*CDIM, T1, CDIM,
        nullptr, nullptr);
    hg64_br(stream, T1, d_so_w + (long)i*CDIM*CDIM, d_so_b + i*CDIM, Xb, T2);
    ln_k<0><<<M/4, 256, 0, stream>>>(T2, d_ln1w + i*CDIM, d_ln1b + i*CDIM, Xb, nullptr, nullptr);
    hgemm_k<64,0,0,true,false,false,false,true><<<dim3(CDIM/128, M/64), 256, 0, stream>>>(
        Xb, d_cqkv_w + (long)i*3*CDIM*CDIM, d_cqkv_b + i*3*CDIM, nullptr, 0,
        nullptr, CDIM, M, CDIM, CDIM, CQh, nullptr, nullptr, nullptr);
    hgemm_k<128,0,0,true,false,false,false,true><<<dim3(2*CDIM/128, M/128), 256, 0, stream>>>(
        MEMB, d_cqkv_w + (long)i*3*CDIM*CDIM + (long)CDIM*CDIM,
        d_cqkv_b + i*3*CDIM + CDIM, nullptr, 0,
        nullptr, 2*CDIM, M, 2*CDIM, CDIM, KVh, nullptr, nullptr, nullptr);
    mattn_k<0,0><<<agrid, 256, 0, stream>>>(CQh, nullptr, CDIM,
        KVh, nullptr, 2*CDIM, KVh+CDIM, nullptr, 2*CDIM, T1, CDIM,
        nullptr, nullptr);
    hg64_br(stream, T1, d_co_w + (long)i*CDIM*CDIM, d_co_b + i*CDIM, Xb, T2);
    ln_k<0><<<M/4, 256, 0, stream>>>(T2, d_ln2w + i*CDIM, d_ln2b + i*CDIM, Xb, nullptr, nullptr);
    hg64_brelu(stream, Xb, d_f1w + (long)i*CDIM*CDIM, d_f1b + i*CDIM, T1);
    hg64_br(stream, T1, d_f2w + (long)i*CDIM*CDIM, d_f2b + i*CDIM, Xb, T2);
    ln_k<0><<<M/4, 256, 0, stream>>>(T2, d_ln3w + i*CDIM, d_ln3b + i*CDIM, Xb, nullptr, nullptr);
  }
  tpose_k<<<tgrid, tblk, 0, stream>>>(Xb, o_quant);
}

// Round 11
// 3841.167 us; speedup vs baseline: 3.2635x; 1.0741x over previous
//
#include <hip/hip_runtime.h>
#include <math.h>

#define S_LEN 1024
#define NB 8
#define CDIM 512
#define KCB 4096
#define DH 64
#define NLAYER 6
#define NTOK (S_LEN*NB)
#define TOKC ((long)NTOK*CDIM)

typedef __attribute__((ext_vector_type(8))) _Float16 f16x8;
typedef __attribute__((ext_vector_type(4))) _Float16 f16x4;
typedef __attribute__((ext_vector_type(2))) _Float16 f16x2;
typedef __attribute__((ext_vector_type(4))) float f32x4;

// ---------------------------------------------------------------------------
// MFMA GEMM: C[M,N] = A[M,K] @ W[N,K]^T (+bias/res/relu).
// TM in {64,128}; N-tile 128. BK=64, mfma_f32_16x16x32_f16, XOR-swizzled LDS.
// SPLIT=1: hi/lo split-fp16, 3 MFMAs/pair (~fp32 accuracy).
// F16IN: 0 = A,W fp32 (convert in-kernel); 1 = A,W fp16; 2 = A,W split fp16
// hi/lo (Avl/Wvl, SPLIT=1); 3 = A fp16, W fp32-converted (SPLIT=0).
// E16: epilogue writes fp16 hi (Ch16) (+lo Cl16 if SPLIT); also fp32 C if C!=0.
// OREMAP: output row (s*NB+b) -> (b*S_LEN+s).
// NOTE: A and C must NOT alias (blocks of one dispatch race) — enforced in
// kernel_launch buffer routing.
// ---------------------------------------------------------------------------
template<int TM, int SPLIT, int F16IN, bool BIAS, bool RES, bool RELU, bool OREMAP, bool E16>
__global__ __launch_bounds__(256)
void hgemm_k(const void* __restrict__ Av, const void* __restrict__ Wv,
             const float* __restrict__ bias, const float* __restrict__ Rsrc, int ldr,
             float* __restrict__ C, int ldc, int M, int N, int K,
             _Float16* __restrict__ Ch16, _Float16* __restrict__ Cl16,
             const void* __restrict__ Avl, const void* __restrict__ Wvl)
{
  constexpr int MI = TM / 32;
  constexpr int ATPR = 256 / TM;
  constexpr int ACOL = 64 / ATPR;
  constexpr bool AF16 = (F16IN >= 1);                 // A arrives fp16
  constexpr bool WF16 = (F16IN == 1 || F16IN == 2);   // W arrives fp16
  __shared__ __align__(16) _Float16 Ah[TM*64];
  __shared__ __align__(16) _Float16 Bh[128*64];
  __shared__ __align__(16) _Float16 Al[SPLIT ? TM*64 : 8];
  __shared__ __align__(16) _Float16 Bl[SPLIT ? 128*64 : 8];
  const int t = threadIdx.x;
  const int m0 = blockIdx.y * TM, n0 = blockIdx.x * 128;

  const int arow = t / ATPR, apart = t % ATPR;
  const int brow = t >> 1, bpart = t & 1;

  const float*    Af  = (const float*)Av;
  const _Float16* Axh = (const _Float16*)Av;
  const _Float16* Axl = (const _Float16*)Avl;
  const float*    Wf  = (const float*)Wv;
  const _Float16* Wxh = (const _Float16*)Wv;
  const _Float16* Wxl = (const _Float16*)Wvl;
  const long aoff = (long)(m0 + arow) * K + apart * ACOL;
  const long boff = (long)(n0 + brow) * K + bpart * 32;

  const int lane = t & 63, wave = t >> 6;
  const int wm = wave >> 1, wn = wave & 1;
  const int lr = lane & 15, lk = lane >> 4;

  f32x4 acc[MI][4];
#pragma unroll
  for (int mi = 0; mi < MI; ++mi)
#pragma unroll
    for (int ni = 0; ni < 4; ++ni)
#pragma unroll
      for (int e = 0; e < 4; ++e) acc[mi][ni][e] = 0.f;

  float4 a4[ACOL/4], b4[8];
  f16x8  a16[ACOL/8], b16[4];
  f16x8  a16l[F16IN==2 ? ACOL/8 : 1], b16l[F16IN==2 ? 4 : 1];
  if (AF16) {
#pragma unroll
    for (int g = 0; g < ACOL/8; ++g) a16[g] = *(const f16x8*)(Axh + aoff + g*8);
    if (F16IN == 2) {
#pragma unroll
      for (int g = 0; g < ACOL/8; ++g) a16l[g] = *(const f16x8*)(Axl + aoff + g*8);
    }
  } else {
#pragma unroll
    for (int j = 0; j < ACOL/4; ++j) a4[j] = *(const float4*)(Af + aoff + j*4);
  }
  if (WF16) {
#pragma unroll
    for (int g = 0; g < 4; ++g) b16[g] = *(const f16x8*)(Wxh + boff + g*8);
    if (F16IN == 2) {
#pragma unroll
      for (int g = 0; g < 4; ++g) b16l[g] = *(const f16x8*)(Wxl + boff + g*8);
    }
  } else {
#pragma unroll
    for (int j = 0; j < 8; ++j) b4[j] = *(const float4*)(Wf + boff + j*4);
  }

  for (int k0 = 0; k0 < K; k0 += 64) {
    __syncthreads();
    // ---- A staging ----
    if (AF16) {
#pragma unroll
      for (int g = 0; g < ACOL/8; ++g) {
        const int sw = (apart*ACOL*2 + g*16) ^ ((arow & 7) << 4);
        *(f16x8*)((char*)Ah + arow*128 + sw) = a16[g];
        if (F16IN == 2) *(f16x8*)((char*)Al + arow*128 + sw) = a16l[g];
      }
    } else {
      const float* af = (const float*)a4;
#pragma unroll
      for (int g = 0; g < ACOL/8; ++g) {
        f16x8 h, l;
#pragma unroll
        for (int j = 0; j < 8; ++j) {
          float xv = af[g*8+j];
          _Float16 hh = (_Float16)xv;
          h[j] = hh;
          if (SPLIT) l[j] = (_Float16)(xv - (float)hh);
        }
        const int sw = (apart*ACOL*2 + g*16) ^ ((arow & 7) << 4);
        *(f16x8*)((char*)Ah + arow*128 + sw) = h;
        if (SPLIT) *(f16x8*)((char*)Al + arow*128 + sw) = l;
      }
    }
    // ---- W staging ----
    if (WF16) {
#pragma unroll
      for (int g = 0; g < 4; ++g) {
        const int sw = (bpart*64 + g*16) ^ ((brow & 7) << 4);
        *(f16x8*)((char*)Bh + brow*128 + sw) = b16[g];
        if (F16IN == 2) *(f16x8*)((char*)Bl + brow*128 + sw) = b16l[g];
      }
    } else {
      const float* bf = (const float*)b4;
#pragma unroll
      for (int g = 0; g < 4; ++g) {
        f16x8 h, l;
#pragma unroll
        for (int j = 0; j < 8; ++j) {
          float xv = bf[g*8+j];
          _Float16 hh = (_Float16)xv;
          h[j] = hh;
          if (SPLIT) l[j] = (_Float16)(xv - (float)hh);
        }
        const int sw = (bpart*64 + g*16) ^ ((brow & 7) << 4);
        *(f16x8*)((char*)Bh + brow*128 + sw) = h;
        if (SPLIT) *(f16x8*)((char*)Bl + brow*128 + sw) = l;
      }
    }
    __syncthreads();
    if (k0 + 64 < K) {
      if (AF16) {
#pragma unroll
        for (int g = 0; g < ACOL/8; ++g) a16[g] = *(const f16x8*)(Axh + aoff + k0 + 64 + g*8);
        if (F16IN == 2) {
#pragma unroll
          for (int g = 0; g < ACOL/8; ++g) a16l[g] = *(const f16x8*)(Axl + aoff + k0 + 64 + g*8);
        }
      } else {
#pragma unroll
        for (int j = 0; j < ACOL/4; ++j) a4[j] = *(const float4*)(Af + aoff + k0 + 64 + j*4);
      }
      if (WF16) {
#pragma unroll
        for (int g = 0; g < 4; ++g) b16[g] = *(const f16x8*)(Wxh + boff + k0 + 64 + g*8);
        if (F16IN == 2) {
#pragma unroll
          for (int g = 0; g < 4; ++g) b16l[g] = *(const f16x8*)(Wxl + boff + k0 + 64 + g*8);
        }
      } else {
#pragma unroll
        for (int j = 0; j < 8; ++j) b4[j] = *(const float4*)(Wf + boff + k0 + 64 + j*4);
      }
    }
#pragma unroll
    for (int kk = 0; kk < 2; ++kk) {
      f16x8 afh[MI], bfh[4], afl[MI], bfl[4];
#pragma unroll
      for (int mi = 0; mi < MI; ++mi) {
        const int r = wm*(TM/2) + mi*16 + lr;
        const int bo = (lk*16 + kk*64) ^ ((r & 7) << 4);
        afh[mi] = *(const f16x8*)((const char*)Ah + r*128 + bo);
        if (SPLIT) afl[mi] = *(const f16x8*)((const char*)Al + r*128 + bo);
      }
#pragma unroll
      for (int ni = 0; ni < 4; ++ni) {
        const int r = wn*64 + ni*16 + lr;
        const int bo = (lk*16 + kk*64) ^ ((r & 7) << 4);
        bfh[ni] = *(const f16x8*)((const char*)Bh + r*128 + bo);
        if (SPLIT) bfl[ni] = *(const f16x8*)((const char*)Bl + r*128 + bo);
      }
#pragma unroll
      for (int mi = 0; mi < MI; ++mi)
#pragma unroll
        for (int ni = 0; ni < 4; ++ni) {
          acc[mi][ni] = __builtin_amdgcn_mfma_f32_16x16x32_f16(afh[mi], bfh[ni], acc[mi][ni], 0, 0, 0);
          if (SPLIT) {
            acc[mi][ni] = __builtin_amdgcn_mfma_f32_16x16x32_f16(afh[mi], bfl[ni], acc[mi][ni], 0, 0, 0);
            acc[mi][ni] = __builtin_amdgcn_mfma_f32_16x16x32_f16(afl[mi], bfh[ni], acc[mi][ni], 0, 0, 0);
          }
        }
    }
  }

  float bvv[4];
  if (BIAS) {
#pragma unroll
    for (int ni = 0; ni < 4; ++ni) bvv[ni] = bias[n0 + wn*64 + ni*16 + lr];
  }
#pragma unroll
  for (int mi = 0; mi < MI; ++mi)
#pragma unroll
  for (int i = 0; i < 4; ++i) {
    const int rm = m0 + wm*(TM/2) + mi*16 + lk*4 + i;
    long orow = rm;
    if (OREMAP) orow = (long)(rm & (NB-1)) * S_LEN + (rm >> 3);
#pragma unroll
    for (int ni = 0; ni < 4; ++ni) {
      const int col = n0 + wn*64 + ni*16 + lr;
      float v = acc[mi][ni][i];
      if (BIAS) v += bvv[ni];
      if (RES)  v += Rsrc[(long)rm*ldr + col];
      if (RELU) v = fmaxf(v, 0.f);
      if (E16) {
        _Float16 hv = (_Float16)v;
        Ch16[(long)rm*ldc + col] = hv;
        if (SPLIT) Cl16[(long)rm*ldc + col] = (_Float16)(v - (float)hv);
        if (C != nullptr) C[orow*(long)ldc + col] = v;
      } else {
        C[orow*(long)ldc + col] = v;
      }
    }
  }
}

// ---------------------------------------------------------------------------
// MFMA flash attention, fp16 hi/lo inputs. 128 q rows x (b,head); 4 waves.
// K/V staged via register prefetch. LDS XOR-swizzled. SPLIT=1: 3 MFMAs/pair.
// Q pre-scaled by 1/8 (exact). OSPLIT: 0 = fp32 out; 1 = split hi/lo fp16;
// 2 = fp16 hi only. All bit-identical to a downstream conversion.
// ---------------------------------------------------------------------------
template<int SPLIT, int OSPLIT>
__global__ __launch_bounds__(256)
void mattn_k(const _Float16* __restrict__ Qh, const _Float16* __restrict__ Ql, int ldq,
             const _Float16* __restrict__ Kh, const _Float16* __restrict__ Kl, int ldk,
             const _Float16* __restrict__ Vh, const _Float16* __restrict__ Vl, int ldv,
             float* __restrict__ Op, int ldo,
             _Float16* __restrict__ Oh, _Float16* __restrict__ Ol)
{
  __shared__ __align__(16) char Pb[SPLIT ? 32768 : 16384];
  __shared__ __align__(16) char Kb[SPLIT ? 16384 : 8192];
  __shared__ __align__(16) char Vb[SPLIT ? 16384 : 8192];

  const int t = threadIdx.x;
  const int b = blockIdx.y >> 3, hd = blockIdx.y & 7;
  const int s0 = blockIdx.x * 128;
  const int qoff = hd * DH;
  const int wave = t >> 6, lane = t & 63;
  const int lr = lane & 15, lk = lane >> 4;
  const int krow = t >> 2, kqd = t & 3;
  const int vtp = t & 31, vdc = t >> 5;

  f16x8 qa[2][2], qal[2][2];
#pragma unroll
  for (int mi = 0; mi < 2; ++mi)
#pragma unroll
    for (int kk = 0; kk < 2; ++kk) {
      const int q = s0 + wave*32 + mi*16 + lr;
      const long base = ((long)q*NB + b)*ldq + qoff + kk*32 + lk*8;
      f16x8 v = *(const f16x8*)(Qh + base);
#pragma unroll
      for (int e = 0; e < 8; ++e) v[e] = v[e] * (_Float16)0.125f;
      qa[mi][kk] = v;
      if (SPLIT) {
        f16x8 w = *(const f16x8*)(Ql + base);
#pragma unroll
        for (int e = 0; e < 8; ++e) w[e] = w[e] * (_Float16)0.125f;
        qal[mi][kk] = w;
      }
    }

  float m_run[2][4], l_run[2][4];
  f32x4 oacc[2][4];
#pragma unroll
  for (int mi = 0; mi < 2; ++mi)
#pragma unroll
    for (int i = 0; i < 4; ++i) {
      m_run[mi][i] = -INFINITY; l_run[mi][i] = 0.f;
#pragma unroll
      for (int ni = 0; ni < 4; ++ni) oacc[mi][ni][i] = 0.f;
    }

  char* Pw  = Pb + wave*4096;
  char* Pwl = Pb + 16384 + wave*4096;
  char* Klo = Kb + 8192;
  char* Vlo = Vb + 8192;

  f16x8 kr0, kr1, krl0, krl1, vr0, vr1, vrl0, vrl1;
  {
    const long kb = ((long)krow*NB + b)*ldk + qoff + kqd*16;
    kr0 = *(const f16x8*)(Kh + kb);
    kr1 = *(const f16x8*)(Kh + kb + 8);
    if (SPLIT) { krl0 = *(const f16x8*)(Kl + kb); krl1 = *(const f16x8*)(Kl + kb + 8); }
    const long vb = ((long)(2*vtp)*NB + b)*ldv + qoff + vdc*8;
    vr0 = *(const f16x8*)(Vh + vb);
    vr1 = *(const f16x8*)(Vh + vb + (long)NB*ldv);
    if (SPLIT) { vrl0 = *(const f16x8*)(Vl + vb); vrl1 = *(const f16x8*)(Vl + vb + (long)NB*ldv); }
  }

  for (int t0 = 0; t0 < S_LEN; t0 += 64) {
    __syncthreads();
    {
      const int sw0 = (kqd*32) ^ ((krow & 7) << 4);
      const int sw1 = (kqd*32 + 16) ^ ((krow & 7) << 4);
      *(f16x8*)(Kb + krow*128 + sw0) = kr0;
      *(f16x8*)(Kb + krow*128 + sw1) = kr1;
      if (SPLIT) {
        *(f16x8*)(Klo + krow*128 + sw0) = krl0;
        *(f16x8*)(Klo + krow*128 + sw1) = krl1;
      }
#pragma unroll
      for (int j = 0; j < 8; ++j) {
        const int dd = vdc*8 + j;
        f16x2 hv = {vr0[j], vr1[j]};
        *(f16x2*)(Vb + dd*128 + ((vtp*4) ^ ((dd & 7) << 4))) = hv;
        if (SPLIT) {
          f16x2 lv = {vrl0[j], vrl1[j]};
          *(f16x2*)(Vlo + dd*128 + ((vtp*4) ^ ((dd & 7) << 4))) = lv;
        }
      }
    }
    if (t0 + 64 < S_LEN) {
      const long kb = ((long)(t0 + 64 + krow)*NB + b)*ldk + qoff + kqd*16;
      kr0 = *(const f16x8*)(Kh + kb);
      kr1 = *(const f16x8*)(Kh + kb + 8);
      if (SPLIT) { krl0 = *(const f16x8*)(Kl + kb); krl1 = *(const f16x8*)(Kl + kb + 8); }
      const long vb = ((long)(t0 + 64 + 2*vtp)*NB + b)*ldv + qoff + vdc*8;
      vr0 = *(const f16x8*)(Vh + vb);
      vr1 = *(const f16x8*)(Vh + vb + (long)NB*ldv);
      if (SPLIT) { vrl0 = *(const f16x8*)(Vl + vb); vrl1 = *(const f16x8*)(Vl + vb + (long)NB*ldv); }
    }
    __syncthreads();

    // ---- S = Q K^T ----
    f32x4 s[2][4];
#pragma unroll
    for (int mi = 0; mi < 2; ++mi)
#pragma unroll
      for (int ni = 0; ni < 4; ++ni)
#pragma unroll
        for (int e = 0; e < 4; ++e) s[mi][ni][e] = 0.f;
#pragma unroll
    for (int kk = 0; kk < 2; ++kk) {
      f16x8 kb[4], kbl[4];
#pragma unroll
      for (int ni = 0; ni < 4; ++ni) {
        const int r = ni*16 + lr;
        const int bo = (lk*16 + kk*64) ^ ((r & 7) << 4);
        kb[ni] = *(const f16x8*)(Kb + r*128 + bo);
        if (SPLIT) kbl[ni] = *(const f16x8*)(Klo + r*128 + bo);
      }
#pragma unroll
      for (int mi = 0; mi < 2; ++mi)
#pragma unroll
        for (int ni = 0; ni < 4; ++ni) {
          s[mi][ni] = __builtin_amdgcn_mfma_f32_16x16x32_f16(qa[mi][kk], kb[ni], s[mi][ni], 0, 0, 0);
          if (SPLIT) {
            s[mi][ni] = __builtin_amdgcn_mfma_f32_16x16x32_f16(qa[mi][kk], kbl[ni], s[mi][ni], 0, 0, 0);
            s[mi][ni] = __builtin_amdgcn_mfma_f32_16x16x32_f16(qal[mi][kk], kb[ni], s[mi][ni], 0, 0, 0);
          }
        }
    }

    // ---- online softmax ----
#pragma unroll
    for (int mi = 0; mi < 2; ++mi) {
      float rm[4];
#pragma unroll
      for (int i = 0; i < 4; ++i)
        rm[i] = fmaxf(fmaxf(s[mi][0][i], s[mi][1][i]), fmaxf(s[mi][2][i], s[mi][3][i]));
#pragma unroll
      for (int off = 1; off < 16; off <<= 1)
#pragma unroll
        for (int i = 0; i < 4; ++i) rm[i] = fmaxf(rm[i], __shfl_xor(rm[i], off));
      float rs[4], corr[4];
#pragma unroll
      for (int i = 0; i < 4; ++i) {
        const float mnew = fmaxf(m_run[mi][i], rm[i]);
        corr[i] = __expf(m_run[mi][i] - mnew);
        m_run[mi][i] = mnew;
        float lsum = 0.f;
#pragma unroll
        for (int ni = 0; ni < 4; ++ni) {
          float p = __expf(s[mi][ni][i] - mnew);
          s[mi][ni][i] = p; lsum += p;
        }
        rs[i] = lsum;
      }
#pragma unroll
      for (int off = 1; off < 16; off <<= 1)
#pragma unroll
        for (int i = 0; i < 4; ++i) rs[i] += __shfl_xor(rs[i], off);
#pragma unroll
      for (int i = 0; i < 4; ++i) {
        l_run[mi][i] = l_run[mi][i]*corr[i] + rs[i];
#pragma unroll
        for (int ni = 0; ni < 4; ++ni) oacc[mi][ni][i] *= corr[i];
      }
    }

    // ---- P -> LDS (wave-private) ----
#pragma unroll
    for (int mi = 0; mi < 2; ++mi)
#pragma unroll
      for (int ni = 0; ni < 4; ++ni)
#pragma unroll
        for (int i = 0; i < 4; ++i) {
          const int row = mi*16 + lk*4 + i;
          const int col = ni*16 + lr;
          const int ad = row*128 + ((col*2) ^ ((row & 7) << 4));
          float pv = s[mi][ni][i];
          _Float16 ph = (_Float16)pv;
          *(_Float16*)(Pw + ad) = ph;
          if (SPLIT) *(_Float16*)(Pwl + ad) = (_Float16)(pv - (float)ph);
        }

    // ---- O += P V ----
#pragma unroll
    for (int kk = 0; kk < 2; ++kk) {
      f16x8 vb[4], vbl[4], pa[2], pal[2];
#pragma unroll
      for (int ni = 0; ni < 4; ++ni) {
        const int r = ni*16 + lr;
        const int bo = (lk*16 + kk*64) ^ ((r & 7) << 4);
        vb[ni] = *(const f16x8*)(Vb + r*128 + bo);
        if (SPLIT) vbl[ni] = *(const f16x8*)(Vlo + r*128 + bo);
      }
#pragma unroll
      for (int mi = 0; mi < 2; ++mi) {
        const int r = mi*16 + lr;
        const int bo = (lk*16 + kk*64) ^ ((r & 7) << 4);
        pa[mi] = *(const f16x8*)(Pw + r*128 + bo);
        if (SPLIT) pal[mi] = *(const f16x8*)(Pwl + r*128 + bo);
      }
#pragma unroll
      for (int mi = 0; mi < 2; ++mi)
#pragma unroll
        for (int ni = 0; ni < 4; ++ni) {
          oacc[mi][ni] = __builtin_amdgcn_mfma_f32_16x16x32_f16(pa[mi], vb[ni], oacc[mi][ni], 0, 0, 0);
          if (SPLIT) {
            oacc[mi][ni] = __builtin_amdgcn_mfma_f32_16x16x32_f16(pa[mi], vbl[ni], oacc[mi][ni], 0, 0, 0);
            oacc[mi][ni] = __builtin_amdgcn_mfma_f32_16x16x32_f16(pal[mi], vb[ni], oacc[mi][ni], 0, 0, 0);
          }
        }
    }
  }

#pragma unroll
  for (int mi = 0; mi < 2; ++mi)
#pragma unroll
    for (int i = 0; i < 4; ++i) {
      const float inv = 1.0f / l_run[mi][i];
      const int q = s0 + wave*32 + mi*16 + lk*4 + i;
      const long base = ((long)q * NB + b) * ldo + qoff;
#pragma unroll
      for (int ni = 0; ni < 4; ++ni) {
        float v = oacc[mi][ni][i] * inv;
        if (OSPLIT == 1) {
          _Float16 h = (_Float16)v;
          Oh[base + ni*16 + lr] = h;
          Ol[base + ni*16 + lr] = (_Float16)(v - (float)h);
        } else if (OSPLIT == 2) {
          Oh[base + ni*16 + lr] = (_Float16)v;
        } else {
          Op[base + ni*16 + lr] = v;
        }
      }
    }
}

// ---------------------------------------------------------------------------
// LayerNorm over c=512, one wave per row.
// ES: 0 = fp32 only; 1 = fp32 + split fp16 hi/lo; 2 = fp32 + fp16 hi.
// ---------------------------------------------------------------------------
template<int ES>
__global__ __launch_bounds__(256)
void ln_k(const float* __restrict__ X, const float* __restrict__ g,
          const float* __restrict__ bb, float* __restrict__ Y,
          _Float16* __restrict__ Yh, _Float16* __restrict__ Yl)
{
  const int t = threadIdx.x;
  const int lane = t & 63;
  const long row = (long)blockIdx.x * 4 + (t >> 6);
  const float* xr = X + row * CDIM;
  float4 v0 = *(const float4*)(xr + lane*4);
  float4 v1 = *(const float4*)(xr + 256 + lane*4);
  float s = v0.x+v0.y+v0.z+v0.w + v1.x+v1.y+v1.z+v1.w;
#pragma unroll
  for (int off = 1; off < 64; off <<= 1) s += __shfl_xor(s, off);
  const float mean = s * (1.0f/512.0f);
  float d[8] = {v0.x-mean, v0.y-mean, v0.z-mean, v0.w-mean,
                v1.x-mean, v1.y-mean, v1.z-mean, v1.w-mean};
  float sq = d[0]*d[0]+d[1]*d[1]+d[2]*d[2]+d[3]*d[3]
           + d[4]*d[4]+d[5]*d[5]+d[6]*d[6]+d[7]*d[7];
#pragma unroll
  for (int off = 1; off < 64; off <<= 1) sq += __shfl_xor(sq, off);
  const float inv = 1.0f / sqrtf(sq * (1.0f/512.0f) + 1e-5f);
  float4 g0 = *(const float4*)(g + lane*4);
  float4 g1 = *(const float4*)(g + 256 + lane*4);
  float4 b0 = *(const float4*)(bb + lane*4);
  float4 b1 = *(const float4*)(bb + 256 + lane*4);
  float o[8];
  o[0] = d[0]*inv*g0.x + b0.x; o[1] = d[1]*inv*g0.y + b0.y;
  o[2] = d[2]*inv*g0.z + b0.z; o[3] = d[3]*inv*g0.w + b0.w;
  o[4] = d[4]*inv*g1.x + b1.x; o[5] = d[5]*inv*g1.y + b1.y;
  o[6] = d[6]*inv*g1.z + b1.z; o[7] = d[7]*inv*g1.w + b1.w;
  *(float4*)(Y + row*CDIM + lane*4) = *(float4*)&o[0];
  *(float4*)(Y + row*CDIM + 256 + lane*4) = *(float4*)&o[4];
  if (ES) {
    f16x4 h0, h1, l0, l1;
#pragma unroll
    for (int j = 0; j < 4; ++j) {
      _Float16 h = (_Float16)o[j];     h0[j] = h;
      _Float16 k = (_Float16)o[4+j];   h1[j] = k;
      if (ES == 1) { l0[j] = (_Float16)(o[j] - (float)h); l1[j] = (_Float16)(o[4+j] - (float)k); }
    }
    *(f16x4*)(Yh + row*CDIM + lane*4) = h0;
    *(f16x4*)(Yh + row*CDIM + 256 + lane*4) = h1;
    if (ES == 1) {
      *(f16x4*)(Yl + row*CDIM + lane*4) = l0;
      *(f16x4*)(Yl + row*CDIM + 256 + lane*4) = l1;
    }
  }
}

// ---------------------------------------------------------------------------
// Pack x (N,C,H,W) -> enc_flat (S,n,c); posisted fp32 + split fp16 hi/lo.
// ---------------------------------------------------------------------------
__global__ void pack_pe_k(const float* __restrict__ x, float* __restrict__ encf,
                          float* __restrict__ posd,
                          _Float16* __restrict__ posh, _Float16* __restrict__ posl)
{
  __shared__ float tl[32][33];
  const int b = blockIdx.z;
  const int s0 = blockIdx.x*32, c0 = blockIdx.y*32;
#pragma unroll
  for (int i = 0; i < 4; ++i) {
    int ci = threadIdx.y + i*8;
    tl[ci][threadIdx.x] = x[((long)b*CDIM + c0+ci)*S_LEN + s0 + threadIdx.x];
  }
  __syncthreads();
#pragma unroll
  for (int i = 0; i < 4; ++i) {
    int si = threadIdx.y + i*8;
    int s = s0 + si;
    int ch = c0 + threadIdx.x;
    float val = tl[threadIdx.x][si];
    long o = ((long)s*NB + b)*CDIM + ch;
    encf[o] = val;
    int pos = (ch < 256) ? (s & 31) : (s >> 5);
    int j = (ch & 255) >> 1;
    float dv = expf((float)(2*j) * (-9.210340371976184f / 256.0f));
    float ang = (float)pos * dv;
    float pe = (ch & 1) ? cosf(ang) : sinf(ang);
    float pv = val + pe;
    posd[o] = pv;
    _Float16 h = (_Float16)pv;
    posh[o] = h;
    posl[o] = (_Float16)(pv - (float)h);
  }
}

// (S,n,c) token-major -> (n,c,S) output layout
__global__ void tpose_k(const float* __restrict__ in, float* __restrict__ out)
{
  __shared__ float tl[32][33];
  const int b = blockIdx.z;
  const int s0 = blockIdx.x*32, c0 = blockIdx.y*32;
#pragma unroll
  for (int i = 0; i < 4; ++i) {
    int si = threadIdx.y + i*8;
    tl[si][threadIdx.x] = in[((long)(s0+si)*NB + b)*CDIM + c0 + threadIdx.x];
  }
  __syncthreads();
#pragma unroll
  for (int i = 0; i < 4; ++i) {
    int ci = threadIdx.y + i*8;
    out[((long)b*CDIM + c0+ci)*S_LEN + s0 + threadIdx.x] = tl[threadIdx.x][ci];
  }
}

// cb_w (c,K) -> transposed split-fp16 codebook [K][c] hi/lo
__global__ void cbt16_k(const float* __restrict__ cb,
                        _Float16* __restrict__ outh, _Float16* __restrict__ outl)
{
  __shared__ float tl[32][33];
  const int k0 = blockIdx.x*32, c0 = blockIdx.y*32;
#pragma unroll
  for (int i = 0; i < 4; ++i) {
    int ci = threadIdx.y + i*8;
    tl[ci][threadIdx.x] = cb[(long)(c0+ci)*KCB + k0 + threadIdx.x];
  }
  __syncthreads();
#pragma unroll
  for (int i = 0; i < 4; ++i) {
    int ki = threadIdx.y + i*8;
    float v = tl[threadIdx.x][ki];
    _Float16 h = (_Float16)v;
    outh[(long)(k0+ki)*CDIM + c0 + threadIdx.x] = h;
    outl[(long)(k0+ki)*CDIM + c0 + threadIdx.x] = (_Float16)(v - (float)h);
  }
}

// fp32 -> fp16 elementwise, 8 per thread
__global__ __launch_bounds__(256)
void conv16_k(const float* __restrict__ in, _Float16* __restrict__ out)
{
  const long i = ((long)blockIdx.x * 256 + threadIdx.x) * 8;
  float4 v0 = *(const float4*)(in + i);
  float4 v1 = *(const float4*)(in + i + 4);
  f16x8 h;
  h[0]=(_Float16)v0.x; h[1]=(_Float16)v0.y; h[2]=(_Float16)v0.z; h[3]=(_Float16)v0.w;
  h[4]=(_Float16)v1.x; h[5]=(_Float16)v1.y; h[6]=(_Float16)v1.z; h[7]=(_Float16)v1.w;
  *(f16x8*)(out + i) = h;
}

// fp32 -> split fp16 hi/lo, 8 per thread
__global__ __launch_bounds__(256)
void convsplit_k(const float* __restrict__ in, _Float16* __restrict__ oh,
                 _Float16* __restrict__ ol)
{
  const long i = ((long)blockIdx.x * 256 + threadIdx.x) * 8;
  float4 v0 = *(const float4*)(in + i);
  float4 v1 = *(const float4*)(in + i + 4);
  float vv[8] = {v0.x,v0.y,v0.z,v0.w,v1.x,v1.y,v1.z,v1.w};
  f16x8 h, l;
#pragma unroll
  for (int j = 0; j < 8; ++j) {
    _Float16 hh = (_Float16)vv[j];
    h[j] = hh;
    l[j] = (_Float16)(vv[j] - (float)hh);
  }
  *(f16x8*)(oh + i) = h;
  *(f16x8*)(ol + i) = l;
}

// Per-token row of logits: argmax (np first-occurrence) + write P (fp16)
__global__ __launch_bounds__(256)
void simstats_k(const float* __restrict__ logits, _Float16* __restrict__ Pbuf,
                int* __restrict__ codes_tok, float* __restrict__ codes_out)
{
  const long phys = blockIdx.x;
  const float* rowp = logits + phys * KCB;
  const int t = threadIdx.x;
  float vals[16];
#pragma unroll
  for (int rep = 0; rep < 4; ++rep) {
    float4 v = *(const float4*)(rowp + rep*1024 + t*4);
    vals[rep*4+0]=v.x; vals[rep*4+1]=v.y; vals[rep*4+2]=v.z; vals[rep*4+3]=v.w;
  }
  float mv = -INFINITY; int mi = 0;
#pragma unroll
  for (int rep = 0; rep < 4; ++rep)
#pragma unroll
    for (int j = 0; j < 4; ++j) {
      float xv = vals[rep*4+j];
      int ix = rep*1024 + t*4 + j;
      if (xv > mv) { mv = xv; mi = ix; }
    }
  const int lane = t & 63, wid = t >> 6;
#pragma unroll
  for (int off = 1; off < 64; off <<= 1) {
    float ov = __shfl_xor(mv, off);
    int   oi = __shfl_xor(mi, off);
    if (ov > mv || (ov == mv && oi < mi)) { mv = ov; mi = oi; }
  }
  __shared__ float smax[4]; __shared__ int sidx[4]; __shared__ float ssum[4];
  __shared__ float fm; __shared__ int fi; __shared__ float sinv;
  if (lane == 0) { smax[wid] = mv; sidx[wid] = mi; }
  __syncthreads();
  if (t == 0) {
    float bm = smax[0]; int bi = sidx[0];
    for (int wq = 1; wq < 4; ++wq)
      if (smax[wq] > bm || (smax[wq] == bm && sidx[wq] < bi)) { bm = smax[wq]; bi = sidx[wq]; }
    fm = bm; fi = bi;
  }
  __syncthreads();
  const float Mx = fm;
  float se = 0.f;
#pragma unroll
  for (int q = 0; q < 16; ++q) se += __expf(vals[q] - Mx);
#pragma unroll
  for (int off = 1; off < 64; off <<= 1) se += __shfl_xor(se, off);
  if (lane == 0) ssum[wid] = se;
  __syncthreads();
  const int b = (int)(phys >> 10), s = (int)(phys & 1023);
  if (t == 0) {
    float tot = ssum[0]+ssum[1]+ssum[2]+ssum[3];
    sinv = 1.0f / tot;
    codes_tok[s*NB + b] = fi;
    codes_out[phys] = (float)fi;
  }
  __syncthreads();
  const float inv = sinv;
  _Float16* prow = Pbuf + ((long)s*NB + b) * KCB;
#pragma unroll
  for (int rep = 0; rep < 4; ++rep) {
    f16x4 pv;
#pragma unroll
    for (int j = 0; j < 4; ++j) pv[j] = (_Float16)(__expf(vals[rep*4+j] - Mx) * inv);
    *(f16x4*)(prow + rep*1024 + t*4) = pv;
  }
}

// quant = (hard - soft) + soft; emit hard fp32 and quant fp32 + fp16-hi.
__global__ __launch_bounds__(128)
void quant_k(const float* __restrict__ soft, const int* __restrict__ codes_tok,
             const _Float16* __restrict__ cbh, const _Float16* __restrict__ cbl,
             float* __restrict__ quant, float* __restrict__ hardb,
             _Float16* __restrict__ qh16)
{
  const int r = blockIdx.x;
  const int code = codes_tok[r];
  const int c = threadIdx.x * 4;
  f16x4 hh = *(const f16x4*)(cbh + (long)code*CDIM + c);
  f16x4 hl = *(const f16x4*)(cbl + (long)code*CDIM + c);
  float4 sf = *(const float4*)(soft + (long)r*CDIM + c);
  float4 h, q;
  h.x = (float)hh[0] + (float)hl[0]; h.y = (float)hh[1] + (float)hl[1];
  h.z = (float)hh[2] + (float)hl[2]; h.w = (float)hh[3] + (float)hl[3];
  q.x = (h.x - sf.x) + sf.x; q.y = (h.y - sf.y) + sf.y;
  q.z = (h.z - sf.z) + sf.z; q.w = (h.w - sf.w) + sf.w;
  *(float4*)(quant + (long)r*CDIM + c) = q;
  *(float4*)(hardb + (long)r*CDIM + c) = h;
  f16x4 qh = {(_Float16)q.x, (_Float16)q.y, (_Float16)q.z, (_Float16)q.w};
  *(f16x4*)(qh16 + (long)r*CDIM + c) = qh;
}

// Detect the storage format of the bool mask buffer.
__global__ void maskdetect_k(const void* __restrict__ mask, int* __restrict__ flag)
{
  const unsigned int* wds = (const unsigned int*)mask;
  int t = threadIdx.x;
  int okI = 1, okF = 1, okL = 1;
  for (int i = t; i < 2048; i += 256) {
    unsigned int u = wds[i];
    if (u > 1u) okI = 0;
    if (u != 0u && u != 0x3F800000u) okF = 0;
    if ((i & 1) ? (u != 0u) : (u > 1u)) okL = 0;
  }
  __shared__ int sI, sF, sL;
  if (t == 0) { sI = 1; sF = 1; sL = 1; }
  __syncthreads();
  if (!okI) atomicAnd(&sI, 0);
  if (!okF) atomicAnd(&sF, 0);
  if (!okL) atomicAnd(&sL, 0);
  __syncthreads();
  if (t == 0) {
    int f;
    if (sI && sL) f = 3;
    else if (sI)  f = 1;
    else if (sF)  f = 2;
    else          f = 0;
    *flag = f;
  }
}

// mixed = mask ? enc_flat : post; fp32 + fp16-hi outputs
__global__ __launch_bounds__(256)
void mixed_k(const float* __restrict__ encf, const float* __restrict__ post,
             const void* __restrict__ mask, const int* __restrict__ flag,
             float* __restrict__ outx, _Float16* __restrict__ outh)
{
  long gid = (long)blockIdx.x * blockDim.x + threadIdx.x;
  int r = (int)(gid >> 7);
  int c = (int)(gid & 127) * 4;
  int f = *flag;
  bool mv;
  if (f == 0)      mv = ((const unsigned char*)mask)[r] != 0;
  else if (f == 1) mv = ((const int*)mask)[r] != 0;
  else if (f == 3) mv = ((const long long*)mask)[r] != 0;
  else             mv = ((const float*)mask)[r] != 0.0f;
  const float* src = mv ? encf : post;
  float4 v = *(const float4*)(src + (long)r*CDIM + c);
  *(float4*)(outx + (long)r*CDIM + c) = v;
  f16x4 h = {(_Float16)v.x, (_Float16)v.y, (_Float16)v.z, (_Float16)v.w};
  *(f16x4*)(outh + (long)r*CDIM + c) = h;
}

extern "C" void kernel_launch(void* const* d_in, const int* in_sizes, int n_in,
                              void* d_out, int out_size, void* d_ws, size_t ws_size,
                              hipStream_t stream)
{
  const float* x       = (const float*)d_in[0];
  const float* pre_w   = (const float*)d_in[1];
  const float* pre_b   = (const float*)d_in[2];
  const float* post_w  = (const float*)d_in[3];
  const float* post_b  = (const float*)d_in[4];
  const float* cb_w    = (const float*)d_in[5];
  const float* e_qkv_w = (const float*)d_in[6];
  const float* e_qkv_b = (const float*)d_in[7];
  const float* e_o_w   = (const float*)d_in[8];
  const float* e_o_b   = (const float*)d_in[9];
  const float* e_ln1_w = (const float*)d_in[10];
  const float* e_ln1_b = (const float*)d_in[11];
  const float* e_ln2_w = (const float*)d_in[12];
  const float* e_ln2_b = (const float*)d_in[13];
  const float* e_f1_w  = (const float*)d_in[14];
  const float* e_f1_b  = (const float*)d_in[15];
  const float* e_f2_w  = (const float*)d_in[16];
  const float* e_f2_b  = (const float*)d_in[17];
  const float* d_sqkv_w= (const float*)d_in[18];
  const float* d_sqkv_b= (const float*)d_in[19];
  const float* d_so_w  = (const float*)d_in[20];
  const float* d_so_b  = (const float*)d_in[21];
  const float* d_cqkv_w= (const float*)d_in[22];
  const float* d_cqkv_b= (const float*)d_in[23];
  const float* d_co_w  = (const float*)d_in[24];
  const float* d_co_b  = (const float*)d_in[25];
  const float* d_ln1w  = (const float*)d_in[26];
  const float* d_ln1b  = (const float*)d_in[27];
  const float* d_ln2w  = (const float*)d_in[28];
  const float* d_ln2b  = (const float*)d_in[29];
  const float* d_ln3w  = (const float*)d_in[30];
  const float* d_ln3b  = (const float*)d_in[31];
  const float* d_f1w   = (const float*)d_in[32];
  const float* d_f1b   = (const float*)d_in[33];
  const float* d_f2w   = (const float*)d_in[34];
  const float* d_f2b   = (const float*)d_in[35];
  const void*  mask    = d_in[36];

  float* out = (float*)d_out;
  float* o_quant  = out;
  float* o_high   = out + 4194304;
  float* o_softs  = out + 8388608;
  float* o_hards  = out + 12582912;
  float* o_codes  = out + 16777216;
  float* o_logits = out + 16785408;

  float* ws    = (float*)d_ws;
  float* ENC   = ws;
  float* Xb    = ws + TOKC;
  float* T1    = ws + 2*TOKC;
  float* T2    = ws + 3*TOKC;
  float* QKV   = ws + 4*TOKC;
  float* MEMB  = ws + 7*TOKC;
  float* CBREG = ws + 8*TOKC;                         // KCB*CDIM floats
  int*   CODES = (int*)(CBREG + (long)KCB*CDIM);
  int*   FLAG  = CODES + NTOK;
  float* HARDB = QKV;
  float* QUANT = QKV + TOKC;
  _Float16* PBUF = (_Float16*)QKV;                    // 64 MiB: QKV+MEMB regions
  _Float16* CBH  = (_Float16*)T1;                     // plain fp16 cb_w (c,K)
  _Float16* QKVh = (_Float16*)QKV;                    // [NTOK][3C] halves [0,24MiB)
  _Float16* QKVl = QKVh + (long)NTOK*3*CDIM;
  _Float16* CQh  = (_Float16*)QKV;                    // [0,8MiB)
  _Float16* KVh  = (_Float16*)(QKV + TOKC);           // [16,32MiB)
  _Float16* CBT16h = (_Float16*)CBREG;                // [K][c] hi
  _Float16* CBT16l = CBT16h + (long)KCB*CDIM;         // [K][c] lo
  _Float16* PREH = (_Float16*)T2;                     // pre in split fp16
  _Float16* PREL = PREH + TOKC;
  // decoder fp16 activation buffers (bit-identical producer conversions):
  _Float16* AH16   = (_Float16*)ENC;                  // attn out, ENC [0,8MiB)
  _Float16* FH16   = AH16 + TOKC;                     // f1 out,   ENC [8,16MiB)
  _Float16* XH16   = ((_Float16*)QKV) + 4*TOKC;       // QKV bytes [32,40MiB)
  _Float16* MEMBH16= XH16 + TOKC;                     // QKV bytes [40,48MiB)
  _Float16* QH16   = ((_Float16*)T1) + TOKC;          // T1 bytes [8,16MiB)

  // ---- encoder scratch inside o_logits (dead until sim GEMM rewrites it) ----
  const long WQSZ = (long)6*3*CDIM*CDIM;   // 4,718,592
  const long WSSZ = (long)6*CDIM*CDIM;     // 1,572,864
  _Float16* SCR  = (_Float16*)o_logits;
  _Float16* WQH = SCR;            _Float16* WQL = WQH + WQSZ;
  _Float16* WOH = WQL + WQSZ;     _Float16* WOL = WOH + WSSZ;
  _Float16* WF1H= WOL + WSSZ;     _Float16* WF1L= WF1H + WSSZ;
  _Float16* WF2H= WF1L + WSSZ;    _Float16* WF2L= WF2H + WSSZ;
  _Float16* WPH = WF2L + WSSZ;    _Float16* WPL = WPH + (long)CDIM*CDIM;
  _Float16* XH  = WPL + (long)CDIM*CDIM;  _Float16* XL  = XH + TOKC;
  _Float16* AH  = XL + TOKC;      _Float16* AL  = AH + TOKC;
  _Float16* L1H = AL + TOKC;      _Float16* L1L = L1H + TOKC;
  _Float16* H1H = L1L + TOKC;     _Float16* H1L = H1H + TOKC;

  const size_t NEED = (size_t)(8*TOKC + (long)KCB*CDIM + 2*NTOK + NTOK + 16) * 4;
  if (ws_size < NEED) return;

  const int M = NTOK;
  dim3 tgrid(S_LEN/32, CDIM/32, NB), tblk(32, 8);
  dim3 agrid(S_LEN/128, NB*8);

  pack_pe_k<<<tgrid, tblk, 0, stream>>>(x, ENC, Xb, XH, XL);
  cbt16_k<<<dim3(KCB/32, CDIM/32), tblk, 0, stream>>>(cb_w, CBT16h, CBT16l);
  maskdetect_k<<<1, 256, 0, stream>>>(mask, FLAG);
  convsplit_k<<<(int)(WQSZ/2048), 256, 0, stream>>>(e_qkv_w, WQH, WQL);
  convsplit_k<<<(int)(WSSZ/2048), 256, 0, stream>>>(e_o_w,  WOH,  WOL);
  convsplit_k<<<(int)(WSSZ/2048), 256, 0, stream>>>(e_f1_w, WF1H, WF1L);
  convsplit_k<<<(int)(WSSZ/2048), 256, 0, stream>>>(e_f2_w, WF2H, WF2L);
  convsplit_k<<<(int)(((long)CDIM*CDIM)/2048), 256, 0, stream>>>(pre_w, WPH, WPL);

  // -------- encoder (split-fp16 MFMA, producer-converted inputs) --------
  for (int i = 0; i < NLAYER; ++i) {
    hgemm_k<128,1,2,true,false,false,false,true><<<dim3(3*CDIM/128, M/128), 256, 0, stream>>>(
        XH, WQH + (long)i*3*CDIM*CDIM, e_qkv_b + i*3*CDIM, nullptr, 0,
        nullptr, 3*CDIM, M, 3*CDIM, CDIM, QKVh, QKVl, XL, WQL + (long)i*3*CDIM*CDIM);
    mattn_k<1,1><<<agrid, 256, 0, stream>>>(QKVh, QKVl, 3*CDIM,
        QKVh+CDIM, QKVl+CDIM, 3*CDIM, QKVh+2*CDIM, QKVl+2*CDIM, 3*CDIM,
        nullptr, CDIM, AH, AL);
    hgemm_k<64,1,2,true,true,false,false,false><<<dim3(CDIM/128, M/64), 256, 0, stream>>>(
        AH, WOH + (long)i*CDIM*CDIM, e_o_b + i*CDIM, Xb, CDIM,
        T2, CDIM, M, CDIM, CDIM, nullptr, nullptr, AL, WOL + (long)i*CDIM*CDIM);
    ln_k<1><<<M/4, 256, 0, stream>>>(T2, e_ln1_w + i*CDIM, e_ln1_b + i*CDIM, T1, L1H, L1L);
    hgemm_k<64,1,2,true,false,true,false,true><<<dim3(CDIM/128, M/64), 256, 0, stream>>>(
        L1H, WF1H + (long)i*CDIM*CDIM, e_f1_b + i*CDIM, nullptr, 0,
        nullptr, CDIM, M, CDIM, CDIM, H1H, H1L, L1L, WF1L + (long)i*CDIM*CDIM);
    hgemm_k<64,1,2,true,true,false,false,false><<<dim3(CDIM/128, M/64), 256, 0, stream>>>(
        H1H, WF2H + (long)i*CDIM*CDIM, e_f2_b + i*CDIM, T1, CDIM,
        T2, CDIM, M, CDIM, CDIM, nullptr, nullptr, H1L, WF2L + (long)i*CDIM*CDIM);
    ln_k<1><<<M/4, 256, 0, stream>>>(T2, e_ln2_w + i*CDIM, e_ln2_b + i*CDIM, Xb, XH, XL);
  }

  // -------- codebook / quantizer --------
  hgemm_k<64,1,2,true,false,false,false,true><<<dim3(CDIM/128, M/64), 256, 0, stream>>>(
      XH, WPH, pre_b, nullptr, 0, T1, CDIM, M, CDIM, CDIM, PREH, PREL, XL, WPL);
  tpose_k<<<tgrid, tblk, 0, stream>>>(T1, o_high);
  hgemm_k<128,1,2,false,false,false,true,false><<<dim3(KCB/128, M/128), 256, 0, stream>>>(
      PREH, CBT16h, nullptr, nullptr, 0, o_logits, KCB, M, KCB, CDIM,
      nullptr, nullptr, PREL, CBT16l);
  conv16_k<<<(CDIM*(long)KCB)/(256*8), 256, 0, stream>>>(cb_w, CBH);
  simstats_k<<<NTOK, 256, 0, stream>>>(o_logits, PBUF, CODES, o_codes);
  hgemm_k<64,0,1,false,false,false,false,false><<<dim3(CDIM/128, M/64), 256, 0, stream>>>(
      PBUF, CBH, nullptr, nullptr, 0, T2, CDIM, M, CDIM, KCB,
      nullptr, nullptr, nullptr, nullptr);                                   // soft
  tpose_k<<<tgrid, tblk, 0, stream>>>(T2, o_softs);
  quant_k<<<NTOK, 128, 0, stream>>>(T2, CODES, CBT16h, CBT16l, QUANT, HARDB, QH16);
  tpose_k<<<tgrid, tblk, 0, stream>>>(HARDB, o_hards);
  hgemm_k<64,0,3,true,false,false,false,false><<<dim3(CDIM/128, M/64), 256, 0, stream>>>(
      QH16, post_w, post_b, nullptr, 0, MEMB, CDIM, M, CDIM, CDIM,
      nullptr, nullptr, nullptr, nullptr);                                   // post
  mixed_k<<<4096, 256, 0, stream>>>(ENC, MEMB, mask, FLAG, Xb, XH16);
  conv16_k<<<(int)(TOKC/2048), 256, 0, stream>>>(MEMB, MEMBH16);

  // -------- decoder (f16 MFMA, producer-converted activations) --------
  for (int i = 0; i < NLAYER; ++i) {
    hgemm_k<128,0,3,true,false,false,false,true><<<dim3(3*CDIM/128, M/128), 256, 0, stream>>>(
        XH16, d_sqkv_w + (long)i*3*CDIM*CDIM, d_sqkv_b + i*3*CDIM, nullptr, 0,
        nullptr, 3*CDIM, M, 3*CDIM, CDIM, QKVh, nullptr, nullptr, nullptr);
    mattn_k<0,2><<<agrid, 256, 0, stream>>>(QKVh, nullptr, 3*CDIM,
        QKVh+CDIM, nullptr, 3*CDIM, QKVh+2*CDIM, nullptr, 3*CDIM, nullptr, CDIM,
        AH16, nullptr);
    hgemm_k<64,0,3,true,true,false,false,false><<<dim3(CDIM/128, M/64), 256, 0, stream>>>(
        AH16, d_so_w + (long)i*CDIM*CDIM, d_so_b + i*CDIM, Xb, CDIM,
        T2, CDIM, M, CDIM, CDIM, nullptr, nullptr, nullptr, nullptr);
    ln_k<2><<<M/4, 256, 0, stream>>>(T2, d_ln1w + i*CDIM, d_ln1b + i*CDIM, Xb, XH16, nullptr);
    hgemm_k<64,0,3,true,false,false,false,true><<<dim3(CDIM/128, M/64), 256, 0, stream>>>(
        XH16, d_cqkv_w + (long)i*3*CDIM*CDIM, d_cqkv_b + i*3*CDIM, nullptr, 0,
        nullptr, CDIM, M, CDIM, CDIM, CQh, nullptr, nullptr, nullptr);
    hgemm_k<128,0,3,true,false,false,false,true><<<dim3(2*CDIM/128, M/128), 256, 0, stream>>>(
        MEMBH16, d_cqkv_w + (long)i*3*CDIM*CDIM + (long)CDIM*CDIM,
        d_cqkv_b + i*3*CDIM + CDIM, nullptr, 0,
        nullptr, 2*CDIM, M, 2*CDIM, CDIM, KVh, nullptr, nullptr, nullptr);
    mattn_k<0,2><<<agrid, 256, 0, stream>>>(CQh, nullptr, CDIM,
        KVh, nullptr, 2*CDIM, KVh+CDIM, nullptr, 2*CDIM, nullptr, CDIM,
        AH16, nullptr);
    hgemm_k<64,0,3,true,true,false,false,false><<<dim3(CDIM/128, M/64), 256, 0, stream>>>(
        AH16, d_co_w + (long)i*CDIM*CDIM, d_co_b + i*CDIM, Xb, CDIM,
        T2, CDIM, M, CDIM, CDIM, nullptr, nullptr, nullptr, nullptr);
    ln_k<2><<<M/4, 256, 0, stream>>>(T2, d_ln2w + i*CDIM, d_ln2b + i*CDIM, Xb, XH16, nullptr);
    hgemm_k<64,0,3,true,false,true,false,true><<<dim3(CDIM/128, M/64), 256, 0, stream>>>(
        XH16, d_f1w + (long)i*CDIM*CDIM, d_f1b + i*CDIM, nullptr, 0,
        nullptr, CDIM, M, CDIM, CDIM, FH16, nullptr, nullptr, nullptr);
    hgemm_k<64,0,3,true,true,false,false,false><<<dim3(CDIM/128, M/64), 256, 0, stream>>>(
        FH16, d_f2w + (long)i*CDIM*CDIM, d_f2b + i*CDIM, Xb, CDIM,
        T2, CDIM, M, CDIM, CDIM, nullptr, nullptr, nullptr, nullptr);
    ln_k<2><<<M/4, 256, 0, stream>>>(T2, d_ln3w + i*CDIM, d_ln3b + i*CDIM, Xb, XH16, nullptr);
  }
  tpose_k<<<tgrid, tblk, 0, stream>>>(Xb, o_quant);
}

// Round 12
// 3819.138 us; speedup vs baseline: 3.2823x; 1.0058x over previous
//
#include <hip/hip_runtime.h>
#include <math.h>

#define S_LEN 1024
#define NB 8
#define CDIM 512
#define KCB 4096
#define DH 64
#define NLAYER 6
#define NTOK (S_LEN*NB)
#define TOKC ((long)NTOK*CDIM)

typedef __attribute__((ext_vector_type(8))) _Float16 f16x8;
typedef __attribute__((ext_vector_type(4))) _Float16 f16x4;
typedef __attribute__((ext_vector_type(2))) _Float16 f16x2;
typedef __attribute__((ext_vector_type(4))) float f32x4;

// ---------------------------------------------------------------------------
// MFMA GEMM: C[M,N] = A[M,K] @ W[N,K]^T (+bias/res/relu).
// TM in {64,128}; N-tile 128. BK=64, mfma_f32_16x16x32_f16, XOR-swizzled LDS.
// SPLIT=1: hi/lo split-fp16, 3 MFMAs/pair (~fp32 accuracy).
// F16IN: 0 = A,W fp32 (convert in-kernel); 1 = A,W fp16; 2 = A,W split fp16
// hi/lo (Avl/Wvl, SPLIT=1); 3 = A fp16, W fp32-converted (SPLIT=0).
// E16: epilogue writes fp16 hi (Ch16) (+lo Cl16 if SPLIT); also fp32 C if C!=0.
// OREMAP: output row (s*NB+b) -> (b*S_LEN+s).
// NOTE: A and C must NOT alias (blocks of one dispatch race) — enforced in
// kernel_launch buffer routing.
// ---------------------------------------------------------------------------
template<int TM, int SPLIT, int F16IN, bool BIAS, bool RES, bool RELU, bool OREMAP, bool E16>
__global__ __launch_bounds__(256)
void hgemm_k(const void* __restrict__ Av, const void* __restrict__ Wv,
             const float* __restrict__ bias, const float* __restrict__ Rsrc, int ldr,
             float* __restrict__ C, int ldc, int M, int N, int K,
             _Float16* __restrict__ Ch16, _Float16* __restrict__ Cl16,
             const void* __restrict__ Avl, const void* __restrict__ Wvl)
{
  constexpr int MI = TM / 32;
  constexpr int ATPR = 256 / TM;
  constexpr int ACOL = 64 / ATPR;
  constexpr bool AF16 = (F16IN >= 1);                 // A arrives fp16
  constexpr bool WF16 = (F16IN == 1 || F16IN == 2);   // W arrives fp16
  __shared__ __align__(16) _Float16 Ah[TM*64];
  __shared__ __align__(16) _Float16 Bh[128*64];
  __shared__ __align__(16) _Float16 Al[SPLIT ? TM*64 : 8];
  __shared__ __align__(16) _Float16 Bl[SPLIT ? 128*64 : 8];
  const int t = threadIdx.x;
  const int m0 = blockIdx.y * TM, n0 = blockIdx.x * 128;

  const int arow = t / ATPR, apart = t % ATPR;
  const int brow = t >> 1, bpart = t & 1;

  const float*    Af  = (const float*)Av;
  const _Float16* Axh = (const _Float16*)Av;
  const _Float16* Axl = (const _Float16*)Avl;
  const float*    Wf  = (const float*)Wv;
  const _Float16* Wxh = (const _Float16*)Wv;
  const _Float16* Wxl = (const _Float16*)Wvl;
  const long aoff = (long)(m0 + arow) * K + apart * ACOL;
  const long boff = (long)(n0 + brow) * K + bpart * 32;

  const int lane = t & 63, wave = t >> 6;
  const int wm = wave >> 1, wn = wave & 1;
  const int lr = lane & 15, lk = lane >> 4;

  f32x4 acc[MI][4];
#pragma unroll
  for (int mi = 0; mi < MI; ++mi)
#pragma unroll
    for (int ni = 0; ni < 4; ++ni)
#pragma unroll
      for (int e = 0; e < 4; ++e) acc[mi][ni][e] = 0.f;

  float4 a4[ACOL/4], b4[8];
  f16x8  a16[ACOL/8], b16[4];
  f16x8  a16l[F16IN==2 ? ACOL/8 : 1], b16l[F16IN==2 ? 4 : 1];
  if (AF16) {
#pragma unroll
    for (int g = 0; g < ACOL/8; ++g) a16[g] = *(const f16x8*)(Axh + aoff + g*8);
    if (F16IN == 2) {
#pragma unroll
      for (int g = 0; g < ACOL/8; ++g) a16l[g] = *(const f16x8*)(Axl + aoff + g*8);
    }
  } else {
#pragma unroll
    for (int j = 0; j < ACOL/4; ++j) a4[j] = *(const float4*)(Af + aoff + j*4);
  }
  if (WF16) {
#pragma unroll
    for (int g = 0; g < 4; ++g) b16[g] = *(const f16x8*)(Wxh + boff + g*8);
    if (F16IN == 2) {
#pragma unroll
      for (int g = 0; g < 4; ++g) b16l[g] = *(const f16x8*)(Wxl + boff + g*8);
    }
  } else {
#pragma unroll
    for (int j = 0; j < 8; ++j) b4[j] = *(const float4*)(Wf + boff + j*4);
  }

  for (int k0 = 0; k0 < K; k0 += 64) {
    __syncthreads();
    // ---- A staging ----
    if (AF16) {
#pragma unroll
      for (int g = 0; g < ACOL/8; ++g) {
        const int sw = (apart*ACOL*2 + g*16) ^ ((arow & 7) << 4);
        *(f16x8*)((char*)Ah + arow*128 + sw) = a16[g];
        if (F16IN == 2) *(f16x8*)((char*)Al + arow*128 + sw) = a16l[g];
      }
    } else {
      const float* af = (const float*)a4;
#pragma unroll
      for (int g = 0; g < ACOL/8; ++g) {
        f16x8 h, l;
#pragma unroll
        for (int j = 0; j < 8; ++j) {
          float xv = af[g*8+j];
          _Float16 hh = (_Float16)xv;
          h[j] = hh;
          if (SPLIT) l[j] = (_Float16)(xv - (float)hh);
        }
        const int sw = (apart*ACOL*2 + g*16) ^ ((arow & 7) << 4);
        *(f16x8*)((char*)Ah + arow*128 + sw) = h;
        if (SPLIT) *(f16x8*)((char*)Al + arow*128 + sw) = l;
      }
    }
    // ---- W staging ----
    if (WF16) {
#pragma unroll
      for (int g = 0; g < 4; ++g) {
        const int sw = (bpart*64 + g*16) ^ ((brow & 7) << 4);
        *(f16x8*)((char*)Bh + brow*128 + sw) = b16[g];
        if (F16IN == 2) *(f16x8*)((char*)Bl + brow*128 + sw) = b16l[g];
      }
    } else {
      const float* bf = (const float*)b4;
#pragma unroll
      for (int g = 0; g < 4; ++g) {
        f16x8 h, l;
#pragma unroll
        for (int j = 0; j < 8; ++j) {
          float xv = bf[g*8+j];
          _Float16 hh = (_Float16)xv;
          h[j] = hh;
          if (SPLIT) l[j] = (_Float16)(xv - (float)hh);
        }
        const int sw = (bpart*64 + g*16) ^ ((brow & 7) << 4);
        *(f16x8*)((char*)Bh + brow*128 + sw) = h;
        if (SPLIT) *(f16x8*)((char*)Bl + brow*128 + sw) = l;
      }
    }
    __syncthreads();
    if (k0 + 64 < K) {
      if (AF16) {
#pragma unroll
        for (int g = 0; g < ACOL/8; ++g) a16[g] = *(const f16x8*)(Axh + aoff + k0 + 64 + g*8);
        if (F16IN == 2) {
#pragma unroll
          for (int g = 0; g < ACOL/8; ++g) a16l[g] = *(const f16x8*)(Axl + aoff + k0 + 64 + g*8);
        }
      } else {
#pragma unroll
        for (int j = 0; j < ACOL/4; ++j) a4[j] = *(const float4*)(Af + aoff + k0 + 64 + j*4);
      }
      if (WF16) {
#pragma unroll
        for (int g = 0; g < 4; ++g) b16[g] = *(const f16x8*)(Wxh + boff + k0 + 64 + g*8);
        if (F16IN == 2) {
#pragma unroll
          for (int g = 0; g < 4; ++g) b16l[g] = *(const f16x8*)(Wxl + boff + k0 + 64 + g*8);
        }
      } else {
#pragma unroll
        for (int j = 0; j < 8; ++j) b4[j] = *(const float4*)(Wf + boff + k0 + 64 + j*4);
      }
    }
#pragma unroll
    for (int kk = 0; kk < 2; ++kk) {
      f16x8 afh[MI], bfh[4], afl[MI], bfl[4];
#pragma unroll
      for (int mi = 0; mi < MI; ++mi) {
        const int r = wm*(TM/2) + mi*16 + lr;
        const int bo = (lk*16 + kk*64) ^ ((r & 7) << 4);
        afh[mi] = *(const f16x8*)((const char*)Ah + r*128 + bo);
        if (SPLIT) afl[mi] = *(const f16x8*)((const char*)Al + r*128 + bo);
      }
#pragma unroll
      for (int ni = 0; ni < 4; ++ni) {
        const int r = wn*64 + ni*16 + lr;
        const int bo = (lk*16 + kk*64) ^ ((r & 7) << 4);
        bfh[ni] = *(const f16x8*)((const char*)Bh + r*128 + bo);
        if (SPLIT) bfl[ni] = *(const f16x8*)((const char*)Bl + r*128 + bo);
      }
#pragma unroll
      for (int mi = 0; mi < MI; ++mi)
#pragma unroll
        for (int ni = 0; ni < 4; ++ni) {
          acc[mi][ni] = __builtin_amdgcn_mfma_f32_16x16x32_f16(afh[mi], bfh[ni], acc[mi][ni], 0, 0, 0);
          if (SPLIT) {
            acc[mi][ni] = __builtin_amdgcn_mfma_f32_16x16x32_f16(afh[mi], bfl[ni], acc[mi][ni], 0, 0, 0);
            acc[mi][ni] = __builtin_amdgcn_mfma_f32_16x16x32_f16(afl[mi], bfh[ni], acc[mi][ni], 0, 0, 0);
          }
        }
    }
  }

  float bvv[4];
  if (BIAS) {
#pragma unroll
    for (int ni = 0; ni < 4; ++ni) bvv[ni] = bias[n0 + wn*64 + ni*16 + lr];
  }
#pragma unroll
  for (int mi = 0; mi < MI; ++mi)
#pragma unroll
  for (int i = 0; i < 4; ++i) {
    const int rm = m0 + wm*(TM/2) + mi*16 + lk*4 + i;
    long orow = rm;
    if (OREMAP) orow = (long)(rm & (NB-1)) * S_LEN + (rm >> 3);
#pragma unroll
    for (int ni = 0; ni < 4; ++ni) {
      const int col = n0 + wn*64 + ni*16 + lr;
      float v = acc[mi][ni][i];
      if (BIAS) v += bvv[ni];
      if (RES)  v += Rsrc[(long)rm*ldr + col];
      if (RELU) v = fmaxf(v, 0.f);
      if (E16) {
        _Float16 hv = (_Float16)v;
        Ch16[(long)rm*ldc + col] = hv;
        if (SPLIT) Cl16[(long)rm*ldc + col] = (_Float16)(v - (float)hv);
        if (C != nullptr) C[orow*(long)ldc + col] = v;
      } else {
        C[orow*(long)ldc + col] = v;
      }
    }
  }
}

// ---------------------------------------------------------------------------
// MFMA flash attention, fp16 hi/lo inputs. 128 q rows x (b,head); 4 waves.
// Grid: (bh, s0-tile) so all s0-blocks sharing one (b,head)'s K/V map to the
// same XCD (block id % 8 == bh % 8) -> K/V served from that XCD's L2.
// K/V staged via register prefetch. LDS XOR-swizzled. SPLIT=1: 3 MFMAs/pair.
// Q pre-scaled by 1/8 (exact). OSPLIT: 0 = fp32 out; 1 = split hi/lo fp16;
// 2 = fp16 hi only. All bit-identical to a downstream conversion.
// ---------------------------------------------------------------------------
template<int SPLIT, int OSPLIT>
__global__ __launch_bounds__(256)
void mattn_k(const _Float16* __restrict__ Qh, const _Float16* __restrict__ Ql, int ldq,
             const _Float16* __restrict__ Kh, const _Float16* __restrict__ Kl, int ldk,
             const _Float16* __restrict__ Vh, const _Float16* __restrict__ Vl, int ldv,
             float* __restrict__ Op, int ldo,
             _Float16* __restrict__ Oh, _Float16* __restrict__ Ol)
{
  __shared__ __align__(16) char Pb[SPLIT ? 32768 : 16384];
  __shared__ __align__(16) char Kb[SPLIT ? 16384 : 8192];
  __shared__ __align__(16) char Vb[SPLIT ? 16384 : 8192];

  const int t = threadIdx.x;
  const int b = blockIdx.x >> 3, hd = blockIdx.x & 7;   // bh on x: same-KV blocks
  const int s0 = blockIdx.y * 128;                      // share one XCD's L2
  const int qoff = hd * DH;
  const int wave = t >> 6, lane = t & 63;
  const int lr = lane & 15, lk = lane >> 4;
  const int krow = t >> 2, kqd = t & 3;
  const int vtp = t & 31, vdc = t >> 5;

  f16x8 qa[2][2], qal[2][2];
#pragma unroll
  for (int mi = 0; mi < 2; ++mi)
#pragma unroll
    for (int kk = 0; kk < 2; ++kk) {
      const int q = s0 + wave*32 + mi*16 + lr;
      const long base = ((long)q*NB + b)*ldq + qoff + kk*32 + lk*8;
      f16x8 v = *(const f16x8*)(Qh + base);
#pragma unroll
      for (int e = 0; e < 8; ++e) v[e] = v[e] * (_Float16)0.125f;
      qa[mi][kk] = v;
      if (SPLIT) {
        f16x8 w = *(const f16x8*)(Ql + base);
#pragma unroll
        for (int e = 0; e < 8; ++e) w[e] = w[e] * (_Float16)0.125f;
        qal[mi][kk] = w;
      }
    }

  float m_run[2][4], l_run[2][4];
  f32x4 oacc[2][4];
#pragma unroll
  for (int mi = 0; mi < 2; ++mi)
#pragma unroll
    for (int i = 0; i < 4; ++i) {
      m_run[mi][i] = -INFINITY; l_run[mi][i] = 0.f;
#pragma unroll
      for (int ni = 0; ni < 4; ++ni) oacc[mi][ni][i] = 0.f;
    }

  char* Pw  = Pb + wave*4096;
  char* Pwl = Pb + 16384 + wave*4096;
  char* Klo = Kb + 8192;
  char* Vlo = Vb + 8192;

  f16x8 kr0, kr1, krl0, krl1, vr0, vr1, vrl0, vrl1;
  {
    const long kb = ((long)krow*NB + b)*ldk + qoff + kqd*16;
    kr0 = *(const f16x8*)(Kh + kb);
    kr1 = *(const f16x8*)(Kh + kb + 8);
    if (SPLIT) { krl0 = *(const f16x8*)(Kl + kb); krl1 = *(const f16x8*)(Kl + kb + 8); }
    const long vb = ((long)(2*vtp)*NB + b)*ldv + qoff + vdc*8;
    vr0 = *(const f16x8*)(Vh + vb);
    vr1 = *(const f16x8*)(Vh + vb + (long)NB*ldv);
    if (SPLIT) { vrl0 = *(const f16x8*)(Vl + vb); vrl1 = *(const f16x8*)(Vl + vb + (long)NB*ldv); }
  }

  for (int t0 = 0; t0 < S_LEN; t0 += 64) {
    __syncthreads();
    {
      const int sw0 = (kqd*32) ^ ((krow & 7) << 4);
      const int sw1 = (kqd*32 + 16) ^ ((krow & 7) << 4);
      *(f16x8*)(Kb + krow*128 + sw0) = kr0;
      *(f16x8*)(Kb + krow*128 + sw1) = kr1;
      if (SPLIT) {
        *(f16x8*)(Klo + krow*128 + sw0) = krl0;
        *(f16x8*)(Klo + krow*128 + sw1) = krl1;
      }
#pragma unroll
      for (int j = 0; j < 8; ++j) {
        const int dd = vdc*8 + j;
        f16x2 hv = {vr0[j], vr1[j]};
        *(f16x2*)(Vb + dd*128 + ((vtp*4) ^ ((dd & 7) << 4))) = hv;
        if (SPLIT) {
          f16x2 lv = {vrl0[j], vrl1[j]};
          *(f16x2*)(Vlo + dd*128 + ((vtp*4) ^ ((dd & 7) << 4))) = lv;
        }
      }
    }
    if (t0 + 64 < S_LEN) {
      const long kb = ((long)(t0 + 64 + krow)*NB + b)*ldk + qoff + kqd*16;
      kr0 = *(const f16x8*)(Kh + kb);
      kr1 = *(const f16x8*)(Kh + kb + 8);
      if (SPLIT) { krl0 = *(const f16x8*)(Kl + kb); krl1 = *(const f16x8*)(Kl + kb + 8); }
      const long vb = ((long)(t0 + 64 + 2*vtp)*NB + b)*ldv + qoff + vdc*8;
      vr0 = *(const f16x8*)(Vh + vb);
      vr1 = *(const f16x8*)(Vh + vb + (long)NB*ldv);
      if (SPLIT) { vrl0 = *(const f16x8*)(Vl + vb); vrl1 = *(const f16x8*)(Vl + vb + (long)NB*ldv); }
    }
    __syncthreads();

    // ---- S = Q K^T ----
    f32x4 s[2][4];
#pragma unroll
    for (int mi = 0; mi < 2; ++mi)
#pragma unroll
      for (int ni = 0; ni < 4; ++ni)
#pragma unroll
        for (int e = 0; e < 4; ++e) s[mi][ni][e] = 0.f;
#pragma unroll
    for (int kk = 0; kk < 2; ++kk) {
      f16x8 kb[4], kbl[4];
#pragma unroll
      for (int ni = 0; ni < 4; ++ni) {
        const int r = ni*16 + lr;
        const int bo = (lk*16 + kk*64) ^ ((r & 7) << 4);
        kb[ni] = *(const f16x8*)(Kb + r*128 + bo);
        if (SPLIT) kbl[ni] = *(const f16x8*)(Klo + r*128 + bo);
      }
#pragma unroll
      for (int mi = 0; mi < 2; ++mi)
#pragma unroll
        for (int ni = 0; ni < 4; ++ni) {
          s[mi][ni] = __builtin_amdgcn_mfma_f32_16x16x32_f16(qa[mi][kk], kb[ni], s[mi][ni], 0, 0, 0);
          if (SPLIT) {
            s[mi][ni] = __builtin_amdgcn_mfma_f32_16x16x32_f16(qa[mi][kk], kbl[ni], s[mi][ni], 0, 0, 0);
            s[mi][ni] = __builtin_amdgcn_mfma_f32_16x16x32_f16(qal[mi][kk], kb[ni], s[mi][ni], 0, 0, 0);
          }
        }
    }

    // ---- online softmax ----
#pragma unroll
    for (int mi = 0; mi < 2; ++mi) {
      float rm[4];
#pragma unroll
      for (int i = 0; i < 4; ++i)
        rm[i] = fmaxf(fmaxf(s[mi][0][i], s[mi][1][i]), fmaxf(s[mi][2][i], s[mi][3][i]));
#pragma unroll
      for (int off = 1; off < 16; off <<= 1)
#pragma unroll
        for (int i = 0; i < 4; ++i) rm[i] = fmaxf(rm[i], __shfl_xor(rm[i], off));
      float rs[4], corr[4];
#pragma unroll
      for (int i = 0; i < 4; ++i) {
        const float mnew = fmaxf(m_run[mi][i], rm[i]);
        corr[i] = __expf(m_run[mi][i] - mnew);
        m_run[mi][i] = mnew;
        float lsum = 0.f;
#pragma unroll
        for (int ni = 0; ni < 4; ++ni) {
          float p = __expf(s[mi][ni][i] - mnew);
          s[mi][ni][i] = p; lsum += p;
        }
        rs[i] = lsum;
      }
#pragma unroll
      for (int off = 1; off < 16; off <<= 1)
#pragma unroll
        for (int i = 0; i < 4; ++i) rs[i] += __shfl_xor(rs[i], off);
#pragma unroll
      for (int i = 0; i < 4; ++i) {
        l_run[mi][i] = l_run[mi][i]*corr[i] + rs[i];
#pragma unroll
        for (int ni = 0; ni < 4; ++ni) oacc[mi][ni][i] *= corr[i];
      }
    }

    // ---- P -> LDS (wave-private) ----
#pragma unroll
    for (int mi = 0; mi < 2; ++mi)
#pragma unroll
      for (int ni = 0; ni < 4; ++ni)
#pragma unroll
        for (int i = 0; i < 4; ++i) {
          const int row = mi*16 + lk*4 + i;
          const int col = ni*16 + lr;
          const int ad = row*128 + ((col*2) ^ ((row & 7) << 4));
          float pv = s[mi][ni][i];
          _Float16 ph = (_Float16)pv;
          *(_Float16*)(Pw + ad) = ph;
          if (SPLIT) *(_Float16*)(Pwl + ad) = (_Float16)(pv - (float)ph);
        }

    // ---- O += P V ----
#pragma unroll
    for (int kk = 0; kk < 2; ++kk) {
      f16x8 vb[4], vbl[4], pa[2], pal[2];
#pragma unroll
      for (int ni = 0; ni < 4; ++ni) {
        const int r = ni*16 + lr;
        const int bo = (lk*16 + kk*64) ^ ((r & 7) << 4);
        vb[ni] = *(const f16x8*)(Vb + r*128 + bo);
        if (SPLIT) vbl[ni] = *(const f16x8*)(Vlo + r*128 + bo);
      }
#pragma unroll
      for (int mi = 0; mi < 2; ++mi) {
        const int r = mi*16 + lr;
        const int bo = (lk*16 + kk*64) ^ ((r & 7) << 4);
        pa[mi] = *(const f16x8*)(Pw + r*128 + bo);
        if (SPLIT) pal[mi] = *(const f16x8*)(Pwl + r*128 + bo);
      }
#pragma unroll
      for (int mi = 0; mi < 2; ++mi)
#pragma unroll
        for (int ni = 0; ni < 4; ++ni) {
          oacc[mi][ni] = __builtin_amdgcn_mfma_f32_16x16x32_f16(pa[mi], vb[ni], oacc[mi][ni], 0, 0, 0);
          if (SPLIT) {
            oacc[mi][ni] = __builtin_amdgcn_mfma_f32_16x16x32_f16(pa[mi], vbl[ni], oacc[mi][ni], 0, 0, 0);
            oacc[mi][ni] = __builtin_amdgcn_mfma_f32_16x16x32_f16(pal[mi], vb[ni], oacc[mi][ni], 0, 0, 0);
          }
        }
    }
  }

#pragma unroll
  for (int mi = 0; mi < 2; ++mi)
#pragma unroll
    for (int i = 0; i < 4; ++i) {
      const float inv = 1.0f / l_run[mi][i];
      const int q = s0 + wave*32 + mi*16 + lk*4 + i;
      const long base = ((long)q * NB + b) * ldo + qoff;
#pragma unroll
      for (int ni = 0; ni < 4; ++ni) {
        float v = oacc[mi][ni][i] * inv;
        if (OSPLIT == 1) {
          _Float16 h = (_Float16)v;
          Oh[base + ni*16 + lr] = h;
          Ol[base + ni*16 + lr] = (_Float16)(v - (float)h);
        } else if (OSPLIT == 2) {
          Oh[base + ni*16 + lr] = (_Float16)v;
        } else {
          Op[base + ni*16 + lr] = v;
        }
      }
    }
}

// ---------------------------------------------------------------------------
// LayerNorm over c=512, one wave per row.
// ES: 0 = fp32 only; 1 = fp32 + split fp16 hi/lo; 2 = fp32 + fp16 hi.
// ---------------------------------------------------------------------------
template<int ES>
__global__ __launch_bounds__(256)
void ln_k(const float* __restrict__ X, const float* __restrict__ g,
          const float* __restrict__ bb, float* __restrict__ Y,
          _Float16* __restrict__ Yh, _Float16* __restrict__ Yl)
{
  const int t = threadIdx.x;
  const int lane = t & 63;
  const long row = (long)blockIdx.x * 4 + (t >> 6);
  const float* xr = X + row * CDIM;
  float4 v0 = *(const float4*)(xr + lane*4);
  float4 v1 = *(const float4*)(xr + 256 + lane*4);
  float s = v0.x+v0.y+v0.z+v0.w + v1.x+v1.y+v1.z+v1.w;
#pragma unroll
  for (int off = 1; off < 64; off <<= 1) s += __shfl_xor(s, off);
  const float mean = s * (1.0f/512.0f);
  float d[8] = {v0.x-mean, v0.y-mean, v0.z-mean, v0.w-mean,
                v1.x-mean, v1.y-mean, v1.z-mean, v1.w-mean};
  float sq = d[0]*d[0]+d[1]*d[1]+d[2]*d[2]+d[3]*d[3]
           + d[4]*d[4]+d[5]*d[5]+d[6]*d[6]+d[7]*d[7];
#pragma unroll
  for (int off = 1; off < 64; off <<= 1) sq += __shfl_xor(sq, off);
  const float inv = 1.0f / sqrtf(sq * (1.0f/512.0f) + 1e-5f);
  float4 g0 = *(const float4*)(g + lane*4);
  float4 g1 = *(const float4*)(g + 256 + lane*4);
  float4 b0 = *(const float4*)(bb + lane*4);
  float4 b1 = *(const float4*)(bb + 256 + lane*4);
  float o[8];
  o[0] = d[0]*inv*g0.x + b0.x; o[1] = d[1]*inv*g0.y + b0.y;
  o[2] = d[2]*inv*g0.z + b0.z; o[3] = d[3]*inv*g0.w + b0.w;
  o[4] = d[4]*inv*g1.x + b1.x; o[5] = d[5]*inv*g1.y + b1.y;
  o[6] = d[6]*inv*g1.z + b1.z; o[7] = d[7]*inv*g1.w + b1.w;
  *(float4*)(Y + row*CDIM + lane*4) = *(float4*)&o[0];
  *(float4*)(Y + row*CDIM + 256 + lane*4) = *(float4*)&o[4];
  if (ES) {
    f16x4 h0, h1, l0, l1;
#pragma unroll
    for (int j = 0; j < 4; ++j) {
      _Float16 h = (_Float16)o[j];     h0[j] = h;
      _Float16 k = (_Float16)o[4+j];   h1[j] = k;
      if (ES == 1) { l0[j] = (_Float16)(o[j] - (float)h); l1[j] = (_Float16)(o[4+j] - (float)k); }
    }
    *(f16x4*)(Yh + row*CDIM + lane*4) = h0;
    *(f16x4*)(Yh + row*CDIM + 256 + lane*4) = h1;
    if (ES == 1) {
      *(f16x4*)(Yl + row*CDIM + lane*4) = l0;
      *(f16x4*)(Yl + row*CDIM + 256 + lane*4) = l1;
    }
  }
}

// ---------------------------------------------------------------------------
// Pack x (N,C,H,W) -> enc_flat (S,n,c); posisted fp32 + split fp16 hi/lo.
// ---------------------------------------------------------------------------
__global__ void pack_pe_k(const float* __restrict__ x, float* __restrict__ encf,
                          float* __restrict__ posd,
                          _Float16* __restrict__ posh, _Float16* __restrict__ posl)
{
  __shared__ float tl[32][33];
  const int b = blockIdx.z;
  const int s0 = blockIdx.x*32, c0 = blockIdx.y*32;
#pragma unroll
  for (int i = 0; i < 4; ++i) {
    int ci = threadIdx.y + i*8;
    tl[ci][threadIdx.x] = x[((long)b*CDIM + c0+ci)*S_LEN + s0 + threadIdx.x];
  }
  __syncthreads();
#pragma unroll
  for (int i = 0; i < 4; ++i) {
    int si = threadIdx.y + i*8;
    int s = s0 + si;
    int ch = c0 + threadIdx.x;
    float val = tl[threadIdx.x][si];
    long o = ((long)s*NB + b)*CDIM + ch;
    encf[o] = val;
    int pos = (ch < 256) ? (s & 31) : (s >> 5);
    int j = (ch & 255) >> 1;
    float dv = expf((float)(2*j) * (-9.210340371976184f / 256.0f));
    float ang = (float)pos * dv;
    float pe = (ch & 1) ? cosf(ang) : sinf(ang);
    float pv = val + pe;
    posd[o] = pv;
    _Float16 h = (_Float16)pv;
    posh[o] = h;
    posl[o] = (_Float16)(pv - (float)h);
  }
}

// (S,n,c) token-major -> (n,c,S) output layout
__global__ void tpose_k(const float* __restrict__ in, float* __restrict__ out)
{
  __shared__ float tl[32][33];
  const int b = blockIdx.z;
  const int s0 = blockIdx.x*32, c0 = blockIdx.y*32;
#pragma unroll
  for (int i = 0; i < 4; ++i) {
    int si = threadIdx.y + i*8;
    tl[si][threadIdx.x] = in[((long)(s0+si)*NB + b)*CDIM + c0 + threadIdx.x];
  }
  __syncthreads();
#pragma unroll
  for (int i = 0; i < 4; ++i) {
    int ci = threadIdx.y + i*8;
    out[((long)b*CDIM + c0+ci)*S_LEN + s0 + threadIdx.x] = tl[threadIdx.x][ci];
  }
}

// cb_w (c,K) -> transposed split-fp16 codebook [K][c] hi/lo
__global__ void cbt16_k(const float* __restrict__ cb,
                        _Float16* __restrict__ outh, _Float16* __restrict__ outl)
{
  __shared__ float tl[32][33];
  const int k0 = blockIdx.x*32, c0 = blockIdx.y*32;
#pragma unroll
  for (int i = 0; i < 4; ++i) {
    int ci = threadIdx.y + i*8;
    tl[ci][threadIdx.x] = cb[(long)(c0+ci)*KCB + k0 + threadIdx.x];
  }
  __syncthreads();
#pragma unroll
  for (int i = 0; i < 4; ++i) {
    int ki = threadIdx.y + i*8;
    float v = tl[threadIdx.x][ki];
    _Float16 h = (_Float16)v;
    outh[(long)(k0+ki)*CDIM + c0 + threadIdx.x] = h;
    outl[(long)(k0+ki)*CDIM + c0 + threadIdx.x] = (_Float16)(v - (float)h);
  }
}

// fp32 -> fp16 elementwise, 8 per thread
__global__ __launch_bounds__(256)
void conv16_k(const float* __restrict__ in, _Float16* __restrict__ out)
{
  const long i = ((long)blockIdx.x * 256 + threadIdx.x) * 8;
  float4 v0 = *(const float4*)(in + i);
  float4 v1 = *(const float4*)(in + i + 4);
  f16x8 h;
  h[0]=(_Float16)v0.x; h[1]=(_Float16)v0.y; h[2]=(_Float16)v0.z; h[3]=(_Float16)v0.w;
  h[4]=(_Float16)v1.x; h[5]=(_Float16)v1.y; h[6]=(_Float16)v1.z; h[7]=(_Float16)v1.w;
  *(f16x8*)(out + i) = h;
}

// fp32 -> split fp16 hi/lo, 8 per thread
__global__ __launch_bounds__(256)
void convsplit_k(const float* __restrict__ in, _Float16* __restrict__ oh,
                 _Float16* __restrict__ ol)
{
  const long i = ((long)blockIdx.x * 256 + threadIdx.x) * 8;
  float4 v0 = *(const float4*)(in + i);
  float4 v1 = *(const float4*)(in + i + 4);
  float vv[8] = {v0.x,v0.y,v0.z,v0.w,v1.x,v1.y,v1.z,v1.w};
  f16x8 h, l;
#pragma unroll
  for (int j = 0; j < 8; ++j) {
    _Float16 hh = (_Float16)vv[j];
    h[j] = hh;
    l[j] = (_Float16)(vv[j] - (float)hh);
  }
  *(f16x8*)(oh + i) = h;
  *(f16x8*)(ol + i) = l;
}

// Per-token row of logits: argmax (np first-occurrence) + write P (fp16)
__global__ __launch_bounds__(256)
void simstats_k(const float* __restrict__ logits, _Float16* __restrict__ Pbuf,
                int* __restrict__ codes_tok, float* __restrict__ codes_out)
{
  const long phys = blockIdx.x;
  const float* rowp = logits + phys * KCB;
  const int t = threadIdx.x;
  float vals[16];
#pragma unroll
  for (int rep = 0; rep < 4; ++rep) {
    float4 v = *(const float4*)(rowp + rep*1024 + t*4);
    vals[rep*4+0]=v.x; vals[rep*4+1]=v.y; vals[rep*4+2]=v.z; vals[rep*4+3]=v.w;
  }
  float mv = -INFINITY; int mi = 0;
#pragma unroll
  for (int rep = 0; rep < 4; ++rep)
#pragma unroll
    for (int j = 0; j < 4; ++j) {
      float xv = vals[rep*4+j];
      int ix = rep*1024 + t*4 + j;
      if (xv > mv) { mv = xv; mi = ix; }
    }
  const int lane = t & 63, wid = t >> 6;
#pragma unroll
  for (int off = 1; off < 64; off <<= 1) {
    float ov = __shfl_xor(mv, off);
    int   oi = __shfl_xor(mi, off);
    if (ov > mv || (ov == mv && oi < mi)) { mv = ov; mi = oi; }
  }
  __shared__ float smax[4]; __shared__ int sidx[4]; __shared__ float ssum[4];
  __shared__ float fm; __shared__ int fi; __shared__ float sinv;
  if (lane == 0) { smax[wid] = mv; sidx[wid] = mi; }
  __syncthreads();
  if (t == 0) {
    float bm = smax[0]; int bi = sidx[0];
    for (int wq = 1; wq < 4; ++wq)
      if (smax[wq] > bm || (smax[wq] == bm && sidx[wq] < bi)) { bm = smax[wq]; bi = sidx[wq]; }
    fm = bm; fi = bi;
  }
  __syncthreads();
  const float Mx = fm;
  float se = 0.f;
#pragma unroll
  for (int q = 0; q < 16; ++q) se += __expf(vals[q] - Mx);
#pragma unroll
  for (int off = 1; off < 64; off <<= 1) se += __shfl_xor(se, off);
  if (lane == 0) ssum[wid] = se;
  __syncthreads();
  const int b = (int)(phys >> 10), s = (int)(phys & 1023);
  if (t == 0) {
    float tot = ssum[0]+ssum[1]+ssum[2]+ssum[3];
    sinv = 1.0f / tot;
    codes_tok[s*NB + b] = fi;
    codes_out[phys] = (float)fi;
  }
  __syncthreads();
  const float inv = sinv;
  _Float16* prow = Pbuf + ((long)s*NB + b) * KCB;
#pragma unroll
  for (int rep = 0; rep < 4; ++rep) {
    f16x4 pv;
#pragma unroll
    for (int j = 0; j < 4; ++j) pv[j] = (_Float16)(__expf(vals[rep*4+j] - Mx) * inv);
    *(f16x4*)(prow + rep*1024 + t*4) = pv;
  }
}

// quant = (hard - soft) + soft; emit hard fp32 and quant fp32 + fp16-hi.
__global__ __launch_bounds__(128)
void quant_k(const float* __restrict__ soft, const int* __restrict__ codes_tok,
             const _Float16* __restrict__ cbh, const _Float16* __restrict__ cbl,
             float* __restrict__ quant, float* __restrict__ hardb,
             _Float16* __restrict__ qh16)
{
  const int r = blockIdx.x;
  const int code = codes_tok[r];
  const int c = threadIdx.x * 4;
  f16x4 hh = *(const f16x4*)(cbh + (long)code*CDIM + c);
  f16x4 hl = *(const f16x4*)(cbl + (long)code*CDIM + c);
  float4 sf = *(const float4*)(soft + (long)r*CDIM + c);
  float4 h, q;
  h.x = (float)hh[0] + (float)hl[0]; h.y = (float)hh[1] + (float)hl[1];
  h.z = (float)hh[2] + (float)hl[2]; h.w = (float)hh[3] + (float)hl[3];
  q.x = (h.x - sf.x) + sf.x; q.y = (h.y - sf.y) + sf.y;
  q.z = (h.z - sf.z) + sf.z; q.w = (h.w - sf.w) + sf.w;
  *(float4*)(quant + (long)r*CDIM + c) = q;
  *(float4*)(hardb + (long)r*CDIM + c) = h;
  f16x4 qh = {(_Float16)q.x, (_Float16)q.y, (_Float16)q.z, (_Float16)q.w};
  *(f16x4*)(qh16 + (long)r*CDIM + c) = qh;
}

// Detect the storage format of the bool mask buffer.
__global__ void maskdetect_k(const void* __restrict__ mask, int* __restrict__ flag)
{
  const unsigned int* wds = (const unsigned int*)mask;
  int t = threadIdx.x;
  int okI = 1, okF = 1, okL = 1;
  for (int i = t; i < 2048; i += 256) {
    unsigned int u = wds[i];
    if (u > 1u) okI = 0;
    if (u != 0u && u != 0x3F800000u) okF = 0;
    if ((i & 1) ? (u != 0u) : (u > 1u)) okL = 0;
  }
  __shared__ int sI, sF, sL;
  if (t == 0) { sI = 1; sF = 1; sL = 1; }
  __syncthreads();
  if (!okI) atomicAnd(&sI, 0);
  if (!okF) atomicAnd(&sF, 0);
  if (!okL) atomicAnd(&sL, 0);
  __syncthreads();
  if (t == 0) {
    int f;
    if (sI && sL) f = 3;
    else if (sI)  f = 1;
    else if (sF)  f = 2;
    else          f = 0;
    *flag = f;
  }
}

// mixed = mask ? enc_flat : post; fp32 + fp16-hi outputs
__global__ __launch_bounds__(256)
void mixed_k(const float* __restrict__ encf, const float* __restrict__ post,
             const void* __restrict__ mask, const int* __restrict__ flag,
             float* __restrict__ outx, _Float16* __restrict__ outh)
{
  long gid = (long)blockIdx.x * blockDim.x + threadIdx.x;
  int r = (int)(gid >> 7);
  int c = (int)(gid & 127) * 4;
  int f = *flag;
  bool mv;
  if (f == 0)      mv = ((const unsigned char*)mask)[r] != 0;
  else if (f == 1) mv = ((const int*)mask)[r] != 0;
  else if (f == 3) mv = ((const long long*)mask)[r] != 0;
  else             mv = ((const float*)mask)[r] != 0.0f;
  const float* src = mv ? encf : post;
  float4 v = *(const float4*)(src + (long)r*CDIM + c);
  *(float4*)(outx + (long)r*CDIM + c) = v;
  f16x4 h = {(_Float16)v.x, (_Float16)v.y, (_Float16)v.z, (_Float16)v.w};
  *(f16x4*)(outh + (long)r*CDIM + c) = h;
}

extern "C" void kernel_launch(void* const* d_in, const int* in_sizes, int n_in,
                              void* d_out, int out_size, void* d_ws, size_t ws_size,
                              hipStream_t stream)
{
  const float* x       = (const float*)d_in[0];
  const float* pre_w   = (const float*)d_in[1];
  const float* pre_b   = (const float*)d_in[2];
  const float* post_w  = (const float*)d_in[3];
  const float* post_b  = (const float*)d_in[4];
  const float* cb_w    = (const float*)d_in[5];
  const float* e_qkv_w = (const float*)d_in[6];
  const float* e_qkv_b = (const float*)d_in[7];
  const float* e_o_w   = (const float*)d_in[8];
  const float* e_o_b   = (const float*)d_in[9];
  const float* e_ln1_w = (const float*)d_in[10];
  const float* e_ln1_b = (const float*)d_in[11];
  const float* e_ln2_w = (const float*)d_in[12];
  const float* e_ln2_b = (const float*)d_in[13];
  const float* e_f1_w  = (const float*)d_in[14];
  const float* e_f1_b  = (const float*)d_in[15];
  const float* e_f2_w  = (const float*)d_in[16];
  const float* e_f2_b  = (const float*)d_in[17];
  const float* d_sqkv_w= (const float*)d_in[18];
  const float* d_sqkv_b= (const float*)d_in[19];
  const float* d_so_w  = (const float*)d_in[20];
  const float* d_so_b  = (const float*)d_in[21];
  const float* d_cqkv_w= (const float*)d_in[22];
  const float* d_cqkv_b= (const float*)d_in[23];
  const float* d_co_w  = (const float*)d_in[24];
  const float* d_co_b  = (const float*)d_in[25];
  const float* d_ln1w  = (const float*)d_in[26];
  const float* d_ln1b  = (const float*)d_in[27];
  const float* d_ln2w  = (const float*)d_in[28];
  const float* d_ln2b  = (const float*)d_in[29];
  const float* d_ln3w  = (const float*)d_in[30];
  const float* d_ln3b  = (const float*)d_in[31];
  const float* d_f1w   = (const float*)d_in[32];
  const float* d_f1b   = (const float*)d_in[33];
  const float* d_f2w   = (const float*)d_in[34];
  const float* d_f2b   = (const float*)d_in[35];
  const void*  mask    = d_in[36];

  float* out = (float*)d_out;
  float* o_quant  = out;
  float* o_high   = out + 4194304;
  float* o_softs  = out + 8388608;
  float* o_hards  = out + 12582912;
  float* o_codes  = out + 16777216;
  float* o_logits = out + 16785408;

  float* ws    = (float*)d_ws;
  float* ENC   = ws;
  float* Xb    = ws + TOKC;
  float* T1    = ws + 2*TOKC;
  float* T2    = ws + 3*TOKC;
  float* QKV   = ws + 4*TOKC;
  float* MEMB  = ws + 7*TOKC;
  float* CBREG = ws + 8*TOKC;                         // KCB*CDIM floats
  int*   CODES = (int*)(CBREG + (long)KCB*CDIM);
  int*   FLAG  = CODES + NTOK;
  float* HARDB = QKV;
  float* QUANT = QKV + TOKC;
  _Float16* PBUF = (_Float16*)QKV;                    // 64 MiB: QKV+MEMB regions
  _Float16* CBH  = (_Float16*)T1;                     // plain fp16 cb_w (c,K)
  _Float16* QKVh = (_Float16*)QKV;                    // [NTOK][3C] halves [0,24MiB)
  _Float16* QKVl = QKVh + (long)NTOK*3*CDIM;
  _Float16* CQh  = (_Float16*)QKV;                    // [0,8MiB)
  _Float16* KVh  = (_Float16*)(QKV + TOKC);           // [16,32MiB)
  _Float16* CBT16h = (_Float16*)CBREG;                // [K][c] hi
  _Float16* CBT16l = CBT16h + (long)KCB*CDIM;         // [K][c] lo
  _Float16* PREH = (_Float16*)T2;                     // pre in split fp16
  _Float16* PREL = PREH + TOKC;
  // decoder fp16 activation buffers (bit-identical producer conversions):
  _Float16* AH16   = (_Float16*)ENC;                  // attn out, ENC [0,8MiB)
  _Float16* FH16   = AH16 + TOKC;                     // f1 out,   ENC [8,16MiB)
  _Float16* XH16   = ((_Float16*)QKV) + 4*TOKC;       // QKV bytes [32,40MiB)
  _Float16* MEMBH16= XH16 + TOKC;                     // QKV bytes [40,48MiB)
  _Float16* QH16   = ((_Float16*)T1) + TOKC;          // T1 bytes [8,16MiB)

  // ---- encoder scratch inside o_logits (dead until sim GEMM rewrites it) ----
  const long WQSZ = (long)6*3*CDIM*CDIM;   // 4,718,592
  const long WSSZ = (long)6*CDIM*CDIM;     // 1,572,864
  _Float16* SCR  = (_Float16*)o_logits;
  _Float16* WQH = SCR;            _Float16* WQL = WQH + WQSZ;
  _Float16* WOH = WQL + WQSZ;     _Float16* WOL = WOH + WSSZ;
  _Float16* WF1H= WOL + WSSZ;     _Float16* WF1L= WF1H + WSSZ;
  _Float16* WF2H= WF1L + WSSZ;    _Float16* WF2L= WF2H + WSSZ;
  _Float16* WPH = WF2L + WSSZ;    _Float16* WPL = WPH + (long)CDIM*CDIM;
  _Float16* XH  = WPL + (long)CDIM*CDIM;  _Float16* XL  = XH + TOKC;
  _Float16* AH  = XL + TOKC;      _Float16* AL  = AH + TOKC;
  _Float16* L1H = AL + TOKC;      _Float16* L1L = L1H + TOKC;
  _Float16* H1H = L1L + TOKC;     _Float16* H1L = H1H + TOKC;

  const size_t NEED = (size_t)(8*TOKC + (long)KCB*CDIM + 2*NTOK + NTOK + 16) * 4;
  if (ws_size < NEED) return;

  const int M = NTOK;
  dim3 tgrid(S_LEN/32, CDIM/32, NB), tblk(32, 8);
  dim3 agrid(NB*8, S_LEN/128);   // bh fastest: same-KV blocks share an XCD

  pack_pe_k<<<tgrid, tblk, 0, stream>>>(x, ENC, Xb, XH, XL);
  cbt16_k<<<dim3(KCB/32, CDIM/32), tblk, 0, stream>>>(cb_w, CBT16h, CBT16l);
  maskdetect_k<<<1, 256, 0, stream>>>(mask, FLAG);
  convsplit_k<<<(int)(WQSZ/2048), 256, 0, stream>>>(e_qkv_w, WQH, WQL);
  convsplit_k<<<(int)(WSSZ/2048), 256, 0, stream>>>(e_o_w,  WOH,  WOL);
  convsplit_k<<<(int)(WSSZ/2048), 256, 0, stream>>>(e_f1_w, WF1H, WF1L);
  convsplit_k<<<(int)(WSSZ/2048), 256, 0, stream>>>(e_f2_w, WF2H, WF2L);
  convsplit_k<<<(int)(((long)CDIM*CDIM)/2048), 256, 0, stream>>>(pre_w, WPH, WPL);

  // -------- encoder (split-fp16 MFMA, producer-converted inputs) --------
  for (int i = 0; i < NLAYER; ++i) {
    hgemm_k<128,1,2,true,false,false,false,true><<<dim3(3*CDIM/128, M/128), 256, 0, stream>>>(
        XH, WQH + (long)i*3*CDIM*CDIM, e_qkv_b + i*3*CDIM, nullptr, 0,
        nullptr, 3*CDIM, M, 3*CDIM, CDIM, QKVh, QKVl, XL, WQL + (long)i*3*CDIM*CDIM);
    mattn_k<1,1><<<agrid, 256, 0, stream>>>(QKVh, QKVl, 3*CDIM,
        QKVh+CDIM, QKVl+CDIM, 3*CDIM, QKVh+2*CDIM, QKVl+2*CDIM, 3*CDIM,
        nullptr, CDIM, AH, AL);
    hgemm_k<64,1,2,true,true,false,false,false><<<dim3(CDIM/128, M/64), 256, 0, stream>>>(
        AH, WOH + (long)i*CDIM*CDIM, e_o_b + i*CDIM, Xb, CDIM,
        T2, CDIM, M, CDIM, CDIM, nullptr, nullptr, AL, WOL + (long)i*CDIM*CDIM);
    ln_k<1><<<M/4, 256, 0, stream>>>(T2, e_ln1_w + i*CDIM, e_ln1_b + i*CDIM, T1, L1H, L1L);
    hgemm_k<64,1,2,true,false,true,false,true><<<dim3(CDIM/128, M/64), 256, 0, stream>>>(
        L1H, WF1H + (long)i*CDIM*CDIM, e_f1_b + i*CDIM, nullptr, 0,
        nullptr, CDIM, M, CDIM, CDIM, H1H, H1L, L1L, WF1L + (long)i*CDIM*CDIM);
    hgemm_k<64,1,2,true,true,false,false,false><<<dim3(CDIM/128, M/64), 256, 0, stream>>>(
        H1H, WF2H + (long)i*CDIM*CDIM, e_f2_b + i*CDIM, T1, CDIM,
        T2, CDIM, M, CDIM, CDIM, nullptr, nullptr, H1L, WF2L + (long)i*CDIM*CDIM);
    ln_k<1><<<M/4, 256, 0, stream>>>(T2, e_ln2_w + i*CDIM, e_ln2_b + i*CDIM, Xb, XH, XL);
  }

  // -------- codebook / quantizer --------
  hgemm_k<64,1,2,true,false,false,false,true><<<dim3(CDIM/128, M/64), 256, 0, stream>>>(
      XH, WPH, pre_b, nullptr, 0, T1, CDIM, M, CDIM, CDIM, PREH, PREL, XL, WPL);
  tpose_k<<<tgrid, tblk, 0, stream>>>(T1, o_high);
  hgemm_k<128,1,2,false,false,false,true,false><<<dim3(KCB/128, M/128), 256, 0, stream>>>(
      PREH, CBT16h, nullptr, nullptr, 0, o_logits, KCB, M, KCB, CDIM,
      nullptr, nullptr, PREL, CBT16l);
  conv16_k<<<(CDIM*(long)KCB)/(256*8), 256, 0, stream>>>(cb_w, CBH);
  simstats_k<<<NTOK, 256, 0, stream>>>(o_logits, PBUF, CODES, o_codes);
  hgemm_k<64,0,1,false,false,false,false,false><<<dim3(CDIM/128, M/64), 256, 0, stream>>>(
      PBUF, CBH, nullptr, nullptr, 0, T2, CDIM, M, CDIM, KCB,
      nullptr, nullptr, nullptr, nullptr);                                   // soft
  tpose_k<<<tgrid, tblk, 0, stream>>>(T2, o_softs);
  quant_k<<<NTOK, 128, 0, stream>>>(T2, CODES, CBT16h, CBT16l, QUANT, HARDB, QH16);
  tpose_k<<<tgrid, tblk, 0, stream>>>(HARDB, o_hards);
  hgemm_k<64,0,3,true,false,false,false,false><<<dim3(CDIM/128, M/64), 256, 0, stream>>>(
      QH16, post_w, post_b, nullptr, 0, MEMB, CDIM, M, CDIM, CDIM,
      nullptr, nullptr, nullptr, nullptr);                                   // post
  mixed_k<<<4096, 256, 0, stream>>>(ENC, MEMB, mask, FLAG, Xb, XH16);
  conv16_k<<<(int)(TOKC/2048), 256, 0, stream>>>(MEMB, MEMBH16);

  // -------- decoder (f16 MFMA, producer-converted activations) --------
  for (int i = 0; i < NLAYER; ++i) {
    hgemm_k<128,0,3,true,false,false,false,true><<<dim3(3*CDIM/128, M/128), 256, 0, stream>>>(
        XH16, d_sqkv_w + (long)i*3*CDIM*CDIM, d_sqkv_b + i*3*CDIM, nullptr, 0,
        nullptr, 3*CDIM, M, 3*CDIM, CDIM, QKVh, nullptr, nullptr, nullptr);
    mattn_k<0,2><<<agrid, 256, 0, stream>>>(QKVh, nullptr, 3*CDIM,
        QKVh+CDIM, nullptr, 3*CDIM, QKVh+2*CDIM, nullptr, 3*CDIM, nullptr, CDIM,
        AH16, nullptr);
    hgemm_k<64,0,3,true,true,false,false,false><<<dim3(CDIM/128, M/64), 256, 0, stream>>>(
        AH16, d_so_w + (long)i*CDIM*CDIM, d_so_b + i*CDIM, Xb, CDIM,
        T2, CDIM, M, CDIM, CDIM, nullptr, nullptr, nullptr, nullptr);
    ln_k<2><<<M/4, 256, 0, stream>>>(T2, d_ln1w + i*CDIM, d_ln1b + i*CDIM, Xb, XH16, nullptr);
    hgemm_k<64,0,3,true,false,false,false,true><<<dim3(CDIM/128, M/64), 256, 0, stream>>>(
        XH16, d_cqkv_w + (long)i*3*CDIM*CDIM, d_cqkv_b + i*3*CDIM, nullptr, 0,
        nullptr, CDIM, M, CDIM, CDIM, CQh, nullptr, nullptr, nullptr);
    hgemm_k<128,0,3,true,false,false,false,true><<<dim3(2*CDIM/128, M/128), 256, 0, stream>>>(
        MEMBH16, d_cqkv_w + (long)i*3*CDIM*CDIM + (long)CDIM*CDIM,
        d_cqkv_b + i*3*CDIM + CDIM, nullptr, 0,
        nullptr, 2*CDIM, M, 2*CDIM, CDIM, KVh, nullptr, nullptr, nullptr);
    mattn_k<0,2><<<agrid, 256, 0, stream>>>(CQh, nullptr, CDIM,
        KVh, nullptr, 2*CDIM, KVh+CDIM, nullptr, 2*CDIM, nullptr, CDIM,
        AH16, nullptr);
    hgemm_k<64,0,3,true,true,false,false,false><<<dim3(CDIM/128, M/64), 256, 0, stream>>>(
        AH16, d_co_w + (long)i*CDIM*CDIM, d_co_b + i*CDIM, Xb, CDIM,
        T2, CDIM, M, CDIM, CDIM, nullptr, nullptr, nullptr, nullptr);
    ln_k<2><<<M/4, 256, 0, stream>>>(T2, d_ln2w + i*CDIM, d_ln2b + i*CDIM, Xb, XH16, nullptr);
    hgemm_k<64,0,3,true,false,true,false,true><<<dim3(CDIM/128, M/64), 256, 0, stream>>>(
        XH16, d_f1w + (long)i*CDIM*CDIM, d_f1b + i*CDIM, nullptr, 0,
        nullptr, CDIM, M, CDIM, CDIM, FH16, nullptr, nullptr, nullptr);
    hgemm_k<64,0,3,true,true,false,false,false><<<dim3(CDIM/128, M/64), 256, 0, stream>>>(
        FH16, d_f2w + (long)i*CDIM*CDIM, d_f2b + i*CDIM, Xb, CDIM,
        T2, CDIM, M, CDIM, CDIM, nullptr, nullptr, nullptr, nullptr);
    ln_k<2><<<M/4, 256, 0, stream>>>(T2, d_ln3w + i*CDIM, d_ln3b + i*CDIM, Xb, XH16, nullptr);
  }
  tpose_k<<<tgrid, tblk, 0, stream>>>(Xb, o_quant);
}

// Round 13
// 3586.921 us; speedup vs baseline: 3.4948x; 1.0647x over previous
//
#include <hip/hip_runtime.h>
#include <math.h>

#define S_LEN 1024
#define NB 8
#define CDIM 512
#define KCB 4096
#define DH 64
#define NLAYER 6
#define NTOK (S_LEN*NB)
#define TOKC ((long)NTOK*CDIM)

typedef __attribute__((ext_vector_type(8))) _Float16 f16x8;
typedef __attribute__((ext_vector_type(4))) _Float16 f16x4;
typedef __attribute__((ext_vector_type(2))) _Float16 f16x2;
typedef __attribute__((ext_vector_type(4))) float f32x4;

// ---------------------------------------------------------------------------
// MFMA GEMM: C[M,N] = A[M,K] @ W[N,K]^T (+bias/res/relu).
// TM in {64,128}; N-tile 128. BK=64, mfma_f32_16x16x32_f16, XOR-swizzled LDS.
// SPLIT=1: hi/lo split-fp16, 3 MFMAs/pair (~fp32 accuracy).
// F16IN: 0 = A,W fp32 (convert in-kernel); 1 = A,W fp16; 2 = A,W split fp16
// hi/lo (Avl/Wvl, SPLIT=1); 3 = A fp16, W fp32-converted (SPLIT=0).
// E16: epilogue writes fp16 hi (Ch16) (+lo Cl16 if SPLIT); also fp32 C if C!=0.
// OREMAP: output row (s*NB+b) -> (b*S_LEN+s).
// NOTE: A and C must NOT alias (blocks of one dispatch race).
// ---------------------------------------------------------------------------
template<int TM, int SPLIT, int F16IN, bool BIAS, bool RES, bool RELU, bool OREMAP, bool E16>
__global__ __launch_bounds__(256)
void hgemm_k(const void* __restrict__ Av, const void* __restrict__ Wv,
             const float* __restrict__ bias, const float* __restrict__ Rsrc, int ldr,
             float* __restrict__ C, int ldc, int M, int N, int K,
             _Float16* __restrict__ Ch16, _Float16* __restrict__ Cl16,
             const void* __restrict__ Avl, const void* __restrict__ Wvl)
{
  constexpr int MI = TM / 32;
  constexpr int ATPR = 256 / TM;
  constexpr int ACOL = 64 / ATPR;
  constexpr bool AF16 = (F16IN >= 1);
  constexpr bool WF16 = (F16IN == 1 || F16IN == 2);
  __shared__ __align__(16) _Float16 Ah[TM*64];
  __shared__ __align__(16) _Float16 Bh[128*64];
  __shared__ __align__(16) _Float16 Al[SPLIT ? TM*64 : 8];
  __shared__ __align__(16) _Float16 Bl[SPLIT ? 128*64 : 8];
  const int t = threadIdx.x;
  const int m0 = blockIdx.y * TM, n0 = blockIdx.x * 128;

  const int arow = t / ATPR, apart = t % ATPR;
  const int brow = t >> 1, bpart = t & 1;

  const float*    Af  = (const float*)Av;
  const _Float16* Axh = (const _Float16*)Av;
  const _Float16* Axl = (const _Float16*)Avl;
  const float*    Wf  = (const float*)Wv;
  const _Float16* Wxh = (const _Float16*)Wv;
  const _Float16* Wxl = (const _Float16*)Wvl;
  const long aoff = (long)(m0 + arow) * K + apart * ACOL;
  const long boff = (long)(n0 + brow) * K + bpart * 32;

  const int lane = t & 63, wave = t >> 6;
  const int wm = wave >> 1, wn = wave & 1;
  const int lr = lane & 15, lk = lane >> 4;

  f32x4 acc[MI][4];
#pragma unroll
  for (int mi = 0; mi < MI; ++mi)
#pragma unroll
    for (int ni = 0; ni < 4; ++ni)
#pragma unroll
      for (int e = 0; e < 4; ++e) acc[mi][ni][e] = 0.f;

  float4 a4[ACOL/4], b4[8];
  f16x8  a16[ACOL/8], b16[4];
  f16x8  a16l[F16IN==2 ? ACOL/8 : 1], b16l[F16IN==2 ? 4 : 1];
  if (AF16) {
#pragma unroll
    for (int g = 0; g < ACOL/8; ++g) a16[g] = *(const f16x8*)(Axh + aoff + g*8);
    if (F16IN == 2) {
#pragma unroll
      for (int g = 0; g < ACOL/8; ++g) a16l[g] = *(const f16x8*)(Axl + aoff + g*8);
    }
  } else {
#pragma unroll
    for (int j = 0; j < ACOL/4; ++j) a4[j] = *(const float4*)(Af + aoff + j*4);
  }
  if (WF16) {
#pragma unroll
    for (int g = 0; g < 4; ++g) b16[g] = *(const f16x8*)(Wxh + boff + g*8);
    if (F16IN == 2) {
#pragma unroll
      for (int g = 0; g < 4; ++g) b16l[g] = *(const f16x8*)(Wxl + boff + g*8);
    }
  } else {
#pragma unroll
    for (int j = 0; j < 8; ++j) b4[j] = *(const float4*)(Wf + boff + j*4);
  }

  for (int k0 = 0; k0 < K; k0 += 64) {
    __syncthreads();
    if (AF16) {
#pragma unroll
      for (int g = 0; g < ACOL/8; ++g) {
        const int sw = (apart*ACOL*2 + g*16) ^ ((arow & 7) << 4);
        *(f16x8*)((char*)Ah + arow*128 + sw) = a16[g];
        if (F16IN == 2) *(f16x8*)((char*)Al + arow*128 + sw) = a16l[g];
      }
    } else {
      const float* af = (const float*)a4;
#pragma unroll
      for (int g = 0; g < ACOL/8; ++g) {
        f16x8 h, l;
#pragma unroll
        for (int j = 0; j < 8; ++j) {
          float xv = af[g*8+j];
          _Float16 hh = (_Float16)xv;
          h[j] = hh;
          if (SPLIT) l[j] = (_Float16)(xv - (float)hh);
        }
        const int sw = (apart*ACOL*2 + g*16) ^ ((arow & 7) << 4);
        *(f16x8*)((char*)Ah + arow*128 + sw) = h;
        if (SPLIT) *(f16x8*)((char*)Al + arow*128 + sw) = l;
      }
    }
    if (WF16) {
#pragma unroll
      for (int g = 0; g < 4; ++g) {
        const int sw = (bpart*64 + g*16) ^ ((brow & 7) << 4);
        *(f16x8*)((char*)Bh + brow*128 + sw) = b16[g];
        if (F16IN == 2) *(f16x8*)((char*)Bl + brow*128 + sw) = b16l[g];
      }
    } else {
      const float* bf = (const float*)b4;
#pragma unroll
      for (int g = 0; g < 4; ++g) {
        f16x8 h, l;
#pragma unroll
        for (int j = 0; j < 8; ++j) {
          float xv = bf[g*8+j];
          _Float16 hh = (_Float16)xv;
          h[j] = hh;
          if (SPLIT) l[j] = (_Float16)(xv - (float)hh);
        }
        const int sw = (bpart*64 + g*16) ^ ((brow & 7) << 4);
        *(f16x8*)((char*)Bh + brow*128 + sw) = h;
        if (SPLIT) *(f16x8*)((char*)Bl + brow*128 + sw) = l;
      }
    }
    __syncthreads();
    if (k0 + 64 < K) {
      if (AF16) {
#pragma unroll
        for (int g = 0; g < ACOL/8; ++g) a16[g] = *(const f16x8*)(Axh + aoff + k0 + 64 + g*8);
        if (F16IN == 2) {
#pragma unroll
          for (int g = 0; g < ACOL/8; ++g) a16l[g] = *(const f16x8*)(Axl + aoff + k0 + 64 + g*8);
        }
      } else {
#pragma unroll
        for (int j = 0; j < ACOL/4; ++j) a4[j] = *(const float4*)(Af + aoff + k0 + 64 + j*4);
      }
      if (WF16) {
#pragma unroll
        for (int g = 0; g < 4; ++g) b16[g] = *(const f16x8*)(Wxh + boff + k0 + 64 + g*8);
        if (F16IN == 2) {
#pragma unroll
          for (int g = 0; g < 4; ++g) b16l[g] = *(const f16x8*)(Wxl + boff + k0 + 64 + g*8);
        }
      } else {
#pragma unroll
        for (int j = 0; j < 8; ++j) b4[j] = *(const float4*)(Wf + boff + k0 + 64 + j*4);
      }
    }
#pragma unroll
    for (int kk = 0; kk < 2; ++kk) {
      f16x8 afh[MI], bfh[4], afl[MI], bfl[4];
#pragma unroll
      for (int mi = 0; mi < MI; ++mi) {
        const int r = wm*(TM/2) + mi*16 + lr;
        const int bo = (lk*16 + kk*64) ^ ((r & 7) << 4);
        afh[mi] = *(const f16x8*)((const char*)Ah + r*128 + bo);
        if (SPLIT) afl[mi] = *(const f16x8*)((const char*)Al + r*128 + bo);
      }
#pragma unroll
      for (int ni = 0; ni < 4; ++ni) {
        const int r = wn*64 + ni*16 + lr;
        const int bo = (lk*16 + kk*64) ^ ((r & 7) << 4);
        bfh[ni] = *(const f16x8*)((const char*)Bh + r*128 + bo);
        if (SPLIT) bfl[ni] = *(const f16x8*)((const char*)Bl + r*128 + bo);
      }
#pragma unroll
      for (int mi = 0; mi < MI; ++mi)
#pragma unroll
        for (int ni = 0; ni < 4; ++ni) {
          acc[mi][ni] = __builtin_amdgcn_mfma_f32_16x16x32_f16(afh[mi], bfh[ni], acc[mi][ni], 0, 0, 0);
          if (SPLIT) {
            acc[mi][ni] = __builtin_amdgcn_mfma_f32_16x16x32_f16(afh[mi], bfl[ni], acc[mi][ni], 0, 0, 0);
            acc[mi][ni] = __builtin_amdgcn_mfma_f32_16x16x32_f16(afl[mi], bfh[ni], acc[mi][ni], 0, 0, 0);
          }
        }
    }
  }

  float bvv[4];
  if (BIAS) {
#pragma unroll
    for (int ni = 0; ni < 4; ++ni) bvv[ni] = bias[n0 + wn*64 + ni*16 + lr];
  }
#pragma unroll
  for (int mi = 0; mi < MI; ++mi)
#pragma unroll
  for (int i = 0; i < 4; ++i) {
    const int rm = m0 + wm*(TM/2) + mi*16 + lk*4 + i;
    long orow = rm;
    if (OREMAP) orow = (long)(rm & (NB-1)) * S_LEN + (rm >> 3);
#pragma unroll
    for (int ni = 0; ni < 4; ++ni) {
      const int col = n0 + wn*64 + ni*16 + lr;
      float v = acc[mi][ni][i];
      if (BIAS) v += bvv[ni];
      if (RES)  v += Rsrc[(long)rm*ldr + col];
      if (RELU) v = fmaxf(v, 0.f);
      if (E16) {
        _Float16 hv = (_Float16)v;
        Ch16[(long)rm*ldc + col] = hv;
        if (SPLIT) Cl16[(long)rm*ldc + col] = (_Float16)(v - (float)hv);
        if (C != nullptr) C[orow*(long)ldc + col] = v;
      } else {
        C[orow*(long)ldc + col] = v;
      }
    }
  }
}

// ---------------------------------------------------------------------------
// MFMA flash attention, fp16 hi/lo inputs (ENCODER, split path — validated).
// Grid: (bh, s0-tile). 128 q x (b,head); 4 waves. SPLIT=1: 3 MFMAs/pair.
// OSPLIT: 0 fp32 out; 1 split hi/lo fp16; 2 fp16 hi.
// ---------------------------------------------------------------------------
template<int SPLIT, int OSPLIT>
__global__ __launch_bounds__(256)
void mattn_k(const _Float16* __restrict__ Qh, const _Float16* __restrict__ Ql, int ldq,
             const _Float16* __restrict__ Kh, const _Float16* __restrict__ Kl, int ldk,
             const _Float16* __restrict__ Vh, const _Float16* __restrict__ Vl, int ldv,
             float* __restrict__ Op, int ldo,
             _Float16* __restrict__ Oh, _Float16* __restrict__ Ol)
{
  __shared__ __align__(16) char Pb[SPLIT ? 32768 : 16384];
  __shared__ __align__(16) char Kb[SPLIT ? 16384 : 8192];
  __shared__ __align__(16) char Vb[SPLIT ? 16384 : 8192];

  const int t = threadIdx.x;
  const int b = blockIdx.x >> 3, hd = blockIdx.x & 7;
  const int s0 = blockIdx.y * 128;
  const int qoff = hd * DH;
  const int wave = t >> 6, lane = t & 63;
  const int lr = lane & 15, lk = lane >> 4;
  const int krow = t >> 2, kqd = t & 3;
  const int vtp = t & 31, vdc = t >> 5;

  f16x8 qa[2][2], qal[2][2];
#pragma unroll
  for (int mi = 0; mi < 2; ++mi)
#pragma unroll
    for (int kk = 0; kk < 2; ++kk) {
      const int q = s0 + wave*32 + mi*16 + lr;
      const long base = ((long)q*NB + b)*ldq + qoff + kk*32 + lk*8;
      f16x8 v = *(const f16x8*)(Qh + base);
#pragma unroll
      for (int e = 0; e < 8; ++e) v[e] = v[e] * (_Float16)0.125f;
      qa[mi][kk] = v;
      if (SPLIT) {
        f16x8 w = *(const f16x8*)(Ql + base);
#pragma unroll
        for (int e = 0; e < 8; ++e) w[e] = w[e] * (_Float16)0.125f;
        qal[mi][kk] = w;
      }
    }

  float m_run[2][4], l_run[2][4];
  f32x4 oacc[2][4];
#pragma unroll
  for (int mi = 0; mi < 2; ++mi)
#pragma unroll
    for (int i = 0; i < 4; ++i) {
      m_run[mi][i] = -INFINITY; l_run[mi][i] = 0.f;
#pragma unroll
      for (int ni = 0; ni < 4; ++ni) oacc[mi][ni][i] = 0.f;
    }

  char* Pw  = Pb + wave*4096;
  char* Pwl = Pb + 16384 + wave*4096;
  char* Klo = Kb + 8192;
  char* Vlo = Vb + 8192;

  f16x8 kr0, kr1, krl0, krl1, vr0, vr1, vrl0, vrl1;
  {
    const long kb = ((long)krow*NB + b)*ldk + qoff + kqd*16;
    kr0 = *(const f16x8*)(Kh + kb);
    kr1 = *(const f16x8*)(Kh + kb + 8);
    if (SPLIT) { krl0 = *(const f16x8*)(Kl + kb); krl1 = *(const f16x8*)(Kl + kb + 8); }
    const long vb = ((long)(2*vtp)*NB + b)*ldv + qoff + vdc*8;
    vr0 = *(const f16x8*)(Vh + vb);
    vr1 = *(const f16x8*)(Vh + vb + (long)NB*ldv);
    if (SPLIT) { vrl0 = *(const f16x8*)(Vl + vb); vrl1 = *(const f16x8*)(Vl + vb + (long)NB*ldv); }
  }

  for (int t0 = 0; t0 < S_LEN; t0 += 64) {
    __syncthreads();
    {
      const int sw0 = (kqd*32) ^ ((krow & 7) << 4);
      const int sw1 = (kqd*32 + 16) ^ ((krow & 7) << 4);
      *(f16x8*)(Kb + krow*128 + sw0) = kr0;
      *(f16x8*)(Kb + krow*128 + sw1) = kr1;
      if (SPLIT) {
        *(f16x8*)(Klo + krow*128 + sw0) = krl0;
        *(f16x8*)(Klo + krow*128 + sw1) = krl1;
      }
#pragma unroll
      for (int j = 0; j < 8; ++j) {
        const int dd = vdc*8 + j;
        f16x2 hv = {vr0[j], vr1[j]};
        *(f16x2*)(Vb + dd*128 + ((vtp*4) ^ ((dd & 7) << 4))) = hv;
        if (SPLIT) {
          f16x2 lv = {vrl0[j], vrl1[j]};
          *(f16x2*)(Vlo + dd*128 + ((vtp*4) ^ ((dd & 7) << 4))) = lv;
        }
      }
    }
    if (t0 + 64 < S_LEN) {
      const long kb = ((long)(t0 + 64 + krow)*NB + b)*ldk + qoff + kqd*16;
      kr0 = *(const f16x8*)(Kh + kb);
      kr1 = *(const f16x8*)(Kh + kb + 8);
      if (SPLIT) { krl0 = *(const f16x8*)(Kl + kb); krl1 = *(const f16x8*)(Kl + kb + 8); }
      const long vb = ((long)(t0 + 64 + 2*vtp)*NB + b)*ldv + qoff + vdc*8;
      vr0 = *(const f16x8*)(Vh + vb);
      vr1 = *(const f16x8*)(Vh + vb + (long)NB*ldv);
      if (SPLIT) { vrl0 = *(const f16x8*)(Vl + vb); vrl1 = *(const f16x8*)(Vl + vb + (long)NB*ldv); }
    }
    __syncthreads();

    f32x4 s[2][4];
#pragma unroll
    for (int mi = 0; mi < 2; ++mi)
#pragma unroll
      for (int ni = 0; ni < 4; ++ni)
#pragma unroll
        for (int e = 0; e < 4; ++e) s[mi][ni][e] = 0.f;
#pragma unroll
    for (int kk = 0; kk < 2; ++kk) {
      f16x8 kb[4], kbl[4];
#pragma unroll
      for (int ni = 0; ni < 4; ++ni) {
        const int r = ni*16 + lr;
        const int bo = (lk*16 + kk*64) ^ ((r & 7) << 4);
        kb[ni] = *(const f16x8*)(Kb + r*128 + bo);
        if (SPLIT) kbl[ni] = *(const f16x8*)(Klo + r*128 + bo);
      }
#pragma unroll
      for (int mi = 0; mi < 2; ++mi)
#pragma unroll
        for (int ni = 0; ni < 4; ++ni) {
          s[mi][ni] = __builtin_amdgcn_mfma_f32_16x16x32_f16(qa[mi][kk], kb[ni], s[mi][ni], 0, 0, 0);
          if (SPLIT) {
            s[mi][ni] = __builtin_amdgcn_mfma_f32_16x16x32_f16(qa[mi][kk], kbl[ni], s[mi][ni], 0, 0, 0);
            s[mi][ni] = __builtin_amdgcn_mfma_f32_16x16x32_f16(qal[mi][kk], kb[ni], s[mi][ni], 0, 0, 0);
          }
        }
    }

#pragma unroll
    for (int mi = 0; mi < 2; ++mi) {
      float rm[4];
#pragma unroll
      for (int i = 0; i < 4; ++i)
        rm[i] = fmaxf(fmaxf(s[mi][0][i], s[mi][1][i]), fmaxf(s[mi][2][i], s[mi][3][i]));
#pragma unroll
      for (int off = 1; off < 16; off <<= 1)
#pragma unroll
        for (int i = 0; i < 4; ++i) rm[i] = fmaxf(rm[i], __shfl_xor(rm[i], off));
      float rs[4], corr[4];
#pragma unroll
      for (int i = 0; i < 4; ++i) {
        const float mnew = fmaxf(m_run[mi][i], rm[i]);
        corr[i] = __expf(m_run[mi][i] - mnew);
        m_run[mi][i] = mnew;
        float lsum = 0.f;
#pragma unroll
        for (int ni = 0; ni < 4; ++ni) {
          float p = __expf(s[mi][ni][i] - mnew);
          s[mi][ni][i] = p; lsum += p;
        }
        rs[i] = lsum;
      }
#pragma unroll
      for (int off = 1; off < 16; off <<= 1)
#pragma unroll
        for (int i = 0; i < 4; ++i) rs[i] += __shfl_xor(rs[i], off);
#pragma unroll
      for (int i = 0; i < 4; ++i) {
        l_run[mi][i] = l_run[mi][i]*corr[i] + rs[i];
#pragma unroll
        for (int ni = 0; ni < 4; ++ni) oacc[mi][ni][i] *= corr[i];
      }
    }

#pragma unroll
    for (int mi = 0; mi < 2; ++mi)
#pragma unroll
      for (int ni = 0; ni < 4; ++ni)
#pragma unroll
        for (int i = 0; i < 4; ++i) {
          const int row = mi*16 + lk*4 + i;
          const int col = ni*16 + lr;
          const int ad = row*128 + ((col*2) ^ ((row & 7) << 4));
          float pv = s[mi][ni][i];
          _Float16 ph = (_Float16)pv;
          *(_Float16*)(Pw + ad) = ph;
          if (SPLIT) *(_Float16*)(Pwl + ad) = (_Float16)(pv - (float)ph);
        }

#pragma unroll
    for (int kk = 0; kk < 2; ++kk) {
      f16x8 vb[4], vbl[4], pa[2], pal[2];
#pragma unroll
      for (int ni = 0; ni < 4; ++ni) {
        const int r = ni*16 + lr;
        const int bo = (lk*16 + kk*64) ^ ((r & 7) << 4);
        vb[ni] = *(const f16x8*)(Vb + r*128 + bo);
        if (SPLIT) vbl[ni] = *(const f16x8*)(Vlo + r*128 + bo);
      }
#pragma unroll
      for (int mi = 0; mi < 2; ++mi) {
        const int r = mi*16 + lr;
        const int bo = (lk*16 + kk*64) ^ ((r & 7) << 4);
        pa[mi] = *(const f16x8*)(Pw + r*128 + bo);
        if (SPLIT) pal[mi] = *(const f16x8*)(Pwl + r*128 + bo);
      }
#pragma unroll
      for (int mi = 0; mi < 2; ++mi)
#pragma unroll
        for (int ni = 0; ni < 4; ++ni) {
          oacc[mi][ni] = __builtin_amdgcn_mfma_f32_16x16x32_f16(pa[mi], vb[ni], oacc[mi][ni], 0, 0, 0);
          if (SPLIT) {
            oacc[mi][ni] = __builtin_amdgcn_mfma_f32_16x16x32_f16(pa[mi], vbl[ni], oacc[mi][ni], 0, 0, 0);
            oacc[mi][ni] = __builtin_amdgcn_mfma_f32_16x16x32_f16(pal[mi], vb[ni], oacc[mi][ni], 0, 0, 0);
          }
        }
    }
  }

#pragma unroll
  for (int mi = 0; mi < 2; ++mi)
#pragma unroll
    for (int i = 0; i < 4; ++i) {
      const float inv = 1.0f / l_run[mi][i];
      const int q = s0 + wave*32 + mi*16 + lk*4 + i;
      const long base = ((long)q * NB + b) * ldo + qoff;
#pragma unroll
      for (int ni = 0; ni < 4; ++ni) {
        float v = oacc[mi][ni][i] * inv;
        if (OSPLIT == 1) {
          _Float16 h = (_Float16)v;
          Oh[base + ni*16 + lr] = h;
          Ol[base + ni*16 + lr] = (_Float16)(v - (float)h);
        } else if (OSPLIT == 2) {
          Oh[base + ni*16 + lr] = (_Float16)v;
        } else {
          Op[base + ni*16 + lr] = v;
        }
      }
    }
}

// ---------------------------------------------------------------------------
// DECODER attention: swapped-operand flash attention, plain fp16, fp16-hi out.
// S^T = mfma(K,Q) puts a full q-row's scores lane-local -> softmax is 15 local
// ops + 2 shfl; P converts in-register to the exact B-fragment of
// mfma_f32_16x16x16_f16 (lane k = lk*4..+3) -> NO P LDS round-trip.
// PV computes O^T[d][q] with A = V^T (b64 LDS reads). LDS = 16 KB total.
// ---------------------------------------------------------------------------
__global__ __launch_bounds__(256)
void sattn_k(const _Float16* __restrict__ Qh, int ldq,
             const _Float16* __restrict__ Kh, int ldk,
             const _Float16* __restrict__ Vh, int ldv,
             _Float16* __restrict__ Oh, int ldo)
{
  __shared__ __align__(16) char Kb[8192];
  __shared__ __align__(16) char Vb[8192];

  const int t = threadIdx.x;
  const int b = blockIdx.x >> 3, hd = blockIdx.x & 7;
  const int s0 = blockIdx.y * 128;
  const int qoff = hd * DH;
  const int wave = t >> 6, lane = t & 63;
  const int lr = lane & 15, lk = lane >> 4;
  const int krow = t >> 2, kqd = t & 3;
  const int vtp = t & 31, vdc = t >> 5;

  // Q fragments (B-side of swapped QK), pre-scaled by 1/8 (exact)
  f16x8 qa[2][2];
#pragma unroll
  for (int qb = 0; qb < 2; ++qb)
#pragma unroll
    for (int kk = 0; kk < 2; ++kk) {
      const int q = s0 + wave*32 + qb*16 + lr;
      const long base = ((long)q*NB + b)*ldq + qoff + kk*32 + lk*8;
      f16x8 v = *(const f16x8*)(Qh + base);
#pragma unroll
      for (int e = 0; e < 8; ++e) v[e] = v[e] * (_Float16)0.125f;
      qa[qb][kk] = v;
    }

  float m_run[2] = {-INFINITY, -INFINITY};
  float l_run[2] = {0.f, 0.f};
  f32x4 oaccT[4][2];
#pragma unroll
  for (int nd = 0; nd < 4; ++nd)
#pragma unroll
    for (int qb = 0; qb < 2; ++qb)
#pragma unroll
      for (int e = 0; e < 4; ++e) oaccT[nd][qb][e] = 0.f;

  f16x8 kr0, kr1, vr0, vr1;
  {
    const long kb = ((long)krow*NB + b)*ldk + qoff + kqd*16;
    kr0 = *(const f16x8*)(Kh + kb);
    kr1 = *(const f16x8*)(Kh + kb + 8);
    const long vb = ((long)(2*vtp)*NB + b)*ldv + qoff + vdc*8;
    vr0 = *(const f16x8*)(Vh + vb);
    vr1 = *(const f16x8*)(Vh + vb + (long)NB*ldv);
  }

  for (int t0 = 0; t0 < S_LEN; t0 += 64) {
    __syncthreads();
    {
      const int sw0 = (kqd*32) ^ ((krow & 7) << 4);
      const int sw1 = (kqd*32 + 16) ^ ((krow & 7) << 4);
      *(f16x8*)(Kb + krow*128 + sw0) = kr0;
      *(f16x8*)(Kb + krow*128 + sw1) = kr1;
#pragma unroll
      for (int j = 0; j < 8; ++j) {
        const int dd = vdc*8 + j;
        f16x2 hv = {vr0[j], vr1[j]};
        *(f16x2*)(Vb + dd*128 + ((vtp*4) ^ ((dd & 7) << 4))) = hv;
      }
    }
    if (t0 + 64 < S_LEN) {
      const long kb = ((long)(t0 + 64 + krow)*NB + b)*ldk + qoff + kqd*16;
      kr0 = *(const f16x8*)(Kh + kb);
      kr1 = *(const f16x8*)(Kh + kb + 8);
      const long vb = ((long)(t0 + 64 + 2*vtp)*NB + b)*ldv + qoff + vdc*8;
      vr0 = *(const f16x8*)(Vh + vb);
      vr1 = *(const f16x8*)(Vh + vb + (long)NB*ldv);
    }
    __syncthreads();

    // ---- S^T[key][q] = mfma(K, Q) ----
    f32x4 st[4][2];
#pragma unroll
    for (int ki = 0; ki < 4; ++ki)
#pragma unroll
      for (int qb = 0; qb < 2; ++qb)
#pragma unroll
        for (int e = 0; e < 4; ++e) st[ki][qb][e] = 0.f;
#pragma unroll
    for (int kk = 0; kk < 2; ++kk) {
      f16x8 kb[4];
#pragma unroll
      for (int ki = 0; ki < 4; ++ki) {
        const int r = ki*16 + lr;
        const int bo = (lk*16 + kk*64) ^ ((r & 7) << 4);
        kb[ki] = *(const f16x8*)(Kb + r*128 + bo);
      }
#pragma unroll
      for (int ki = 0; ki < 4; ++ki)
#pragma unroll
        for (int qb = 0; qb < 2; ++qb)
          st[ki][qb] = __builtin_amdgcn_mfma_f32_16x16x32_f16(kb[ki], qa[qb][kk], st[ki][qb], 0, 0, 0);
    }

    // ---- online softmax: each lane owns q = qb*16+lr, 16 key-values local ----
    f16x4 pb[4][2];
#pragma unroll
    for (int qb = 0; qb < 2; ++qb) {
      float rm = st[0][qb][0];
#pragma unroll
      for (int ki = 0; ki < 4; ++ki)
#pragma unroll
        for (int e = 0; e < 4; ++e) rm = fmaxf(rm, st[ki][qb][e]);
      rm = fmaxf(rm, __shfl_xor(rm, 16));
      rm = fmaxf(rm, __shfl_xor(rm, 32));
      const float mnew = fmaxf(m_run[qb], rm);
      const float corr = __expf(m_run[qb] - mnew);
      m_run[qb] = mnew;
      float ls = 0.f;
#pragma unroll
      for (int ki = 0; ki < 4; ++ki) {
        f16x4 pv;
#pragma unroll
        for (int e = 0; e < 4; ++e) {
          float p = __expf(st[ki][qb][e] - mnew);
          ls += p;
          pv[e] = (_Float16)p;
        }
        pb[ki][qb] = pv;
      }
      ls += __shfl_xor(ls, 16);
      ls += __shfl_xor(ls, 32);
      l_run[qb] = l_run[qb]*corr + ls;
#pragma unroll
      for (int nd = 0; nd < 4; ++nd)
#pragma unroll
        for (int e = 0; e < 4; ++e) oaccT[nd][qb][e] *= corr;
    }

    // ---- O^T[d][q] += mfma16(V^T, P^T) — P never touches LDS ----
#pragma unroll
    for (int ki = 0; ki < 4; ++ki) {
      f16x4 av[4];
#pragma unroll
      for (int nd = 0; nd < 4; ++nd) {
        const int row = nd*16 + lr;
        const int bo = (ki*32 + lk*8) ^ ((row & 7) << 4);
        av[nd] = *(const f16x4*)(Vb + row*128 + bo);
      }
#pragma unroll
      for (int nd = 0; nd < 4; ++nd)
#pragma unroll
        for (int qb = 0; qb < 2; ++qb)
          oaccT[nd][qb] = __builtin_amdgcn_mfma_f32_16x16x16f16(av[nd], pb[ki][qb], oaccT[nd][qb], 0, 0, 0);
    }
  }

  // ---- epilogue: O[q][d] fp16-hi, packed b64 stores ----
#pragma unroll
  for (int qb = 0; qb < 2; ++qb) {
    const float inv = 1.0f / l_run[qb];
    const int q = s0 + wave*32 + qb*16 + lr;
    const long base = ((long)q * NB + b) * ldo + qoff;
#pragma unroll
    for (int nd = 0; nd < 4; ++nd) {
      f16x4 o;
#pragma unroll
      for (int e = 0; e < 4; ++e) o[e] = (_Float16)(oaccT[nd][qb][e] * inv);
      *(f16x4*)(Oh + base + nd*16 + lk*4) = o;
    }
  }
}

// ---------------------------------------------------------------------------
// LayerNorm over c=512, one wave per row.
// ES: 0 = fp32 only; 1 = fp32 + split fp16 hi/lo; 2 = fp32 + fp16 hi.
// ---------------------------------------------------------------------------
template<int ES>
__global__ __launch_bounds__(256)
void ln_k(const float* __restrict__ X, const float* __restrict__ g,
          const float* __restrict__ bb, float* __restrict__ Y,
          _Float16* __restrict__ Yh, _Float16* __restrict__ Yl)
{
  const int t = threadIdx.x;
  const int lane = t & 63;
  const long row = (long)blockIdx.x * 4 + (t >> 6);
  const float* xr = X + row * CDIM;
  float4 v0 = *(const float4*)(xr + lane*4);
  float4 v1 = *(const float4*)(xr + 256 + lane*4);
  float s = v0.x+v0.y+v0.z+v0.w + v1.x+v1.y+v1.z+v1.w;
#pragma unroll
  for (int off = 1; off < 64; off <<= 1) s += __shfl_xor(s, off);
  const float mean = s * (1.0f/512.0f);
  float d[8] = {v0.x-mean, v0.y-mean, v0.z-mean, v0.w-mean,
                v1.x-mean, v1.y-mean, v1.z-mean, v1.w-mean};
  float sq = d[0]*d[0]+d[1]*d[1]+d[2]*d[2]+d[3]*d[3]
           + d[4]*d[4]+d[5]*d[5]+d[6]*d[6]+d[7]*d[7];
#pragma unroll
  for (int off = 1; off < 64; off <<= 1) sq += __shfl_xor(sq, off);
  const float inv = 1.0f / sqrtf(sq * (1.0f/512.0f) + 1e-5f);
  float4 g0 = *(const float4*)(g + lane*4);
  float4 g1 = *(const float4*)(g + 256 + lane*4);
  float4 b0 = *(const float4*)(bb + lane*4);
  float4 b1 = *(const float4*)(bb + 256 + lane*4);
  float o[8];
  o[0] = d[0]*inv*g0.x + b0.x; o[1] = d[1]*inv*g0.y + b0.y;
  o[2] = d[2]*inv*g0.z + b0.z; o[3] = d[3]*inv*g0.w + b0.w;
  o[4] = d[4]*inv*g1.x + b1.x; o[5] = d[5]*inv*g1.y + b1.y;
  o[6] = d[6]*inv*g1.z + b1.z; o[7] = d[7]*inv*g1.w + b1.w;
  *(float4*)(Y + row*CDIM + lane*4) = *(float4*)&o[0];
  *(float4*)(Y + row*CDIM + 256 + lane*4) = *(float4*)&o[4];
  if (ES) {
    f16x4 h0, h1, l0, l1;
#pragma unroll
    for (int j = 0; j < 4; ++j) {
      _Float16 h = (_Float16)o[j];     h0[j] = h;
      _Float16 k = (_Float16)o[4+j];   h1[j] = k;
      if (ES == 1) { l0[j] = (_Float16)(o[j] - (float)h); l1[j] = (_Float16)(o[4+j] - (float)k); }
    }
    *(f16x4*)(Yh + row*CDIM + lane*4) = h0;
    *(f16x4*)(Yh + row*CDIM + 256 + lane*4) = h1;
    if (ES == 1) {
      *(f16x4*)(Yl + row*CDIM + lane*4) = l0;
      *(f16x4*)(Yl + row*CDIM + 256 + lane*4) = l1;
    }
  }
}

// ---------------------------------------------------------------------------
// Pack x (N,C,H,W) -> enc_flat (S,n,c); posisted fp32 + split fp16 hi/lo.
// ---------------------------------------------------------------------------
__global__ void pack_pe_k(const float* __restrict__ x, float* __restrict__ encf,
                          float* __restrict__ posd,
                          _Float16* __restrict__ posh, _Float16* __restrict__ posl)
{
  __shared__ float tl[32][33];
  const int b = blockIdx.z;
  const int s0 = blockIdx.x*32, c0 = blockIdx.y*32;
#pragma unroll
  for (int i = 0; i < 4; ++i) {
    int ci = threadIdx.y + i*8;
    tl[ci][threadIdx.x] = x[((long)b*CDIM + c0+ci)*S_LEN + s0 + threadIdx.x];
  }
  __syncthreads();
#pragma unroll
  for (int i = 0; i < 4; ++i) {
    int si = threadIdx.y + i*8;
    int s = s0 + si;
    int ch = c0 + threadIdx.x;
    float val = tl[threadIdx.x][si];
    long o = ((long)s*NB + b)*CDIM + ch;
    encf[o] = val;
    int pos = (ch < 256) ? (s & 31) : (s >> 5);
    int j = (ch & 255) >> 1;
    float dv = expf((float)(2*j) * (-9.210340371976184f / 256.0f));
    float ang = (float)pos * dv;
    float pe = (ch & 1) ? cosf(ang) : sinf(ang);
    float pv = val + pe;
    posd[o] = pv;
    _Float16 h = (_Float16)pv;
    posh[o] = h;
    posl[o] = (_Float16)(pv - (float)h);
  }
}

// (S,n,c) token-major -> (n,c,S) output layout
__global__ void tpose_k(const float* __restrict__ in, float* __restrict__ out)
{
  __shared__ float tl[32][33];
  const int b = blockIdx.z;
  const int s0 = blockIdx.x*32, c0 = blockIdx.y*32;
#pragma unroll
  for (int i = 0; i < 4; ++i) {
    int si = threadIdx.y + i*8;
    tl[si][threadIdx.x] = in[((long)(s0+si)*NB + b)*CDIM + c0 + threadIdx.x];
  }
  __syncthreads();
#pragma unroll
  for (int i = 0; i < 4; ++i) {
    int ci = threadIdx.y + i*8;
    out[((long)b*CDIM + c0+ci)*S_LEN + s0 + threadIdx.x] = tl[threadIdx.x][ci];
  }
}

// cb_w (c,K) -> transposed split-fp16 codebook [K][c] hi/lo
__global__ void cbt16_k(const float* __restrict__ cb,
                        _Float16* __restrict__ outh, _Float16* __restrict__ outl)
{
  __shared__ float tl[32][33];
  const int k0 = blockIdx.x*32, c0 = blockIdx.y*32;
#pragma unroll
  for (int i = 0; i < 4; ++i) {
    int ci = threadIdx.y + i*8;
    tl[ci][threadIdx.x] = cb[(long)(c0+ci)*KCB + k0 + threadIdx.x];
  }
  __syncthreads();
#pragma unroll
  for (int i = 0; i < 4; ++i) {
    int ki = threadIdx.y + i*8;
    float v = tl[threadIdx.x][ki];
    _Float16 h = (_Float16)v;
    outh[(long)(k0+ki)*CDIM + c0 + threadIdx.x] = h;
    outl[(long)(k0+ki)*CDIM + c0 + threadIdx.x] = (_Float16)(v - (float)h);
  }
}

// fp32 -> fp16 elementwise, 8 per thread
__global__ __launch_bounds__(256)
void conv16_k(const float* __restrict__ in, _Float16* __restrict__ out)
{
  const long i = ((long)blockIdx.x * 256 + threadIdx.x) * 8;
  float4 v0 = *(const float4*)(in + i);
  float4 v1 = *(const float4*)(in + i + 4);
  f16x8 h;
  h[0]=(_Float16)v0.x; h[1]=(_Float16)v0.y; h[2]=(_Float16)v0.z; h[3]=(_Float16)v0.w;
  h[4]=(_Float16)v1.x; h[5]=(_Float16)v1.y; h[6]=(_Float16)v1.z; h[7]=(_Float16)v1.w;
  *(f16x8*)(out + i) = h;
}

// fp32 -> split fp16 hi/lo, 8 per thread
__global__ __launch_bounds__(256)
void convsplit_k(const float* __restrict__ in, _Float16* __restrict__ oh,
                 _Float16* __restrict__ ol)
{
  const long i = ((long)blockIdx.x * 256 + threadIdx.x) * 8;
  float4 v0 = *(const float4*)(in + i);
  float4 v1 = *(const float4*)(in + i + 4);
  float vv[8] = {v0.x,v0.y,v0.z,v0.w,v1.x,v1.y,v1.z,v1.w};
  f16x8 h, l;
#pragma unroll
  for (int j = 0; j < 8; ++j) {
    _Float16 hh = (_Float16)vv[j];
    h[j] = hh;
    l[j] = (_Float16)(vv[j] - (float)hh);
  }
  *(f16x8*)(oh + i) = h;
  *(f16x8*)(ol + i) = l;
}

// Per-token row of logits: argmax (np first-occurrence) + write P (fp16)
__global__ __launch_bounds__(256)
void simstats_k(const float* __restrict__ logits, _Float16* __restrict__ Pbuf,
                int* __restrict__ codes_tok, float* __restrict__ codes_out)
{
  const long phys = blockIdx.x;
  const float* rowp = logits + phys * KCB;
  const int t = threadIdx.x;
  float vals[16];
#pragma unroll
  for (int rep = 0; rep < 4; ++rep) {
    float4 v = *(const float4*)(rowp + rep*1024 + t*4);
    vals[rep*4+0]=v.x; vals[rep*4+1]=v.y; vals[rep*4+2]=v.z; vals[rep*4+3]=v.w;
  }
  float mv = -INFINITY; int mi = 0;
#pragma unroll
  for (int rep = 0; rep < 4; ++rep)
#pragma unroll
    for (int j = 0; j < 4; ++j) {
      float xv = vals[rep*4+j];
      int ix = rep*1024 + t*4 + j;
      if (xv > mv) { mv = xv; mi = ix; }
    }
  const int lane = t & 63, wid = t >> 6;
#pragma unroll
  for (int off = 1; off < 64; off <<= 1) {
    float ov = __shfl_xor(mv, off);
    int   oi = __shfl_xor(mi, off);
    if (ov > mv || (ov == mv && oi < mi)) { mv = ov; mi = oi; }
  }
  __shared__ float smax[4]; __shared__ int sidx[4]; __shared__ float ssum[4];
  __shared__ float fm; __shared__ int fi; __shared__ float sinv;
  if (lane == 0) { smax[wid] = mv; sidx[wid] = mi; }
  __syncthreads();
  if (t == 0) {
    float bm = smax[0]; int bi = sidx[0];
    for (int wq = 1; wq < 4; ++wq)
      if (smax[wq] > bm || (smax[wq] == bm && sidx[wq] < bi)) { bm = smax[wq]; bi = sidx[wq]; }
    fm = bm; fi = bi;
  }
  __syncthreads();
  const float Mx = fm;
  float se = 0.f;
#pragma unroll
  for (int q = 0; q < 16; ++q) se += __expf(vals[q] - Mx);
#pragma unroll
  for (int off = 1; off < 64; off <<= 1) se += __shfl_xor(se, off);
  if (lane == 0) ssum[wid] = se;
  __syncthreads();
  const int b = (int)(phys >> 10), s = (int)(phys & 1023);
  if (t == 0) {
    float tot = ssum[0]+ssum[1]+ssum[2]+ssum[3];
    sinv = 1.0f / tot;
    codes_tok[s*NB + b] = fi;
    codes_out[phys] = (float)fi;
  }
  __syncthreads();
  const float inv = sinv;
  _Float16* prow = Pbuf + ((long)s*NB + b) * KCB;
#pragma unroll
  for (int rep = 0; rep < 4; ++rep) {
    f16x4 pv;
#pragma unroll
    for (int j = 0; j < 4; ++j) pv[j] = (_Float16)(__expf(vals[rep*4+j] - Mx) * inv);
    *(f16x4*)(prow + rep*1024 + t*4) = pv;
  }
}

// quant = (hard - soft) + soft; emit hard fp32 and quant fp32 + fp16-hi.
__global__ __launch_bounds__(128)
void quant_k(const float* __restrict__ soft, const int* __restrict__ codes_tok,
             const _Float16* __restrict__ cbh, const _Float16* __restrict__ cbl,
             float* __restrict__ quant, float* __restrict__ hardb,
             _Float16* __restrict__ qh16)
{
  const int r = blockIdx.x;
  const int code = codes_tok[r];
  const int c = threadIdx.x * 4;
  f16x4 hh = *(const f16x4*)(cbh + (long)code*CDIM + c);
  f16x4 hl = *(const f16x4*)(cbl + (long)code*CDIM + c);
  float4 sf = *(const float4*)(soft + (long)r*CDIM + c);
  float4 h, q;
  h.x = (float)hh[0] + (float)hl[0]; h.y = (float)hh[1] + (float)hl[1];
  h.z = (float)hh[2] + (float)hl[2]; h.w = (float)hh[3] + (float)hl[3];
  q.x = (h.x - sf.x) + sf.x; q.y = (h.y - sf.y) + sf.y;
  q.z = (h.z - sf.z) + sf.z; q.w = (h.w - sf.w) + sf.w;
  *(float4*)(quant + (long)r*CDIM + c) = q;
  *(float4*)(hardb + (long)r*CDIM + c) = h;
  f16x4 qh = {(_Float16)q.x, (_Float16)q.y, (_Float16)q.z, (_Float16)q.w};
  *(f16x4*)(qh16 + (long)r*CDIM + c) = qh;
}

// Detect the storage format of the bool mask buffer.
__global__ void maskdetect_k(const void* __restrict__ mask, int* __restrict__ flag)
{
  const unsigned int* wds = (const unsigned int*)mask;
  int t = threadIdx.x;
  int okI = 1, okF = 1, okL = 1;
  for (int i = t; i < 2048; i += 256) {
    unsigned int u = wds[i];
    if (u > 1u) okI = 0;
    if (u != 0u && u != 0x3F800000u) okF = 0;
    if ((i & 1) ? (u != 0u) : (u > 1u)) okL = 0;
  }
  __shared__ int sI, sF, sL;
  if (t == 0) { sI = 1; sF = 1; sL = 1; }
  __syncthreads();
  if (!okI) atomicAnd(&sI, 0);
  if (!okF) atomicAnd(&sF, 0);
  if (!okL) atomicAnd(&sL, 0);
  __syncthreads();
  if (t == 0) {
    int f;
    if (sI && sL) f = 3;
    else if (sI)  f = 1;
    else if (sF)  f = 2;
    else          f = 0;
    *flag = f;
  }
}

// mixed = mask ? enc_flat : post; fp32 + fp16-hi outputs
__global__ __launch_bounds__(256)
void mixed_k(const float* __restrict__ encf, const float* __restrict__ post,
             const void* __restrict__ mask, const int* __restrict__ flag,
             float* __restrict__ outx, _Float16* __restrict__ outh)
{
  long gid = (long)blockIdx.x * blockDim.x + threadIdx.x;
  int r = (int)(gid >> 7);
  int c = (int)(gid & 127) * 4;
  int f = *flag;
  bool mv;
  if (f == 0)      mv = ((const unsigned char*)mask)[r] != 0;
  else if (f == 1) mv = ((const int*)mask)[r] != 0;
  else if (f == 3) mv = ((const long long*)mask)[r] != 0;
  else             mv = ((const float*)mask)[r] != 0.0f;
  const float* src = mv ? encf : post;
  float4 v = *(const float4*)(src + (long)r*CDIM + c);
  *(float4*)(outx + (long)r*CDIM + c) = v;
  f16x4 h = {(_Float16)v.x, (_Float16)v.y, (_Float16)v.z, (_Float16)v.w};
  *(f16x4*)(outh + (long)r*CDIM + c) = h;
}

extern "C" void kernel_launch(void* const* d_in, const int* in_sizes, int n_in,
                              void* d_out, int out_size, void* d_ws, size_t ws_size,
                              hipStream_t stream)
{
  const float* x       = (const float*)d_in[0];
  const float* pre_w   = (const float*)d_in[1];
  const float* pre_b   = (const float*)d_in[2];
  const float* post_w  = (const float*)d_in[3];
  const float* post_b  = (const float*)d_in[4];
  const float* cb_w    = (const float*)d_in[5];
  const float* e_qkv_w = (const float*)d_in[6];
  const float* e_qkv_b = (const float*)d_in[7];
  const float* e_o_w   = (const float*)d_in[8];
  const float* e_o_b   = (const float*)d_in[9];
  const float* e_ln1_w = (const float*)d_in[10];
  const float* e_ln1_b = (const float*)d_in[11];
  const float* e_ln2_w = (const float*)d_in[12];
  const float* e_ln2_b = (const float*)d_in[13];
  const float* e_f1_w  = (const float*)d_in[14];
  const float* e_f1_b  = (const float*)d_in[15];
  const float* e_f2_w  = (const float*)d_in[16];
  const float* e_f2_b  = (const float*)d_in[17];
  const float* d_sqkv_w= (const float*)d_in[18];
  const float* d_sqkv_b= (const float*)d_in[19];
  const float* d_so_w  = (const float*)d_in[20];
  const float* d_so_b  = (const float*)d_in[21];
  const float* d_cqkv_w= (const float*)d_in[22];
  const float* d_cqkv_b= (const float*)d_in[23];
  const float* d_co_w  = (const float*)d_in[24];
  const float* d_co_b  = (const float*)d_in[25];
  const float* d_ln1w  = (const float*)d_in[26];
  const float* d_ln1b  = (const float*)d_in[27];
  const float* d_ln2w  = (const float*)d_in[28];
  const float* d_ln2b  = (const float*)d_in[29];
  const float* d_ln3w  = (const float*)d_in[30];
  const float* d_ln3b  = (const float*)d_in[31];
  const float* d_f1w   = (const float*)d_in[32];
  const float* d_f1b   = (const float*)d_in[33];
  const float* d_f2w   = (const float*)d_in[34];
  const float* d_f2b   = (const float*)d_in[35];
  const void*  mask    = d_in[36];

  float* out = (float*)d_out;
  float* o_quant  = out;
  float* o_high   = out + 4194304;
  float* o_softs  = out + 8388608;
  float* o_hards  = out + 12582912;
  float* o_codes  = out + 16777216;
  float* o_logits = out + 16785408;

  float* ws    = (float*)d_ws;
  float* ENC   = ws;
  float* Xb    = ws + TOKC;
  float* T1    = ws + 2*TOKC;
  float* T2    = ws + 3*TOKC;
  float* QKV   = ws + 4*TOKC;
  float* MEMB  = ws + 7*TOKC;
  float* CBREG = ws + 8*TOKC;
  int*   CODES = (int*)(CBREG + (long)KCB*CDIM);
  int*   FLAG  = CODES + NTOK;
  float* HARDB = QKV;
  float* QUANT = QKV + TOKC;
  _Float16* PBUF = (_Float16*)QKV;
  _Float16* CBH  = (_Float16*)T1;
  _Float16* QKVh = (_Float16*)QKV;
  _Float16* QKVl = QKVh + (long)NTOK*3*CDIM;
  _Float16* CQh  = (_Float16*)QKV;
  _Float16* KVh  = (_Float16*)(QKV + TOKC);
  _Float16* CBT16h = (_Float16*)CBREG;
  _Float16* CBT16l = CBT16h + (long)KCB*CDIM;
  _Float16* PREH = (_Float16*)T2;
  _Float16* PREL = PREH + TOKC;
  _Float16* AH16   = (_Float16*)ENC;
  _Float16* FH16   = AH16 + TOKC;
  _Float16* XH16   = ((_Float16*)QKV) + 4*TOKC;
  _Float16* MEMBH16= XH16 + TOKC;
  _Float16* QH16   = ((_Float16*)T1) + TOKC;

  const long WQSZ = (long)6*3*CDIM*CDIM;
  const long WSSZ = (long)6*CDIM*CDIM;
  _Float16* SCR  = (_Float16*)o_logits;
  _Float16* WQH = SCR;            _Float16* WQL = WQH + WQSZ;
  _Float16* WOH = WQL + WQSZ;     _Float16* WOL = WOH + WSSZ;
  _Float16* WF1H= WOL + WSSZ;     _Float16* WF1L= WF1H + WSSZ;
  _Float16* WF2H= WF1L + WSSZ;    _Float16* WF2L= WF2H + WSSZ;
  _Float16* WPH = WF2L + WSSZ;    _Float16* WPL = WPH + (long)CDIM*CDIM;
  _Float16* XH  = WPL + (long)CDIM*CDIM;  _Float16* XL  = XH + TOKC;
  _Float16* AH  = XL + TOKC;      _Float16* AL  = AH + TOKC;
  _Float16* L1H = AL + TOKC;      _Float16* L1L = L1H + TOKC;
  _Float16* H1H = L1L + TOKC;     _Float16* H1L = H1H + TOKC;

  const size_t NEED = (size_t)(8*TOKC + (long)KCB*CDIM + 2*NTOK + NTOK + 16) * 4;
  if (ws_size < NEED) return;

  const int M = NTOK;
  dim3 tgrid(S_LEN/32, CDIM/32, NB), tblk(32, 8);
  dim3 agrid(NB*8, S_LEN/128);

  pack_pe_k<<<tgrid, tblk, 0, stream>>>(x, ENC, Xb, XH, XL);
  cbt16_k<<<dim3(KCB/32, CDIM/32), tblk, 0, stream>>>(cb_w, CBT16h, CBT16l);
  maskdetect_k<<<1, 256, 0, stream>>>(mask, FLAG);
  convsplit_k<<<(int)(WQSZ/2048), 256, 0, stream>>>(e_qkv_w, WQH, WQL);
  convsplit_k<<<(int)(WSSZ/2048), 256, 0, stream>>>(e_o_w,  WOH,  WOL);
  convsplit_k<<<(int)(WSSZ/2048), 256, 0, stream>>>(e_f1_w, WF1H, WF1L);
  convsplit_k<<<(int)(WSSZ/2048), 256, 0, stream>>>(e_f2_w, WF2H, WF2L);
  convsplit_k<<<(int)(((long)CDIM*CDIM)/2048), 256, 0, stream>>>(pre_w, WPH, WPL);

  // -------- encoder (split-fp16 MFMA, producer-converted inputs) --------
  for (int i = 0; i < NLAYER; ++i) {
    hgemm_k<128,1,2,true,false,false,false,true><<<dim3(3*CDIM/128, M/128), 256, 0, stream>>>(
        XH, WQH + (long)i*3*CDIM*CDIM, e_qkv_b + i*3*CDIM, nullptr, 0,
        nullptr, 3*CDIM, M, 3*CDIM, CDIM, QKVh, QKVl, XL, WQL + (long)i*3*CDIM*CDIM);
    mattn_k<1,1><<<agrid, 256, 0, stream>>>(QKVh, QKVl, 3*CDIM,
        QKVh+CDIM, QKVl+CDIM, 3*CDIM, QKVh+2*CDIM, QKVl+2*CDIM, 3*CDIM,
        nullptr, CDIM, AH, AL);
    hgemm_k<64,1,2,true,true,false,false,false><<<dim3(CDIM/128, M/64), 256, 0, stream>>>(
        AH, WOH + (long)i*CDIM*CDIM, e_o_b + i*CDIM, Xb, CDIM,
        T2, CDIM, M, CDIM, CDIM, nullptr, nullptr, AL, WOL + (long)i*CDIM*CDIM);
    ln_k<1><<<M/4, 256, 0, stream>>>(T2, e_ln1_w + i*CDIM, e_ln1_b + i*CDIM, T1, L1H, L1L);
    hgemm_k<64,1,2,true,false,true,false,true><<<dim3(CDIM/128, M/64), 256, 0, stream>>>(
        L1H, WF1H + (long)i*CDIM*CDIM, e_f1_b + i*CDIM, nullptr, 0,
        nullptr, CDIM, M, CDIM, CDIM, H1H, H1L, L1L, WF1L + (long)i*CDIM*CDIM);
    hgemm_k<64,1,2,true,true,false,false,false><<<dim3(CDIM/128, M/64), 256, 0, stream>>>(
        H1H, WF2H + (long)i*CDIM*CDIM, e_f2_b + i*CDIM, T1, CDIM,
        T2, CDIM, M, CDIM, CDIM, nullptr, nullptr, H1L, WF2L + (long)i*CDIM*CDIM);
    ln_k<1><<<M/4, 256, 0, stream>>>(T2, e_ln2_w + i*CDIM, e_ln2_b + i*CDIM, Xb, XH, XL);
  }

  // -------- codebook / quantizer --------
  hgemm_k<64,1,2,true,false,false,false,true><<<dim3(CDIM/128, M/64), 256, 0, stream>>>(
      XH, WPH, pre_b, nullptr, 0, T1, CDIM, M, CDIM, CDIM, PREH, PREL, XL, WPL);
  tpose_k<<<tgrid, tblk, 0, stream>>>(T1, o_high);
  hgemm_k<128,1,2,false,false,false,true,false><<<dim3(KCB/128, M/128), 256, 0, stream>>>(
      PREH, CBT16h, nullptr, nullptr, 0, o_logits, KCB, M, KCB, CDIM,
      nullptr, nullptr, PREL, CBT16l);
  conv16_k<<<(CDIM*(long)KCB)/(256*8), 256, 0, stream>>>(cb_w, CBH);
  simstats_k<<<NTOK, 256, 0, stream>>>(o_logits, PBUF, CODES, o_codes);
  hgemm_k<64,0,1,false,false,false,false,false><<<dim3(CDIM/128, M/64), 256, 0, stream>>>(
      PBUF, CBH, nullptr, nullptr, 0, T2, CDIM, M, CDIM, KCB,
      nullptr, nullptr, nullptr, nullptr);
  tpose_k<<<tgrid, tblk, 0, stream>>>(T2, o_softs);
  quant_k<<<NTOK, 128, 0, stream>>>(T2, CODES, CBT16h, CBT16l, QUANT, HARDB, QH16);
  tpose_k<<<tgrid, tblk, 0, stream>>>(HARDB, o_hards);
  hgemm_k<64,0,3,true,false,false,false,false><<<dim3(CDIM/128, M/64), 256, 0, stream>>>(
      QH16, post_w, post_b, nullptr, 0, MEMB, CDIM, M, CDIM, CDIM,
      nullptr, nullptr, nullptr, nullptr);
  mixed_k<<<4096, 256, 0, stream>>>(ENC, MEMB, mask, FLAG, Xb, XH16);
  conv16_k<<<(int)(TOKC/2048), 256, 0, stream>>>(MEMB, MEMBH16);

  // -------- decoder (f16 MFMA, swapped-operand attention) --------
  for (int i = 0; i < NLAYER; ++i) {
    hgemm_k<128,0,3,true,false,false,false,true><<<dim3(3*CDIM/128, M/128), 256, 0, stream>>>(
        XH16, d_sqkv_w + (long)i*3*CDIM*CDIM, d_sqkv_b + i*3*CDIM, nullptr, 0,
        nullptr, 3*CDIM, M, 3*CDIM, CDIM, QKVh, nullptr, nullptr, nullptr);
    sattn_k<<<agrid, 256, 0, stream>>>(QKVh, 3*CDIM,
        QKVh+CDIM, 3*CDIM, QKVh+2*CDIM, 3*CDIM, AH16, CDIM);
    hgemm_k<64,0,3,true,true,false,false,false><<<dim3(CDIM/128, M/64), 256, 0, stream>>>(
        AH16, d_so_w + (long)i*CDIM*CDIM, d_so_b + i*CDIM, Xb, CDIM,
        T2, CDIM, M, CDIM, CDIM, nullptr, nullptr, nullptr, nullptr);
    ln_k<2><<<M/4, 256, 0, stream>>>(T2, d_ln1w + i*CDIM, d_ln1b + i*CDIM, Xb, XH16, nullptr);
    hgemm_k<64,0,3,true,false,false,false,true><<<dim3(CDIM/128, M/64), 256, 0, stream>>>(
        XH16, d_cqkv_w + (long)i*3*CDIM*CDIM, d_cqkv_b + i*3*CDIM, nullptr, 0,
        nullptr, CDIM, M, CDIM, CDIM, CQh, nullptr, nullptr, nullptr);
    hgemm_k<128,0,3,true,false,false,false,true><<<dim3(2*CDIM/128, M/128), 256, 0, stream>>>(
        MEMBH16, d_cqkv_w + (long)i*3*CDIM*CDIM + (long)CDIM*CDIM,
        d_cqkv_b + i*3*CDIM + CDIM, nullptr, 0,
        nullptr, 2*CDIM, M, 2*CDIM, CDIM, KVh, nullptr, nullptr, nullptr);
    sattn_k<<<agrid, 256, 0, stream>>>(CQh, CDIM,
        KVh, 2*CDIM, KVh+CDIM, 2*CDIM, AH16, CDIM);
    hgemm_k<64,0,3,true,true,false,false,false><<<dim3(CDIM/128, M/64), 256, 0, stream>>>(
        AH16, d_co_w + (long)i*CDIM*CDIM, d_co_b + i*CDIM, Xb, CDIM,
        T2, CDIM, M, CDIM, CDIM, nullptr, nullptr, nullptr, nullptr);
    ln_k<2><<<M/4, 256, 0, stream>>>(T2, d_ln2w + i*CDIM, d_ln2b + i*CDIM, Xb, XH16, nullptr);
    hgemm_k<64,0,3,true,false,true,false,true><<<dim3(CDIM/128, M/64), 256, 0, stream>>>(
        XH16, d_f1w + (long)i*CDIM*CDIM, d_f1b + i*CDIM, nullptr, 0,
        nullptr, CDIM, M, CDIM, CDIM, FH16, nullptr, nullptr, nullptr);
    hgemm_k<64,0,3,true,true,false,false,false><<<dim3(CDIM/128, M/64), 256, 0, stream>>>(
        FH16, d_f2w + (long)i*CDIM*CDIM, d_f2b + i*CDIM, Xb, CDIM,
        T2, CDIM, M, CDIM, CDIM, nullptr, nullptr, nullptr, nullptr);
    ln_k<2><<<M/4, 256, 0, stream>>>(T2, d_ln3w + i*CDIM, d_ln3b + i*CDIM, Xb, XH16, nullptr);
  }
  tpose_k<<<tgrid, tblk, 0, stream>>>(Xb, o_quant);
}